// Round 1
// baseline (10588.894 us; speedup 1.0000x reference)
//
#include <hip/hip_runtime.h>
#include <hip/hip_bf16.h>
#include <math.h>

// ---------------------------------------------------------------------------
// Constants (problem-fixed)
// ---------------------------------------------------------------------------
static const int NNODES = 10240;
static const int NEDGES = 40960;
static const int NB     = 256;     // graphs / batch
static const int VOCAB  = 26;
static const int EMB    = 128;

// ---------------------------------------------------------------------------
// Generic tiled f32 GEMM: C[M,N] = act(A[M,K] @ B[K,N] + bias)
// ACT: 0=none, 1=relu, 2=elu
// ---------------------------------------------------------------------------
template<int ACT>
__global__ __launch_bounds__(256) void gemm_f32(
    const float* __restrict__ A, const float* __restrict__ B,
    const float* __restrict__ bias, float* __restrict__ C,
    int M, int N, int K, int ldC)
{
    __shared__ float As[16][64];
    __shared__ float Bs[16][64];
    int tid = threadIdx.x;
    int bm = blockIdx.y * 64;
    int bn = blockIdx.x * 64;
    int tx = tid & 15, ty = tid >> 4;
    float acc[4][4] = {};
    for (int k0 = 0; k0 < K; k0 += 16) {
#pragma unroll
        for (int l = 0; l < 4; ++l) {
            int idx = tid + l * 256;
            int r = idx >> 4, c = idx & 15;
            int gr = bm + r, gc = k0 + c;
            As[c][r] = (gr < M && gc < K) ? A[(size_t)gr * K + gc] : 0.f;
        }
#pragma unroll
        for (int l = 0; l < 4; ++l) {
            int idx = tid + l * 256;
            int r = idx >> 6, c = idx & 63;
            int gr = k0 + r, gc = bn + c;
            Bs[r][c] = (gr < K && gc < N) ? B[(size_t)gr * N + gc] : 0.f;
        }
        __syncthreads();
#pragma unroll
        for (int kk = 0; kk < 16; ++kk) {
            float a[4], b[4];
#pragma unroll
            for (int i = 0; i < 4; ++i) a[i] = As[kk][ty * 4 + i];
#pragma unroll
            for (int j = 0; j < 4; ++j) b[j] = Bs[kk][tx * 4 + j];
#pragma unroll
            for (int i = 0; i < 4; ++i)
#pragma unroll
                for (int j = 0; j < 4; ++j)
                    acc[i][j] += a[i] * b[j];
        }
        __syncthreads();
    }
#pragma unroll
    for (int i = 0; i < 4; ++i) {
        int gr = bm + ty * 4 + i;
        if (gr >= M) continue;
#pragma unroll
        for (int j = 0; j < 4; ++j) {
            int gc = bn + tx * 4 + j;
            if (gc >= N) continue;
            float v = acc[i][j];
            if (bias) v += bias[gc];
            if (ACT == 1) v = v > 0.f ? v : 0.f;
            else if (ACT == 2) v = v > 0.f ? v : expm1f(v);
            C[(size_t)gr * ldC + gc] = v;
        }
    }
}

// ---------------------------------------------------------------------------
// GAT helpers
// ---------------------------------------------------------------------------
__device__ __forceinline__ unsigned fmap(float f) {
    unsigned u = __float_as_uint(f);
    return (u & 0x80000000u) ? ~u : (u | 0x80000000u);
}
__device__ __forceinline__ float funmap(unsigned u) {
    return (u & 0x80000000u) ? __uint_as_float(u ^ 0x80000000u)
                             : __uint_as_float(~u);
}

// a_s[n,h] = dot(lin[n, h*F: (h+1)*F], att_src[h,:]); same for a_d.
__global__ void attn_ab_kernel(const float* __restrict__ lin,
                               const float* __restrict__ att_s,
                               const float* __restrict__ att_d,
                               float* __restrict__ a_s, float* __restrict__ a_d,
                               int H, int F)
{
    int bid = blockIdx.x;           // n*H + h
    int h = bid % H;
    int lane = threadIdx.x;
    const float* row = lin + (size_t)bid * F;   // (n*H+h)*F == n*(H*F)+h*F
    const float* wsrc = att_s + h * F;
    const float* wdst = att_d + h * F;
    float ss = 0.f, sd = 0.f;
    for (int f = lane; f < F; f += 64) {
        float v = row[f];
        ss += v * wsrc[f];
        sd += v * wdst[f];
    }
    for (int o = 32; o; o >>= 1) {
        ss += __shfl_down(ss, o);
        sd += __shfl_down(sd, o);
    }
    if (lane == 0) { a_s[bid] = ss; a_d[bid] = sd; }
}

// Pass A: leaky_relu(a_s[s]+a_d[d]); store; segment-max via uint atomicMax.
__global__ void edge_max_kernel(const int* __restrict__ ei,
                                const float* __restrict__ a_s,
                                const float* __restrict__ a_d,
                                float* __restrict__ eval,
                                unsigned* __restrict__ mmax,
                                int E, int Etot, int H)
{
    int t = blockIdx.x * blockDim.x + threadIdx.x;
    if (t >= Etot * H) return;
    int e = t / H, h = t - e * H;
    int s, d;
    if (e < E) { s = ei[e]; d = ei[E + e]; } else { s = d = e - E; }
    float v = a_s[s * H + h] + a_d[d * H + h];
    v = v > 0.f ? v : 0.2f * v;
    eval[t] = v;
    atomicMax(&mmax[d * H + h], fmap(v));
}

// Pass B: exp(val - max) ; segment-sum denominators.
__global__ void edge_exp_kernel(const int* __restrict__ ei,
                                const unsigned* __restrict__ mmax,
                                float* __restrict__ eval,
                                float* __restrict__ denom,
                                int E, int Etot, int H)
{
    int t = blockIdx.x * blockDim.x + threadIdx.x;
    if (t >= Etot * H) return;
    int e = t / H, h = t - e * H;
    int d = (e < E) ? ei[E + e] : e - E;
    float m = funmap(mmax[d * H + h]);
    float ex = expf(eval[t] - m);
    eval[t] = ex;
    atomicAdd(&denom[d * H + h], ex);
}

// Pass C: out[d, :] += alpha[h] * lin[s, :]
__global__ __launch_bounds__(256) void edge_scatter_kernel(
    const int* __restrict__ ei, const float* __restrict__ eval,
    const float* __restrict__ denom, const float* __restrict__ lin,
    float* __restrict__ out, int E, int Etot, int H, int F)
{
    __shared__ float s_alpha[16];
    int e = blockIdx.x;
    int s, d;
    if (e < E) { s = ei[e]; d = ei[E + e]; } else { s = d = e - E; }
    int tid = threadIdx.x;
    if (tid < H) s_alpha[tid] = eval[e * H + tid] / (denom[d * H + tid] + 1e-16f);
    __syncthreads();
    int Ft = H * F;
    const float* srow = lin + (size_t)s * Ft;
    float* drow = out + (size_t)d * Ft;
    for (int c = tid; c < Ft; c += 256) {
        int h = c / F;
        atomicAdd(&drow[c], s_alpha[h] * srow[c]);
    }
}

template<int ACT>
__global__ void bias_act_kernel(float* __restrict__ x, const float* __restrict__ b,
                                int total, int C)
{
    int t = blockIdx.x * blockDim.x + threadIdx.x;
    if (t >= total) return;
    int c = t % C;
    float v = x[t] + b[c];
    if (ACT == 1) v = v > 0.f ? v : 0.f;
    else if (ACT == 2) v = v > 0.f ? v : expm1f(v);
    x[t] = v;
}

// g[b,f] = max over `per` consecutive nodes
__global__ void pool_max_kernel(const float* __restrict__ h, float* __restrict__ g,
                                int B, int per, int C)
{
    int t = blockIdx.x * blockDim.x + threadIdx.x;
    if (t >= B * C) return;
    int b = t / C, f = t - b * C;
    const float* p = h + (size_t)b * per * C + f;
    float m = -INFINITY;
    for (int j = 0; j < per; ++j) m = fmaxf(m, p[(size_t)j * C]);
    g[t] = m;
}

// ---------------------------------------------------------------------------
// CNN branch
// ---------------------------------------------------------------------------
// conv1 fused with embedding gather: y[n,o,t] = relu(cb1[o] +
//   sum_{i<1000,k<8} emb[target[n,i]][t+k] * cw1[o,i,k]),  t < 121
__global__ __launch_bounds__(256) void conv1_emb_kernel(
    const int* __restrict__ target, const float* __restrict__ emb,
    const float* __restrict__ w, const float* __restrict__ b,
    float* __restrict__ y)
{
    __shared__ float s_emb[VOCAB * EMB];
    int tid = threadIdx.x;
    for (int i = tid; i < VOCAB * EMB; i += 256) s_emb[i] = emb[i];
    __syncthreads();
    int n = blockIdx.y;
    int o = tid & 31;
    int tt = tid >> 5;
    int t = blockIdx.x * 8 + tt;
    if (t >= 121) return;
    const int* trow = target + n * 1000;
    float acc = 0.f;
    for (int i = 0; i < 1000; ++i) {
        int v = trow[i];
        const float* er = s_emb + v * EMB + t;
        const float4* wr = (const float4*)(w + ((size_t)o * 1000 + i) * 8);
        float4 w0 = wr[0], w1 = wr[1];
        acc += er[0] * w0.x + er[1] * w0.y + er[2] * w0.z + er[3] * w0.w
             + er[4] * w1.x + er[5] * w1.y + er[6] * w1.z + er[7] * w1.w;
    }
    acc += b[o];
    y[((size_t)n * 32 + o) * 121 + t] = acc > 0.f ? acc : 0.f;
}

// generic small conv1d (NCH, OIH, valid, k=8) + relu
template<int Ci>
__global__ void conv_kernel(const float* __restrict__ x, const float* __restrict__ w,
                            const float* __restrict__ b, float* __restrict__ y,
                            int Co, int Lin, int Lout)
{
    int idx = blockIdx.x * blockDim.x + threadIdx.x;
    int total = NB * Co * Lout;
    if (idx >= total) return;
    int t = idx % Lout;
    int rest = idx / Lout;
    int o = rest % Co;
    int n = rest / Co;
    const float* xr = x + ((size_t)n * Ci) * Lin + t;
    const float* wr = w + (size_t)o * Ci * 8;
    float acc = b[o];
#pragma unroll 4
    for (int i = 0; i < Ci; ++i) {
        const float* xi = xr + (size_t)i * Lin;
        const float4* wv = (const float4*)(wr + i * 8);
        float4 w0 = wv[0], w1 = wv[1];
        acc += xi[0] * w0.x + xi[1] * w0.y + xi[2] * w0.z + xi[3] * w0.w
             + xi[4] * w1.x + xi[5] * w1.y + xi[6] * w1.z + xi[7] * w1.w;
    }
    y[idx] = acc > 0.f ? acc : 0.f;
}

// maxpool(k=3,s=3) over last dim [256,128,100] -> [256, 128*33] flat
__global__ void pool3_kernel(const float* __restrict__ x, float* __restrict__ y)
{
    int idx = blockIdx.x * blockDim.x + threadIdx.x;
    if (idx >= NB * 128 * 33) return;
    int t = idx % 33;
    int rest = idx / 33;
    int c = rest % 128;
    int n = rest / 128;
    const float* p = x + ((size_t)n * 128 + c) * 100 + t * 3;
    y[idx] = fmaxf(fmaxf(p[0], p[1]), p[2]);
}

// ---------------------------------------------------------------------------
// Host-side launch
// ---------------------------------------------------------------------------
extern "C" void kernel_launch(void* const* d_in, const int* in_sizes, int n_in,
                              void* d_out, int out_size, void* d_ws, size_t ws_size,
                              hipStream_t stream)
{
    const float* x      = (const float*)d_in[0];
    const int*   ei     = (const int*)d_in[1];
    const int*   target = (const int*)d_in[3];
    const float* W1  = (const float*)d_in[4];
    const float* as1 = (const float*)d_in[5];
    const float* ad1 = (const float*)d_in[6];
    const float* b1  = (const float*)d_in[7];
    const float* W2  = (const float*)d_in[8];
    const float* as2 = (const float*)d_in[9];
    const float* ad2 = (const float*)d_in[10];
    const float* b2  = (const float*)d_in[11];
    const float* W3  = (const float*)d_in[12];
    const float* as3 = (const float*)d_in[13];
    const float* ad3 = (const float*)d_in[14];
    const float* b3  = (const float*)d_in[15];
    const float* fc_g1_w = (const float*)d_in[16];
    const float* fc_g1_b = (const float*)d_in[17];
    const float* fc_g2_w = (const float*)d_in[18];
    const float* fc_g2_b = (const float*)d_in[19];
    const float* emb_xt  = (const float*)d_in[20];
    const float* cw1 = (const float*)d_in[21];
    const float* cb1 = (const float*)d_in[22];
    const float* cw2 = (const float*)d_in[23];
    const float* cb2 = (const float*)d_in[24];
    const float* cw3 = (const float*)d_in[25];
    const float* cb3 = (const float*)d_in[26];
    const float* cw4 = (const float*)d_in[27];
    const float* cb4 = (const float*)d_in[28];
    const float* fc1_xt_w = (const float*)d_in[29];
    const float* fc1_xt_b = (const float*)d_in[30];
    const float* fc2_xt_w = (const float*)d_in[31];
    const float* fc2_xt_b = (const float*)d_in[32];
    const float* fc1_w = (const float*)d_in[33];
    const float* fc1_b = (const float*)d_in[34];
    const float* fc2_w = (const float*)d_in[35];
    const float* fc2_b = (const float*)d_in[36];
    const float* out_w = (const float*)d_in[37];
    const float* out_b = (const float*)d_in[38];
    float* out = (float*)d_out;

    const int N = NNODES, E = NEDGES, Etot = E + N;

    // ---- workspace carve ----
    char* ws = (char*)d_ws;
    size_t off = 0;
    auto alloc = [&](size_t bytes) -> char* {
        char* p = ws + off;
        off = (off + bytes + 255) & ~(size_t)255;
        return p;
    };
    const size_t BIG = (size_t)N * 3120 * sizeof(float);   // 127.8 MB
    float*    bufA  = (float*)alloc(BIG);   // lin1/lin2/lin3, then CNN scratch
    float*    bufB  = (float*)alloc(BIG);   // out1/out2/out3
    float*    a_s   = (float*)alloc((size_t)N * 10 * 4);
    float*    a_d   = (float*)alloc((size_t)N * 10 * 4);
    unsigned* mmax  = (unsigned*)alloc((size_t)N * 10 * 4);
    float*    denom = (float*)alloc((size_t)N * 10 * 4);
    float*    eval  = (float*)alloc((size_t)Etot * 10 * 4);
    float*    gbuf  = (float*)alloc((size_t)NB * 3120 * 4);
    float*    g1    = (float*)alloc((size_t)NB * 1024 * 4);
    float*    xt1   = (float*)alloc((size_t)NB * 1024 * 4);
    float*    xc    = (float*)alloc((size_t)NB * 256 * 4);
    float*    f1    = (float*)alloc((size_t)NB * 1024 * 4);
    float*    f2    = (float*)alloc((size_t)NB * 256 * 4);
    // CNN scratch carved from bufA (dead after GAT layer 3 scatter):
    char* cnn = (char*)bufA;
    float* c1 = (float*)cnn;                       cnn += (size_t)NB * 32 * 121 * 4 + 256;
    float* c2 = (float*)cnn;                       cnn += (size_t)NB * 64 * 114 * 4 + 256;
    float* c3 = (float*)cnn;                       cnn += (size_t)NB * 96 * 107 * 4 + 256;
    float* c4 = (float*)cnn;                       cnn += (size_t)NB * 128 * 100 * 4 + 256;
    float* xt = (float*)cnn;                       cnn += (size_t)NB * 4224 * 4 + 256;

    // ---- one GAT layer ----
    auto gat_layer = [&](const float* hin, int Fin, const float* W,
                         const float* atts, const float* attd, const float* bias,
                         int H, int F, int act, float* lin, float* outb) {
        int Ft = H * F;
        dim3 gg((Ft + 63) / 64, (N + 63) / 64);
        gemm_f32<0><<<gg, 256, 0, stream>>>(hin, W, nullptr, lin, N, Ft, Fin, Ft);
        attn_ab_kernel<<<N * H, 64, 0, stream>>>(lin, atts, attd, a_s, a_d, H, F);
        hipMemsetAsync(mmax, 0, (size_t)N * H * 4, stream);
        hipMemsetAsync(denom, 0, (size_t)N * H * 4, stream);
        hipMemsetAsync(outb, 0, (size_t)N * Ft * 4, stream);
        int tot = Etot * H;
        edge_max_kernel<<<(tot + 255) / 256, 256, 0, stream>>>(ei, a_s, a_d, eval, mmax, E, Etot, H);
        edge_exp_kernel<<<(tot + 255) / 256, 256, 0, stream>>>(ei, mmax, eval, denom, E, Etot, H);
        edge_scatter_kernel<<<Etot, 256, 0, stream>>>(ei, eval, denom, lin, outb, E, Etot, H, F);
        int total = N * Ft;
        if (act == 1)
            bias_act_kernel<1><<<(total + 255) / 256, 256, 0, stream>>>(outb, bias, total, Ft);
        else
            bias_act_kernel<2><<<(total + 255) / 256, 256, 0, stream>>>(outb, bias, total, Ft);
    };

    // ---- GAT branch ----
    gat_layer(x,    78,   W1, as1, ad1, b1, 10, 78,   2, bufA, bufB);
    gat_layer(bufB, 780,  W2, as2, ad2, b2, 2,  780,  1, bufA, bufB);
    gat_layer(bufB, 1560, W3, as3, ad3, b3, 1,  3120, 1, bufA, bufB);

    // global max pool (40 consecutive nodes per graph) + graph FCs
    {
        int tot = NB * 3120;
        pool_max_kernel<<<(tot + 255) / 256, 256, 0, stream>>>(bufB, gbuf, NB, N / NB, 3120);
        dim3 g1g((1024 + 63) / 64, (NB + 63) / 64);
        gemm_f32<1><<<g1g, 256, 0, stream>>>(gbuf, fc_g1_w, fc_g1_b, g1, NB, 1024, 3120, 1024);
        dim3 g2g((128 + 63) / 64, (NB + 63) / 64);
        gemm_f32<0><<<g2g, 256, 0, stream>>>(g1, fc_g2_w, fc_g2_b, xc, NB, 128, 1024, 256);
    }

    // ---- CNN branch (bufA is dead now; c1..xt live inside it) ----
    {
        dim3 cg(16, NB);
        conv1_emb_kernel<<<cg, 256, 0, stream>>>(target, emb_xt, cw1, cb1, c1);
        int t2 = NB * 64 * 114;
        conv_kernel<32><<<(t2 + 255) / 256, 256, 0, stream>>>(c1, cw2, cb2, c2, 64, 121, 114);
        int t3 = NB * 96 * 107;
        conv_kernel<64><<<(t3 + 255) / 256, 256, 0, stream>>>(c2, cw3, cb3, c3, 96, 114, 107);
        int t4 = NB * 128 * 100;
        conv_kernel<96><<<(t4 + 255) / 256, 256, 0, stream>>>(c3, cw4, cb4, c4, 128, 107, 100);
        int tp = NB * 128 * 33;
        pool3_kernel<<<(tp + 255) / 256, 256, 0, stream>>>(c4, xt);
        dim3 xg((1024 + 63) / 64, (NB + 63) / 64);
        gemm_f32<1><<<xg, 256, 0, stream>>>(xt, fc1_xt_w, fc1_xt_b, xt1, NB, 1024, 4224, 1024);
        dim3 x2g((128 + 63) / 64, (NB + 63) / 64);
        gemm_f32<0><<<x2g, 256, 0, stream>>>(xt1, fc2_xt_w, fc2_xt_b, xc + 128, NB, 128, 1024, 256);
    }

    // ---- fusion head ----
    {
        dim3 h1g((1024 + 63) / 64, (NB + 63) / 64);
        gemm_f32<1><<<h1g, 256, 0, stream>>>(xc, fc1_w, fc1_b, f1, NB, 1024, 256, 1024);
        dim3 h2g((256 + 63) / 64, (NB + 63) / 64);
        gemm_f32<1><<<h2g, 256, 0, stream>>>(f1, fc2_w, fc2_b, f2, NB, 256, 1024, 256);
        dim3 og(1, (NB + 63) / 64);
        gemm_f32<0><<<og, 256, 0, stream>>>(f2, out_w, out_b, out, NB, 1, 256, 1);
    }
}

// Round 2
// 6755.918 us; speedup vs baseline: 1.5674x; 1.5674x over previous
//
#include <hip/hip_runtime.h>
#include <hip/hip_bf16.h>
#include <math.h>

// ---------------------------------------------------------------------------
// Constants (problem-fixed)
// ---------------------------------------------------------------------------
static const int NNODES = 10240;
static const int NEDGES = 40960;
static const int NB     = 256;     // graphs / batch
static const int VOCAB  = 26;
static const int EMB    = 128;

// ---------------------------------------------------------------------------
// Small tiled f32 GEMM (64x64 tile, 4x4 micro): for M=256 batch GEMMs.
// ACT: 0=none, 1=relu, 2=elu
// ---------------------------------------------------------------------------
template<int ACT>
__global__ __launch_bounds__(256) void gemm_f32(
    const float* __restrict__ A, const float* __restrict__ B,
    const float* __restrict__ bias, float* __restrict__ C,
    int M, int N, int K, int ldC)
{
    __shared__ float As[16][64];
    __shared__ float Bs[16][64];
    int tid = threadIdx.x;
    int bm = blockIdx.y * 64;
    int bn = blockIdx.x * 64;
    int tx = tid & 15, ty = tid >> 4;
    float acc[4][4] = {};
    for (int k0 = 0; k0 < K; k0 += 16) {
#pragma unroll
        for (int l = 0; l < 4; ++l) {
            int idx = tid + l * 256;
            int r = idx >> 4, c = idx & 15;
            int gr = bm + r, gc = k0 + c;
            As[c][r] = (gr < M && gc < K) ? A[(size_t)gr * K + gc] : 0.f;
        }
#pragma unroll
        for (int l = 0; l < 4; ++l) {
            int idx = tid + l * 256;
            int r = idx >> 6, c = idx & 63;
            int gr = k0 + r, gc = bn + c;
            Bs[r][c] = (gr < K && gc < N) ? B[(size_t)gr * N + gc] : 0.f;
        }
        __syncthreads();
#pragma unroll
        for (int kk = 0; kk < 16; ++kk) {
            float a[4], b[4];
#pragma unroll
            for (int i = 0; i < 4; ++i) a[i] = As[kk][ty * 4 + i];
#pragma unroll
            for (int j = 0; j < 4; ++j) b[j] = Bs[kk][tx * 4 + j];
#pragma unroll
            for (int i = 0; i < 4; ++i)
#pragma unroll
                for (int j = 0; j < 4; ++j)
                    acc[i][j] += a[i] * b[j];
        }
        __syncthreads();
    }
#pragma unroll
    for (int i = 0; i < 4; ++i) {
        int gr = bm + ty * 4 + i;
        if (gr >= M) continue;
#pragma unroll
        for (int j = 0; j < 4; ++j) {
            int gc = bn + tx * 4 + j;
            if (gc >= N) continue;
            float v = acc[i][j];
            if (bias) v += bias[gc];
            if (ACT == 1) v = v > 0.f ? v : 0.f;
            else if (ACT == 2) v = v > 0.f ? v : expm1f(v);
            C[(size_t)gr * ldC + gc] = v;
        }
    }
}

// ---------------------------------------------------------------------------
// Big tiled f32 GEMM (128x128 tile, BK=16, 8x8 micro): for node GEMMs.
// As stored transposed [k][m] with +4 pad; Bs [k][n] with +4 pad.
// ---------------------------------------------------------------------------
template<int ACT>
__global__ __launch_bounds__(256) void gemm_f32_big(
    const float* __restrict__ A, const float* __restrict__ B,
    const float* __restrict__ bias, float* __restrict__ C,
    int M, int N, int K, int ldC)
{
    __shared__ float As[16][132];
    __shared__ float Bs[16][132];
    int tid = threadIdx.x;
    int bm = blockIdx.y * 128;
    int bn = blockIdx.x * 128;
    int tx = tid & 15, ty = tid >> 4;

    // load mapping
    int ar = tid >> 1;                 // 0..127 (A row within tile)
    int ac = (tid & 1) * 8;            // 0 or 8 (A col base within k-tile)
    int br = tid >> 4;                 // 0..15  (B row within k-tile)
    int bc = (tid & 15) * 8;           // 0..120 (B col base)

    float acc[8][8] = {};
    int gar = bm + ar;
    const float* Arow = A + (size_t)gar * K;
    const float* Brow0 = B + bn + bc;

    for (int k0 = 0; k0 < K; k0 += 16) {
        // A tile: 128x16
#pragma unroll
        for (int c = 0; c < 8; ++c) {
            int gc = k0 + ac + c;
            As[ac + c][ar] = (gar < M && gc < K) ? Arow[gc] : 0.f;
        }
        // B tile: 16x128
#pragma unroll
        for (int c = 0; c < 8; ++c) {
            int gr = k0 + br;
            int gc = bn + bc + c;
            Bs[br][bc + c] = (gr < K && gc < N) ? B[(size_t)gr * N + bc + c + bn] : 0.f;
        }
        __syncthreads();
#pragma unroll
        for (int kk = 0; kk < 16; ++kk) {
            float a[8], b[8];
#pragma unroll
            for (int i = 0; i < 8; ++i) a[i] = As[kk][ty * 8 + i];
#pragma unroll
            for (int j = 0; j < 8; ++j) b[j] = Bs[kk][tx * 8 + j];
#pragma unroll
            for (int i = 0; i < 8; ++i)
#pragma unroll
                for (int j = 0; j < 8; ++j)
                    acc[i][j] += a[i] * b[j];
        }
        __syncthreads();
    }
#pragma unroll
    for (int i = 0; i < 8; ++i) {
        int gr = bm + ty * 8 + i;
        if (gr >= M) continue;
#pragma unroll
        for (int j = 0; j < 8; ++j) {
            int gc = bn + tx * 8 + j;
            if (gc >= N) continue;
            float v = acc[i][j];
            if (bias) v += bias[gc];
            if (ACT == 1) v = v > 0.f ? v : 0.f;
            else if (ACT == 2) v = v > 0.f ? v : expm1f(v);
            C[(size_t)gr * ldC + gc] = v;
        }
    }
}

// ---------------------------------------------------------------------------
// GAT helpers
// ---------------------------------------------------------------------------
__device__ __forceinline__ unsigned fmap(float f) {
    unsigned u = __float_as_uint(f);
    return (u & 0x80000000u) ? ~u : (u | 0x80000000u);
}
__device__ __forceinline__ float funmap(unsigned u) {
    return (u & 0x80000000u) ? __uint_as_float(u ^ 0x80000000u)
                             : __uint_as_float(~u);
}

__global__ void attn_ab_kernel(const float* __restrict__ lin,
                               const float* __restrict__ att_s,
                               const float* __restrict__ att_d,
                               float* __restrict__ a_s, float* __restrict__ a_d,
                               int H, int F)
{
    int bid = blockIdx.x;           // n*H + h
    int h = bid % H;
    int lane = threadIdx.x;
    const float* row = lin + (size_t)bid * F;
    const float* wsrc = att_s + h * F;
    const float* wdst = att_d + h * F;
    float ss = 0.f, sd = 0.f;
    for (int f = lane; f < F; f += 64) {
        float v = row[f];
        ss += v * wsrc[f];
        sd += v * wdst[f];
    }
    for (int o = 32; o; o >>= 1) {
        ss += __shfl_down(ss, o);
        sd += __shfl_down(sd, o);
    }
    if (lane == 0) { a_s[bid] = ss; a_d[bid] = sd; }
}

__global__ void edge_max_kernel(const int* __restrict__ ei,
                                const float* __restrict__ a_s,
                                const float* __restrict__ a_d,
                                float* __restrict__ eval,
                                unsigned* __restrict__ mmax,
                                int E, int Etot, int H)
{
    int t = blockIdx.x * blockDim.x + threadIdx.x;
    if (t >= Etot * H) return;
    int e = t / H, h = t - e * H;
    int s, d;
    if (e < E) { s = ei[e]; d = ei[E + e]; } else { s = d = e - E; }
    float v = a_s[s * H + h] + a_d[d * H + h];
    v = v > 0.f ? v : 0.2f * v;
    eval[t] = v;
    atomicMax(&mmax[d * H + h], fmap(v));
}

__global__ void edge_exp_kernel(const int* __restrict__ ei,
                                const unsigned* __restrict__ mmax,
                                float* __restrict__ eval,
                                float* __restrict__ denom,
                                int E, int Etot, int H)
{
    int t = blockIdx.x * blockDim.x + threadIdx.x;
    if (t >= Etot * H) return;
    int e = t / H, h = t - e * H;
    int d = (e < E) ? ei[E + e] : e - E;
    float m = funmap(mmax[d * H + h]);
    float ex = expf(eval[t] - m);
    eval[t] = ex;
    atomicAdd(&denom[d * H + h], ex);
}

__global__ __launch_bounds__(256) void edge_scatter_kernel(
    const int* __restrict__ ei, const float* __restrict__ eval,
    const float* __restrict__ denom, const float* __restrict__ lin,
    float* __restrict__ out, int E, int Etot, int H, int F)
{
    __shared__ float s_alpha[16];
    int e = blockIdx.x;
    int s, d;
    if (e < E) { s = ei[e]; d = ei[E + e]; } else { s = d = e - E; }
    int tid = threadIdx.x;
    if (tid < H) s_alpha[tid] = eval[e * H + tid] / (denom[d * H + tid] + 1e-16f);
    __syncthreads();
    int Ft = H * F;
    const float* srow = lin + (size_t)s * Ft;
    float* drow = out + (size_t)d * Ft;
    for (int c = tid; c < Ft; c += 256) {
        int h = c / F;
        atomicAdd(&drow[c], s_alpha[h] * srow[c]);
    }
}

template<int ACT>
__global__ void bias_act_kernel(float* __restrict__ x, const float* __restrict__ b,
                                int total, int C)
{
    int t = blockIdx.x * blockDim.x + threadIdx.x;
    if (t >= total) return;
    int c = t % C;
    float v = x[t] + b[c];
    if (ACT == 1) v = v > 0.f ? v : 0.f;
    else if (ACT == 2) v = v > 0.f ? v : expm1f(v);
    x[t] = v;
}

__global__ void pool_max_kernel(const float* __restrict__ h, float* __restrict__ g,
                                int B, int per, int C)
{
    int t = blockIdx.x * blockDim.x + threadIdx.x;
    if (t >= B * C) return;
    int b = t / C, f = t - b * C;
    const float* p = h + (size_t)b * per * C + f;
    float m = -INFINITY;
    for (int j = 0; j < per; ++j) m = fmaxf(m, p[(size_t)j * C]);
    g[t] = m;
}

// ---------------------------------------------------------------------------
// CNN branch
// ---------------------------------------------------------------------------
// conv1 vocab-factorized. One block per graph n.
// Phase 1: S[v][o][k] = sum_{i: target[n,i]==v} w[o,i,k]   (thread = (o,k))
// Phase 2: y[n,o,t] = relu(b[o] + sum_{v,k} S[v][o][k] * emb[v][t+k])
__global__ __launch_bounds__(256) void conv1_fact_kernel(
    const int* __restrict__ target, const float* __restrict__ emb,
    const float* __restrict__ w, const float* __restrict__ b,
    float* __restrict__ y)
{
    __shared__ float s_emb[VOCAB * EMB];     // 13312 B
    __shared__ float s_S[VOCAB * 256];       // 26624 B, S[v*256 + o*8 + k]
    __shared__ int   s_trow[1000];           // 4000 B
    int tid = threadIdx.x;
    int n = blockIdx.x;
    for (int i = tid; i < VOCAB * EMB; i += 256) s_emb[i] = emb[i];
    for (int i = tid; i < VOCAB * 256; i += 256) s_S[i] = 0.f;
    for (int i = tid; i < 1000; i += 256) s_trow[i] = target[n * 1000 + i];
    __syncthreads();

    // phase 1: thread owns (o,k) = (tid>>3, tid&7); accumulates into S[v][tid]
    {
        const float* wcol = w + (size_t)(tid >> 3) * 8000 + (tid & 7);
        for (int i = 0; i < 1000; i += 4) {
            int v0 = s_trow[i + 0], v1 = s_trow[i + 1];
            int v2 = s_trow[i + 2], v3 = s_trow[i + 3];
            float w0 = wcol[(i + 0) * 8];
            float w1 = wcol[(i + 1) * 8];
            float w2 = wcol[(i + 2) * 8];
            float w3 = wcol[(i + 3) * 8];
            s_S[v0 * 256 + tid] += w0;
            s_S[v1 * 256 + tid] += w1;
            s_S[v2 * 256 + tid] += w2;
            s_S[v3 * 256 + tid] += w3;
        }
    }
    __syncthreads();

    // phase 2
    for (int idx = tid; idx < 32 * 121; idx += 256) {
        int o = idx / 121, t = idx - o * 121;
        float acc = b[o];
#pragma unroll
        for (int v = 0; v < VOCAB; ++v) {
            const float* Sv = s_S + v * 256 + o * 8;
            const float* ev = s_emb + v * EMB + t;
#pragma unroll
            for (int k = 0; k < 8; ++k) acc += Sv[k] * ev[k];
        }
        y[((size_t)n * 32 + o) * 121 + t] = acc > 0.f ? acc : 0.f;
    }
}

// generic small conv1d (NCH, OIH, valid, k=8) + relu
template<int Ci>
__global__ void conv_kernel(const float* __restrict__ x, const float* __restrict__ w,
                            const float* __restrict__ b, float* __restrict__ y,
                            int Co, int Lin, int Lout)
{
    int idx = blockIdx.x * blockDim.x + threadIdx.x;
    int total = NB * Co * Lout;
    if (idx >= total) return;
    int t = idx % Lout;
    int rest = idx / Lout;
    int o = rest % Co;
    int n = rest / Co;
    const float* xr = x + ((size_t)n * Ci) * Lin + t;
    const float* wr = w + (size_t)o * Ci * 8;
    float acc = b[o];
#pragma unroll 4
    for (int i = 0; i < Ci; ++i) {
        const float* xi = xr + (size_t)i * Lin;
        const float4* wv = (const float4*)(wr + i * 8);
        float4 w0 = wv[0], w1 = wv[1];
        acc += xi[0] * w0.x + xi[1] * w0.y + xi[2] * w0.z + xi[3] * w0.w
             + xi[4] * w1.x + xi[5] * w1.y + xi[6] * w1.z + xi[7] * w1.w;
    }
    y[idx] = acc > 0.f ? acc : 0.f;
}

__global__ void pool3_kernel(const float* __restrict__ x, float* __restrict__ y)
{
    int idx = blockIdx.x * blockDim.x + threadIdx.x;
    if (idx >= NB * 128 * 33) return;
    int t = idx % 33;
    int rest = idx / 33;
    int c = rest % 128;
    int n = rest / 128;
    const float* p = x + ((size_t)n * 128 + c) * 100 + t * 3;
    y[idx] = fmaxf(fmaxf(p[0], p[1]), p[2]);
}

// ---------------------------------------------------------------------------
// Host-side launch
// ---------------------------------------------------------------------------
extern "C" void kernel_launch(void* const* d_in, const int* in_sizes, int n_in,
                              void* d_out, int out_size, void* d_ws, size_t ws_size,
                              hipStream_t stream)
{
    const float* x      = (const float*)d_in[0];
    const int*   ei     = (const int*)d_in[1];
    const int*   target = (const int*)d_in[3];
    const float* W1  = (const float*)d_in[4];
    const float* as1 = (const float*)d_in[5];
    const float* ad1 = (const float*)d_in[6];
    const float* b1  = (const float*)d_in[7];
    const float* W2  = (const float*)d_in[8];
    const float* as2 = (const float*)d_in[9];
    const float* ad2 = (const float*)d_in[10];
    const float* b2  = (const float*)d_in[11];
    const float* W3  = (const float*)d_in[12];
    const float* as3 = (const float*)d_in[13];
    const float* ad3 = (const float*)d_in[14];
    const float* b3  = (const float*)d_in[15];
    const float* fc_g1_w = (const float*)d_in[16];
    const float* fc_g1_b = (const float*)d_in[17];
    const float* fc_g2_w = (const float*)d_in[18];
    const float* fc_g2_b = (const float*)d_in[19];
    const float* emb_xt  = (const float*)d_in[20];
    const float* cw1 = (const float*)d_in[21];
    const float* cb1 = (const float*)d_in[22];
    const float* cw2 = (const float*)d_in[23];
    const float* cb2 = (const float*)d_in[24];
    const float* cw3 = (const float*)d_in[25];
    const float* cb3 = (const float*)d_in[26];
    const float* cw4 = (const float*)d_in[27];
    const float* cb4 = (const float*)d_in[28];
    const float* fc1_xt_w = (const float*)d_in[29];
    const float* fc1_xt_b = (const float*)d_in[30];
    const float* fc2_xt_w = (const float*)d_in[31];
    const float* fc2_xt_b = (const float*)d_in[32];
    const float* fc1_w = (const float*)d_in[33];
    const float* fc1_b = (const float*)d_in[34];
    const float* fc2_w = (const float*)d_in[35];
    const float* fc2_b = (const float*)d_in[36];
    const float* out_w = (const float*)d_in[37];
    const float* out_b = (const float*)d_in[38];
    float* out = (float*)d_out;

    const int N = NNODES, E = NEDGES, Etot = E + N;

    // ---- workspace carve ----
    char* ws = (char*)d_ws;
    size_t off = 0;
    auto alloc = [&](size_t bytes) -> char* {
        char* p = ws + off;
        off = (off + bytes + 255) & ~(size_t)255;
        return p;
    };
    const size_t BIG = (size_t)N * 3120 * sizeof(float);   // 127.8 MB
    float*    bufA  = (float*)alloc(BIG);   // lin1/lin2/lin3, then CNN scratch
    float*    bufB  = (float*)alloc(BIG);   // out1/out2/out3
    float*    a_s   = (float*)alloc((size_t)N * 10 * 4);
    float*    a_d   = (float*)alloc((size_t)N * 10 * 4);
    unsigned* mmax  = (unsigned*)alloc((size_t)N * 10 * 4);
    float*    denom = (float*)alloc((size_t)N * 10 * 4);
    float*    eval  = (float*)alloc((size_t)Etot * 10 * 4);
    float*    gbuf  = (float*)alloc((size_t)NB * 3120 * 4);
    float*    g1    = (float*)alloc((size_t)NB * 1024 * 4);
    float*    xt1   = (float*)alloc((size_t)NB * 1024 * 4);
    float*    xc    = (float*)alloc((size_t)NB * 256 * 4);
    float*    f1    = (float*)alloc((size_t)NB * 1024 * 4);
    float*    f2    = (float*)alloc((size_t)NB * 256 * 4);
    // CNN scratch carved from bufA (dead after GAT layer 3 scatter):
    char* cnn = (char*)bufA;
    float* c1 = (float*)cnn;                       cnn += (size_t)NB * 32 * 121 * 4 + 256;
    float* c2 = (float*)cnn;                       cnn += (size_t)NB * 64 * 114 * 4 + 256;
    float* c3 = (float*)cnn;                       cnn += (size_t)NB * 96 * 107 * 4 + 256;
    float* c4 = (float*)cnn;                       cnn += (size_t)NB * 128 * 100 * 4 + 256;
    float* xt = (float*)cnn;                       cnn += (size_t)NB * 4224 * 4 + 256;

    // ---- one GAT layer ----
    auto gat_layer = [&](const float* hin, int Fin, const float* W,
                         const float* atts, const float* attd, const float* bias,
                         int H, int F, int act, float* lin, float* outb) {
        int Ft = H * F;
        dim3 gg((Ft + 127) / 128, (N + 127) / 128);
        gemm_f32_big<0><<<gg, 256, 0, stream>>>(hin, W, nullptr, lin, N, Ft, Fin, Ft);
        attn_ab_kernel<<<N * H, 64, 0, stream>>>(lin, atts, attd, a_s, a_d, H, F);
        hipMemsetAsync(mmax, 0, (size_t)N * H * 4, stream);
        hipMemsetAsync(denom, 0, (size_t)N * H * 4, stream);
        hipMemsetAsync(outb, 0, (size_t)N * Ft * 4, stream);
        int tot = Etot * H;
        edge_max_kernel<<<(tot + 255) / 256, 256, 0, stream>>>(ei, a_s, a_d, eval, mmax, E, Etot, H);
        edge_exp_kernel<<<(tot + 255) / 256, 256, 0, stream>>>(ei, mmax, eval, denom, E, Etot, H);
        edge_scatter_kernel<<<Etot, 256, 0, stream>>>(ei, eval, denom, lin, outb, E, Etot, H, F);
        int total = N * Ft;
        if (act == 1)
            bias_act_kernel<1><<<(total + 255) / 256, 256, 0, stream>>>(outb, bias, total, Ft);
        else
            bias_act_kernel<2><<<(total + 255) / 256, 256, 0, stream>>>(outb, bias, total, Ft);
    };

    // ---- GAT branch ----
    gat_layer(x,    78,   W1, as1, ad1, b1, 10, 78,   2, bufA, bufB);
    gat_layer(bufB, 780,  W2, as2, ad2, b2, 2,  780,  1, bufA, bufB);
    gat_layer(bufB, 1560, W3, as3, ad3, b3, 1,  3120, 1, bufA, bufB);

    // global max pool (40 consecutive nodes per graph) + graph FCs
    {
        int tot = NB * 3120;
        pool_max_kernel<<<(tot + 255) / 256, 256, 0, stream>>>(bufB, gbuf, NB, N / NB, 3120);
        dim3 g1g((1024 + 63) / 64, (NB + 63) / 64);
        gemm_f32<1><<<g1g, 256, 0, stream>>>(gbuf, fc_g1_w, fc_g1_b, g1, NB, 1024, 3120, 1024);
        dim3 g2g((128 + 63) / 64, (NB + 63) / 64);
        gemm_f32<0><<<g2g, 256, 0, stream>>>(g1, fc_g2_w, fc_g2_b, xc, NB, 128, 1024, 256);
    }

    // ---- CNN branch (bufA is dead now; c1..xt live inside it) ----
    {
        conv1_fact_kernel<<<NB, 256, 0, stream>>>(target, emb_xt, cw1, cb1, c1);
        int t2 = NB * 64 * 114;
        conv_kernel<32><<<(t2 + 255) / 256, 256, 0, stream>>>(c1, cw2, cb2, c2, 64, 121, 114);
        int t3 = NB * 96 * 107;
        conv_kernel<64><<<(t3 + 255) / 256, 256, 0, stream>>>(c2, cw3, cb3, c3, 96, 114, 107);
        int t4 = NB * 128 * 100;
        conv_kernel<96><<<(t4 + 255) / 256, 256, 0, stream>>>(c3, cw4, cb4, c4, 128, 107, 100);
        int tp = NB * 128 * 33;
        pool3_kernel<<<(tp + 255) / 256, 256, 0, stream>>>(c4, xt);
        dim3 xg((1024 + 63) / 64, (NB + 63) / 64);
        gemm_f32<1><<<xg, 256, 0, stream>>>(xt, fc1_xt_w, fc1_xt_b, xt1, NB, 1024, 4224, 1024);
        dim3 x2g((128 + 63) / 64, (NB + 63) / 64);
        gemm_f32<0><<<x2g, 256, 0, stream>>>(xt1, fc2_xt_w, fc2_xt_b, xc + 128, NB, 128, 1024, 256);
    }

    // ---- fusion head ----
    {
        dim3 h1g((1024 + 63) / 64, (NB + 63) / 64);
        gemm_f32<1><<<h1g, 256, 0, stream>>>(xc, fc1_w, fc1_b, f1, NB, 1024, 256, 1024);
        dim3 h2g((256 + 63) / 64, (NB + 63) / 64);
        gemm_f32<1><<<h2g, 256, 0, stream>>>(f1, fc2_w, fc2_b, f2, NB, 256, 1024, 256);
        dim3 og(1, (NB + 63) / 64);
        gemm_f32<0><<<og, 256, 0, stream>>>(f2, out_w, out_b, out, NB, 1, 256, 1);
    }
}

// Round 4
// 4628.984 us; speedup vs baseline: 2.2875x; 1.4595x over previous
//
#include <hip/hip_runtime.h>
#include <hip/hip_bf16.h>
#include <math.h>

// ---------------------------------------------------------------------------
// Constants (problem-fixed)
// ---------------------------------------------------------------------------
static const int NNODES = 10240;
static const int NEDGES = 40960;
static const int NB     = 256;     // graphs / batch
static const int VOCAB  = 26;
static const int EMB    = 128;

typedef short bf16x8 __attribute__((ext_vector_type(8)));   // 8 bf16 (4 VGPRs)
typedef float f32x4  __attribute__((ext_vector_type(4)));   // 4 fp32

// ---------------------------------------------------------------------------
// Small tiled f32 GEMM (64x64 tile, 4x4 micro): for M=256 batch GEMMs.
// ACT: 0=none, 1=relu, 2=elu
// ---------------------------------------------------------------------------
template<int ACT>
__global__ __launch_bounds__(256) void gemm_f32(
    const float* __restrict__ A, const float* __restrict__ B,
    const float* __restrict__ bias, float* __restrict__ C,
    int M, int N, int K, int ldC)
{
    __shared__ float As[16][64];
    __shared__ float Bs[16][64];
    int tid = threadIdx.x;
    int bm = blockIdx.y * 64;
    int bn = blockIdx.x * 64;
    int tx = tid & 15, ty = tid >> 4;
    float acc[4][4] = {};
    for (int k0 = 0; k0 < K; k0 += 16) {
#pragma unroll
        for (int l = 0; l < 4; ++l) {
            int idx = tid + l * 256;
            int r = idx >> 4, c = idx & 15;
            int gr = bm + r, gc = k0 + c;
            As[c][r] = (gr < M && gc < K) ? A[(size_t)gr * K + gc] : 0.f;
        }
#pragma unroll
        for (int l = 0; l < 4; ++l) {
            int idx = tid + l * 256;
            int r = idx >> 6, c = idx & 63;
            int gr = k0 + r, gc = bn + c;
            Bs[r][c] = (gr < K && gc < N) ? B[(size_t)gr * N + gc] : 0.f;
        }
        __syncthreads();
#pragma unroll
        for (int kk = 0; kk < 16; ++kk) {
            float a[4], b[4];
#pragma unroll
            for (int i = 0; i < 4; ++i) a[i] = As[kk][ty * 4 + i];
#pragma unroll
            for (int j = 0; j < 4; ++j) b[j] = Bs[kk][tx * 4 + j];
#pragma unroll
            for (int i = 0; i < 4; ++i)
#pragma unroll
                for (int j = 0; j < 4; ++j)
                    acc[i][j] += a[i] * b[j];
        }
        __syncthreads();
    }
#pragma unroll
    for (int i = 0; i < 4; ++i) {
        int gr = bm + ty * 4 + i;
        if (gr >= M) continue;
#pragma unroll
        for (int j = 0; j < 4; ++j) {
            int gc = bn + tx * 4 + j;
            if (gc >= N) continue;
            float v = acc[i][j];
            if (bias) v += bias[gc];
            if (ACT == 1) v = v > 0.f ? v : 0.f;
            else if (ACT == 2) v = v > 0.f ? v : expm1f(v);
            C[(size_t)gr * ldC + gc] = v;
        }
    }
}

// ---------------------------------------------------------------------------
// Big tiled f32 GEMM (128x128 tile, BK=16, 8x8 micro): used for lin1 only.
// ---------------------------------------------------------------------------
template<int ACT>
__global__ __launch_bounds__(256) void gemm_f32_big(
    const float* __restrict__ A, const float* __restrict__ B,
    const float* __restrict__ bias, float* __restrict__ C,
    int M, int N, int K, int ldC)
{
    __shared__ float As[16][132];
    __shared__ float Bs[16][132];
    int tid = threadIdx.x;
    int bm = blockIdx.y * 128;
    int bn = blockIdx.x * 128;
    int tx = tid & 15, ty = tid >> 4;

    int ar = tid >> 1;
    int ac = (tid & 1) * 8;
    int br = tid >> 4;
    int bc = (tid & 15) * 8;

    float acc[8][8] = {};
    int gar = bm + ar;
    const float* Arow = A + (size_t)gar * K;

    for (int k0 = 0; k0 < K; k0 += 16) {
#pragma unroll
        for (int c = 0; c < 8; ++c) {
            int gc = k0 + ac + c;
            As[ac + c][ar] = (gar < M && gc < K) ? Arow[gc] : 0.f;
        }
#pragma unroll
        for (int c = 0; c < 8; ++c) {
            int gr = k0 + br;
            int gc = bn + bc + c;
            Bs[br][bc + c] = (gr < K && gc < N) ? B[(size_t)gr * N + gc] : 0.f;
        }
        __syncthreads();
#pragma unroll
        for (int kk = 0; kk < 16; ++kk) {
            float a[8], b[8];
#pragma unroll
            for (int i = 0; i < 8; ++i) a[i] = As[kk][ty * 8 + i];
#pragma unroll
            for (int j = 0; j < 8; ++j) b[j] = Bs[kk][tx * 8 + j];
#pragma unroll
            for (int i = 0; i < 8; ++i)
#pragma unroll
                for (int j = 0; j < 8; ++j)
                    acc[i][j] += a[i] * b[j];
        }
        __syncthreads();
    }
#pragma unroll
    for (int i = 0; i < 8; ++i) {
        int gr = bm + ty * 8 + i;
        if (gr >= M) continue;
#pragma unroll
        for (int j = 0; j < 8; ++j) {
            int gc = bn + tx * 8 + j;
            if (gc >= N) continue;
            float v = acc[i][j];
            if (bias) v += bias[gc];
            if (ACT == 1) v = v > 0.f ? v : 0.f;
            else if (ACT == 2) v = v > 0.f ? v : expm1f(v);
            C[(size_t)gr * ldC + gc] = v;
        }
    }
}

// ---------------------------------------------------------------------------
// bf16 cast helpers for MFMA GEMM
// ---------------------------------------------------------------------------
// out[r][k] (stride Kp) = bf16(in[r][k]) for k<K else 0
__global__ void cast_a_kernel(const float* __restrict__ in, __hip_bfloat16* __restrict__ out,
                              int M, int K, int Kp)
{
    int idx = blockIdx.x * 256 + threadIdx.x;
    if (idx >= M * Kp) return;
    int r = idx / Kp, k = idx - r * Kp;
    out[idx] = __float2bfloat16(k < K ? in[(size_t)r * K + k] : 0.f);
}

// out[n][k] ([Npad][Kp] bf16) = in[k][n] ([K][N] f32), zero-padded.
__global__ __launch_bounds__(256) void transpose_cast_kernel(
    const float* __restrict__ in, __hip_bfloat16* __restrict__ out,
    int K, int N, int Kp, int Npad)
{
    __shared__ float tile[32][33];
    int k0 = blockIdx.x * 32;
    int n0 = blockIdx.y * 32;
    int tx = threadIdx.x & 31;
    int ty = threadIdx.x >> 5;   // 0..7
#pragma unroll
    for (int j = 0; j < 4; ++j) {
        int k = k0 + ty + j * 8, n = n0 + tx;
        tile[ty + j * 8][tx] = (k < K && n < N) ? in[(size_t)k * N + n] : 0.f;
    }
    __syncthreads();
#pragma unroll
    for (int j = 0; j < 4; ++j) {
        int n = n0 + ty + j * 8, k = k0 + tx;
        if (n < Npad && k < Kp)
            out[(size_t)n * Kp + k] = __float2bfloat16(tile[tx][ty + j * 8]);
    }
}

// ---------------------------------------------------------------------------
// MFMA bf16 GEMM: C[M,N] = A[M,Kp] @ Bt[N,Kp]^T  (both operands k-contiguous)
// 128x128 tile, BK=64, 4 waves x (4x4) 16x16x32 fragments, double-buffered
// LDS with global_load_lds(16B) staging, XOR-swizzled (slot ^= row&7).
// ---------------------------------------------------------------------------
__device__ __forceinline__ void stage_tile(
    const __hip_bfloat16* __restrict__ gA,   // A + bm*Kp + k0
    const __hip_bfloat16* __restrict__ gB,   // Bt + bn*Kp + k0
    short* ldsbuf, int Kp, int w, int l)
{
#pragma unroll
    for (int j = 0; j < 4; ++j) {
        int u = (w * 4 + j) * 64 + l;          // 16B-slot index in tile
        int r = u >> 3, s = u & 7;
        const __hip_bfloat16* src = gA + (size_t)r * Kp + ((s ^ (r & 7)) << 3);
        __builtin_amdgcn_global_load_lds(
            (const __attribute__((address_space(1))) void*)src,
            (__attribute__((address_space(3))) void*)(ldsbuf + (w * 4 + j) * 512),
            16, 0, 0);
    }
#pragma unroll
    for (int j = 0; j < 4; ++j) {
        int u = (w * 4 + j) * 64 + l;
        int r = u >> 3, s = u & 7;
        const __hip_bfloat16* src = gB + (size_t)r * Kp + ((s ^ (r & 7)) << 3);
        __builtin_amdgcn_global_load_lds(
            (const __attribute__((address_space(1))) void*)src,
            (__attribute__((address_space(3))) void*)(ldsbuf + 8192 + (w * 4 + j) * 512),
            16, 0, 0);
    }
}

__global__ __launch_bounds__(256, 2) void gemm_mfma_bf16(
    const __hip_bfloat16* __restrict__ A,   // [M][Kp]
    const __hip_bfloat16* __restrict__ Bt,  // [Npad][Kp]
    float* __restrict__ C, int M, int N, int Kp, int ldC)
{
    __shared__ __align__(16) short lds[2][16384];   // 2 x (A 16KB + B 16KB)
    const int tid = threadIdx.x;
    const int w = tid >> 6, l = tid & 63;
    const int bm = blockIdx.y * 128, bn = blockIdx.x * 128;
    const int wr = w >> 1, wc = w & 1;
    const int lane15 = l & 15, lhi = l >> 4;

    const __hip_bfloat16* gA = A + (size_t)bm * Kp;
    const __hip_bfloat16* gB = Bt + (size_t)bn * Kp;

    f32x4 acc[4][4] = {};

    const int nk = Kp >> 6;
    stage_tile(gA, gB, &lds[0][0], Kp, w, l);
    __syncthreads();
    int cur = 0;
    for (int t = 0; t < nk; ++t) {
        if (t + 1 < nk)
            stage_tile(gA + (t + 1) * 64, gB + (t + 1) * 64, &lds[cur ^ 1][0], Kp, w, l);
        const short* bA = &lds[cur][0];
        const short* bB = &lds[cur][8192];
#pragma unroll
        for (int ks = 0; ks < 2; ++ks) {
            bf16x8 af[4], bfr[4];
#pragma unroll
            for (int m = 0; m < 4; ++m) {
                int r = wr * 64 + m * 16 + lane15;
                int slot = (ks * 4 + lhi) ^ (r & 7);
                af[m] = *(const bf16x8*)(bA + r * 64 + slot * 8);
            }
#pragma unroll
            for (int n = 0; n < 4; ++n) {
                int r = wc * 64 + n * 16 + lane15;
                int slot = (ks * 4 + lhi) ^ (r & 7);
                bfr[n] = *(const bf16x8*)(bB + r * 64 + slot * 8);
            }
#pragma unroll
            for (int m = 0; m < 4; ++m)
#pragma unroll
                for (int n = 0; n < 4; ++n)
                    acc[m][n] = __builtin_amdgcn_mfma_f32_16x16x32_bf16(
                        af[m], bfr[n], acc[m][n], 0, 0, 0);
        }
        __syncthreads();
        cur ^= 1;
    }
    // C/D layout (verified): col = lane&15, row = (lane>>4)*4 + reg
#pragma unroll
    for (int m = 0; m < 4; ++m) {
#pragma unroll
        for (int n = 0; n < 4; ++n) {
            int col = bn + wc * 64 + n * 16 + lane15;
            if (col >= N) continue;
            int row0 = bm + wr * 64 + m * 16 + lhi * 4;
#pragma unroll
            for (int q = 0; q < 4; ++q)
                C[(size_t)(row0 + q) * ldC + col] = acc[m][n][q];
        }
    }
}

// ---------------------------------------------------------------------------
// GAT helpers
// ---------------------------------------------------------------------------
__device__ __forceinline__ unsigned fmap(float f) {
    unsigned u = __float_as_uint(f);
    return (u & 0x80000000u) ? ~u : (u | 0x80000000u);
}
__device__ __forceinline__ float funmap(unsigned u) {
    return (u & 0x80000000u) ? __uint_as_float(u ^ 0x80000000u)
                             : __uint_as_float(~u);
}

__global__ void attn_ab_kernel(const float* __restrict__ lin,
                               const float* __restrict__ att_s,
                               const float* __restrict__ att_d,
                               float* __restrict__ a_s, float* __restrict__ a_d,
                               int H, int F)
{
    int bid = blockIdx.x;           // n*H + h
    int h = bid % H;
    int lane = threadIdx.x;
    const float* row = lin + (size_t)bid * F;
    const float* wsrc = att_s + h * F;
    const float* wdst = att_d + h * F;
    float ss = 0.f, sd = 0.f;
    for (int f = lane; f < F; f += 64) {
        float v = row[f];
        ss += v * wsrc[f];
        sd += v * wdst[f];
    }
    for (int o = 32; o; o >>= 1) {
        ss += __shfl_down(ss, o);
        sd += __shfl_down(sd, o);
    }
    if (lane == 0) { a_s[bid] = ss; a_d[bid] = sd; }
}

__global__ void edge_max_kernel(const int* __restrict__ ei,
                                const float* __restrict__ a_s,
                                const float* __restrict__ a_d,
                                float* __restrict__ eval,
                                unsigned* __restrict__ mmax,
                                int E, int Etot, int H)
{
    int t = blockIdx.x * blockDim.x + threadIdx.x;
    if (t >= Etot * H) return;
    int e = t / H, h = t - e * H;
    int s, d;
    if (e < E) { s = ei[e]; d = ei[E + e]; } else { s = d = e - E; }
    float v = a_s[s * H + h] + a_d[d * H + h];
    v = v > 0.f ? v : 0.2f * v;
    eval[t] = v;
    atomicMax(&mmax[d * H + h], fmap(v));
}

__global__ void edge_exp_kernel(const int* __restrict__ ei,
                                const unsigned* __restrict__ mmax,
                                float* __restrict__ eval,
                                float* __restrict__ denom,
                                int E, int Etot, int H)
{
    int t = blockIdx.x * blockDim.x + threadIdx.x;
    if (t >= Etot * H) return;
    int e = t / H, h = t - e * H;
    int d = (e < E) ? ei[E + e] : e - E;
    float m = funmap(mmax[d * H + h]);
    float ex = expf(eval[t] - m);
    eval[t] = ex;
    atomicAdd(&denom[d * H + h], ex);
}

__global__ __launch_bounds__(256) void edge_scatter_kernel(
    const int* __restrict__ ei, const float* __restrict__ eval,
    const float* __restrict__ denom, const float* __restrict__ lin,
    float* __restrict__ out, int E, int Etot, int H, int F)
{
    __shared__ float s_alpha[16];
    int e = blockIdx.x;
    int s, d;
    if (e < E) { s = ei[e]; d = ei[E + e]; } else { s = d = e - E; }
    int tid = threadIdx.x;
    if (tid < H) s_alpha[tid] = eval[e * H + tid] / (denom[d * H + tid] + 1e-16f);
    __syncthreads();
    int Ft = H * F;
    const float* srow = lin + (size_t)s * Ft;
    float* drow = out + (size_t)d * Ft;
    for (int c = tid; c < Ft; c += 256) {
        int h = c / F;
        atomicAdd(&drow[c], s_alpha[h] * srow[c]);
    }
}

template<int ACT>
__global__ void bias_act_kernel(float* __restrict__ x, const float* __restrict__ b,
                                int total, int C)
{
    int t = blockIdx.x * blockDim.x + threadIdx.x;
    if (t >= total) return;
    int c = t % C;
    float v = x[t] + b[c];
    if (ACT == 1) v = v > 0.f ? v : 0.f;
    else if (ACT == 2) v = v > 0.f ? v : expm1f(v);
    x[t] = v;
}

__global__ void pool_max_kernel(const float* __restrict__ h, float* __restrict__ g,
                                int B, int per, int C)
{
    int t = blockIdx.x * blockDim.x + threadIdx.x;
    if (t >= B * C) return;
    int b = t / C, f = t - b * C;
    const float* p = h + (size_t)b * per * C + f;
    float m = -INFINITY;
    for (int j = 0; j < per; ++j) m = fmaxf(m, p[(size_t)j * C]);
    g[t] = m;
}

// ---------------------------------------------------------------------------
// CNN branch
// ---------------------------------------------------------------------------
__global__ __launch_bounds__(256) void conv1_fact_kernel(
    const int* __restrict__ target, const float* __restrict__ emb,
    const float* __restrict__ w, const float* __restrict__ b,
    float* __restrict__ y)
{
    __shared__ float s_emb[VOCAB * EMB];
    __shared__ float s_S[VOCAB * 256];
    __shared__ int   s_trow[1000];
    int tid = threadIdx.x;
    int n = blockIdx.x;
    for (int i = tid; i < VOCAB * EMB; i += 256) s_emb[i] = emb[i];
    for (int i = tid; i < VOCAB * 256; i += 256) s_S[i] = 0.f;
    for (int i = tid; i < 1000; i += 256) s_trow[i] = target[n * 1000 + i];
    __syncthreads();
    {
        const float* wcol = w + (size_t)(tid >> 3) * 8000 + (tid & 7);
        for (int i = 0; i < 1000; i += 4) {
            int v0 = s_trow[i + 0], v1 = s_trow[i + 1];
            int v2 = s_trow[i + 2], v3 = s_trow[i + 3];
            float w0 = wcol[(i + 0) * 8];
            float w1 = wcol[(i + 1) * 8];
            float w2 = wcol[(i + 2) * 8];
            float w3 = wcol[(i + 3) * 8];
            s_S[v0 * 256 + tid] += w0;
            s_S[v1 * 256 + tid] += w1;
            s_S[v2 * 256 + tid] += w2;
            s_S[v3 * 256 + tid] += w3;
        }
    }
    __syncthreads();
    for (int idx = tid; idx < 32 * 121; idx += 256) {
        int o = idx / 121, t = idx - o * 121;
        float acc = b[o];
#pragma unroll
        for (int v = 0; v < VOCAB; ++v) {
            const float* Sv = s_S + v * 256 + o * 8;
            const float* ev = s_emb + v * EMB + t;
#pragma unroll
            for (int k = 0; k < 8; ++k) acc += Sv[k] * ev[k];
        }
        y[((size_t)n * 32 + o) * 121 + t] = acc > 0.f ? acc : 0.f;
    }
}

template<int Ci>
__global__ void conv_kernel(const float* __restrict__ x, const float* __restrict__ w,
                            const float* __restrict__ b, float* __restrict__ y,
                            int Co, int Lin, int Lout)
{
    int idx = blockIdx.x * blockDim.x + threadIdx.x;
    int total = NB * Co * Lout;
    if (idx >= total) return;
    int t = idx % Lout;
    int rest = idx / Lout;
    int o = rest % Co;
    int n = rest / Co;
    const float* xr = x + ((size_t)n * Ci) * Lin + t;
    const float* wr = w + (size_t)o * Ci * 8;
    float acc = b[o];
#pragma unroll 4
    for (int i = 0; i < Ci; ++i) {
        const float* xi = xr + (size_t)i * Lin;
        const float4* wv = (const float4*)(wr + i * 8);
        float4 w0 = wv[0], w1 = wv[1];
        acc += xi[0] * w0.x + xi[1] * w0.y + xi[2] * w0.z + xi[3] * w0.w
             + xi[4] * w1.x + xi[5] * w1.y + xi[6] * w1.z + xi[7] * w1.w;
    }
    y[idx] = acc > 0.f ? acc : 0.f;
}

__global__ void pool3_kernel(const float* __restrict__ x, float* __restrict__ y)
{
    int idx = blockIdx.x * blockDim.x + threadIdx.x;
    if (idx >= NB * 128 * 33) return;
    int t = idx % 33;
    int rest = idx / 33;
    int c = rest % 128;
    int n = rest / 128;
    const float* p = x + ((size_t)n * 128 + c) * 100 + t * 3;
    y[idx] = fmaxf(fmaxf(p[0], p[1]), p[2]);
}

// ---------------------------------------------------------------------------
// Host-side launch
// ---------------------------------------------------------------------------
extern "C" void kernel_launch(void* const* d_in, const int* in_sizes, int n_in,
                              void* d_out, int out_size, void* d_ws, size_t ws_size,
                              hipStream_t stream)
{
    const float* x      = (const float*)d_in[0];
    const int*   ei     = (const int*)d_in[1];
    const int*   target = (const int*)d_in[3];
    const float* W1  = (const float*)d_in[4];
    const float* as1 = (const float*)d_in[5];
    const float* ad1 = (const float*)d_in[6];
    const float* b1  = (const float*)d_in[7];
    const float* W2  = (const float*)d_in[8];
    const float* as2 = (const float*)d_in[9];
    const float* ad2 = (const float*)d_in[10];
    const float* b2  = (const float*)d_in[11];
    const float* W3  = (const float*)d_in[12];
    const float* as3 = (const float*)d_in[13];
    const float* ad3 = (const float*)d_in[14];
    const float* b3  = (const float*)d_in[15];
    const float* fc_g1_w = (const float*)d_in[16];
    const float* fc_g1_b = (const float*)d_in[17];
    const float* fc_g2_w = (const float*)d_in[18];
    const float* fc_g2_b = (const float*)d_in[19];
    const float* emb_xt  = (const float*)d_in[20];
    const float* cw1 = (const float*)d_in[21];
    const float* cb1 = (const float*)d_in[22];
    const float* cw2 = (const float*)d_in[23];
    const float* cb2 = (const float*)d_in[24];
    const float* cw3 = (const float*)d_in[25];
    const float* cb3 = (const float*)d_in[26];
    const float* cw4 = (const float*)d_in[27];
    const float* cb4 = (const float*)d_in[28];
    const float* fc1_xt_w = (const float*)d_in[29];
    const float* fc1_xt_b = (const float*)d_in[30];
    const float* fc2_xt_w = (const float*)d_in[31];
    const float* fc2_xt_b = (const float*)d_in[32];
    const float* fc1_w = (const float*)d_in[33];
    const float* fc1_b = (const float*)d_in[34];
    const float* fc2_w = (const float*)d_in[35];
    const float* fc2_b = (const float*)d_in[36];
    const float* out_w = (const float*)d_in[37];
    const float* out_b = (const float*)d_in[38];
    float* out = (float*)d_out;

    const int N = NNODES, E = NEDGES, Etot = E + N;

    // ---- workspace carve (identical footprint to the known-good R2 layout) ----
    char* ws = (char*)d_ws;
    size_t off = 0;
    auto alloc = [&](size_t bytes) -> char* {
        char* p = ws + off;
        off = (off + bytes + 255) & ~(size_t)255;
        return p;
    };
    const size_t BIG = (size_t)N * 3120 * sizeof(float);   // 127.8 MB
    float*    bufA  = (float*)alloc(BIG);   // lin1/lin2/lin3, then CNN scratch
    float*    bufB  = (float*)alloc(BIG);   // out1/out2/out3 (+ bf16 staging up top)
    float*    a_s   = (float*)alloc((size_t)N * 10 * 4);
    float*    a_d   = (float*)alloc((size_t)N * 10 * 4);
    unsigned* mmax  = (unsigned*)alloc((size_t)N * 10 * 4);
    float*    denom = (float*)alloc((size_t)N * 10 * 4);
    float*    eval  = (float*)alloc((size_t)Etot * 10 * 4);
    float*    gbuf  = (float*)alloc((size_t)NB * 3120 * 4);
    float*    g1    = (float*)alloc((size_t)NB * 1024 * 4);
    float*    xt1   = (float*)alloc((size_t)NB * 1024 * 4);
    float*    xc    = (float*)alloc((size_t)NB * 256 * 4);
    float*    f1    = (float*)alloc((size_t)NB * 1024 * 4);
    float*    f2    = (float*)alloc((size_t)NB * 256 * 4);

    // bf16 staging lives INSIDE bufB's upper region (no extra ws):
    //   cast source (worst case, layer 3) reads bufB[0 .. 60.9 MiB)
    //   Ab at +64 MiB needs <= 10240*1600*2 = 31.25 MiB  -> ends ~95.3 MiB
    //   Wt at +100 MiB needs <= 3200*1600*2 = 9.77 MiB   -> ends ~109.8 MiB < 121.9 MiB
    // Ab/Wt are consumed by the GEMM before gat_tail overwrites bufB.
    __hip_bfloat16* Ab = (__hip_bfloat16*)((char*)bufB + (size_t)64 * 1024 * 1024);
    __hip_bfloat16* Wt = (__hip_bfloat16*)((char*)bufB + (size_t)100 * 1024 * 1024);

    // CNN scratch carved from bufA (dead after GAT layer 3 scatter):
    char* cnn = (char*)bufA;
    float* c1 = (float*)cnn;                       cnn += (size_t)NB * 32 * 121 * 4 + 256;
    float* c2 = (float*)cnn;                       cnn += (size_t)NB * 64 * 114 * 4 + 256;
    float* c3 = (float*)cnn;                       cnn += (size_t)NB * 96 * 107 * 4 + 256;
    float* c4 = (float*)cnn;                       cnn += (size_t)NB * 128 * 100 * 4 + 256;
    float* xt = (float*)cnn;                       cnn += (size_t)NB * 4224 * 4 + 256;

    // ---- GAT softmax/scatter chain (shared by all layers) ----
    auto gat_tail = [&](const float* atts, const float* attd, const float* bias,
                        int H, int F, int act, float* lin, float* outb) {
        int Ft = H * F;
        attn_ab_kernel<<<N * H, 64, 0, stream>>>(lin, atts, attd, a_s, a_d, H, F);
        hipMemsetAsync(mmax, 0, (size_t)N * H * 4, stream);
        hipMemsetAsync(denom, 0, (size_t)N * H * 4, stream);
        hipMemsetAsync(outb, 0, (size_t)N * Ft * 4, stream);
        int tot = Etot * H;
        edge_max_kernel<<<(tot + 255) / 256, 256, 0, stream>>>(ei, a_s, a_d, eval, mmax, E, Etot, H);
        edge_exp_kernel<<<(tot + 255) / 256, 256, 0, stream>>>(ei, mmax, eval, denom, E, Etot, H);
        edge_scatter_kernel<<<Etot, 256, 0, stream>>>(ei, eval, denom, lin, outb, E, Etot, H, F);
        int total = N * Ft;
        if (act == 1)
            bias_act_kernel<1><<<(total + 255) / 256, 256, 0, stream>>>(outb, bias, total, Ft);
        else
            bias_act_kernel<2><<<(total + 255) / 256, 256, 0, stream>>>(outb, bias, total, Ft);
    };

    // ---- layer 1: f32 GEMM (keep full precision; cheap K=78) ----
    {
        dim3 gg((780 + 127) / 128, (N + 127) / 128);
        gemm_f32_big<0><<<gg, 256, 0, stream>>>(x, W1, nullptr, bufA, N, 780, 78, 780);
        gat_tail(as1, ad1, b1, 10, 78, 2, bufA, bufB);
    }
    // ---- layer 2: bf16 MFMA GEMM (K=780->832, N=1560->1664) ----
    {
        const int K = 780, Kp = 832, Nout = 1560, Npad = 1664;
        cast_a_kernel<<<(N * Kp + 255) / 256, 256, 0, stream>>>(bufB, Ab, N, K, Kp);
        transpose_cast_kernel<<<dim3(Kp / 32, Npad / 32), 256, 0, stream>>>(W2, Wt, K, Nout, Kp, Npad);
        gemm_mfma_bf16<<<dim3(Npad / 128, N / 128), 256, 0, stream>>>(Ab, Wt, bufA, N, Nout, Kp, Nout);
        gat_tail(as2, ad2, b2, 2, 780, 1, bufA, bufB);
    }
    // ---- layer 3: bf16 MFMA GEMM (K=1560->1600, N=3120->3200) ----
    {
        const int K = 1560, Kp = 1600, Nout = 3120, Npad = 3200;
        cast_a_kernel<<<(N * Kp + 255) / 256, 256, 0, stream>>>(bufB, Ab, N, K, Kp);
        transpose_cast_kernel<<<dim3(Kp / 32, Npad / 32), 256, 0, stream>>>(W3, Wt, K, Nout, Kp, Npad);
        gemm_mfma_bf16<<<dim3(Npad / 128, N / 128), 256, 0, stream>>>(Ab, Wt, bufA, N, Nout, Kp, Nout);
        gat_tail(as3, ad3, b3, 1, 3120, 1, bufA, bufB);
    }

    // global max pool (40 consecutive nodes per graph) + graph FCs
    {
        int tot = NB * 3120;
        pool_max_kernel<<<(tot + 255) / 256, 256, 0, stream>>>(bufB, gbuf, NB, N / NB, 3120);
        dim3 g1g((1024 + 63) / 64, (NB + 63) / 64);
        gemm_f32<1><<<g1g, 256, 0, stream>>>(gbuf, fc_g1_w, fc_g1_b, g1, NB, 1024, 3120, 1024);
        dim3 g2g((128 + 63) / 64, (NB + 63) / 64);
        gemm_f32<0><<<g2g, 256, 0, stream>>>(g1, fc_g2_w, fc_g2_b, xc, NB, 128, 1024, 256);
    }

    // ---- CNN branch (bufA is dead now; c1..xt live inside it) ----
    {
        conv1_fact_kernel<<<NB, 256, 0, stream>>>(target, emb_xt, cw1, cb1, c1);
        int t2 = NB * 64 * 114;
        conv_kernel<32><<<(t2 + 255) / 256, 256, 0, stream>>>(c1, cw2, cb2, c2, 64, 121, 114);
        int t3 = NB * 96 * 107;
        conv_kernel<64><<<(t3 + 255) / 256, 256, 0, stream>>>(c2, cw3, cb3, c3, 96, 114, 107);
        int t4 = NB * 128 * 100;
        conv_kernel<96><<<(t4 + 255) / 256, 256, 0, stream>>>(c3, cw4, cb4, c4, 128, 107, 100);
        int tp = NB * 128 * 33;
        pool3_kernel<<<(tp + 255) / 256, 256, 0, stream>>>(c4, xt);
        dim3 xg((1024 + 63) / 64, (NB + 63) / 64);
        gemm_f32<1><<<xg, 256, 0, stream>>>(xt, fc1_xt_w, fc1_xt_b, xt1, NB, 1024, 4224, 1024);
        dim3 x2g((128 + 63) / 64, (NB + 63) / 64);
        gemm_f32<0><<<x2g, 256, 0, stream>>>(xt1, fc2_xt_w, fc2_xt_b, xc + 128, NB, 128, 1024, 256);
    }

    // ---- fusion head ----
    {
        dim3 h1g((1024 + 63) / 64, (NB + 63) / 64);
        gemm_f32<1><<<h1g, 256, 0, stream>>>(xc, fc1_w, fc1_b, f1, NB, 1024, 256, 1024);
        dim3 h2g((256 + 63) / 64, (NB + 63) / 64);
        gemm_f32<1><<<h2g, 256, 0, stream>>>(f1, fc2_w, fc2_b, f2, NB, 256, 1024, 256);
        dim3 og(1, (NB + 63) / 64);
        gemm_f32<0><<<og, 256, 0, stream>>>(f2, out_w, out_b, out, NB, 1, 256, 1);
    }
}

// Round 5
// 2924.054 us; speedup vs baseline: 3.6213x; 1.5831x over previous
//
#include <hip/hip_runtime.h>
#include <hip/hip_bf16.h>
#include <math.h>

// ---------------------------------------------------------------------------
// Constants (problem-fixed)
// ---------------------------------------------------------------------------
static const int NNODES = 10240;
static const int NEDGES = 40960;
static const int NB     = 256;     // graphs / batch
static const int VOCAB  = 26;
static const int EMB    = 128;

typedef short bf16x8 __attribute__((ext_vector_type(8)));   // 8 bf16 (4 VGPRs)
typedef float f32x4  __attribute__((ext_vector_type(4)));   // 4 fp32

// ---------------------------------------------------------------------------
// Split-K f32 GEMM for skinny-M head GEMMs. Partials atomicAdd'ed into P[M][N]
// (pre-zeroed). LDS padded [16][65] -> conflict-free A-tile store.
// ---------------------------------------------------------------------------
__global__ __launch_bounds__(256) void gemm_f32_splitk(
    const float* __restrict__ A, const float* __restrict__ B,
    float* __restrict__ P, int M, int N, int K, int kchunk)
{
    __shared__ float As[16][65];
    __shared__ float Bs[16][65];
    int tid = threadIdx.x;
    int bm = blockIdx.y * 64;
    int bn = blockIdx.x * 64;
    int k0 = blockIdx.z * kchunk;
    int k1 = min(k0 + kchunk, K);
    int tx = tid & 15, ty = tid >> 4;
    float acc[4][4] = {};
    for (int kb = k0; kb < k1; kb += 16) {
#pragma unroll
        for (int l = 0; l < 4; ++l) {
            int idx = tid + l * 256;
            int r = idx >> 4, c = idx & 15;
            int gr = bm + r, gc = kb + c;
            As[c][r] = (gr < M && gc < k1) ? A[(size_t)gr * K + gc] : 0.f;
        }
#pragma unroll
        for (int l = 0; l < 4; ++l) {
            int idx = tid + l * 256;
            int r = idx >> 6, c = idx & 63;
            int gr = kb + r, gc = bn + c;
            Bs[r][c] = (gr < k1 && gc < N) ? B[(size_t)gr * N + gc] : 0.f;
        }
        __syncthreads();
#pragma unroll
        for (int kk = 0; kk < 16; ++kk) {
            float a[4], b[4];
#pragma unroll
            for (int i = 0; i < 4; ++i) a[i] = As[kk][ty * 4 + i];
#pragma unroll
            for (int j = 0; j < 4; ++j) b[j] = Bs[kk][tx * 4 + j];
#pragma unroll
            for (int i = 0; i < 4; ++i)
#pragma unroll
                for (int j = 0; j < 4; ++j)
                    acc[i][j] += a[i] * b[j];
        }
        __syncthreads();
    }
#pragma unroll
    for (int i = 0; i < 4; ++i) {
        int gr = bm + ty * 4 + i;
        if (gr >= M) continue;
#pragma unroll
        for (int j = 0; j < 4; ++j) {
            int gc = bn + tx * 4 + j;
            if (gc >= N) continue;
            atomicAdd(&P[(size_t)gr * N + gc], acc[i][j]);
        }
    }
}

// C[r*ldC+c] = act(P[r*N+c] + bias[c])
template<int ACT>
__global__ void bias_act_ld_kernel(const float* __restrict__ P,
                                   const float* __restrict__ bias,
                                   float* __restrict__ C, int M, int N, int ldC)
{
    int t = blockIdx.x * 256 + threadIdx.x;
    if (t >= M * N) return;
    int r = t / N, c = t - r * N;
    float v = P[t] + bias[c];
    if (ACT == 1) v = fmaxf(v, 0.f);
    C[(size_t)r * ldC + c] = v;
}

// final 256x1 projection: out[r] = dot(f2[r,:], w) + b
__global__ void out_head_kernel(const float* __restrict__ f2,
                                const float* __restrict__ w,
                                const float* __restrict__ b,
                                float* __restrict__ out)
{
    __shared__ float sw[256];
    int t = threadIdx.x;
    sw[t] = w[t];
    __syncthreads();
    float acc = 0.f;
    const float* row = f2 + (size_t)t * 256;
    for (int k = 0; k < 256; ++k) acc += row[k] * sw[k];
    out[t] = acc + b[0];
}

// ---------------------------------------------------------------------------
// Big tiled f32 GEMM (128x128 tile, BK=16, 8x8 micro): used for lin1 only.
// ---------------------------------------------------------------------------
template<int ACT>
__global__ __launch_bounds__(256) void gemm_f32_big(
    const float* __restrict__ A, const float* __restrict__ B,
    const float* __restrict__ bias, float* __restrict__ C,
    int M, int N, int K, int ldC)
{
    __shared__ float As[16][132];
    __shared__ float Bs[16][132];
    int tid = threadIdx.x;
    int bm = blockIdx.y * 128;
    int bn = blockIdx.x * 128;
    int tx = tid & 15, ty = tid >> 4;

    int ar = tid >> 1;
    int ac = (tid & 1) * 8;
    int br = tid >> 4;
    int bc = (tid & 15) * 8;

    float acc[8][8] = {};
    int gar = bm + ar;
    const float* Arow = A + (size_t)gar * K;

    for (int k0 = 0; k0 < K; k0 += 16) {
#pragma unroll
        for (int c = 0; c < 8; ++c) {
            int gc = k0 + ac + c;
            As[ac + c][ar] = (gar < M && gc < K) ? Arow[gc] : 0.f;
        }
#pragma unroll
        for (int c = 0; c < 8; ++c) {
            int gr = k0 + br;
            int gc = bn + bc + c;
            Bs[br][bc + c] = (gr < K && gc < N) ? B[(size_t)gr * N + gc] : 0.f;
        }
        __syncthreads();
#pragma unroll
        for (int kk = 0; kk < 16; ++kk) {
            float a[8], b[8];
#pragma unroll
            for (int i = 0; i < 8; ++i) a[i] = As[kk][ty * 8 + i];
#pragma unroll
            for (int j = 0; j < 8; ++j) b[j] = Bs[kk][tx * 8 + j];
#pragma unroll
            for (int i = 0; i < 8; ++i)
#pragma unroll
                for (int j = 0; j < 8; ++j)
                    acc[i][j] += a[i] * b[j];
        }
        __syncthreads();
    }
#pragma unroll
    for (int i = 0; i < 8; ++i) {
        int gr = bm + ty * 8 + i;
        if (gr >= M) continue;
#pragma unroll
        for (int j = 0; j < 8; ++j) {
            int gc = bn + tx * 8 + j;
            if (gc >= N) continue;
            float v = acc[i][j];
            if (bias) v += bias[gc];
            if (ACT == 1) v = v > 0.f ? v : 0.f;
            else if (ACT == 2) v = v > 0.f ? v : expm1f(v);
            C[(size_t)gr * ldC + gc] = v;
        }
    }
}

// ---------------------------------------------------------------------------
// bf16 cast helpers for MFMA GEMM
// ---------------------------------------------------------------------------
__global__ void cast_a_kernel(const float* __restrict__ in, __hip_bfloat16* __restrict__ out,
                              int M, int K, int Kp)
{
    int idx = blockIdx.x * 256 + threadIdx.x;
    if (idx >= M * Kp) return;
    int r = idx / Kp, k = idx - r * Kp;
    out[idx] = __float2bfloat16(k < K ? in[(size_t)r * K + k] : 0.f);
}

// out[n][k] ([Npad][Kp] bf16) = in[k][n] ([K][N] f32), zero-padded.
__global__ __launch_bounds__(256) void transpose_cast_kernel(
    const float* __restrict__ in, __hip_bfloat16* __restrict__ out,
    int K, int N, int Kp, int Npad)
{
    __shared__ float tile[32][33];
    int k0 = blockIdx.x * 32;
    int n0 = blockIdx.y * 32;
    int tx = threadIdx.x & 31;
    int ty = threadIdx.x >> 5;   // 0..7
#pragma unroll
    for (int j = 0; j < 4; ++j) {
        int k = k0 + ty + j * 8, n = n0 + tx;
        tile[ty + j * 8][tx] = (k < K && n < N) ? in[(size_t)k * N + n] : 0.f;
    }
    __syncthreads();
#pragma unroll
    for (int j = 0; j < 4; ++j) {
        int n = n0 + ty + j * 8, k = k0 + tx;
        if (n < Npad && k < Kp)
            out[(size_t)n * Kp + k] = __float2bfloat16(tile[tx][ty + j * 8]);
    }
}

// ---------------------------------------------------------------------------
// MFMA bf16 GEMM: C[M,N] = A[M,Kp] @ Bt[N,Kp]^T  (both operands k-contiguous)
// 128x128 tile, BK=64, 4 waves x (4x4) 16x16x32 fragments, double-buffered
// LDS with global_load_lds(16B) staging, XOR-swizzled (slot ^= row&7).
// ---------------------------------------------------------------------------
__device__ __forceinline__ void stage_tile(
    const __hip_bfloat16* __restrict__ gA,   // A + bm*Kp + k0
    const __hip_bfloat16* __restrict__ gB,   // Bt + bn*Kp + k0
    short* ldsbuf, int Kp, int w, int l)
{
#pragma unroll
    for (int j = 0; j < 4; ++j) {
        int u = (w * 4 + j) * 64 + l;          // 16B-slot index in tile
        int r = u >> 3, s = u & 7;
        const __hip_bfloat16* src = gA + (size_t)r * Kp + ((s ^ (r & 7)) << 3);
        __builtin_amdgcn_global_load_lds(
            (const __attribute__((address_space(1))) void*)src,
            (__attribute__((address_space(3))) void*)(ldsbuf + (w * 4 + j) * 512),
            16, 0, 0);
    }
#pragma unroll
    for (int j = 0; j < 4; ++j) {
        int u = (w * 4 + j) * 64 + l;
        int r = u >> 3, s = u & 7;
        const __hip_bfloat16* src = gB + (size_t)r * Kp + ((s ^ (r & 7)) << 3);
        __builtin_amdgcn_global_load_lds(
            (const __attribute__((address_space(1))) void*)src,
            (__attribute__((address_space(3))) void*)(ldsbuf + 8192 + (w * 4 + j) * 512),
            16, 0, 0);
    }
}

__global__ __launch_bounds__(256, 2) void gemm_mfma_bf16(
    const __hip_bfloat16* __restrict__ A,   // [M][Kp]
    const __hip_bfloat16* __restrict__ Bt,  // [Npad][Kp]
    float* __restrict__ C, int M, int N, int Kp, int ldC)
{
    __shared__ __align__(16) short lds[2][16384];   // 2 x (A 16KB + B 16KB)
    const int tid = threadIdx.x;
    const int w = tid >> 6, l = tid & 63;
    const int bm = blockIdx.y * 128, bn = blockIdx.x * 128;
    const int wr = w >> 1, wc = w & 1;
    const int lane15 = l & 15, lhi = l >> 4;

    const __hip_bfloat16* gA = A + (size_t)bm * Kp;
    const __hip_bfloat16* gB = Bt + (size_t)bn * Kp;

    f32x4 acc[4][4] = {};

    const int nk = Kp >> 6;
    stage_tile(gA, gB, &lds[0][0], Kp, w, l);
    __syncthreads();
    int cur = 0;
    for (int t = 0; t < nk; ++t) {
        if (t + 1 < nk)
            stage_tile(gA + (t + 1) * 64, gB + (t + 1) * 64, &lds[cur ^ 1][0], Kp, w, l);
        const short* bA = &lds[cur][0];
        const short* bB = &lds[cur][8192];
#pragma unroll
        for (int ks = 0; ks < 2; ++ks) {
            bf16x8 af[4], bfr[4];
#pragma unroll
            for (int m = 0; m < 4; ++m) {
                int r = wr * 64 + m * 16 + lane15;
                int slot = (ks * 4 + lhi) ^ (r & 7);
                af[m] = *(const bf16x8*)(bA + r * 64 + slot * 8);
            }
#pragma unroll
            for (int n = 0; n < 4; ++n) {
                int r = wc * 64 + n * 16 + lane15;
                int slot = (ks * 4 + lhi) ^ (r & 7);
                bfr[n] = *(const bf16x8*)(bB + r * 64 + slot * 8);
            }
#pragma unroll
            for (int m = 0; m < 4; ++m)
#pragma unroll
                for (int n = 0; n < 4; ++n)
                    acc[m][n] = __builtin_amdgcn_mfma_f32_16x16x32_bf16(
                        af[m], bfr[n], acc[m][n], 0, 0, 0);
        }
        __syncthreads();
        cur ^= 1;
    }
    // C/D layout (verified): col = lane&15, row = (lane>>4)*4 + reg
#pragma unroll
    for (int m = 0; m < 4; ++m) {
#pragma unroll
        for (int n = 0; n < 4; ++n) {
            int col = bn + wc * 64 + n * 16 + lane15;
            if (col >= N) continue;
            int row0 = bm + wr * 64 + m * 16 + lhi * 4;
#pragma unroll
            for (int q = 0; q < 4; ++q)
                C[(size_t)(row0 + q) * ldC + col] = acc[m][n][q];
        }
    }
}

// ---------------------------------------------------------------------------
// GAT helpers
// ---------------------------------------------------------------------------
__device__ __forceinline__ unsigned fmap(float f) {
    unsigned u = __float_as_uint(f);
    return (u & 0x80000000u) ? ~u : (u | 0x80000000u);
}
__device__ __forceinline__ float funmap(unsigned u) {
    return (u & 0x80000000u) ? __uint_as_float(u ^ 0x80000000u)
                             : __uint_as_float(~u);
}

__global__ void attn_ab_kernel(const float* __restrict__ lin,
                               const float* __restrict__ att_s,
                               const float* __restrict__ att_d,
                               float* __restrict__ a_s, float* __restrict__ a_d,
                               int H, int F)
{
    int bid = blockIdx.x;           // n*H + h
    int h = bid % H;
    int lane = threadIdx.x;
    const float* row = lin + (size_t)bid * F;
    const float* wsrc = att_s + h * F;
    const float* wdst = att_d + h * F;
    float ss = 0.f, sd = 0.f;
    for (int f = lane; f < F; f += 64) {
        float v = row[f];
        ss += v * wsrc[f];
        sd += v * wdst[f];
    }
    for (int o = 32; o; o >>= 1) {
        ss += __shfl_down(ss, o);
        sd += __shfl_down(sd, o);
    }
    if (lane == 0) { a_s[bid] = ss; a_d[bid] = sd; }
}

__global__ void edge_max_kernel(const int* __restrict__ ei,
                                const float* __restrict__ a_s,
                                const float* __restrict__ a_d,
                                float* __restrict__ eval,
                                unsigned* __restrict__ mmax,
                                int E, int Etot, int H)
{
    int t = blockIdx.x * blockDim.x + threadIdx.x;
    if (t >= Etot * H) return;
    int e = t / H, h = t - e * H;
    int s, d;
    if (e < E) { s = ei[e]; d = ei[E + e]; } else { s = d = e - E; }
    float v = a_s[s * H + h] + a_d[d * H + h];
    v = v > 0.f ? v : 0.2f * v;
    eval[t] = v;
    atomicMax(&mmax[d * H + h], fmap(v));
}

__global__ void edge_exp_kernel(const int* __restrict__ ei,
                                const unsigned* __restrict__ mmax,
                                float* __restrict__ eval,
                                float* __restrict__ denom,
                                int E, int Etot, int H)
{
    int t = blockIdx.x * blockDim.x + threadIdx.x;
    if (t >= Etot * H) return;
    int e = t / H, h = t - e * H;
    int d = (e < E) ? ei[E + e] : e - E;
    float m = funmap(mmax[d * H + h]);
    float ex = expf(eval[t] - m);
    eval[t] = ex;
    atomicAdd(&denom[d * H + h], ex);
}

__global__ __launch_bounds__(256) void edge_scatter_kernel(
    const int* __restrict__ ei, const float* __restrict__ eval,
    const float* __restrict__ denom, const float* __restrict__ lin,
    float* __restrict__ out, int E, int Etot, int H, int F)
{
    __shared__ float s_alpha[16];
    int e = blockIdx.x;
    int s, d;
    if (e < E) { s = ei[e]; d = ei[E + e]; } else { s = d = e - E; }
    int tid = threadIdx.x;
    if (tid < H) s_alpha[tid] = eval[e * H + tid] / (denom[d * H + tid] + 1e-16f);
    __syncthreads();
    int Ft = H * F;
    const float* srow = lin + (size_t)s * Ft;
    float* drow = out + (size_t)d * Ft;
    for (int c = tid; c < Ft; c += 256) {
        int h = c / F;
        atomicAdd(&drow[c], s_alpha[h] * srow[c]);
    }
}

template<int ACT>
__global__ void bias_act_kernel(float* __restrict__ x, const float* __restrict__ b,
                                int total, int C)
{
    int t = blockIdx.x * blockDim.x + threadIdx.x;
    if (t >= total) return;
    int c = t % C;
    float v = x[t] + b[c];
    if (ACT == 1) v = v > 0.f ? v : 0.f;
    else if (ACT == 2) v = v > 0.f ? v : expm1f(v);
    x[t] = v;
}

__global__ void pool_max_kernel(const float* __restrict__ h, float* __restrict__ g,
                                int B, int per, int C)
{
    int t = blockIdx.x * blockDim.x + threadIdx.x;
    if (t >= B * C) return;
    int b = t / C, f = t - b * C;
    const float* p = h + (size_t)b * per * C + f;
    float m = -INFINITY;
    for (int j = 0; j < per; ++j) m = fmaxf(m, p[(size_t)j * C]);
    g[t] = m;
}

// ---------------------------------------------------------------------------
// CNN branch
// ---------------------------------------------------------------------------
__global__ __launch_bounds__(256) void conv1_fact_kernel(
    const int* __restrict__ target, const float* __restrict__ emb,
    const float* __restrict__ w, const float* __restrict__ b,
    float* __restrict__ y)
{
    __shared__ float s_emb[VOCAB * EMB];
    __shared__ float s_S[VOCAB * 256];
    __shared__ int   s_trow[1000];
    int tid = threadIdx.x;
    int n = blockIdx.x;
    for (int i = tid; i < VOCAB * EMB; i += 256) s_emb[i] = emb[i];
    for (int i = tid; i < VOCAB * 256; i += 256) s_S[i] = 0.f;
    for (int i = tid; i < 1000; i += 256) s_trow[i] = target[n * 1000 + i];
    __syncthreads();
    {
        const float* wcol = w + (size_t)(tid >> 3) * 8000 + (tid & 7);
        for (int i = 0; i < 1000; i += 4) {
            int v0 = s_trow[i + 0], v1 = s_trow[i + 1];
            int v2 = s_trow[i + 2], v3 = s_trow[i + 3];
            float w0 = wcol[(i + 0) * 8];
            float w1 = wcol[(i + 1) * 8];
            float w2 = wcol[(i + 2) * 8];
            float w3 = wcol[(i + 3) * 8];
            s_S[v0 * 256 + tid] += w0;
            s_S[v1 * 256 + tid] += w1;
            s_S[v2 * 256 + tid] += w2;
            s_S[v3 * 256 + tid] += w3;
        }
    }
    __syncthreads();
    for (int idx = tid; idx < 32 * 121; idx += 256) {
        int o = idx / 121, t = idx - o * 121;
        float acc = b[o];
#pragma unroll
        for (int v = 0; v < VOCAB; ++v) {
            const float* Sv = s_S + v * 256 + o * 8;
            const float* ev = s_emb + v * EMB + t;
#pragma unroll
            for (int k = 0; k < 8; ++k) acc += Sv[k] * ev[k];
        }
        y[((size_t)n * 32 + o) * 121 + t] = acc > 0.f ? acc : 0.f;
    }
}

template<int Ci>
__global__ void conv_kernel(const float* __restrict__ x, const float* __restrict__ w,
                            const float* __restrict__ b, float* __restrict__ y,
                            int Co, int Lin, int Lout)
{
    int idx = blockIdx.x * blockDim.x + threadIdx.x;
    int total = NB * Co * Lout;
    if (idx >= total) return;
    int t = idx % Lout;
    int rest = idx / Lout;
    int o = rest % Co;
    int n = rest / Co;
    const float* xr = x + ((size_t)n * Ci) * Lin + t;
    const float* wr = w + (size_t)o * Ci * 8;
    float acc = b[o];
#pragma unroll 4
    for (int i = 0; i < Ci; ++i) {
        const float* xi = xr + (size_t)i * Lin;
        const float4* wv = (const float4*)(wr + i * 8);
        float4 w0 = wv[0], w1 = wv[1];
        acc += xi[0] * w0.x + xi[1] * w0.y + xi[2] * w0.z + xi[3] * w0.w
             + xi[4] * w1.x + xi[5] * w1.y + xi[6] * w1.z + xi[7] * w1.w;
    }
    y[idx] = acc > 0.f ? acc : 0.f;
}

__global__ void pool3_kernel(const float* __restrict__ x, float* __restrict__ y)
{
    int idx = blockIdx.x * blockDim.x + threadIdx.x;
    if (idx >= NB * 128 * 33) return;
    int t = idx % 33;
    int rest = idx / 33;
    int c = rest % 128;
    int n = rest / 128;
    const float* p = x + ((size_t)n * 128 + c) * 100 + t * 3;
    y[idx] = fmaxf(fmaxf(p[0], p[1]), p[2]);
}

// ---------------------------------------------------------------------------
// Host-side launch
// ---------------------------------------------------------------------------
extern "C" void kernel_launch(void* const* d_in, const int* in_sizes, int n_in,
                              void* d_out, int out_size, void* d_ws, size_t ws_size,
                              hipStream_t stream)
{
    const float* x      = (const float*)d_in[0];
    const int*   ei     = (const int*)d_in[1];
    const int*   target = (const int*)d_in[3];
    const float* W1  = (const float*)d_in[4];
    const float* as1 = (const float*)d_in[5];
    const float* ad1 = (const float*)d_in[6];
    const float* b1  = (const float*)d_in[7];
    const float* W2  = (const float*)d_in[8];
    const float* as2 = (const float*)d_in[9];
    const float* ad2 = (const float*)d_in[10];
    const float* b2  = (const float*)d_in[11];
    const float* W3  = (const float*)d_in[12];
    const float* as3 = (const float*)d_in[13];
    const float* ad3 = (const float*)d_in[14];
    const float* b3  = (const float*)d_in[15];
    const float* fc_g1_w = (const float*)d_in[16];
    const float* fc_g1_b = (const float*)d_in[17];
    const float* fc_g2_w = (const float*)d_in[18];
    const float* fc_g2_b = (const float*)d_in[19];
    const float* emb_xt  = (const float*)d_in[20];
    const float* cw1 = (const float*)d_in[21];
    const float* cb1 = (const float*)d_in[22];
    const float* cw2 = (const float*)d_in[23];
    const float* cb2 = (const float*)d_in[24];
    const float* cw3 = (const float*)d_in[25];
    const float* cb3 = (const float*)d_in[26];
    const float* cw4 = (const float*)d_in[27];
    const float* cb4 = (const float*)d_in[28];
    const float* fc1_xt_w = (const float*)d_in[29];
    const float* fc1_xt_b = (const float*)d_in[30];
    const float* fc2_xt_w = (const float*)d_in[31];
    const float* fc2_xt_b = (const float*)d_in[32];
    const float* fc1_w = (const float*)d_in[33];
    const float* fc1_b = (const float*)d_in[34];
    const float* fc2_w = (const float*)d_in[35];
    const float* fc2_b = (const float*)d_in[36];
    const float* out_w = (const float*)d_in[37];
    const float* out_b = (const float*)d_in[38];
    float* out = (float*)d_out;

    const int N = NNODES, E = NEDGES, Etot = E + N;

    // ---- workspace carve (identical footprint to the known-good R2 layout) ----
    char* ws = (char*)d_ws;
    size_t off = 0;
    auto alloc = [&](size_t bytes) -> char* {
        char* p = ws + off;
        off = (off + bytes + 255) & ~(size_t)255;
        return p;
    };
    const size_t BIG = (size_t)N * 3120 * sizeof(float);   // 127.8 MB
    float*    bufA  = (float*)alloc(BIG);   // lin1/lin2/lin3, then CNN scratch
    float*    bufB  = (float*)alloc(BIG);   // out1/out2/out3 (+ bf16 staging up top)
    float*    a_s   = (float*)alloc((size_t)N * 10 * 4);
    float*    a_d   = (float*)alloc((size_t)N * 10 * 4);
    unsigned* mmax  = (unsigned*)alloc((size_t)N * 10 * 4);
    float*    denom = (float*)alloc((size_t)N * 10 * 4);
    float*    eval  = (float*)alloc((size_t)Etot * 10 * 4);
    float*    gbuf  = (float*)alloc((size_t)NB * 3120 * 4);
    float*    g1    = (float*)alloc((size_t)NB * 1024 * 4);
    float*    xt1   = (float*)alloc((size_t)NB * 1024 * 4);
    float*    xc    = (float*)alloc((size_t)NB * 256 * 4);
    float*    f1    = (float*)alloc((size_t)NB * 1024 * 4);
    float*    f2    = (float*)alloc((size_t)NB * 256 * 4);

    // bf16 staging lives INSIDE bufB's upper region (no extra ws):
    __hip_bfloat16* Ab = (__hip_bfloat16*)((char*)bufB + (size_t)64 * 1024 * 1024);
    __hip_bfloat16* Wt = (__hip_bfloat16*)((char*)bufB + (size_t)100 * 1024 * 1024);
    // split-K partial accumulator (1 MB) in bufB's low region (bufB is dead
    // once pool_max has consumed it; head GEMMs all run after that).
    float* Ptmp = bufB;

    // CNN scratch carved from bufA (dead after GAT layer 3 scatter):
    char* cnn = (char*)bufA;
    float* c1 = (float*)cnn;                       cnn += (size_t)NB * 32 * 121 * 4 + 256;
    float* c2 = (float*)cnn;                       cnn += (size_t)NB * 64 * 114 * 4 + 256;
    float* c3 = (float*)cnn;                       cnn += (size_t)NB * 96 * 107 * 4 + 256;
    float* c4 = (float*)cnn;                       cnn += (size_t)NB * 128 * 100 * 4 + 256;
    float* xt = (float*)cnn;                       cnn += (size_t)NB * 4224 * 4 + 256;

    // ---- split-K head GEMM: C[M,N](ldC) = act(A@B + bias) ----
    auto head_gemm = [&](const float* A, const float* B, const float* bias, float* C,
                         int M, int Nc, int K, int ldC, int act, int S) {
        hipMemsetAsync(Ptmp, 0, (size_t)M * Nc * 4, stream);
        int kchunk = (K + S - 1) / S;
        dim3 g((Nc + 63) / 64, (M + 63) / 64, S);
        gemm_f32_splitk<<<g, 256, 0, stream>>>(A, B, Ptmp, M, Nc, K, kchunk);
        int tot = M * Nc;
        if (act == 1)
            bias_act_ld_kernel<1><<<(tot + 255) / 256, 256, 0, stream>>>(Ptmp, bias, C, M, Nc, ldC);
        else
            bias_act_ld_kernel<0><<<(tot + 255) / 256, 256, 0, stream>>>(Ptmp, bias, C, M, Nc, ldC);
    };

    // ---- GAT softmax/scatter chain (shared by all layers) ----
    auto gat_tail = [&](const float* atts, const float* attd, const float* bias,
                        int H, int F, int act, float* lin, float* outb) {
        int Ft = H * F;
        attn_ab_kernel<<<N * H, 64, 0, stream>>>(lin, atts, attd, a_s, a_d, H, F);
        hipMemsetAsync(mmax, 0, (size_t)N * H * 4, stream);
        hipMemsetAsync(denom, 0, (size_t)N * H * 4, stream);
        hipMemsetAsync(outb, 0, (size_t)N * Ft * 4, stream);
        int tot = Etot * H;
        edge_max_kernel<<<(tot + 255) / 256, 256, 0, stream>>>(ei, a_s, a_d, eval, mmax, E, Etot, H);
        edge_exp_kernel<<<(tot + 255) / 256, 256, 0, stream>>>(ei, mmax, eval, denom, E, Etot, H);
        edge_scatter_kernel<<<Etot, 256, 0, stream>>>(ei, eval, denom, lin, outb, E, Etot, H, F);
        int total = N * Ft;
        if (act == 1)
            bias_act_kernel<1><<<(total + 255) / 256, 256, 0, stream>>>(outb, bias, total, Ft);
        else
            bias_act_kernel<2><<<(total + 255) / 256, 256, 0, stream>>>(outb, bias, total, Ft);
    };

    // ---- layer 1: f32 GEMM (keep full precision; cheap K=78) ----
    {
        dim3 gg((780 + 127) / 128, (N + 127) / 128);
        gemm_f32_big<0><<<gg, 256, 0, stream>>>(x, W1, nullptr, bufA, N, 780, 78, 780);
        gat_tail(as1, ad1, b1, 10, 78, 2, bufA, bufB);
    }
    // ---- layer 2: bf16 MFMA GEMM (K=780->832, N=1560->1664) ----
    {
        const int K = 780, Kp = 832, Nout = 1560, Npad = 1664;
        cast_a_kernel<<<(N * Kp + 255) / 256, 256, 0, stream>>>(bufB, Ab, N, K, Kp);
        transpose_cast_kernel<<<dim3(Kp / 32, Npad / 32), 256, 0, stream>>>(W2, Wt, K, Nout, Kp, Npad);
        gemm_mfma_bf16<<<dim3(Npad / 128, N / 128), 256, 0, stream>>>(Ab, Wt, bufA, N, Nout, Kp, Nout);
        gat_tail(as2, ad2, b2, 2, 780, 1, bufA, bufB);
    }
    // ---- layer 3: bf16 MFMA GEMM (K=1560->1600, N=3120->3200) ----
    {
        const int K = 1560, Kp = 1600, Nout = 3120, Npad = 3200;
        cast_a_kernel<<<(N * Kp + 255) / 256, 256, 0, stream>>>(bufB, Ab, N, K, Kp);
        transpose_cast_kernel<<<dim3(Kp / 32, Npad / 32), 256, 0, stream>>>(W3, Wt, K, Nout, Kp, Npad);
        gemm_mfma_bf16<<<dim3(Npad / 128, N / 128), 256, 0, stream>>>(Ab, Wt, bufA, N, Nout, Kp, Nout);
        gat_tail(as3, ad3, b3, 1, 3120, 1, bufA, bufB);
    }

    // global max pool (40 consecutive nodes per graph) + graph FCs
    {
        int tot = NB * 3120;
        pool_max_kernel<<<(tot + 255) / 256, 256, 0, stream>>>(bufB, gbuf, NB, N / NB, 3120);
        head_gemm(gbuf, fc_g1_w, fc_g1_b, g1, NB, 1024, 3120, 1024, 1, 16);
        head_gemm(g1, fc_g2_w, fc_g2_b, xc, NB, 128, 1024, 256, 0, 32);
    }

    // ---- CNN branch (bufA is dead now; c1..xt live inside it) ----
    {
        conv1_fact_kernel<<<NB, 256, 0, stream>>>(target, emb_xt, cw1, cb1, c1);
        int t2 = NB * 64 * 114;
        conv_kernel<32><<<(t2 + 255) / 256, 256, 0, stream>>>(c1, cw2, cb2, c2, 64, 121, 114);
        int t3 = NB * 96 * 107;
        conv_kernel<64><<<(t3 + 255) / 256, 256, 0, stream>>>(c2, cw3, cb3, c3, 96, 114, 107);
        int t4 = NB * 128 * 100;
        conv_kernel<96><<<(t4 + 255) / 256, 256, 0, stream>>>(c3, cw4, cb4, c4, 128, 107, 100);
        int tp = NB * 128 * 33;
        pool3_kernel<<<(tp + 255) / 256, 256, 0, stream>>>(c4, xt);
        head_gemm(xt, fc1_xt_w, fc1_xt_b, xt1, NB, 1024, 4224, 1024, 1, 16);
        head_gemm(xt1, fc2_xt_w, fc2_xt_b, xc + 128, NB, 128, 1024, 256, 0, 32);
    }

    // ---- fusion head ----
    {
        head_gemm(xc, fc1_w, fc1_b, f1, NB, 1024, 256, 1024, 1, 8);
        head_gemm(f1, fc2_w, fc2_b, f2, NB, 256, 1024, 256, 1, 16);
        out_head_kernel<<<1, 256, 0, stream>>>(f2, out_w, out_b, out);
    }
}

// Round 6
// 2602.309 us; speedup vs baseline: 4.0690x; 1.1236x over previous
//
#include <hip/hip_runtime.h>
#include <hip/hip_bf16.h>
#include <math.h>

// ---------------------------------------------------------------------------
// Constants (problem-fixed)
// ---------------------------------------------------------------------------
static const int NNODES = 10240;
static const int NEDGES = 40960;
static const int NB     = 256;     // graphs / batch
static const int VOCAB  = 26;
static const int EMB    = 128;

typedef short bf16x8 __attribute__((ext_vector_type(8)));   // 8 bf16 (4 VGPRs)
typedef float f32x4  __attribute__((ext_vector_type(4)));   // 4 fp32

// ---------------------------------------------------------------------------
// Split-K f32 GEMM for skinny-M head GEMMs. Partials atomicAdd'ed into P[M][N]
// (pre-zeroed). LDS padded [16][65] -> conflict-free A-tile store.
// ---------------------------------------------------------------------------
__global__ __launch_bounds__(256) void gemm_f32_splitk(
    const float* __restrict__ A, const float* __restrict__ B,
    float* __restrict__ P, int M, int N, int K, int kchunk)
{
    __shared__ float As[16][65];
    __shared__ float Bs[16][65];
    int tid = threadIdx.x;
    int bm = blockIdx.y * 64;
    int bn = blockIdx.x * 64;
    int k0 = blockIdx.z * kchunk;
    int k1 = min(k0 + kchunk, K);
    int tx = tid & 15, ty = tid >> 4;
    float acc[4][4] = {};
    for (int kb = k0; kb < k1; kb += 16) {
#pragma unroll
        for (int l = 0; l < 4; ++l) {
            int idx = tid + l * 256;
            int r = idx >> 4, c = idx & 15;
            int gr = bm + r, gc = kb + c;
            As[c][r] = (gr < M && gc < k1) ? A[(size_t)gr * K + gc] : 0.f;
        }
#pragma unroll
        for (int l = 0; l < 4; ++l) {
            int idx = tid + l * 256;
            int r = idx >> 6, c = idx & 63;
            int gr = kb + r, gc = bn + c;
            Bs[r][c] = (gr < k1 && gc < N) ? B[(size_t)gr * N + gc] : 0.f;
        }
        __syncthreads();
#pragma unroll
        for (int kk = 0; kk < 16; ++kk) {
            float a[4], b[4];
#pragma unroll
            for (int i = 0; i < 4; ++i) a[i] = As[kk][ty * 4 + i];
#pragma unroll
            for (int j = 0; j < 4; ++j) b[j] = Bs[kk][tx * 4 + j];
#pragma unroll
            for (int i = 0; i < 4; ++i)
#pragma unroll
                for (int j = 0; j < 4; ++j)
                    acc[i][j] += a[i] * b[j];
        }
        __syncthreads();
    }
#pragma unroll
    for (int i = 0; i < 4; ++i) {
        int gr = bm + ty * 4 + i;
        if (gr >= M) continue;
#pragma unroll
        for (int j = 0; j < 4; ++j) {
            int gc = bn + tx * 4 + j;
            if (gc >= N) continue;
            atomicAdd(&P[(size_t)gr * N + gc], acc[i][j]);
        }
    }
}

// C[r*ldC+c] = act(P[r*N+c] + bias[c])
template<int ACT>
__global__ void bias_act_ld_kernel(const float* __restrict__ P,
                                   const float* __restrict__ bias,
                                   float* __restrict__ C, int M, int N, int ldC)
{
    int t = blockIdx.x * 256 + threadIdx.x;
    if (t >= M * N) return;
    int r = t / N, c = t - r * N;
    float v = P[t] + bias[c];
    if (ACT == 1) v = fmaxf(v, 0.f);
    C[(size_t)r * ldC + c] = v;
}

// final 256x1 projection: out[r] = dot(f2[r,:], w) + b
__global__ void out_head_kernel(const float* __restrict__ f2,
                                const float* __restrict__ w,
                                const float* __restrict__ b,
                                float* __restrict__ out)
{
    __shared__ float sw[256];
    int t = threadIdx.x;
    sw[t] = w[t];
    __syncthreads();
    float acc = 0.f;
    const float* row = f2 + (size_t)t * 256;
    for (int k = 0; k < 256; ++k) acc += row[k] * sw[k];
    out[t] = acc + b[0];
}

// ---------------------------------------------------------------------------
// Big tiled f32 GEMM (128x128 tile, BK=16, 8x8 micro): used for lin1 only.
// ---------------------------------------------------------------------------
template<int ACT>
__global__ __launch_bounds__(256) void gemm_f32_big(
    const float* __restrict__ A, const float* __restrict__ B,
    const float* __restrict__ bias, float* __restrict__ C,
    int M, int N, int K, int ldC)
{
    __shared__ float As[16][132];
    __shared__ float Bs[16][132];
    int tid = threadIdx.x;
    int bm = blockIdx.y * 128;
    int bn = blockIdx.x * 128;
    int tx = tid & 15, ty = tid >> 4;

    int ar = tid >> 1;
    int ac = (tid & 1) * 8;
    int br = tid >> 4;
    int bc = (tid & 15) * 8;

    float acc[8][8] = {};
    int gar = bm + ar;
    const float* Arow = A + (size_t)gar * K;

    for (int k0 = 0; k0 < K; k0 += 16) {
#pragma unroll
        for (int c = 0; c < 8; ++c) {
            int gc = k0 + ac + c;
            As[ac + c][ar] = (gar < M && gc < K) ? Arow[gc] : 0.f;
        }
#pragma unroll
        for (int c = 0; c < 8; ++c) {
            int gr = k0 + br;
            int gc = bn + bc + c;
            Bs[br][bc + c] = (gr < K && gc < N) ? B[(size_t)gr * N + gc] : 0.f;
        }
        __syncthreads();
#pragma unroll
        for (int kk = 0; kk < 16; ++kk) {
            float a[8], b[8];
#pragma unroll
            for (int i = 0; i < 8; ++i) a[i] = As[kk][ty * 8 + i];
#pragma unroll
            for (int j = 0; j < 8; ++j) b[j] = Bs[kk][tx * 8 + j];
#pragma unroll
            for (int i = 0; i < 8; ++i)
#pragma unroll
                for (int j = 0; j < 8; ++j)
                    acc[i][j] += a[i] * b[j];
        }
        __syncthreads();
    }
#pragma unroll
    for (int i = 0; i < 8; ++i) {
        int gr = bm + ty * 8 + i;
        if (gr >= M) continue;
#pragma unroll
        for (int j = 0; j < 8; ++j) {
            int gc = bn + tx * 8 + j;
            if (gc >= N) continue;
            float v = acc[i][j];
            if (bias) v += bias[gc];
            if (ACT == 1) v = v > 0.f ? v : 0.f;
            else if (ACT == 2) v = v > 0.f ? v : expm1f(v);
            C[(size_t)gr * ldC + gc] = v;
        }
    }
}

// ---------------------------------------------------------------------------
// bf16 cast helpers for MFMA GEMM
// ---------------------------------------------------------------------------
__global__ void cast_a_kernel(const float* __restrict__ in, __hip_bfloat16* __restrict__ out,
                              int M, int K, int Kp)
{
    int idx = blockIdx.x * 256 + threadIdx.x;
    if (idx >= M * Kp) return;
    int r = idx / Kp, k = idx - r * Kp;
    out[idx] = __float2bfloat16(k < K ? in[(size_t)r * K + k] : 0.f);
}

// out[n][k] ([Npad][Kp] bf16) = in[k][n] ([K][N] f32), zero-padded.
__global__ __launch_bounds__(256) void transpose_cast_kernel(
    const float* __restrict__ in, __hip_bfloat16* __restrict__ out,
    int K, int N, int Kp, int Npad)
{
    __shared__ float tile[32][33];
    int k0 = blockIdx.x * 32;
    int n0 = blockIdx.y * 32;
    int tx = threadIdx.x & 31;
    int ty = threadIdx.x >> 5;   // 0..7
#pragma unroll
    for (int j = 0; j < 4; ++j) {
        int k = k0 + ty + j * 8, n = n0 + tx;
        tile[ty + j * 8][tx] = (k < K && n < N) ? in[(size_t)k * N + n] : 0.f;
    }
    __syncthreads();
#pragma unroll
    for (int j = 0; j < 4; ++j) {
        int n = n0 + ty + j * 8, k = k0 + tx;
        if (n < Npad && k < Kp)
            out[(size_t)n * Kp + k] = __float2bfloat16(tile[tx][ty + j * 8]);
    }
}

// ---------------------------------------------------------------------------
// MFMA bf16 GEMM: C[M,N] = A[M,Kp] @ Bt[N,Kp]^T  (both operands k-contiguous)
// 128x128 tile, BK=64, 4 waves x (4x4) 16x16x32 fragments, double-buffered
// LDS with global_load_lds(16B) staging, XOR-swizzled (slot ^= row&7).
// ---------------------------------------------------------------------------
__device__ __forceinline__ void stage_tile(
    const __hip_bfloat16* __restrict__ gA,   // A + bm*Kp + k0
    const __hip_bfloat16* __restrict__ gB,   // Bt + bn*Kp + k0
    short* ldsbuf, int Kp, int w, int l)
{
#pragma unroll
    for (int j = 0; j < 4; ++j) {
        int u = (w * 4 + j) * 64 + l;          // 16B-slot index in tile
        int r = u >> 3, s = u & 7;
        const __hip_bfloat16* src = gA + (size_t)r * Kp + ((s ^ (r & 7)) << 3);
        __builtin_amdgcn_global_load_lds(
            (const __attribute__((address_space(1))) void*)src,
            (__attribute__((address_space(3))) void*)(ldsbuf + (w * 4 + j) * 512),
            16, 0, 0);
    }
#pragma unroll
    for (int j = 0; j < 4; ++j) {
        int u = (w * 4 + j) * 64 + l;
        int r = u >> 3, s = u & 7;
        const __hip_bfloat16* src = gB + (size_t)r * Kp + ((s ^ (r & 7)) << 3);
        __builtin_amdgcn_global_load_lds(
            (const __attribute__((address_space(1))) void*)src,
            (__attribute__((address_space(3))) void*)(ldsbuf + 8192 + (w * 4 + j) * 512),
            16, 0, 0);
    }
}

__global__ __launch_bounds__(256, 2) void gemm_mfma_bf16(
    const __hip_bfloat16* __restrict__ A,   // [M][Kp]
    const __hip_bfloat16* __restrict__ Bt,  // [Npad][Kp]
    float* __restrict__ C, int M, int N, int Kp, int ldC)
{
    __shared__ __align__(16) short lds[2][16384];   // 2 x (A 16KB + B 16KB)
    const int tid = threadIdx.x;
    const int w = tid >> 6, l = tid & 63;
    const int bm = blockIdx.y * 128, bn = blockIdx.x * 128;
    const int wr = w >> 1, wc = w & 1;
    const int lane15 = l & 15, lhi = l >> 4;

    const __hip_bfloat16* gA = A + (size_t)bm * Kp;
    const __hip_bfloat16* gB = Bt + (size_t)bn * Kp;

    f32x4 acc[4][4] = {};

    const int nk = Kp >> 6;
    stage_tile(gA, gB, &lds[0][0], Kp, w, l);
    __syncthreads();
    int cur = 0;
    for (int t = 0; t < nk; ++t) {
        if (t + 1 < nk)
            stage_tile(gA + (t + 1) * 64, gB + (t + 1) * 64, &lds[cur ^ 1][0], Kp, w, l);
        const short* bA = &lds[cur][0];
        const short* bB = &lds[cur][8192];
#pragma unroll
        for (int ks = 0; ks < 2; ++ks) {
            bf16x8 af[4], bfr[4];
#pragma unroll
            for (int m = 0; m < 4; ++m) {
                int r = wr * 64 + m * 16 + lane15;
                int slot = (ks * 4 + lhi) ^ (r & 7);
                af[m] = *(const bf16x8*)(bA + r * 64 + slot * 8);
            }
#pragma unroll
            for (int n = 0; n < 4; ++n) {
                int r = wc * 64 + n * 16 + lane15;
                int slot = (ks * 4 + lhi) ^ (r & 7);
                bfr[n] = *(const bf16x8*)(bB + r * 64 + slot * 8);
            }
#pragma unroll
            for (int m = 0; m < 4; ++m)
#pragma unroll
                for (int n = 0; n < 4; ++n)
                    acc[m][n] = __builtin_amdgcn_mfma_f32_16x16x32_bf16(
                        af[m], bfr[n], acc[m][n], 0, 0, 0);
        }
        __syncthreads();
        cur ^= 1;
    }
    // C/D layout (verified): col = lane&15, row = (lane>>4)*4 + reg
#pragma unroll
    for (int m = 0; m < 4; ++m) {
#pragma unroll
        for (int n = 0; n < 4; ++n) {
            int col = bn + wc * 64 + n * 16 + lane15;
            if (col >= N) continue;
            int row0 = bm + wr * 64 + m * 16 + lhi * 4;
#pragma unroll
            for (int q = 0; q < 4; ++q)
                C[(size_t)(row0 + q) * ldC + col] = acc[m][n][q];
        }
    }
}

// ---------------------------------------------------------------------------
// GAT helpers
// ---------------------------------------------------------------------------
__device__ __forceinline__ unsigned fmap(float f) {
    unsigned u = __float_as_uint(f);
    return (u & 0x80000000u) ? ~u : (u | 0x80000000u);
}
__device__ __forceinline__ float funmap(unsigned u) {
    return (u & 0x80000000u) ? __uint_as_float(u ^ 0x80000000u)
                             : __uint_as_float(~u);
}

__global__ void attn_ab_kernel(const float* __restrict__ lin,
                               const float* __restrict__ att_s,
                               const float* __restrict__ att_d,
                               float* __restrict__ a_s, float* __restrict__ a_d,
                               int H, int F)
{
    int bid = blockIdx.x;           // n*H + h
    int h = bid % H;
    int lane = threadIdx.x;
    const float* row = lin + (size_t)bid * F;
    const float* wsrc = att_s + h * F;
    const float* wdst = att_d + h * F;
    float ss = 0.f, sd = 0.f;
    for (int f = lane; f < F; f += 64) {
        float v = row[f];
        ss += v * wsrc[f];
        sd += v * wdst[f];
    }
    for (int o = 32; o; o >>= 1) {
        ss += __shfl_down(ss, o);
        sd += __shfl_down(sd, o);
    }
    if (lane == 0) { a_s[bid] = ss; a_d[bid] = sd; }
}

__global__ void edge_max_kernel(const int* __restrict__ ei,
                                const float* __restrict__ a_s,
                                const float* __restrict__ a_d,
                                float* __restrict__ eval,
                                unsigned* __restrict__ mmax,
                                int E, int Etot, int H)
{
    int t = blockIdx.x * blockDim.x + threadIdx.x;
    if (t >= Etot * H) return;
    int e = t / H, h = t - e * H;
    int s, d;
    if (e < E) { s = ei[e]; d = ei[E + e]; } else { s = d = e - E; }
    float v = a_s[s * H + h] + a_d[d * H + h];
    v = v > 0.f ? v : 0.2f * v;
    eval[t] = v;
    atomicMax(&mmax[d * H + h], fmap(v));
}

__global__ void edge_exp_kernel(const int* __restrict__ ei,
                                const unsigned* __restrict__ mmax,
                                float* __restrict__ eval,
                                float* __restrict__ denom,
                                int E, int Etot, int H)
{
    int t = blockIdx.x * blockDim.x + threadIdx.x;
    if (t >= Etot * H) return;
    int e = t / H, h = t - e * H;
    int d = (e < E) ? ei[E + e] : e - E;
    float m = funmap(mmax[d * H + h]);
    float ex = expf(eval[t] - m);
    eval[t] = ex;
    atomicAdd(&denom[d * H + h], ex);
}

__global__ __launch_bounds__(256) void edge_scatter_kernel(
    const int* __restrict__ ei, const float* __restrict__ eval,
    const float* __restrict__ denom, const float* __restrict__ lin,
    float* __restrict__ out, int E, int Etot, int H, int F)
{
    __shared__ float s_alpha[16];
    int e = blockIdx.x;
    int s, d;
    if (e < E) { s = ei[e]; d = ei[E + e]; } else { s = d = e - E; }
    int tid = threadIdx.x;
    if (tid < H) s_alpha[tid] = eval[e * H + tid] / (denom[d * H + tid] + 1e-16f);
    __syncthreads();
    int Ft = H * F;
    const float* srow = lin + (size_t)s * Ft;
    float* drow = out + (size_t)d * Ft;
    for (int c = tid; c < Ft; c += 256) {
        int h = c / F;
        atomicAdd(&drow[c], s_alpha[h] * srow[c]);
    }
}

template<int ACT>
__global__ void bias_act_kernel(float* __restrict__ x, const float* __restrict__ b,
                                int total, int C)
{
    int t = blockIdx.x * blockDim.x + threadIdx.x;
    if (t >= total) return;
    int c = t % C;
    float v = x[t] + b[c];
    if (ACT == 1) v = v > 0.f ? v : 0.f;
    else if (ACT == 2) v = v > 0.f ? v : expm1f(v);
    x[t] = v;
}

__global__ void pool_max_kernel(const float* __restrict__ h, float* __restrict__ g,
                                int B, int per, int C)
{
    int t = blockIdx.x * blockDim.x + threadIdx.x;
    if (t >= B * C) return;
    int b = t / C, f = t - b * C;
    const float* p = h + (size_t)b * per * C + f;
    float m = -INFINITY;
    for (int j = 0; j < per; ++j) m = fmaxf(m, p[(size_t)j * C]);
    g[t] = m;
}

// ---------------------------------------------------------------------------
// CNN branch
// ---------------------------------------------------------------------------
__global__ __launch_bounds__(256) void conv1_fact_kernel(
    const int* __restrict__ target, const float* __restrict__ emb,
    const float* __restrict__ w, const float* __restrict__ b,
    float* __restrict__ y)
{
    __shared__ float s_emb[VOCAB * EMB];
    __shared__ float s_S[VOCAB * 256];
    __shared__ int   s_trow[1000];
    int tid = threadIdx.x;
    int n = blockIdx.x;
    for (int i = tid; i < VOCAB * EMB; i += 256) s_emb[i] = emb[i];
    for (int i = tid; i < VOCAB * 256; i += 256) s_S[i] = 0.f;
    for (int i = tid; i < 1000; i += 256) s_trow[i] = target[n * 1000 + i];
    __syncthreads();
    {
        const float* wcol = w + (size_t)(tid >> 3) * 8000 + (tid & 7);
        for (int i = 0; i < 1000; i += 4) {
            int v0 = s_trow[i + 0], v1 = s_trow[i + 1];
            int v2 = s_trow[i + 2], v3 = s_trow[i + 3];
            float w0 = wcol[(i + 0) * 8];
            float w1 = wcol[(i + 1) * 8];
            float w2 = wcol[(i + 2) * 8];
            float w3 = wcol[(i + 3) * 8];
            s_S[v0 * 256 + tid] += w0;
            s_S[v1 * 256 + tid] += w1;
            s_S[v2 * 256 + tid] += w2;
            s_S[v3 * 256 + tid] += w3;
        }
    }
    __syncthreads();
    for (int idx = tid; idx < 32 * 121; idx += 256) {
        int o = idx / 121, t = idx - o * 121;
        float acc = b[o];
#pragma unroll
        for (int v = 0; v < VOCAB; ++v) {
            const float* Sv = s_S + v * 256 + o * 8;
            const float* ev = s_emb + v * EMB + t;
#pragma unroll
            for (int k = 0; k < 8; ++k) acc += Sv[k] * ev[k];
        }
        y[((size_t)n * 32 + o) * 121 + t] = acc > 0.f ? acc : 0.f;
    }
}

// t-blocked conv1d (k=8, valid) + relu: each thread computes T consecutive
// outputs for one (n,o). i-outer loop -> 2 float4 w-loads + (T+7) x-loads
// feed T*8 FMAs (vs 10 loads per 8 FMAs in the naive version).
template<int Ci, int T>
__global__ __launch_bounds__(256) void conv_quad_kernel(
    const float* __restrict__ x, const float* __restrict__ w,
    const float* __restrict__ b, float* __restrict__ y,
    int Co, int Lin, int Lout)
{
    int tq = (Lout + T - 1) / T;
    int idx = blockIdx.x * 256 + threadIdx.x;
    int total = NB * Co * tq;
    if (idx >= total) return;
    int q = idx % tq;
    int rest = idx / tq;
    int o = rest % Co;
    int n = rest / Co;
    int t0 = q * T;
    const float* xr = x + ((size_t)n * Ci) * Lin + t0;
    const float* wr = w + (size_t)o * Ci * 8;
    float acc[T] = {};
    if (t0 + T + 7 <= Lin) {
        // full tile: unguarded loads
        for (int i = 0; i < Ci; ++i) {
            const float* xi = xr + (size_t)i * Lin;
            float4 w0 = ((const float4*)(wr + (size_t)i * 8))[0];
            float4 w1 = ((const float4*)(wr + (size_t)i * 8))[1];
            float xv[T + 7];
#pragma unroll
            for (int j = 0; j < T + 7; ++j) xv[j] = xi[j];
#pragma unroll
            for (int d = 0; d < T; ++d)
                acc[d] += xv[d] * w0.x + xv[d+1] * w0.y + xv[d+2] * w0.z + xv[d+3] * w0.w
                        + xv[d+4] * w1.x + xv[d+5] * w1.y + xv[d+6] * w1.z + xv[d+7] * w1.w;
        }
    } else {
        for (int i = 0; i < Ci; ++i) {
            const float* xi = xr + (size_t)i * Lin;
            float4 w0 = ((const float4*)(wr + (size_t)i * 8))[0];
            float4 w1 = ((const float4*)(wr + (size_t)i * 8))[1];
            float xv[T + 7];
#pragma unroll
            for (int j = 0; j < T + 7; ++j) xv[j] = (t0 + j < Lin) ? xi[j] : 0.f;
#pragma unroll
            for (int d = 0; d < T; ++d)
                acc[d] += xv[d] * w0.x + xv[d+1] * w0.y + xv[d+2] * w0.z + xv[d+3] * w0.w
                        + xv[d+4] * w1.x + xv[d+5] * w1.y + xv[d+6] * w1.z + xv[d+7] * w1.w;
        }
    }
    float bb = b[o];
    float* yr = y + ((size_t)n * Co + o) * Lout;
#pragma unroll
    for (int d = 0; d < T; ++d) {
        int t = t0 + d;
        if (t < Lout) yr[t] = fmaxf(acc[d] + bb, 0.f);
    }
}

__global__ void pool3_kernel(const float* __restrict__ x, float* __restrict__ y)
{
    int idx = blockIdx.x * blockDim.x + threadIdx.x;
    if (idx >= NB * 128 * 33) return;
    int t = idx % 33;
    int rest = idx / 33;
    int c = rest % 128;
    int n = rest / 128;
    const float* p = x + ((size_t)n * 128 + c) * 100 + t * 3;
    y[idx] = fmaxf(fmaxf(p[0], p[1]), p[2]);
}

// ---------------------------------------------------------------------------
// Host-side launch
// ---------------------------------------------------------------------------
extern "C" void kernel_launch(void* const* d_in, const int* in_sizes, int n_in,
                              void* d_out, int out_size, void* d_ws, size_t ws_size,
                              hipStream_t stream)
{
    const float* x      = (const float*)d_in[0];
    const int*   ei     = (const int*)d_in[1];
    const int*   target = (const int*)d_in[3];
    const float* W1  = (const float*)d_in[4];
    const float* as1 = (const float*)d_in[5];
    const float* ad1 = (const float*)d_in[6];
    const float* b1  = (const float*)d_in[7];
    const float* W2  = (const float*)d_in[8];
    const float* as2 = (const float*)d_in[9];
    const float* ad2 = (const float*)d_in[10];
    const float* b2  = (const float*)d_in[11];
    const float* W3  = (const float*)d_in[12];
    const float* as3 = (const float*)d_in[13];
    const float* ad3 = (const float*)d_in[14];
    const float* b3  = (const float*)d_in[15];
    const float* fc_g1_w = (const float*)d_in[16];
    const float* fc_g1_b = (const float*)d_in[17];
    const float* fc_g2_w = (const float*)d_in[18];
    const float* fc_g2_b = (const float*)d_in[19];
    const float* emb_xt  = (const float*)d_in[20];
    const float* cw1 = (const float*)d_in[21];
    const float* cb1 = (const float*)d_in[22];
    const float* cw2 = (const float*)d_in[23];
    const float* cb2 = (const float*)d_in[24];
    const float* cw3 = (const float*)d_in[25];
    const float* cb3 = (const float*)d_in[26];
    const float* cw4 = (const float*)d_in[27];
    const float* cb4 = (const float*)d_in[28];
    const float* fc1_xt_w = (const float*)d_in[29];
    const float* fc1_xt_b = (const float*)d_in[30];
    const float* fc2_xt_w = (const float*)d_in[31];
    const float* fc2_xt_b = (const float*)d_in[32];
    const float* fc1_w = (const float*)d_in[33];
    const float* fc1_b = (const float*)d_in[34];
    const float* fc2_w = (const float*)d_in[35];
    const float* fc2_b = (const float*)d_in[36];
    const float* out_w = (const float*)d_in[37];
    const float* out_b = (const float*)d_in[38];
    float* out = (float*)d_out;

    const int N = NNODES, E = NEDGES, Etot = E + N;

    // ---- workspace carve (identical footprint to the known-good R2 layout) ----
    char* ws = (char*)d_ws;
    size_t off = 0;
    auto alloc = [&](size_t bytes) -> char* {
        char* p = ws + off;
        off = (off + bytes + 255) & ~(size_t)255;
        return p;
    };
    const size_t BIG = (size_t)N * 3120 * sizeof(float);   // 127.8 MB
    float*    bufA  = (float*)alloc(BIG);   // lin1/lin2/lin3, then CNN scratch
    float*    bufB  = (float*)alloc(BIG);   // out1/out2/out3 (+ bf16 staging up top)
    float*    a_s   = (float*)alloc((size_t)N * 10 * 4);
    float*    a_d   = (float*)alloc((size_t)N * 10 * 4);
    unsigned* mmax  = (unsigned*)alloc((size_t)N * 10 * 4);
    float*    denom = (float*)alloc((size_t)N * 10 * 4);
    float*    eval  = (float*)alloc((size_t)Etot * 10 * 4);
    float*    gbuf  = (float*)alloc((size_t)NB * 3120 * 4);
    float*    g1    = (float*)alloc((size_t)NB * 1024 * 4);
    float*    xt1   = (float*)alloc((size_t)NB * 1024 * 4);
    float*    xc    = (float*)alloc((size_t)NB * 256 * 4);
    float*    f1    = (float*)alloc((size_t)NB * 1024 * 4);
    float*    f2    = (float*)alloc((size_t)NB * 256 * 4);

    // bf16 staging lives INSIDE bufB's upper region (no extra ws):
    __hip_bfloat16* Ab = (__hip_bfloat16*)((char*)bufB + (size_t)64 * 1024 * 1024);
    __hip_bfloat16* Wt = (__hip_bfloat16*)((char*)bufB + (size_t)100 * 1024 * 1024);
    // split-K partial accumulator (1 MB) in bufB's low region (bufB is dead
    // once pool_max has consumed it; head GEMMs all run after that).
    float* Ptmp = bufB;

    // CNN scratch carved from bufA (dead after GAT layer 3 scatter):
    char* cnn = (char*)bufA;
    float* c1 = (float*)cnn;                       cnn += (size_t)NB * 32 * 121 * 4 + 256;
    float* c2 = (float*)cnn;                       cnn += (size_t)NB * 64 * 114 * 4 + 256;
    float* c3 = (float*)cnn;                       cnn += (size_t)NB * 96 * 107 * 4 + 256;
    float* c4 = (float*)cnn;                       cnn += (size_t)NB * 128 * 100 * 4 + 256;
    float* xt = (float*)cnn;                       cnn += (size_t)NB * 4224 * 4 + 256;

    // ---- split-K head GEMM: C[M,N](ldC) = act(A@B + bias) ----
    auto head_gemm = [&](const float* A, const float* B, const float* bias, float* C,
                         int M, int Nc, int K, int ldC, int act, int S) {
        hipMemsetAsync(Ptmp, 0, (size_t)M * Nc * 4, stream);
        int kchunk = (K + S - 1) / S;
        dim3 g((Nc + 63) / 64, (M + 63) / 64, S);
        gemm_f32_splitk<<<g, 256, 0, stream>>>(A, B, Ptmp, M, Nc, K, kchunk);
        int tot = M * Nc;
        if (act == 1)
            bias_act_ld_kernel<1><<<(tot + 255) / 256, 256, 0, stream>>>(Ptmp, bias, C, M, Nc, ldC);
        else
            bias_act_ld_kernel<0><<<(tot + 255) / 256, 256, 0, stream>>>(Ptmp, bias, C, M, Nc, ldC);
    };

    // ---- GAT softmax/scatter chain (shared by all layers) ----
    auto gat_tail = [&](const float* atts, const float* attd, const float* bias,
                        int H, int F, int act, float* lin, float* outb) {
        int Ft = H * F;
        attn_ab_kernel<<<N * H, 64, 0, stream>>>(lin, atts, attd, a_s, a_d, H, F);
        hipMemsetAsync(mmax, 0, (size_t)N * H * 4, stream);
        hipMemsetAsync(denom, 0, (size_t)N * H * 4, stream);
        hipMemsetAsync(outb, 0, (size_t)N * Ft * 4, stream);
        int tot = Etot * H;
        edge_max_kernel<<<(tot + 255) / 256, 256, 0, stream>>>(ei, a_s, a_d, eval, mmax, E, Etot, H);
        edge_exp_kernel<<<(tot + 255) / 256, 256, 0, stream>>>(ei, mmax, eval, denom, E, Etot, H);
        edge_scatter_kernel<<<Etot, 256, 0, stream>>>(ei, eval, denom, lin, outb, E, Etot, H, F);
        int total = N * Ft;
        if (act == 1)
            bias_act_kernel<1><<<(total + 255) / 256, 256, 0, stream>>>(outb, bias, total, Ft);
        else
            bias_act_kernel<2><<<(total + 255) / 256, 256, 0, stream>>>(outb, bias, total, Ft);
    };

    // ---- layer 1: f32 GEMM (keep full precision; cheap K=78) ----
    {
        dim3 gg((780 + 127) / 128, (N + 127) / 128);
        gemm_f32_big<0><<<gg, 256, 0, stream>>>(x, W1, nullptr, bufA, N, 780, 78, 780);
        gat_tail(as1, ad1, b1, 10, 78, 2, bufA, bufB);
    }
    // ---- layer 2: bf16 MFMA GEMM (K=780->832, N=1560->1664) ----
    {
        const int K = 780, Kp = 832, Nout = 1560, Npad = 1664;
        cast_a_kernel<<<(N * Kp + 255) / 256, 256, 0, stream>>>(bufB, Ab, N, K, Kp);
        transpose_cast_kernel<<<dim3(Kp / 32, Npad / 32), 256, 0, stream>>>(W2, Wt, K, Nout, Kp, Npad);
        gemm_mfma_bf16<<<dim3(Npad / 128, N / 128), 256, 0, stream>>>(Ab, Wt, bufA, N, Nout, Kp, Nout);
        gat_tail(as2, ad2, b2, 2, 780, 1, bufA, bufB);
    }
    // ---- layer 3: bf16 MFMA GEMM (K=1560->1600, N=3120->3200) ----
    {
        const int K = 1560, Kp = 1600, Nout = 3120, Npad = 3200;
        cast_a_kernel<<<(N * Kp + 255) / 256, 256, 0, stream>>>(bufB, Ab, N, K, Kp);
        transpose_cast_kernel<<<dim3(Kp / 32, Npad / 32), 256, 0, stream>>>(W3, Wt, K, Nout, Kp, Npad);
        gemm_mfma_bf16<<<dim3(Npad / 128, N / 128), 256, 0, stream>>>(Ab, Wt, bufA, N, Nout, Kp, Nout);
        gat_tail(as3, ad3, b3, 1, 3120, 1, bufA, bufB);
    }

    // global max pool (40 consecutive nodes per graph) + graph FCs
    {
        int tot = NB * 3120;
        pool_max_kernel<<<(tot + 255) / 256, 256, 0, stream>>>(bufB, gbuf, NB, N / NB, 3120);
        head_gemm(gbuf, fc_g1_w, fc_g1_b, g1, NB, 1024, 3120, 1024, 1, 16);
        head_gemm(g1, fc_g2_w, fc_g2_b, xc, NB, 128, 1024, 256, 0, 32);
    }

    // ---- CNN branch (bufA is dead now; c1..xt live inside it) ----
    {
        conv1_fact_kernel<<<NB, 256, 0, stream>>>(target, emb_xt, cw1, cb1, c1);
        int t2 = NB * 64 * ((114 + 7) / 8);
        conv_quad_kernel<32, 8><<<(t2 + 255) / 256, 256, 0, stream>>>(c1, cw2, cb2, c2, 64, 121, 114);
        int t3 = NB * 96 * ((107 + 7) / 8);
        conv_quad_kernel<64, 8><<<(t3 + 255) / 256, 256, 0, stream>>>(c2, cw3, cb3, c3, 96, 114, 107);
        int t4 = NB * 128 * ((100 + 7) / 8);
        conv_quad_kernel<96, 8><<<(t4 + 255) / 256, 256, 0, stream>>>(c3, cw4, cb4, c4, 128, 107, 100);
        int tp = NB * 128 * 33;
        pool3_kernel<<<(tp + 255) / 256, 256, 0, stream>>>(c4, xt);
        head_gemm(xt, fc1_xt_w, fc1_xt_b, xt1, NB, 1024, 4224, 1024, 1, 16);
        head_gemm(xt1, fc2_xt_w, fc2_xt_b, xc + 128, NB, 128, 1024, 256, 0, 32);
    }

    // ---- fusion head ----
    {
        head_gemm(xc, fc1_w, fc1_b, f1, NB, 1024, 256, 1024, 1, 8);
        head_gemm(f1, fc2_w, fc2_b, f2, NB, 256, 1024, 256, 1, 16);
        out_head_kernel<<<1, 256, 0, stream>>>(f2, out_w, out_b, out);
    }
}

// Round 7
// 2006.241 us; speedup vs baseline: 5.2780x; 1.2971x over previous
//
#include <hip/hip_runtime.h>
#include <hip/hip_bf16.h>
#include <math.h>

// ---------------------------------------------------------------------------
// Constants (problem-fixed)
// ---------------------------------------------------------------------------
static const int NNODES = 10240;
static const int NEDGES = 40960;
static const int NB     = 256;     // graphs / batch
static const int VOCAB  = 26;
static const int EMB    = 128;

typedef short bf16x8 __attribute__((ext_vector_type(8)));   // 8 bf16 (4 VGPRs)
typedef float f32x4  __attribute__((ext_vector_type(4)));   // 4 fp32

// ---------------------------------------------------------------------------
// Split-K f32 GEMM for skinny-M head GEMMs. Partials atomicAdd'ed into P[M][N]
// (pre-zeroed). LDS padded [16][65] -> conflict-free A-tile store.
// ---------------------------------------------------------------------------
__global__ __launch_bounds__(256) void gemm_f32_splitk(
    const float* __restrict__ A, const float* __restrict__ B,
    float* __restrict__ P, int M, int N, int K, int kchunk)
{
    __shared__ float As[16][65];
    __shared__ float Bs[16][65];
    int tid = threadIdx.x;
    int bm = blockIdx.y * 64;
    int bn = blockIdx.x * 64;
    int k0 = blockIdx.z * kchunk;
    int k1 = min(k0 + kchunk, K);
    int tx = tid & 15, ty = tid >> 4;
    float acc[4][4] = {};
    for (int kb = k0; kb < k1; kb += 16) {
#pragma unroll
        for (int l = 0; l < 4; ++l) {
            int idx = tid + l * 256;
            int r = idx >> 4, c = idx & 15;
            int gr = bm + r, gc = kb + c;
            As[c][r] = (gr < M && gc < k1) ? A[(size_t)gr * K + gc] : 0.f;
        }
#pragma unroll
        for (int l = 0; l < 4; ++l) {
            int idx = tid + l * 256;
            int r = idx >> 6, c = idx & 63;
            int gr = kb + r, gc = bn + c;
            Bs[r][c] = (gr < k1 && gc < N) ? B[(size_t)gr * N + gc] : 0.f;
        }
        __syncthreads();
#pragma unroll
        for (int kk = 0; kk < 16; ++kk) {
            float a[4], b[4];
#pragma unroll
            for (int i = 0; i < 4; ++i) a[i] = As[kk][ty * 4 + i];
#pragma unroll
            for (int j = 0; j < 4; ++j) b[j] = Bs[kk][tx * 4 + j];
#pragma unroll
            for (int i = 0; i < 4; ++i)
#pragma unroll
                for (int j = 0; j < 4; ++j)
                    acc[i][j] += a[i] * b[j];
        }
        __syncthreads();
    }
#pragma unroll
    for (int i = 0; i < 4; ++i) {
        int gr = bm + ty * 4 + i;
        if (gr >= M) continue;
#pragma unroll
        for (int j = 0; j < 4; ++j) {
            int gc = bn + tx * 4 + j;
            if (gc >= N) continue;
            atomicAdd(&P[(size_t)gr * N + gc], acc[i][j]);
        }
    }
}

// C[r*ldC+c] = act(P[r*N+c] + bias[c])
template<int ACT>
__global__ void bias_act_ld_kernel(const float* __restrict__ P,
                                   const float* __restrict__ bias,
                                   float* __restrict__ C, int M, int N, int ldC)
{
    int t = blockIdx.x * 256 + threadIdx.x;
    if (t >= M * N) return;
    int r = t / N, c = t - r * N;
    float v = P[t] + bias[c];
    if (ACT == 1) v = fmaxf(v, 0.f);
    C[(size_t)r * ldC + c] = v;
}

// final 256x1 projection: out[r] = dot(f2[r,:], w) + b
__global__ void out_head_kernel(const float* __restrict__ f2,
                                const float* __restrict__ w,
                                const float* __restrict__ b,
                                float* __restrict__ out)
{
    __shared__ float sw[256];
    int t = threadIdx.x;
    sw[t] = w[t];
    __syncthreads();
    float acc = 0.f;
    const float* row = f2 + (size_t)t * 256;
    for (int k = 0; k < 256; ++k) acc += row[k] * sw[k];
    out[t] = acc + b[0];
}

// ---------------------------------------------------------------------------
// Big tiled f32 GEMM (128x128 tile, BK=16, 8x8 micro): used for lin1 only.
// ---------------------------------------------------------------------------
template<int ACT>
__global__ __launch_bounds__(256) void gemm_f32_big(
    const float* __restrict__ A, const float* __restrict__ B,
    const float* __restrict__ bias, float* __restrict__ C,
    int M, int N, int K, int ldC)
{
    __shared__ float As[16][132];
    __shared__ float Bs[16][132];
    int tid = threadIdx.x;
    int bm = blockIdx.y * 128;
    int bn = blockIdx.x * 128;
    int tx = tid & 15, ty = tid >> 4;

    int ar = tid >> 1;
    int ac = (tid & 1) * 8;
    int br = tid >> 4;
    int bc = (tid & 15) * 8;

    float acc[8][8] = {};
    int gar = bm + ar;
    const float* Arow = A + (size_t)gar * K;

    for (int k0 = 0; k0 < K; k0 += 16) {
#pragma unroll
        for (int c = 0; c < 8; ++c) {
            int gc = k0 + ac + c;
            As[ac + c][ar] = (gar < M && gc < K) ? Arow[gc] : 0.f;
        }
#pragma unroll
        for (int c = 0; c < 8; ++c) {
            int gr = k0 + br;
            int gc = bn + bc + c;
            Bs[br][bc + c] = (gr < K && gc < N) ? B[(size_t)gr * N + gc] : 0.f;
        }
        __syncthreads();
#pragma unroll
        for (int kk = 0; kk < 16; ++kk) {
            float a[8], b[8];
#pragma unroll
            for (int i = 0; i < 8; ++i) a[i] = As[kk][ty * 8 + i];
#pragma unroll
            for (int j = 0; j < 8; ++j) b[j] = Bs[kk][tx * 8 + j];
#pragma unroll
            for (int i = 0; i < 8; ++i)
#pragma unroll
                for (int j = 0; j < 8; ++j)
                    acc[i][j] += a[i] * b[j];
        }
        __syncthreads();
    }
#pragma unroll
    for (int i = 0; i < 8; ++i) {
        int gr = bm + ty * 8 + i;
        if (gr >= M) continue;
#pragma unroll
        for (int j = 0; j < 8; ++j) {
            int gc = bn + tx * 8 + j;
            if (gc >= N) continue;
            float v = acc[i][j];
            if (bias) v += bias[gc];
            if (ACT == 1) v = v > 0.f ? v : 0.f;
            else if (ACT == 2) v = v > 0.f ? v : expm1f(v);
            C[(size_t)gr * ldC + gc] = v;
        }
    }
}

// ---------------------------------------------------------------------------
// bf16 cast helpers for MFMA GEMM
// ---------------------------------------------------------------------------
__global__ void cast_a_kernel(const float* __restrict__ in, __hip_bfloat16* __restrict__ out,
                              int M, int K, int Kp)
{
    int idx = blockIdx.x * 256 + threadIdx.x;
    if (idx >= M * Kp) return;
    int r = idx / Kp, k = idx - r * Kp;
    out[idx] = __float2bfloat16(k < K ? in[(size_t)r * K + k] : 0.f);
}

// out[n][k] ([Npad][Kp] bf16) = in[k][n] ([K][N] f32), zero-padded.
__global__ __launch_bounds__(256) void transpose_cast_kernel(
    const float* __restrict__ in, __hip_bfloat16* __restrict__ out,
    int K, int N, int Kp, int Npad)
{
    __shared__ float tile[32][33];
    int k0 = blockIdx.x * 32;
    int n0 = blockIdx.y * 32;
    int tx = threadIdx.x & 31;
    int ty = threadIdx.x >> 5;   // 0..7
#pragma unroll
    for (int j = 0; j < 4; ++j) {
        int k = k0 + ty + j * 8, n = n0 + tx;
        tile[ty + j * 8][tx] = (k < K && n < N) ? in[(size_t)k * N + n] : 0.f;
    }
    __syncthreads();
#pragma unroll
    for (int j = 0; j < 4; ++j) {
        int n = n0 + ty + j * 8, k = k0 + tx;
        if (n < Npad && k < Kp)
            out[(size_t)n * Kp + k] = __float2bfloat16(tile[tx][ty + j * 8]);
    }
}

// ---------------------------------------------------------------------------
// MFMA bf16 GEMM: C[M,N] = A[M,Kp] @ Bt[N,Kp]^T  (both operands k-contiguous)
// ---------------------------------------------------------------------------
__device__ __forceinline__ void stage_tile(
    const __hip_bfloat16* __restrict__ gA,
    const __hip_bfloat16* __restrict__ gB,
    short* ldsbuf, int Kp, int w, int l)
{
#pragma unroll
    for (int j = 0; j < 4; ++j) {
        int u = (w * 4 + j) * 64 + l;
        int r = u >> 3, s = u & 7;
        const __hip_bfloat16* src = gA + (size_t)r * Kp + ((s ^ (r & 7)) << 3);
        __builtin_amdgcn_global_load_lds(
            (const __attribute__((address_space(1))) void*)src,
            (__attribute__((address_space(3))) void*)(ldsbuf + (w * 4 + j) * 512),
            16, 0, 0);
    }
#pragma unroll
    for (int j = 0; j < 4; ++j) {
        int u = (w * 4 + j) * 64 + l;
        int r = u >> 3, s = u & 7;
        const __hip_bfloat16* src = gB + (size_t)r * Kp + ((s ^ (r & 7)) << 3);
        __builtin_amdgcn_global_load_lds(
            (const __attribute__((address_space(1))) void*)src,
            (__attribute__((address_space(3))) void*)(ldsbuf + 8192 + (w * 4 + j) * 512),
            16, 0, 0);
    }
}

__global__ __launch_bounds__(256, 2) void gemm_mfma_bf16(
    const __hip_bfloat16* __restrict__ A,   // [M][Kp]
    const __hip_bfloat16* __restrict__ Bt,  // [Npad][Kp]
    float* __restrict__ C, int M, int N, int Kp, int ldC)
{
    __shared__ __align__(16) short lds[2][16384];
    const int tid = threadIdx.x;
    const int w = tid >> 6, l = tid & 63;
    const int bm = blockIdx.y * 128, bn = blockIdx.x * 128;
    const int wr = w >> 1, wc = w & 1;
    const int lane15 = l & 15, lhi = l >> 4;

    const __hip_bfloat16* gA = A + (size_t)bm * Kp;
    const __hip_bfloat16* gB = Bt + (size_t)bn * Kp;

    f32x4 acc[4][4] = {};

    const int nk = Kp >> 6;
    stage_tile(gA, gB, &lds[0][0], Kp, w, l);
    __syncthreads();
    int cur = 0;
    for (int t = 0; t < nk; ++t) {
        if (t + 1 < nk)
            stage_tile(gA + (t + 1) * 64, gB + (t + 1) * 64, &lds[cur ^ 1][0], Kp, w, l);
        const short* bA = &lds[cur][0];
        const short* bB = &lds[cur][8192];
#pragma unroll
        for (int ks = 0; ks < 2; ++ks) {
            bf16x8 af[4], bfr[4];
#pragma unroll
            for (int m = 0; m < 4; ++m) {
                int r = wr * 64 + m * 16 + lane15;
                int slot = (ks * 4 + lhi) ^ (r & 7);
                af[m] = *(const bf16x8*)(bA + r * 64 + slot * 8);
            }
#pragma unroll
            for (int n = 0; n < 4; ++n) {
                int r = wc * 64 + n * 16 + lane15;
                int slot = (ks * 4 + lhi) ^ (r & 7);
                bfr[n] = *(const bf16x8*)(bB + r * 64 + slot * 8);
            }
#pragma unroll
            for (int m = 0; m < 4; ++m)
#pragma unroll
                for (int n = 0; n < 4; ++n)
                    acc[m][n] = __builtin_amdgcn_mfma_f32_16x16x32_bf16(
                        af[m], bfr[n], acc[m][n], 0, 0, 0);
        }
        __syncthreads();
        cur ^= 1;
    }
#pragma unroll
    for (int m = 0; m < 4; ++m) {
#pragma unroll
        for (int n = 0; n < 4; ++n) {
            int col = bn + wc * 64 + n * 16 + lane15;
            if (col >= N) continue;
            int row0 = bm + wr * 64 + m * 16 + lhi * 4;
#pragma unroll
            for (int q = 0; q < 4; ++q)
                C[(size_t)(row0 + q) * ldC + col] = acc[m][n][q];
        }
    }
}

// ---------------------------------------------------------------------------
// GAT helpers
// ---------------------------------------------------------------------------
__device__ __forceinline__ unsigned fmap(float f) {
    unsigned u = __float_as_uint(f);
    return (u & 0x80000000u) ? ~u : (u | 0x80000000u);
}
__device__ __forceinline__ float funmap(unsigned u) {
    return (u & 0x80000000u) ? __uint_as_float(u ^ 0x80000000u)
                             : __uint_as_float(~u);
}

__global__ void attn_ab_kernel(const float* __restrict__ lin,
                               const float* __restrict__ att_s,
                               const float* __restrict__ att_d,
                               float* __restrict__ a_s, float* __restrict__ a_d,
                               int H, int F)
{
    int bid = blockIdx.x;           // n*H + h
    int h = bid % H;
    int lane = threadIdx.x;
    const float* row = lin + (size_t)bid * F;
    const float* wsrc = att_s + h * F;
    const float* wdst = att_d + h * F;
    float ss = 0.f, sd = 0.f;
    for (int f = lane; f < F; f += 64) {
        float v = row[f];
        ss += v * wsrc[f];
        sd += v * wdst[f];
    }
    for (int o = 32; o; o >>= 1) {
        ss += __shfl_down(ss, o);
        sd += __shfl_down(sd, o);
    }
    if (lane == 0) { a_s[bid] = ss; a_d[bid] = sd; }
}

__global__ void edge_max_kernel(const int* __restrict__ ei,
                                const float* __restrict__ a_s,
                                const float* __restrict__ a_d,
                                float* __restrict__ eval,
                                unsigned* __restrict__ mmax,
                                int E, int Etot, int H)
{
    int t = blockIdx.x * blockDim.x + threadIdx.x;
    if (t >= Etot * H) return;
    int e = t / H, h = t - e * H;
    int s, d;
    if (e < E) { s = ei[e]; d = ei[E + e]; } else { s = d = e - E; }
    float v = a_s[s * H + h] + a_d[d * H + h];
    v = v > 0.f ? v : 0.2f * v;
    eval[t] = v;
    atomicMax(&mmax[d * H + h], fmap(v));
}

__global__ void edge_exp_kernel(const int* __restrict__ ei,
                                const unsigned* __restrict__ mmax,
                                float* __restrict__ eval,
                                float* __restrict__ denom,
                                int E, int Etot, int H)
{
    int t = blockIdx.x * blockDim.x + threadIdx.x;
    if (t >= Etot * H) return;
    int e = t / H, h = t - e * H;
    int d = (e < E) ? ei[E + e] : e - E;
    float m = funmap(mmax[d * H + h]);
    float ex = expf(eval[t] - m);
    eval[t] = ex;
    atomicAdd(&denom[d * H + h], ex);
}

// alpha[t] = eval[t] / (denom[d,h] + 1e-16)   (in place)
__global__ void alpha_norm_kernel(const int* __restrict__ ei,
                                  const float* __restrict__ denom,
                                  float* __restrict__ eval,
                                  int E, int Etot, int H)
{
    int t = blockIdx.x * blockDim.x + threadIdx.x;
    if (t >= Etot * H) return;
    int e = t / H, h = t - e * H;
    int d = (e < E) ? ei[E + e] : e - E;
    eval[t] = eval[t] / (denom[d * H + h] + 1e-16f);
}

// ---- dst-CSR build (dst set is identical across all 3 layers) ----
__global__ void deg_kernel(const int* __restrict__ ei, int* __restrict__ deg,
                           int E, int Etot)
{
    int e = blockIdx.x * 256 + threadIdx.x;
    if (e >= Etot) return;
    int d = (e < E) ? ei[E + e] : e - E;
    atomicAdd(&deg[d], 1);
}

// single-block inclusive scan over n=10240 degrees -> rowptr[0..n]
__global__ __launch_bounds__(256) void scan_kernel(const int* __restrict__ deg,
                                                   int* __restrict__ rowptr, int n)
{
    __shared__ int partial[256];
    int tid = threadIdx.x;
    const int per = (n + 255) / 256;
    int base = tid * per;
    int sum = 0;
    for (int i = 0; i < per; ++i) {
        int idx = base + i;
        if (idx < n) sum += deg[idx];
    }
    partial[tid] = sum;
    __syncthreads();
    for (int offs = 1; offs < 256; offs <<= 1) {
        int v = (tid >= offs) ? partial[tid - offs] : 0;
        __syncthreads();
        partial[tid] += v;
        __syncthreads();
    }
    int run = (tid == 0) ? 0 : partial[tid - 1];
    for (int i = 0; i < per; ++i) {
        int idx = base + i;
        if (idx < n) { rowptr[idx] = run; run += deg[idx]; }
    }
    if (tid == 255) rowptr[n] = run;
}

__global__ void fill_csr_kernel(const int* __restrict__ ei, int* __restrict__ cursor,
                                int* __restrict__ eidx, int E, int Etot)
{
    int e = blockIdx.x * 256 + threadIdx.x;
    if (e >= Etot) return;
    int d = (e < E) ? ei[E + e] : e - E;
    int pos = atomicAdd(&cursor[d], 1);
    eidx[pos] = e;
}

// Gather aggregation: out[d,c] = act( sum_e alpha[e,h]*lin[src_e,c] + bias[c] )
// block = (dst node, 256-col chunk); one plain write per output element.
template<int ACT>
__global__ __launch_bounds__(256) void gat_gather_kernel(
    const int* __restrict__ rowptr, const int* __restrict__ eidx,
    const int* __restrict__ ei, const float* __restrict__ alpha,
    const float* __restrict__ lin, const float* __restrict__ bias,
    float* __restrict__ outb, int E, int H, int F, int Ft)
{
    int d = blockIdx.x;
    int c = blockIdx.y * 256 + threadIdx.x;
    if (c >= Ft) return;
    int h = (H == 1) ? 0 : c / F;
    int p0 = rowptr[d], p1 = rowptr[d + 1];
    float acc = 0.f;
    for (int p = p0; p < p1; ++p) {
        int e = eidx[p];
        int s = (e < E) ? ei[e] : e - E;
        acc += alpha[(size_t)e * H + h] * lin[(size_t)s * Ft + c];
    }
    float v = acc + bias[c];
    if (ACT == 1) v = fmaxf(v, 0.f);
    else if (ACT == 2) v = v > 0.f ? v : expm1f(v);
    outb[(size_t)d * Ft + c] = v;
}

__global__ void pool_max_kernel(const float* __restrict__ h, float* __restrict__ g,
                                int B, int per, int C)
{
    int t = blockIdx.x * blockDim.x + threadIdx.x;
    if (t >= B * C) return;
    int b = t / C, f = t - b * C;
    const float* p = h + (size_t)b * per * C + f;
    float m = -INFINITY;
    for (int j = 0; j < per; ++j) m = fmaxf(m, p[(size_t)j * C]);
    g[t] = m;
}

// ---------------------------------------------------------------------------
// CNN branch
// ---------------------------------------------------------------------------
__global__ __launch_bounds__(256) void conv1_fact_kernel(
    const int* __restrict__ target, const float* __restrict__ emb,
    const float* __restrict__ w, const float* __restrict__ b,
    float* __restrict__ y)
{
    __shared__ float s_emb[VOCAB * EMB];
    __shared__ float s_S[VOCAB * 256];
    __shared__ int   s_trow[1000];
    int tid = threadIdx.x;
    int n = blockIdx.x;
    for (int i = tid; i < VOCAB * EMB; i += 256) s_emb[i] = emb[i];
    for (int i = tid; i < VOCAB * 256; i += 256) s_S[i] = 0.f;
    for (int i = tid; i < 1000; i += 256) s_trow[i] = target[n * 1000 + i];
    __syncthreads();
    {
        const float* wcol = w + (size_t)(tid >> 3) * 8000 + (tid & 7);
        for (int i = 0; i < 1000; i += 4) {
            int v0 = s_trow[i + 0], v1 = s_trow[i + 1];
            int v2 = s_trow[i + 2], v3 = s_trow[i + 3];
            float w0 = wcol[(i + 0) * 8];
            float w1 = wcol[(i + 1) * 8];
            float w2 = wcol[(i + 2) * 8];
            float w3 = wcol[(i + 3) * 8];
            s_S[v0 * 256 + tid] += w0;
            s_S[v1 * 256 + tid] += w1;
            s_S[v2 * 256 + tid] += w2;
            s_S[v3 * 256 + tid] += w3;
        }
    }
    __syncthreads();
    for (int idx = tid; idx < 32 * 121; idx += 256) {
        int o = idx / 121, t = idx - o * 121;
        float acc = b[o];
#pragma unroll
        for (int v = 0; v < VOCAB; ++v) {
            const float* Sv = s_S + v * 256 + o * 8;
            const float* ev = s_emb + v * EMB + t;
#pragma unroll
            for (int k = 0; k < 8; ++k) acc += Sv[k] * ev[k];
        }
        y[((size_t)n * 32 + o) * 121 + t] = acc > 0.f ? acc : 0.f;
    }
}

// t-blocked conv1d (k=8, valid) + relu
template<int Ci, int T>
__global__ __launch_bounds__(256) void conv_quad_kernel(
    const float* __restrict__ x, const float* __restrict__ w,
    const float* __restrict__ b, float* __restrict__ y,
    int Co, int Lin, int Lout)
{
    int tq = (Lout + T - 1) / T;
    int idx = blockIdx.x * 256 + threadIdx.x;
    int total = NB * Co * tq;
    if (idx >= total) return;
    int q = idx % tq;
    int rest = idx / tq;
    int o = rest % Co;
    int n = rest / Co;
    int t0 = q * T;
    const float* xr = x + ((size_t)n * Ci) * Lin + t0;
    const float* wr = w + (size_t)o * Ci * 8;
    float acc[T] = {};
    if (t0 + T + 7 <= Lin) {
        for (int i = 0; i < Ci; ++i) {
            const float* xi = xr + (size_t)i * Lin;
            float4 w0 = ((const float4*)(wr + (size_t)i * 8))[0];
            float4 w1 = ((const float4*)(wr + (size_t)i * 8))[1];
            float xv[T + 7];
#pragma unroll
            for (int j = 0; j < T + 7; ++j) xv[j] = xi[j];
#pragma unroll
            for (int d = 0; d < T; ++d)
                acc[d] += xv[d] * w0.x + xv[d+1] * w0.y + xv[d+2] * w0.z + xv[d+3] * w0.w
                        + xv[d+4] * w1.x + xv[d+5] * w1.y + xv[d+6] * w1.z + xv[d+7] * w1.w;
        }
    } else {
        for (int i = 0; i < Ci; ++i) {
            const float* xi = xr + (size_t)i * Lin;
            float4 w0 = ((const float4*)(wr + (size_t)i * 8))[0];
            float4 w1 = ((const float4*)(wr + (size_t)i * 8))[1];
            float xv[T + 7];
#pragma unroll
            for (int j = 0; j < T + 7; ++j) xv[j] = (t0 + j < Lin) ? xi[j] : 0.f;
#pragma unroll
            for (int d = 0; d < T; ++d)
                acc[d] += xv[d] * w0.x + xv[d+1] * w0.y + xv[d+2] * w0.z + xv[d+3] * w0.w
                        + xv[d+4] * w1.x + xv[d+5] * w1.y + xv[d+6] * w1.z + xv[d+7] * w1.w;
        }
    }
    float bb = b[o];
    float* yr = y + ((size_t)n * Co + o) * Lout;
#pragma unroll
    for (int d = 0; d < T; ++d) {
        int t = t0 + d;
        if (t < Lout) yr[t] = fmaxf(acc[d] + bb, 0.f);
    }
}

__global__ void pool3_kernel(const float* __restrict__ x, float* __restrict__ y)
{
    int idx = blockIdx.x * blockDim.x + threadIdx.x;
    if (idx >= NB * 128 * 33) return;
    int t = idx % 33;
    int rest = idx / 33;
    int c = rest % 128;
    int n = rest / 128;
    const float* p = x + ((size_t)n * 128 + c) * 100 + t * 3;
    y[idx] = fmaxf(fmaxf(p[0], p[1]), p[2]);
}

// ---------------------------------------------------------------------------
// Host-side launch
// ---------------------------------------------------------------------------
extern "C" void kernel_launch(void* const* d_in, const int* in_sizes, int n_in,
                              void* d_out, int out_size, void* d_ws, size_t ws_size,
                              hipStream_t stream)
{
    const float* x      = (const float*)d_in[0];
    const int*   ei     = (const int*)d_in[1];
    const int*   target = (const int*)d_in[3];
    const float* W1  = (const float*)d_in[4];
    const float* as1 = (const float*)d_in[5];
    const float* ad1 = (const float*)d_in[6];
    const float* b1  = (const float*)d_in[7];
    const float* W2  = (const float*)d_in[8];
    const float* as2 = (const float*)d_in[9];
    const float* ad2 = (const float*)d_in[10];
    const float* b2  = (const float*)d_in[11];
    const float* W3  = (const float*)d_in[12];
    const float* as3 = (const float*)d_in[13];
    const float* ad3 = (const float*)d_in[14];
    const float* b3  = (const float*)d_in[15];
    const float* fc_g1_w = (const float*)d_in[16];
    const float* fc_g1_b = (const float*)d_in[17];
    const float* fc_g2_w = (const float*)d_in[18];
    const float* fc_g2_b = (const float*)d_in[19];
    const float* emb_xt  = (const float*)d_in[20];
    const float* cw1 = (const float*)d_in[21];
    const float* cb1 = (const float*)d_in[22];
    const float* cw2 = (const float*)d_in[23];
    const float* cb2 = (const float*)d_in[24];
    const float* cw3 = (const float*)d_in[25];
    const float* cb3 = (const float*)d_in[26];
    const float* cw4 = (const float*)d_in[27];
    const float* cb4 = (const float*)d_in[28];
    const float* fc1_xt_w = (const float*)d_in[29];
    const float* fc1_xt_b = (const float*)d_in[30];
    const float* fc2_xt_w = (const float*)d_in[31];
    const float* fc2_xt_b = (const float*)d_in[32];
    const float* fc1_w = (const float*)d_in[33];
    const float* fc1_b = (const float*)d_in[34];
    const float* fc2_w = (const float*)d_in[35];
    const float* fc2_b = (const float*)d_in[36];
    const float* out_w = (const float*)d_in[37];
    const float* out_b = (const float*)d_in[38];
    float* out = (float*)d_out;

    const int N = NNODES, E = NEDGES, Etot = E + N;

    // ---- workspace carve ----
    char* ws = (char*)d_ws;
    size_t off = 0;
    auto alloc = [&](size_t bytes) -> char* {
        char* p = ws + off;
        off = (off + bytes + 255) & ~(size_t)255;
        return p;
    };
    const size_t BIG = (size_t)N * 3120 * sizeof(float);   // 127.8 MB
    float*    bufA  = (float*)alloc(BIG);   // lin1/lin2/lin3, then CNN scratch
    float*    bufB  = (float*)alloc(BIG);   // out1/out2/out3 (+ bf16 staging up top)
    float*    a_s   = (float*)alloc((size_t)N * 10 * 4);
    float*    a_d   = (float*)alloc((size_t)N * 10 * 4);
    unsigned* mmax  = (unsigned*)alloc((size_t)N * 10 * 4);
    float*    denom = (float*)alloc((size_t)N * 10 * 4);
    float*    eval  = (float*)alloc((size_t)Etot * 10 * 4);
    float*    gbuf  = (float*)alloc((size_t)NB * 3120 * 4);
    float*    g1    = (float*)alloc((size_t)NB * 1024 * 4);
    float*    xt1   = (float*)alloc((size_t)NB * 1024 * 4);
    float*    xc    = (float*)alloc((size_t)NB * 256 * 4);
    float*    f1    = (float*)alloc((size_t)NB * 1024 * 4);
    float*    f2    = (float*)alloc((size_t)NB * 256 * 4);
    int*      deg     = (int*)alloc((size_t)N * 4);
    int*      rowptr  = (int*)alloc((size_t)(N + 1) * 4);
    int*      cursor  = (int*)alloc((size_t)N * 4);
    int*      eidx    = (int*)alloc((size_t)Etot * 4);

    // bf16 staging lives INSIDE bufB's upper region (no extra ws):
    __hip_bfloat16* Ab = (__hip_bfloat16*)((char*)bufB + (size_t)64 * 1024 * 1024);
    __hip_bfloat16* Wt = (__hip_bfloat16*)((char*)bufB + (size_t)100 * 1024 * 1024);
    float* Ptmp = bufB;   // head-GEMM split-K accumulator (bufB dead by then)

    // CNN scratch carved from bufA (dead after GAT layer 3):
    char* cnn = (char*)bufA;
    float* c1 = (float*)cnn;                       cnn += (size_t)NB * 32 * 121 * 4 + 256;
    float* c2 = (float*)cnn;                       cnn += (size_t)NB * 64 * 114 * 4 + 256;
    float* c3 = (float*)cnn;                       cnn += (size_t)NB * 96 * 107 * 4 + 256;
    float* c4 = (float*)cnn;                       cnn += (size_t)NB * 128 * 100 * 4 + 256;
    float* xt = (float*)cnn;                       cnn += (size_t)NB * 4224 * 4 + 256;

    // ---- build dst-CSR once (dst set identical for all layers) ----
    {
        hipMemsetAsync(deg, 0, (size_t)N * 4, stream);
        deg_kernel<<<(Etot + 255) / 256, 256, 0, stream>>>(ei, deg, E, Etot);
        scan_kernel<<<1, 256, 0, stream>>>(deg, rowptr, N);
        hipMemcpyAsync(cursor, rowptr, (size_t)N * 4, hipMemcpyDeviceToDevice, stream);
        fill_csr_kernel<<<(Etot + 255) / 256, 256, 0, stream>>>(ei, cursor, eidx, E, Etot);
    }

    // ---- split-K head GEMM: C[M,N](ldC) = act(A@B + bias) ----
    auto head_gemm = [&](const float* A, const float* B, const float* bias, float* C,
                         int M, int Nc, int K, int ldC, int act, int S) {
        hipMemsetAsync(Ptmp, 0, (size_t)M * Nc * 4, stream);
        int kchunk = (K + S - 1) / S;
        dim3 g((Nc + 63) / 64, (M + 63) / 64, S);
        gemm_f32_splitk<<<g, 256, 0, stream>>>(A, B, Ptmp, M, Nc, K, kchunk);
        int tot = M * Nc;
        if (act == 1)
            bias_act_ld_kernel<1><<<(tot + 255) / 256, 256, 0, stream>>>(Ptmp, bias, C, M, Nc, ldC);
        else
            bias_act_ld_kernel<0><<<(tot + 255) / 256, 256, 0, stream>>>(Ptmp, bias, C, M, Nc, ldC);
    };

    // ---- GAT softmax + CSR-gather chain ----
    auto gat_tail = [&](const float* atts, const float* attd, const float* bias,
                        int H, int F, int act, float* lin, float* outb) {
        int Ft = H * F;
        attn_ab_kernel<<<N * H, 64, 0, stream>>>(lin, atts, attd, a_s, a_d, H, F);
        hipMemsetAsync(mmax, 0, (size_t)N * H * 4, stream);
        hipMemsetAsync(denom, 0, (size_t)N * H * 4, stream);
        int tot = Etot * H;
        edge_max_kernel<<<(tot + 255) / 256, 256, 0, stream>>>(ei, a_s, a_d, eval, mmax, E, Etot, H);
        edge_exp_kernel<<<(tot + 255) / 256, 256, 0, stream>>>(ei, mmax, eval, denom, E, Etot, H);
        alpha_norm_kernel<<<(tot + 255) / 256, 256, 0, stream>>>(ei, denom, eval, E, Etot, H);
        dim3 gg(N, (Ft + 255) / 256);
        if (act == 1)
            gat_gather_kernel<1><<<gg, 256, 0, stream>>>(rowptr, eidx, ei, eval, lin, bias, outb, E, H, F, Ft);
        else
            gat_gather_kernel<2><<<gg, 256, 0, stream>>>(rowptr, eidx, ei, eval, lin, bias, outb, E, H, F, Ft);
    };

    // ---- layer 1: f32 GEMM (keep full precision; cheap K=78) ----
    {
        dim3 gg((780 + 127) / 128, (N + 127) / 128);
        gemm_f32_big<0><<<gg, 256, 0, stream>>>(x, W1, nullptr, bufA, N, 780, 78, 780);
        gat_tail(as1, ad1, b1, 10, 78, 2, bufA, bufB);
    }
    // ---- layer 2: bf16 MFMA GEMM ----
    {
        const int K = 780, Kp = 832, Nout = 1560, Npad = 1664;
        cast_a_kernel<<<(N * Kp + 255) / 256, 256, 0, stream>>>(bufB, Ab, N, K, Kp);
        transpose_cast_kernel<<<dim3(Kp / 32, Npad / 32), 256, 0, stream>>>(W2, Wt, K, Nout, Kp, Npad);
        gemm_mfma_bf16<<<dim3(Npad / 128, N / 128), 256, 0, stream>>>(Ab, Wt, bufA, N, Nout, Kp, Nout);
        gat_tail(as2, ad2, b2, 2, 780, 1, bufA, bufB);
    }
    // ---- layer 3: bf16 MFMA GEMM ----
    {
        const int K = 1560, Kp = 1600, Nout = 3120, Npad = 3200;
        cast_a_kernel<<<(N * Kp + 255) / 256, 256, 0, stream>>>(bufB, Ab, N, K, Kp);
        transpose_cast_kernel<<<dim3(Kp / 32, Npad / 32), 256, 0, stream>>>(W3, Wt, K, Nout, Kp, Npad);
        gemm_mfma_bf16<<<dim3(Npad / 128, N / 128), 256, 0, stream>>>(Ab, Wt, bufA, N, Nout, Kp, Nout);
        gat_tail(as3, ad3, b3, 1, 3120, 1, bufA, bufB);
    }

    // global max pool + graph FCs
    {
        int tot = NB * 3120;
        pool_max_kernel<<<(tot + 255) / 256, 256, 0, stream>>>(bufB, gbuf, NB, N / NB, 3120);
        head_gemm(gbuf, fc_g1_w, fc_g1_b, g1, NB, 1024, 3120, 1024, 1, 16);
        head_gemm(g1, fc_g2_w, fc_g2_b, xc, NB, 128, 1024, 256, 0, 32);
    }

    // ---- CNN branch ----
    {
        conv1_fact_kernel<<<NB, 256, 0, stream>>>(target, emb_xt, cw1, cb1, c1);
        int t2 = NB * 64 * ((114 + 7) / 8);
        conv_quad_kernel<32, 8><<<(t2 + 255) / 256, 256, 0, stream>>>(c1, cw2, cb2, c2, 64, 121, 114);
        int t3 = NB * 96 * ((107 + 7) / 8);
        conv_quad_kernel<64, 8><<<(t3 + 255) / 256, 256, 0, stream>>>(c2, cw3, cb3, c3, 96, 114, 107);
        int t4 = NB * 128 * ((100 + 7) / 8);
        conv_quad_kernel<96, 8><<<(t4 + 255) / 256, 256, 0, stream>>>(c3, cw4, cb4, c4, 128, 107, 100);
        int tp = NB * 128 * 33;
        pool3_kernel<<<(tp + 255) / 256, 256, 0, stream>>>(c4, xt);
        head_gemm(xt, fc1_xt_w, fc1_xt_b, xt1, NB, 1024, 4224, 1024, 1, 16);
        head_gemm(xt1, fc2_xt_w, fc2_xt_b, xc + 128, NB, 128, 1024, 256, 0, 32);
    }

    // ---- fusion head ----
    {
        head_gemm(xc, fc1_w, fc1_b, f1, NB, 1024, 256, 1024, 1, 8);
        head_gemm(f1, fc2_w, fc2_b, f2, NB, 256, 1024, 256, 1, 16);
        out_head_kernel<<<1, 256, 0, stream>>>(f2, out_w, out_b, out);
    }
}

// Round 8
// 1453.299 us; speedup vs baseline: 7.2861x; 1.3805x over previous
//
#include <hip/hip_runtime.h>
#include <hip/hip_bf16.h>
#include <math.h>

// ---------------------------------------------------------------------------
// Constants (problem-fixed)
// ---------------------------------------------------------------------------
static const int NNODES = 10240;
static const int NEDGES = 40960;
static const int NB     = 256;     // graphs / batch
static const int VOCAB  = 26;
static const int EMB    = 128;
static const int LP     = 128;     // padded t-length for NHC conv activations

typedef short bf16x8 __attribute__((ext_vector_type(8)));   // 8 bf16 (4 VGPRs)
typedef float f32x4  __attribute__((ext_vector_type(4)));   // 4 fp32

// ---------------------------------------------------------------------------
// Split-K f32 GEMM for skinny-M head GEMMs. Partials atomicAdd'ed into P[M][N]
// ---------------------------------------------------------------------------
__global__ __launch_bounds__(256) void gemm_f32_splitk(
    const float* __restrict__ A, const float* __restrict__ B,
    float* __restrict__ P, int M, int N, int K, int kchunk)
{
    __shared__ float As[16][65];
    __shared__ float Bs[16][65];
    int tid = threadIdx.x;
    int bm = blockIdx.y * 64;
    int bn = blockIdx.x * 64;
    int k0 = blockIdx.z * kchunk;
    int k1 = min(k0 + kchunk, K);
    int tx = tid & 15, ty = tid >> 4;
    float acc[4][4] = {};
    for (int kb = k0; kb < k1; kb += 16) {
#pragma unroll
        for (int l = 0; l < 4; ++l) {
            int idx = tid + l * 256;
            int r = idx >> 4, c = idx & 15;
            int gr = bm + r, gc = kb + c;
            As[c][r] = (gr < M && gc < k1) ? A[(size_t)gr * K + gc] : 0.f;
        }
#pragma unroll
        for (int l = 0; l < 4; ++l) {
            int idx = tid + l * 256;
            int r = idx >> 6, c = idx & 63;
            int gr = kb + r, gc = bn + c;
            Bs[r][c] = (gr < k1 && gc < N) ? B[(size_t)gr * N + gc] : 0.f;
        }
        __syncthreads();
#pragma unroll
        for (int kk = 0; kk < 16; ++kk) {
            float a[4], b[4];
#pragma unroll
            for (int i = 0; i < 4; ++i) a[i] = As[kk][ty * 4 + i];
#pragma unroll
            for (int j = 0; j < 4; ++j) b[j] = Bs[kk][tx * 4 + j];
#pragma unroll
            for (int i = 0; i < 4; ++i)
#pragma unroll
                for (int j = 0; j < 4; ++j)
                    acc[i][j] += a[i] * b[j];
        }
        __syncthreads();
    }
#pragma unroll
    for (int i = 0; i < 4; ++i) {
        int gr = bm + ty * 4 + i;
        if (gr >= M) continue;
#pragma unroll
        for (int j = 0; j < 4; ++j) {
            int gc = bn + tx * 4 + j;
            if (gc >= N) continue;
            atomicAdd(&P[(size_t)gr * N + gc], acc[i][j]);
        }
    }
}

template<int ACT>
__global__ void bias_act_ld_kernel(const float* __restrict__ P,
                                   const float* __restrict__ bias,
                                   float* __restrict__ C, int M, int N, int ldC)
{
    int t = blockIdx.x * 256 + threadIdx.x;
    if (t >= M * N) return;
    int r = t / N, c = t - r * N;
    float v = P[t] + bias[c];
    if (ACT == 1) v = fmaxf(v, 0.f);
    C[(size_t)r * ldC + c] = v;
}

__global__ void out_head_kernel(const float* __restrict__ f2,
                                const float* __restrict__ w,
                                const float* __restrict__ b,
                                float* __restrict__ out)
{
    __shared__ float sw[256];
    int t = threadIdx.x;
    sw[t] = w[t];
    __syncthreads();
    float acc = 0.f;
    const float* row = f2 + (size_t)t * 256;
    for (int k = 0; k < 256; ++k) acc += row[k] * sw[k];
    out[t] = acc + b[0];
}

// ---------------------------------------------------------------------------
// Big tiled f32 GEMM: used for lin1 only.
// ---------------------------------------------------------------------------
template<int ACT>
__global__ __launch_bounds__(256) void gemm_f32_big(
    const float* __restrict__ A, const float* __restrict__ B,
    const float* __restrict__ bias, float* __restrict__ C,
    int M, int N, int K, int ldC)
{
    __shared__ float As[16][132];
    __shared__ float Bs[16][132];
    int tid = threadIdx.x;
    int bm = blockIdx.y * 128;
    int bn = blockIdx.x * 128;
    int tx = tid & 15, ty = tid >> 4;

    int ar = tid >> 1;
    int ac = (tid & 1) * 8;
    int br = tid >> 4;
    int bc = (tid & 15) * 8;

    float acc[8][8] = {};
    int gar = bm + ar;
    const float* Arow = A + (size_t)gar * K;

    for (int k0 = 0; k0 < K; k0 += 16) {
#pragma unroll
        for (int c = 0; c < 8; ++c) {
            int gc = k0 + ac + c;
            As[ac + c][ar] = (gar < M && gc < K) ? Arow[gc] : 0.f;
        }
#pragma unroll
        for (int c = 0; c < 8; ++c) {
            int gr = k0 + br;
            int gc = bn + bc + c;
            Bs[br][bc + c] = (gr < K && gc < N) ? B[(size_t)gr * N + gc] : 0.f;
        }
        __syncthreads();
#pragma unroll
        for (int kk = 0; kk < 16; ++kk) {
            float a[8], b[8];
#pragma unroll
            for (int i = 0; i < 8; ++i) a[i] = As[kk][ty * 8 + i];
#pragma unroll
            for (int j = 0; j < 8; ++j) b[j] = Bs[kk][tx * 8 + j];
#pragma unroll
            for (int i = 0; i < 8; ++i)
#pragma unroll
                for (int j = 0; j < 8; ++j)
                    acc[i][j] += a[i] * b[j];
        }
        __syncthreads();
    }
#pragma unroll
    for (int i = 0; i < 8; ++i) {
        int gr = bm + ty * 8 + i;
        if (gr >= M) continue;
#pragma unroll
        for (int j = 0; j < 8; ++j) {
            int gc = bn + tx * 8 + j;
            if (gc >= N) continue;
            float v = acc[i][j];
            if (bias) v += bias[gc];
            if (ACT == 1) v = v > 0.f ? v : 0.f;
            else if (ACT == 2) v = v > 0.f ? v : expm1f(v);
            C[(size_t)gr * ldC + gc] = v;
        }
    }
}

// ---------------------------------------------------------------------------
// bf16 cast helpers for MFMA GEMM
// ---------------------------------------------------------------------------
__global__ void cast_a_kernel(const float* __restrict__ in, __hip_bfloat16* __restrict__ out,
                              int M, int K, int Kp)
{
    int idx = blockIdx.x * 256 + threadIdx.x;
    if (idx >= M * Kp) return;
    int r = idx / Kp, k = idx - r * Kp;
    out[idx] = __float2bfloat16(k < K ? in[(size_t)r * K + k] : 0.f);
}

__global__ __launch_bounds__(256) void transpose_cast_kernel(
    const float* __restrict__ in, __hip_bfloat16* __restrict__ out,
    int K, int N, int Kp, int Npad)
{
    __shared__ float tile[32][33];
    int k0 = blockIdx.x * 32;
    int n0 = blockIdx.y * 32;
    int tx = threadIdx.x & 31;
    int ty = threadIdx.x >> 5;
#pragma unroll
    for (int j = 0; j < 4; ++j) {
        int k = k0 + ty + j * 8, n = n0 + tx;
        tile[ty + j * 8][tx] = (k < K && n < N) ? in[(size_t)k * N + n] : 0.f;
    }
    __syncthreads();
#pragma unroll
    for (int j = 0; j < 4; ++j) {
        int n = n0 + ty + j * 8, k = k0 + tx;
        if (n < Npad && k < Kp)
            out[(size_t)n * Kp + k] = __float2bfloat16(tile[tx][ty + j * 8]);
    }
}

// wt[o][k*Ci+i] = bf16(w[o][i][k])  (conv weight k-major reorder)
__global__ void conv_wt_kernel(const float* __restrict__ w, __hip_bfloat16* __restrict__ wt,
                               int Co, int Ci)
{
    int idx = blockIdx.x * 256 + threadIdx.x;
    if (idx >= Co * Ci * 8) return;
    int o = idx / (Ci * 8);
    int rem = idx - o * Ci * 8;
    int i = rem >> 3, k = rem & 7;
    wt[(size_t)o * Ci * 8 + k * Ci + i] = __float2bfloat16(w[idx]);
}

// ---------------------------------------------------------------------------
// Shared MFMA staging: row r of tile from gX + r*ld (+swizzled 16B slot)
// ---------------------------------------------------------------------------
__device__ __forceinline__ void stage_tile(
    const __hip_bfloat16* __restrict__ gA, int ldA,
    const __hip_bfloat16* __restrict__ gB, int ldB,
    short* ldsbuf, int w, int l)
{
#pragma unroll
    for (int j = 0; j < 4; ++j) {
        int u = (w * 4 + j) * 64 + l;
        int r = u >> 3, s = u & 7;
        const __hip_bfloat16* src = gA + (size_t)r * ldA + ((s ^ (r & 7)) << 3);
        __builtin_amdgcn_global_load_lds(
            (const __attribute__((address_space(1))) void*)src,
            (__attribute__((address_space(3))) void*)(ldsbuf + (w * 4 + j) * 512),
            16, 0, 0);
    }
#pragma unroll
    for (int j = 0; j < 4; ++j) {
        int u = (w * 4 + j) * 64 + l;
        int r = u >> 3, s = u & 7;
        const __hip_bfloat16* src = gB + (size_t)r * ldB + ((s ^ (r & 7)) << 3);
        __builtin_amdgcn_global_load_lds(
            (const __attribute__((address_space(1))) void*)src,
            (__attribute__((address_space(3))) void*)(ldsbuf + 8192 + (w * 4 + j) * 512),
            16, 0, 0);
    }
}

// ---------------------------------------------------------------------------
// MFMA bf16 GEMM (FC form): C[M,N] f32 = A[M,Kp] @ Bt[Npad,Kp]^T
// ---------------------------------------------------------------------------
__global__ __launch_bounds__(256, 2) void gemm_mfma_bf16(
    const __hip_bfloat16* __restrict__ A,
    const __hip_bfloat16* __restrict__ Bt,
    float* __restrict__ C, int M, int N, int Kp, int ldC)
{
    __shared__ __align__(16) short lds[2][16384];
    const int tid = threadIdx.x;
    const int w = tid >> 6, l = tid & 63;
    const int bm = blockIdx.y * 128, bn = blockIdx.x * 128;
    const int wr = w >> 1, wc = w & 1;
    const int lane15 = l & 15, lhi = l >> 4;

    const __hip_bfloat16* gA = A + (size_t)bm * Kp;
    const __hip_bfloat16* gB = Bt + (size_t)bn * Kp;

    f32x4 acc[4][4] = {};

    const int nk = Kp >> 6;
    stage_tile(gA, Kp, gB, Kp, &lds[0][0], w, l);
    __syncthreads();
    int cur = 0;
    for (int t = 0; t < nk; ++t) {
        if (t + 1 < nk)
            stage_tile(gA + (t + 1) * 64, Kp, gB + (t + 1) * 64, Kp, &lds[cur ^ 1][0], w, l);
        const short* bA = &lds[cur][0];
        const short* bB = &lds[cur][8192];
#pragma unroll
        for (int ks = 0; ks < 2; ++ks) {
            bf16x8 af[4], bfr[4];
#pragma unroll
            for (int m = 0; m < 4; ++m) {
                int r = wr * 64 + m * 16 + lane15;
                int slot = (ks * 4 + lhi) ^ (r & 7);
                af[m] = *(const bf16x8*)(bA + r * 64 + slot * 8);
            }
#pragma unroll
            for (int n = 0; n < 4; ++n) {
                int r = wc * 64 + n * 16 + lane15;
                int slot = (ks * 4 + lhi) ^ (r & 7);
                bfr[n] = *(const bf16x8*)(bB + r * 64 + slot * 8);
            }
#pragma unroll
            for (int m = 0; m < 4; ++m)
#pragma unroll
                for (int n = 0; n < 4; ++n)
                    acc[m][n] = __builtin_amdgcn_mfma_f32_16x16x32_bf16(
                        af[m], bfr[n], acc[m][n], 0, 0, 0);
        }
        __syncthreads();
        cur ^= 1;
    }
#pragma unroll
    for (int m = 0; m < 4; ++m) {
#pragma unroll
        for (int n = 0; n < 4; ++n) {
            int col = bn + wc * 64 + n * 16 + lane15;
            if (col >= N) continue;
            int row0 = bm + wr * 64 + m * 16 + lhi * 4;
#pragma unroll
            for (int q = 0; q < 4; ++q)
                C[(size_t)(row0 + q) * ldC + col] = acc[m][n][q];
        }
    }
}

// ---------------------------------------------------------------------------
// MFMA conv GEMM (zero-im2col): A = NHC bf16 act [(n*128+t)*Ci], window 8*Ci
// with lda=Ci (overlapping rows). Bt[o][k*Ci+i]. One block per n (grid.y).
// C = bf16 NHC act [(n*128+t)*Co], fused bias+relu, guarded t<Lout, col<Co.
// ---------------------------------------------------------------------------
template<int Ci, int Co, int Lout>
__global__ __launch_bounds__(256, 2) void gemm_conv_bf16(
    const __hip_bfloat16* __restrict__ A,
    const __hip_bfloat16* __restrict__ Bt,
    const float* __restrict__ bias,
    __hip_bfloat16* __restrict__ C)
{
    const int Kp = 8 * Ci;
    __shared__ __align__(16) short lds[2][16384];
    const int tid = threadIdx.x;
    const int w = tid >> 6, l = tid & 63;
    const int bm = blockIdx.y * 128;          // = n*128
    const int wr = w >> 1, wc = w & 1;
    const int lane15 = l & 15, lhi = l >> 4;

    const __hip_bfloat16* gA = A + (size_t)bm * Ci;
    const __hip_bfloat16* gB = Bt;

    f32x4 acc[4][4] = {};

    const int nk = Kp >> 6;
    stage_tile(gA, Ci, gB, Kp, &lds[0][0], w, l);
    __syncthreads();
    int cur = 0;
    for (int t = 0; t < nk; ++t) {
        if (t + 1 < nk)
            stage_tile(gA + (t + 1) * 64, Ci, gB + (t + 1) * 64, Kp, &lds[cur ^ 1][0], w, l);
        const short* bA = &lds[cur][0];
        const short* bB = &lds[cur][8192];
#pragma unroll
        for (int ks = 0; ks < 2; ++ks) {
            bf16x8 af[4], bfr[4];
#pragma unroll
            for (int m = 0; m < 4; ++m) {
                int r = wr * 64 + m * 16 + lane15;
                int slot = (ks * 4 + lhi) ^ (r & 7);
                af[m] = *(const bf16x8*)(bA + r * 64 + slot * 8);
            }
#pragma unroll
            for (int n = 0; n < 4; ++n) {
                int r = wc * 64 + n * 16 + lane15;
                int slot = (ks * 4 + lhi) ^ (r & 7);
                bfr[n] = *(const bf16x8*)(bB + r * 64 + slot * 8);
            }
#pragma unroll
            for (int m = 0; m < 4; ++m)
#pragma unroll
                for (int n = 0; n < 4; ++n)
                    acc[m][n] = __builtin_amdgcn_mfma_f32_16x16x32_bf16(
                        af[m], bfr[n], acc[m][n], 0, 0, 0);
        }
        __syncthreads();
        cur ^= 1;
    }
#pragma unroll
    for (int m = 0; m < 4; ++m) {
#pragma unroll
        for (int n = 0; n < 4; ++n) {
            int col = wc * 64 + n * 16 + lane15;
            if (col >= Co) continue;
            float bb = bias[col];
            int lr0 = wr * 64 + m * 16 + lhi * 4;
#pragma unroll
            for (int q = 0; q < 4; ++q) {
                int lr = lr0 + q;
                if (lr < Lout)
                    C[((size_t)bm + lr) * Co + col] =
                        __float2bfloat16(fmaxf(acc[m][n][q] + bb, 0.f));
            }
        }
    }
}

// ---------------------------------------------------------------------------
// GAT helpers
// ---------------------------------------------------------------------------
__device__ __forceinline__ unsigned fmap(float f) {
    unsigned u = __float_as_uint(f);
    return (u & 0x80000000u) ? ~u : (u | 0x80000000u);
}
__device__ __forceinline__ float funmap(unsigned u) {
    return (u & 0x80000000u) ? __uint_as_float(u ^ 0x80000000u)
                             : __uint_as_float(~u);
}

__global__ void attn_ab_kernel(const float* __restrict__ lin,
                               const float* __restrict__ att_s,
                               const float* __restrict__ att_d,
                               float* __restrict__ a_s, float* __restrict__ a_d,
                               int H, int F)
{
    int bid = blockIdx.x;           // n*H + h
    int h = bid % H;
    int lane = threadIdx.x;
    const float* row = lin + (size_t)bid * F;
    const float* wsrc = att_s + h * F;
    const float* wdst = att_d + h * F;
    float ss = 0.f, sd = 0.f;
    for (int f = lane; f < F; f += 64) {
        float v = row[f];
        ss += v * wsrc[f];
        sd += v * wdst[f];
    }
    for (int o = 32; o; o >>= 1) {
        ss += __shfl_down(ss, o);
        sd += __shfl_down(sd, o);
    }
    if (lane == 0) { a_s[bid] = ss; a_d[bid] = sd; }
}

__global__ void edge_max_kernel(const int* __restrict__ ei,
                                const float* __restrict__ a_s,
                                const float* __restrict__ a_d,
                                float* __restrict__ eval,
                                unsigned* __restrict__ mmax,
                                int E, int Etot, int H)
{
    int t = blockIdx.x * blockDim.x + threadIdx.x;
    if (t >= Etot * H) return;
    int e = t / H, h = t - e * H;
    int s, d;
    if (e < E) { s = ei[e]; d = ei[E + e]; } else { s = d = e - E; }
    float v = a_s[s * H + h] + a_d[d * H + h];
    v = v > 0.f ? v : 0.2f * v;
    eval[t] = v;
    atomicMax(&mmax[d * H + h], fmap(v));
}

__global__ void edge_exp_kernel(const int* __restrict__ ei,
                                const unsigned* __restrict__ mmax,
                                float* __restrict__ eval,
                                float* __restrict__ denom,
                                int E, int Etot, int H)
{
    int t = blockIdx.x * blockDim.x + threadIdx.x;
    if (t >= Etot * H) return;
    int e = t / H, h = t - e * H;
    int d = (e < E) ? ei[E + e] : e - E;
    float m = funmap(mmax[d * H + h]);
    float ex = expf(eval[t] - m);
    eval[t] = ex;
    atomicAdd(&denom[d * H + h], ex);
}

__global__ void alpha_norm_kernel(const int* __restrict__ ei,
                                  const float* __restrict__ denom,
                                  float* __restrict__ eval,
                                  int E, int Etot, int H)
{
    int t = blockIdx.x * blockDim.x + threadIdx.x;
    if (t >= Etot * H) return;
    int e = t / H, h = t - e * H;
    int d = (e < E) ? ei[E + e] : e - E;
    eval[t] = eval[t] / (denom[d * H + h] + 1e-16f);
}

// ---- dst-CSR build ----
__global__ void deg_kernel(const int* __restrict__ ei, int* __restrict__ deg,
                           int E, int Etot)
{
    int e = blockIdx.x * 256 + threadIdx.x;
    if (e >= Etot) return;
    int d = (e < E) ? ei[E + e] : e - E;
    atomicAdd(&deg[d], 1);
}

__global__ __launch_bounds__(256) void scan_kernel(const int* __restrict__ deg,
                                                   int* __restrict__ rowptr, int n)
{
    __shared__ int partial[256];
    int tid = threadIdx.x;
    const int per = (n + 255) / 256;
    int base = tid * per;
    int sum = 0;
    for (int i = 0; i < per; ++i) {
        int idx = base + i;
        if (idx < n) sum += deg[idx];
    }
    partial[tid] = sum;
    __syncthreads();
    for (int offs = 1; offs < 256; offs <<= 1) {
        int v = (tid >= offs) ? partial[tid - offs] : 0;
        __syncthreads();
        partial[tid] += v;
        __syncthreads();
    }
    int run = (tid == 0) ? 0 : partial[tid - 1];
    for (int i = 0; i < per; ++i) {
        int idx = base + i;
        if (idx < n) { rowptr[idx] = run; run += deg[idx]; }
    }
    if (tid == 255) rowptr[n] = run;
}

__global__ void fill_csr_kernel(const int* __restrict__ ei, int* __restrict__ cursor,
                                int* __restrict__ eidx, int E, int Etot)
{
    int e = blockIdx.x * 256 + threadIdx.x;
    if (e >= Etot) return;
    int d = (e < E) ? ei[E + e] : e - E;
    int pos = atomicAdd(&cursor[d], 1);
    eidx[pos] = e;
}

template<int ACT>
__global__ __launch_bounds__(256) void gat_gather_kernel(
    const int* __restrict__ rowptr, const int* __restrict__ eidx,
    const int* __restrict__ ei, const float* __restrict__ alpha,
    const float* __restrict__ lin, const float* __restrict__ bias,
    float* __restrict__ outb, int E, int H, int F, int Ft)
{
    int d = blockIdx.x;
    int c = blockIdx.y * 256 + threadIdx.x;
    if (c >= Ft) return;
    int h = (H == 1) ? 0 : c / F;
    int p0 = rowptr[d], p1 = rowptr[d + 1];
    float acc = 0.f;
    for (int p = p0; p < p1; ++p) {
        int e = eidx[p];
        int s = (e < E) ? ei[e] : e - E;
        acc += alpha[(size_t)e * H + h] * lin[(size_t)s * Ft + c];
    }
    float v = acc + bias[c];
    if (ACT == 1) v = fmaxf(v, 0.f);
    else if (ACT == 2) v = v > 0.f ? v : expm1f(v);
    outb[(size_t)d * Ft + c] = v;
}

__global__ void pool_max_kernel(const float* __restrict__ h, float* __restrict__ g,
                                int B, int per, int C)
{
    int t = blockIdx.x * blockDim.x + threadIdx.x;
    if (t >= B * C) return;
    int b = t / C, f = t - b * C;
    const float* p = h + (size_t)b * per * C + f;
    float m = -INFINITY;
    for (int j = 0; j < per; ++j) m = fmaxf(m, p[(size_t)j * C]);
    g[t] = m;
}

// ---------------------------------------------------------------------------
// CNN branch
// ---------------------------------------------------------------------------
// conv1 vocab-factorized; writes NHC bf16 act1[(n*128+t)*32 + o], t<121.
__global__ __launch_bounds__(256) void conv1_fact_kernel(
    const int* __restrict__ target, const float* __restrict__ emb,
    const float* __restrict__ w, const float* __restrict__ b,
    __hip_bfloat16* __restrict__ y)
{
    __shared__ float s_emb[VOCAB * EMB];
    __shared__ float s_S[VOCAB * 256];
    __shared__ int   s_trow[1000];
    int tid = threadIdx.x;
    int n = blockIdx.x;
    for (int i = tid; i < VOCAB * EMB; i += 256) s_emb[i] = emb[i];
    for (int i = tid; i < VOCAB * 256; i += 256) s_S[i] = 0.f;
    for (int i = tid; i < 1000; i += 256) s_trow[i] = target[n * 1000 + i];
    __syncthreads();
    {
        const float* wcol = w + (size_t)(tid >> 3) * 8000 + (tid & 7);
        for (int i = 0; i < 1000; i += 4) {
            int v0 = s_trow[i + 0], v1 = s_trow[i + 1];
            int v2 = s_trow[i + 2], v3 = s_trow[i + 3];
            float w0 = wcol[(i + 0) * 8];
            float w1 = wcol[(i + 1) * 8];
            float w2 = wcol[(i + 2) * 8];
            float w3 = wcol[(i + 3) * 8];
            s_S[v0 * 256 + tid] += w0;
            s_S[v1 * 256 + tid] += w1;
            s_S[v2 * 256 + tid] += w2;
            s_S[v3 * 256 + tid] += w3;
        }
    }
    __syncthreads();
    for (int idx = tid; idx < 121 * 32; idx += 256) {
        int t = idx >> 5, o = idx & 31;
        float acc = b[o];
#pragma unroll
        for (int v = 0; v < VOCAB; ++v) {
            const float* Sv = s_S + v * 256 + o * 8;
            const float* ev = s_emb + v * EMB + t;
#pragma unroll
            for (int k = 0; k < 8; ++k) acc += Sv[k] * ev[k];
        }
        y[((size_t)n * LP + t) * 32 + o] = __float2bfloat16(fmaxf(acc, 0.f));
    }
}

// maxpool(3) + NHC->flatten transpose: xt[n][c*33+tp] from act4[(n*128+t)*128+c]
__global__ void pool3_kernel(const __hip_bfloat16* __restrict__ x, float* __restrict__ y)
{
    int idx = blockIdx.x * blockDim.x + threadIdx.x;
    if (idx >= NB * 128 * 33) return;
    int tp = idx % 33;
    int rest = idx / 33;
    int c = rest % 128;
    int n = rest / 128;
    const __hip_bfloat16* p = x + ((size_t)n * LP + tp * 3) * 128 + c;
    float m = __bfloat162float(p[0]);
    m = fmaxf(m, __bfloat162float(p[128]));
    m = fmaxf(m, __bfloat162float(p[256]));
    y[(size_t)n * 4224 + c * 33 + tp] = m;
}

// ---------------------------------------------------------------------------
// Host-side launch
// ---------------------------------------------------------------------------
extern "C" void kernel_launch(void* const* d_in, const int* in_sizes, int n_in,
                              void* d_out, int out_size, void* d_ws, size_t ws_size,
                              hipStream_t stream)
{
    const float* x      = (const float*)d_in[0];
    const int*   ei     = (const int*)d_in[1];
    const int*   target = (const int*)d_in[3];
    const float* W1  = (const float*)d_in[4];
    const float* as1 = (const float*)d_in[5];
    const float* ad1 = (const float*)d_in[6];
    const float* b1  = (const float*)d_in[7];
    const float* W2  = (const float*)d_in[8];
    const float* as2 = (const float*)d_in[9];
    const float* ad2 = (const float*)d_in[10];
    const float* b2  = (const float*)d_in[11];
    const float* W3  = (const float*)d_in[12];
    const float* as3 = (const float*)d_in[13];
    const float* ad3 = (const float*)d_in[14];
    const float* b3  = (const float*)d_in[15];
    const float* fc_g1_w = (const float*)d_in[16];
    const float* fc_g1_b = (const float*)d_in[17];
    const float* fc_g2_w = (const float*)d_in[18];
    const float* fc_g2_b = (const float*)d_in[19];
    const float* emb_xt  = (const float*)d_in[20];
    const float* cw1 = (const float*)d_in[21];
    const float* cb1 = (const float*)d_in[22];
    const float* cw2 = (const float*)d_in[23];
    const float* cb2 = (const float*)d_in[24];
    const float* cw3 = (const float*)d_in[25];
    const float* cb3 = (const float*)d_in[26];
    const float* cw4 = (const float*)d_in[27];
    const float* cb4 = (const float*)d_in[28];
    const float* fc1_xt_w = (const float*)d_in[29];
    const float* fc1_xt_b = (const float*)d_in[30];
    const float* fc2_xt_w = (const float*)d_in[31];
    const float* fc2_xt_b = (const float*)d_in[32];
    const float* fc1_w = (const float*)d_in[33];
    const float* fc1_b = (const float*)d_in[34];
    const float* fc2_w = (const float*)d_in[35];
    const float* fc2_b = (const float*)d_in[36];
    const float* out_w = (const float*)d_in[37];
    const float* out_b = (const float*)d_in[38];
    float* out = (float*)d_out;

    const int N = NNODES, E = NEDGES, Etot = E + N;

    // ---- workspace carve ----
    char* ws = (char*)d_ws;
    size_t off = 0;
    auto alloc = [&](size_t bytes) -> char* {
        char* p = ws + off;
        off = (off + bytes + 255) & ~(size_t)255;
        return p;
    };
    const size_t BIG = (size_t)N * 3120 * sizeof(float);   // 127.8 MB
    float*    bufA  = (float*)alloc(BIG);
    float*    bufB  = (float*)alloc(BIG);
    float*    a_s   = (float*)alloc((size_t)N * 10 * 4);
    float*    a_d   = (float*)alloc((size_t)N * 10 * 4);
    unsigned* mmax  = (unsigned*)alloc((size_t)N * 10 * 4);
    float*    denom = (float*)alloc((size_t)N * 10 * 4);
    float*    eval  = (float*)alloc((size_t)Etot * 10 * 4);
    float*    gbuf  = (float*)alloc((size_t)NB * 3120 * 4);
    float*    g1    = (float*)alloc((size_t)NB * 1024 * 4);
    float*    xt1   = (float*)alloc((size_t)NB * 1024 * 4);
    float*    xc    = (float*)alloc((size_t)NB * 256 * 4);
    float*    f1    = (float*)alloc((size_t)NB * 1024 * 4);
    float*    f2    = (float*)alloc((size_t)NB * 256 * 4);
    int*      deg     = (int*)alloc((size_t)N * 4);
    int*      rowptr  = (int*)alloc((size_t)(N + 1) * 4);
    int*      cursor  = (int*)alloc((size_t)N * 4);
    int*      eidx    = (int*)alloc((size_t)Etot * 4);

    // bf16 staging inside bufB's upper region:
    __hip_bfloat16* Ab = (__hip_bfloat16*)((char*)bufB + (size_t)64 * 1024 * 1024);
    __hip_bfloat16* Wt = (__hip_bfloat16*)((char*)bufB + (size_t)100 * 1024 * 1024);
    float* Ptmp = bufB;   // head-GEMM split-K accumulator

    // CNN scratch in bufA (dead after GAT layer 3). NHC bf16 acts + conv wts.
    char* cnn = (char*)bufA;
    auto calloc2 = [&](size_t bytes) -> char* {
        char* p = cnn;
        cnn += (bytes + 255) & ~(size_t)255;
        return p;
    };
    __hip_bfloat16* act1 = (__hip_bfloat16*)calloc2((size_t)NB * LP * 32 * 2 + 4096);
    __hip_bfloat16* act2 = (__hip_bfloat16*)calloc2((size_t)NB * LP * 64 * 2 + 4096);
    __hip_bfloat16* act3 = (__hip_bfloat16*)calloc2((size_t)NB * LP * 96 * 2 + 4096);
    __hip_bfloat16* act4 = (__hip_bfloat16*)calloc2((size_t)NB * LP * 128 * 2 + 4096);
    __hip_bfloat16* wt2  = (__hip_bfloat16*)calloc2((size_t)128 * 256 * 2);
    __hip_bfloat16* wt3  = (__hip_bfloat16*)calloc2((size_t)128 * 512 * 2);
    __hip_bfloat16* wt4  = (__hip_bfloat16*)calloc2((size_t)128 * 768 * 2);
    float* xt = (float*)calloc2((size_t)NB * 4224 * 4);

    // ---- build dst-CSR once ----
    {
        hipMemsetAsync(deg, 0, (size_t)N * 4, stream);
        deg_kernel<<<(Etot + 255) / 256, 256, 0, stream>>>(ei, deg, E, Etot);
        scan_kernel<<<1, 256, 0, stream>>>(deg, rowptr, N);
        hipMemcpyAsync(cursor, rowptr, (size_t)N * 4, hipMemcpyDeviceToDevice, stream);
        fill_csr_kernel<<<(Etot + 255) / 256, 256, 0, stream>>>(ei, cursor, eidx, E, Etot);
    }

    // ---- split-K head GEMM ----
    auto head_gemm = [&](const float* A, const float* B, const float* bias, float* C,
                         int M, int Nc, int K, int ldC, int act, int S) {
        hipMemsetAsync(Ptmp, 0, (size_t)M * Nc * 4, stream);
        int kchunk = (K + S - 1) / S;
        dim3 g((Nc + 63) / 64, (M + 63) / 64, S);
        gemm_f32_splitk<<<g, 256, 0, stream>>>(A, B, Ptmp, M, Nc, K, kchunk);
        int tot = M * Nc;
        if (act == 1)
            bias_act_ld_kernel<1><<<(tot + 255) / 256, 256, 0, stream>>>(Ptmp, bias, C, M, Nc, ldC);
        else
            bias_act_ld_kernel<0><<<(tot + 255) / 256, 256, 0, stream>>>(Ptmp, bias, C, M, Nc, ldC);
    };

    // ---- GAT softmax + CSR-gather chain ----
    auto gat_tail = [&](const float* atts, const float* attd, const float* bias,
                        int H, int F, int act, float* lin, float* outb) {
        int Ft = H * F;
        attn_ab_kernel<<<N * H, 64, 0, stream>>>(lin, atts, attd, a_s, a_d, H, F);
        hipMemsetAsync(mmax, 0, (size_t)N * H * 4, stream);
        hipMemsetAsync(denom, 0, (size_t)N * H * 4, stream);
        int tot = Etot * H;
        edge_max_kernel<<<(tot + 255) / 256, 256, 0, stream>>>(ei, a_s, a_d, eval, mmax, E, Etot, H);
        edge_exp_kernel<<<(tot + 255) / 256, 256, 0, stream>>>(ei, mmax, eval, denom, E, Etot, H);
        alpha_norm_kernel<<<(tot + 255) / 256, 256, 0, stream>>>(ei, denom, eval, E, Etot, H);
        dim3 gg(N, (Ft + 255) / 256);
        if (act == 1)
            gat_gather_kernel<1><<<gg, 256, 0, stream>>>(rowptr, eidx, ei, eval, lin, bias, outb, E, H, F, Ft);
        else
            gat_gather_kernel<2><<<gg, 256, 0, stream>>>(rowptr, eidx, ei, eval, lin, bias, outb, E, H, F, Ft);
    };

    // ---- layer 1: f32 GEMM ----
    {
        dim3 gg((780 + 127) / 128, (N + 127) / 128);
        gemm_f32_big<0><<<gg, 256, 0, stream>>>(x, W1, nullptr, bufA, N, 780, 78, 780);
        gat_tail(as1, ad1, b1, 10, 78, 2, bufA, bufB);
    }
    // ---- layer 2: bf16 MFMA GEMM ----
    {
        const int K = 780, Kp = 832, Nout = 1560, Npad = 1664;
        cast_a_kernel<<<(N * Kp + 255) / 256, 256, 0, stream>>>(bufB, Ab, N, K, Kp);
        transpose_cast_kernel<<<dim3(Kp / 32, Npad / 32), 256, 0, stream>>>(W2, Wt, K, Nout, Kp, Npad);
        gemm_mfma_bf16<<<dim3(Npad / 128, N / 128), 256, 0, stream>>>(Ab, Wt, bufA, N, Nout, Kp, Nout);
        gat_tail(as2, ad2, b2, 2, 780, 1, bufA, bufB);
    }
    // ---- layer 3: bf16 MFMA GEMM ----
    {
        const int K = 1560, Kp = 1600, Nout = 3120, Npad = 3200;
        cast_a_kernel<<<(N * Kp + 255) / 256, 256, 0, stream>>>(bufB, Ab, N, K, Kp);
        transpose_cast_kernel<<<dim3(Kp / 32, Npad / 32), 256, 0, stream>>>(W3, Wt, K, Nout, Kp, Npad);
        gemm_mfma_bf16<<<dim3(Npad / 128, N / 128), 256, 0, stream>>>(Ab, Wt, bufA, N, Nout, Kp, Nout);
        gat_tail(as3, ad3, b3, 1, 3120, 1, bufA, bufB);
    }

    // global max pool + graph FCs
    {
        int tot = NB * 3120;
        pool_max_kernel<<<(tot + 255) / 256, 256, 0, stream>>>(bufB, gbuf, NB, N / NB, 3120);
        head_gemm(gbuf, fc_g1_w, fc_g1_b, g1, NB, 1024, 3120, 1024, 1, 16);
        head_gemm(g1, fc_g2_w, fc_g2_b, xc, NB, 128, 1024, 256, 0, 32);
    }

    // ---- CNN branch: conv1 factorized, conv2-4 as zero-im2col MFMA GEMMs ----
    {
        conv1_fact_kernel<<<NB, 256, 0, stream>>>(target, emb_xt, cw1, cb1, act1);
        conv_wt_kernel<<<(64 * 32 * 8 + 255) / 256, 256, 0, stream>>>(cw2, wt2, 64, 32);
        conv_wt_kernel<<<(96 * 64 * 8 + 255) / 256, 256, 0, stream>>>(cw3, wt3, 96, 64);
        conv_wt_kernel<<<(128 * 96 * 8 + 255) / 256, 256, 0, stream>>>(cw4, wt4, 128, 96);
        gemm_conv_bf16<32, 64, 114><<<dim3(1, NB), 256, 0, stream>>>(act1, wt2, cb2, act2);
        gemm_conv_bf16<64, 96, 107><<<dim3(1, NB), 256, 0, stream>>>(act2, wt3, cb3, act3);
        gemm_conv_bf16<96, 128, 100><<<dim3(1, NB), 256, 0, stream>>>(act3, wt4, cb4, act4);
        int tp = NB * 128 * 33;
        pool3_kernel<<<(tp + 255) / 256, 256, 0, stream>>>(act4, xt);
        head_gemm(xt, fc1_xt_w, fc1_xt_b, xt1, NB, 1024, 4224, 1024, 1, 16);
        head_gemm(xt1, fc2_xt_w, fc2_xt_b, xc + 128, NB, 128, 1024, 256, 0, 32);
    }

    // ---- fusion head ----
    {
        head_gemm(xc, fc1_w, fc1_b, f1, NB, 1024, 256, 1024, 1, 8);
        head_gemm(f1, fc2_w, fc2_b, f2, NB, 256, 1024, 256, 1, 16);
        out_head_kernel<<<1, 256, 0, stream>>>(f2, out_w, out_b, out);
    }
}

// Round 10
// 1103.321 us; speedup vs baseline: 9.5973x; 1.3172x over previous
//
#include <hip/hip_runtime.h>
#include <hip/hip_bf16.h>
#include <math.h>

// ---------------------------------------------------------------------------
// Constants (problem-fixed)
// ---------------------------------------------------------------------------
static const int NNODES = 10240;
static const int NEDGES = 40960;
static const int NB     = 256;     // graphs / batch
static const int VOCAB  = 26;
static const int EMB    = 128;
static const int LP     = 128;     // padded t-length for NHC conv activations

typedef short bf16x8 __attribute__((ext_vector_type(8)));   // 8 bf16 (4 VGPRs)
typedef float f32x4  __attribute__((ext_vector_type(4)));   // 4 fp32

__device__ __forceinline__ float bf16bits2float(short s) {
    return __uint_as_float(((unsigned)(unsigned short)s) << 16);
}

// ---------------------------------------------------------------------------
// Split-K f32 GEMM for skinny-M head GEMMs.
// ---------------------------------------------------------------------------
__global__ __launch_bounds__(256) void gemm_f32_splitk(
    const float* __restrict__ A, const float* __restrict__ B,
    float* __restrict__ P, int M, int N, int K, int kchunk)
{
    __shared__ float As[16][65];
    __shared__ float Bs[16][65];
    int tid = threadIdx.x;
    int bm = blockIdx.y * 64;
    int bn = blockIdx.x * 64;
    int k0 = blockIdx.z * kchunk;
    int k1 = min(k0 + kchunk, K);
    int tx = tid & 15, ty = tid >> 4;
    float acc[4][4] = {};
    for (int kb = k0; kb < k1; kb += 16) {
#pragma unroll
        for (int l = 0; l < 4; ++l) {
            int idx = tid + l * 256;
            int r = idx >> 4, c = idx & 15;
            int gr = bm + r, gc = kb + c;
            As[c][r] = (gr < M && gc < k1) ? A[(size_t)gr * K + gc] : 0.f;
        }
#pragma unroll
        for (int l = 0; l < 4; ++l) {
            int idx = tid + l * 256;
            int r = idx >> 6, c = idx & 63;
            int gr = kb + r, gc = bn + c;
            Bs[r][c] = (gr < k1 && gc < N) ? B[(size_t)gr * N + gc] : 0.f;
        }
        __syncthreads();
#pragma unroll
        for (int kk = 0; kk < 16; ++kk) {
            float a[4], b[4];
#pragma unroll
            for (int i = 0; i < 4; ++i) a[i] = As[kk][ty * 4 + i];
#pragma unroll
            for (int j = 0; j < 4; ++j) b[j] = Bs[kk][tx * 4 + j];
#pragma unroll
            for (int i = 0; i < 4; ++i)
#pragma unroll
                for (int j = 0; j < 4; ++j)
                    acc[i][j] += a[i] * b[j];
        }
        __syncthreads();
    }
#pragma unroll
    for (int i = 0; i < 4; ++i) {
        int gr = bm + ty * 4 + i;
        if (gr >= M) continue;
#pragma unroll
        for (int j = 0; j < 4; ++j) {
            int gc = bn + tx * 4 + j;
            if (gc >= N) continue;
            atomicAdd(&P[(size_t)gr * N + gc], acc[i][j]);
        }
    }
}

template<int ACT>
__global__ void bias_act_ld_kernel(const float* __restrict__ P,
                                   const float* __restrict__ bias,
                                   float* __restrict__ C, int M, int N, int ldC)
{
    int t = blockIdx.x * 256 + threadIdx.x;
    if (t >= M * N) return;
    int r = t / N, c = t - r * N;
    float v = P[t] + bias[c];
    if (ACT == 1) v = fmaxf(v, 0.f);
    C[(size_t)r * ldC + c] = v;
}

__global__ void out_head_kernel(const float* __restrict__ f2,
                                const float* __restrict__ w,
                                const float* __restrict__ b,
                                float* __restrict__ out)
{
    __shared__ float sw[256];
    int t = threadIdx.x;
    sw[t] = w[t];
    __syncthreads();
    float acc = 0.f;
    const float* row = f2 + (size_t)t * 256;
    for (int k = 0; k < 256; ++k) acc += row[k] * sw[k];
    out[t] = acc + b[0];
}

// ---------------------------------------------------------------------------
// Big tiled f32 GEMM with bf16 output: lin1 = x @ W1 (K=78).
// ---------------------------------------------------------------------------
__global__ __launch_bounds__(256) void gemm_f32_big_bf16out(
    const float* __restrict__ A, const float* __restrict__ B,
    __hip_bfloat16* __restrict__ C, int M, int N, int K, int ldC)
{
    __shared__ float As[16][132];
    __shared__ float Bs[16][132];
    int tid = threadIdx.x;
    int bm = blockIdx.y * 128;
    int bn = blockIdx.x * 128;
    int tx = tid & 15, ty = tid >> 4;

    int ar = tid >> 1;
    int ac = (tid & 1) * 8;
    int br = tid >> 4;
    int bc = (tid & 15) * 8;

    float acc[8][8] = {};
    int gar = bm + ar;
    const float* Arow = A + (size_t)gar * K;

    for (int k0 = 0; k0 < K; k0 += 16) {
#pragma unroll
        for (int c = 0; c < 8; ++c) {
            int gc = k0 + ac + c;
            As[ac + c][ar] = (gar < M && gc < K) ? Arow[gc] : 0.f;
        }
#pragma unroll
        for (int c = 0; c < 8; ++c) {
            int gr = k0 + br;
            int gc = bn + bc + c;
            Bs[br][bc + c] = (gr < K && gc < N) ? B[(size_t)gr * N + gc] : 0.f;
        }
        __syncthreads();
#pragma unroll
        for (int kk = 0; kk < 16; ++kk) {
            float a[8], b[8];
#pragma unroll
            for (int i = 0; i < 8; ++i) a[i] = As[kk][ty * 8 + i];
#pragma unroll
            for (int j = 0; j < 8; ++j) b[j] = Bs[kk][tx * 8 + j];
#pragma unroll
            for (int i = 0; i < 8; ++i)
#pragma unroll
                for (int j = 0; j < 8; ++j)
                    acc[i][j] += a[i] * b[j];
        }
        __syncthreads();
    }
#pragma unroll
    for (int i = 0; i < 8; ++i) {
        int gr = bm + ty * 8 + i;
        if (gr >= M) continue;
#pragma unroll
        for (int j = 0; j < 8; ++j) {
            int gc = bn + tx * 8 + j;
            if (gc >= N) continue;
            C[(size_t)gr * ldC + gc] = __float2bfloat16(acc[i][j]);
        }
    }
}

// ---------------------------------------------------------------------------
// bf16 weight transpose-cast: out[n][k] = in[k][n], zero-padded
// ---------------------------------------------------------------------------
__global__ __launch_bounds__(256) void transpose_cast_kernel(
    const float* __restrict__ in, __hip_bfloat16* __restrict__ out,
    int K, int N, int Kp, int Npad)
{
    __shared__ float tile[32][33];
    int k0 = blockIdx.x * 32;
    int n0 = blockIdx.y * 32;
    int tx = threadIdx.x & 31;
    int ty = threadIdx.x >> 5;
#pragma unroll
    for (int j = 0; j < 4; ++j) {
        int k = k0 + ty + j * 8, n = n0 + tx;
        tile[ty + j * 8][tx] = (k < K && n < N) ? in[(size_t)k * N + n] : 0.f;
    }
    __syncthreads();
#pragma unroll
    for (int j = 0; j < 4; ++j) {
        int n = n0 + ty + j * 8, k = k0 + tx;
        if (n < Npad && k < Kp)
            out[(size_t)n * Kp + k] = __float2bfloat16(tile[tx][ty + j * 8]);
    }
}

// wt[o][k*Ci+i] = bf16(w[o][i][k])
__global__ void conv_wt_kernel(const float* __restrict__ w, __hip_bfloat16* __restrict__ wt,
                               int Co, int Ci)
{
    int idx = blockIdx.x * 256 + threadIdx.x;
    if (idx >= Co * Ci * 8) return;
    int o = idx / (Ci * 8);
    int rem = idx - o * Ci * 8;
    int i = rem >> 3, k = rem & 7;
    wt[(size_t)o * Ci * 8 + k * Ci + i] = __float2bfloat16(w[idx]);
}

// ---------------------------------------------------------------------------
// Shared MFMA staging
// ---------------------------------------------------------------------------
__device__ __forceinline__ void stage_tile(
    const __hip_bfloat16* __restrict__ gA, int ldA,
    const __hip_bfloat16* __restrict__ gB, int ldB,
    short* ldsbuf, int w, int l)
{
#pragma unroll
    for (int j = 0; j < 4; ++j) {
        int u = (w * 4 + j) * 64 + l;
        int r = u >> 3, s = u & 7;
        const __hip_bfloat16* src = gA + (size_t)r * ldA + ((s ^ (r & 7)) << 3);
        __builtin_amdgcn_global_load_lds(
            (const __attribute__((address_space(1))) void*)src,
            (__attribute__((address_space(3))) void*)(ldsbuf + (w * 4 + j) * 512),
            16, 0, 0);
    }
#pragma unroll
    for (int j = 0; j < 4; ++j) {
        int u = (w * 4 + j) * 64 + l;
        int r = u >> 3, s = u & 7;
        const __hip_bfloat16* src = gB + (size_t)r * ldB + ((s ^ (r & 7)) << 3);
        __builtin_amdgcn_global_load_lds(
            (const __attribute__((address_space(1))) void*)src,
            (__attribute__((address_space(3))) void*)(ldsbuf + 8192 + (w * 4 + j) * 512),
            16, 0, 0);
    }
}

// ---------------------------------------------------------------------------
// MFMA bf16 GEMM (FC form), bf16 output: C[M,N](ldC) = A[M,Kp] @ Bt[Npad,Kp]^T
// ---------------------------------------------------------------------------
__global__ __launch_bounds__(256, 2) void gemm_mfma_bf16(
    const __hip_bfloat16* __restrict__ A,
    const __hip_bfloat16* __restrict__ Bt,
    __hip_bfloat16* __restrict__ C, int M, int N, int Kp, int ldC)
{
    __shared__ __align__(16) short lds[2][16384];
    const int tid = threadIdx.x;
    const int w = tid >> 6, l = tid & 63;
    const int bm = blockIdx.y * 128, bn = blockIdx.x * 128;
    const int wr = w >> 1, wc = w & 1;
    const int lane15 = l & 15, lhi = l >> 4;

    const __hip_bfloat16* gA = A + (size_t)bm * Kp;
    const __hip_bfloat16* gB = Bt + (size_t)bn * Kp;

    f32x4 acc[4][4] = {};

    const int nk = Kp >> 6;
    stage_tile(gA, Kp, gB, Kp, &lds[0][0], w, l);
    __syncthreads();
    int cur = 0;
    for (int t = 0; t < nk; ++t) {
        if (t + 1 < nk)
            stage_tile(gA + (t + 1) * 64, Kp, gB + (t + 1) * 64, Kp, &lds[cur ^ 1][0], w, l);
        const short* bA = &lds[cur][0];
        const short* bB = &lds[cur][8192];
#pragma unroll
        for (int ks = 0; ks < 2; ++ks) {
            bf16x8 af[4], bfr[4];
#pragma unroll
            for (int m = 0; m < 4; ++m) {
                int r = wr * 64 + m * 16 + lane15;
                int slot = (ks * 4 + lhi) ^ (r & 7);
                af[m] = *(const bf16x8*)(bA + r * 64 + slot * 8);
            }
#pragma unroll
            for (int n = 0; n < 4; ++n) {
                int r = wc * 64 + n * 16 + lane15;
                int slot = (ks * 4 + lhi) ^ (r & 7);
                bfr[n] = *(const bf16x8*)(bB + r * 64 + slot * 8);
            }
#pragma unroll
            for (int m = 0; m < 4; ++m)
#pragma unroll
                for (int n = 0; n < 4; ++n)
                    acc[m][n] = __builtin_amdgcn_mfma_f32_16x16x32_bf16(
                        af[m], bfr[n], acc[m][n], 0, 0, 0);
        }
        __syncthreads();
        cur ^= 1;
    }
#pragma unroll
    for (int m = 0; m < 4; ++m) {
#pragma unroll
        for (int n = 0; n < 4; ++n) {
            int col = bn + wc * 64 + n * 16 + lane15;
            if (col >= N) continue;
            int row0 = bm + wr * 64 + m * 16 + lhi * 4;
#pragma unroll
            for (int q = 0; q < 4; ++q)
                C[(size_t)(row0 + q) * ldC + col] = __float2bfloat16(acc[m][n][q]);
        }
    }
}

// ---------------------------------------------------------------------------
// MFMA conv GEMM (zero-im2col, NHC bf16)
// ---------------------------------------------------------------------------
template<int Ci, int Co, int Lout>
__global__ __launch_bounds__(256, 2) void gemm_conv_bf16(
    const __hip_bfloat16* __restrict__ A,
    const __hip_bfloat16* __restrict__ Bt,
    const float* __restrict__ bias,
    __hip_bfloat16* __restrict__ C)
{
    const int Kp = 8 * Ci;
    __shared__ __align__(16) short lds[2][16384];
    const int tid = threadIdx.x;
    const int w = tid >> 6, l = tid & 63;
    const int bm = blockIdx.y * 128;          // = n*128
    const int wr = w >> 1, wc = w & 1;
    const int lane15 = l & 15, lhi = l >> 4;

    const __hip_bfloat16* gA = A + (size_t)bm * Ci;
    const __hip_bfloat16* gB = Bt;

    f32x4 acc[4][4] = {};

    const int nk = Kp >> 6;
    stage_tile(gA, Ci, gB, Kp, &lds[0][0], w, l);
    __syncthreads();
    int cur = 0;
    for (int t = 0; t < nk; ++t) {
        if (t + 1 < nk)
            stage_tile(gA + (t + 1) * 64, Ci, gB + (t + 1) * 64, Kp, &lds[cur ^ 1][0], w, l);
        const short* bA = &lds[cur][0];
        const short* bB = &lds[cur][8192];
#pragma unroll
        for (int ks = 0; ks < 2; ++ks) {
            bf16x8 af[4], bfr[4];
#pragma unroll
            for (int m = 0; m < 4; ++m) {
                int r = wr * 64 + m * 16 + lane15;
                int slot = (ks * 4 + lhi) ^ (r & 7);
                af[m] = *(const bf16x8*)(bA + r * 64 + slot * 8);
            }
#pragma unroll
            for (int n = 0; n < 4; ++n) {
                int r = wc * 64 + n * 16 + lane15;
                int slot = (ks * 4 + lhi) ^ (r & 7);
                bfr[n] = *(const bf16x8*)(bB + r * 64 + slot * 8);
            }
#pragma unroll
            for (int m = 0; m < 4; ++m)
#pragma unroll
                for (int n = 0; n < 4; ++n)
                    acc[m][n] = __builtin_amdgcn_mfma_f32_16x16x32_bf16(
                        af[m], bfr[n], acc[m][n], 0, 0, 0);
        }
        __syncthreads();
        cur ^= 1;
    }
#pragma unroll
    for (int m = 0; m < 4; ++m) {
#pragma unroll
        for (int n = 0; n < 4; ++n) {
            int col = wc * 64 + n * 16 + lane15;
            if (col >= Co) continue;
            float bb = bias[col];
            int lr0 = wr * 64 + m * 16 + lhi * 4;
#pragma unroll
            for (int q = 0; q < 4; ++q) {
                int lr = lr0 + q;
                if (lr < Lout)
                    C[((size_t)bm + lr) * Co + col] =
                        __float2bfloat16(fmaxf(acc[m][n][q] + bb, 0.f));
            }
        }
    }
}

// ---------------------------------------------------------------------------
// GAT helpers
// ---------------------------------------------------------------------------
__device__ __forceinline__ unsigned fmap(float f) {
    unsigned u = __float_as_uint(f);
    return (u & 0x80000000u) ? ~u : (u | 0x80000000u);
}
__device__ __forceinline__ float funmap(unsigned u) {
    return (u & 0x80000000u) ? __uint_as_float(u ^ 0x80000000u)
                             : __uint_as_float(~u);
}

// a_s/a_d from bf16 lin (row stride Ftp)
__global__ void attn_ab_kernel(const __hip_bfloat16* __restrict__ lin, int Ftp,
                               const float* __restrict__ att_s,
                               const float* __restrict__ att_d,
                               float* __restrict__ a_s, float* __restrict__ a_d,
                               int H, int F)
{
    int bid = blockIdx.x;           // n*H + h
    int n = bid / H, h = bid - n * H;
    int lane = threadIdx.x;
    const __hip_bfloat16* row = lin + (size_t)n * Ftp + h * F;
    const float* wsrc = att_s + h * F;
    const float* wdst = att_d + h * F;
    float ss = 0.f, sd = 0.f;
    for (int f = lane; f < F; f += 64) {
        float v = __bfloat162float(row[f]);
        ss += v * wsrc[f];
        sd += v * wdst[f];
    }
    for (int o = 32; o; o >>= 1) {
        ss += __shfl_down(ss, o);
        sd += __shfl_down(sd, o);
    }
    if (lane == 0) { a_s[bid] = ss; a_d[bid] = sd; }
}

__global__ void edge_max_kernel(const int* __restrict__ ei,
                                const float* __restrict__ a_s,
                                const float* __restrict__ a_d,
                                float* __restrict__ eval,
                                unsigned* __restrict__ mmax,
                                int E, int Etot, int H)
{
    int t = blockIdx.x * blockDim.x + threadIdx.x;
    if (t >= Etot * H) return;
    int e = t / H, h = t - e * H;
    int s, d;
    if (e < E) { s = ei[e]; d = ei[E + e]; } else { s = d = e - E; }
    float v = a_s[s * H + h] + a_d[d * H + h];
    v = v > 0.f ? v : 0.2f * v;
    eval[t] = v;
    atomicMax(&mmax[d * H + h], fmap(v));
}

__global__ void edge_exp_kernel(const int* __restrict__ ei,
                                const unsigned* __restrict__ mmax,
                                float* __restrict__ eval,
                                float* __restrict__ denom,
                                int E, int Etot, int H)
{
    int t = blockIdx.x * blockDim.x + threadIdx.x;
    if (t >= Etot * H) return;
    int e = t / H, h = t - e * H;
    int d = (e < E) ? ei[E + e] : e - E;
    float m = funmap(mmax[d * H + h]);
    float ex = expf(eval[t] - m);
    eval[t] = ex;
    atomicAdd(&denom[d * H + h], ex);
}

__global__ void alpha_norm_kernel(const int* __restrict__ ei,
                                  const float* __restrict__ denom,
                                  float* __restrict__ eval,
                                  int E, int Etot, int H)
{
    int t = blockIdx.x * blockDim.x + threadIdx.x;
    if (t >= Etot * H) return;
    int e = t / H, h = t - e * H;
    int d = (e < E) ? ei[E + e] : e - E;
    eval[t] = eval[t] / (denom[d * H + h] + 1e-16f);
}

// ---- dst-CSR build ----
__global__ void deg_kernel(const int* __restrict__ ei, int* __restrict__ deg,
                           int E, int Etot)
{
    int e = blockIdx.x * 256 + threadIdx.x;
    if (e >= Etot) return;
    int d = (e < E) ? ei[E + e] : e - E;
    atomicAdd(&deg[d], 1);
}

__global__ __launch_bounds__(256) void scan_kernel(const int* __restrict__ deg,
                                                   int* __restrict__ rowptr, int n)
{
    __shared__ int partial[256];
    int tid = threadIdx.x;
    const int per = (n + 255) / 256;
    int base = tid * per;
    int sum = 0;
    for (int i = 0; i < per; ++i) {
        int idx = base + i;
        if (idx < n) sum += deg[idx];
    }
    partial[tid] = sum;
    __syncthreads();
    for (int offs = 1; offs < 256; offs <<= 1) {
        int v = (tid >= offs) ? partial[tid - offs] : 0;
        __syncthreads();
        partial[tid] += v;
        __syncthreads();
    }
    int run = (tid == 0) ? 0 : partial[tid - 1];
    for (int i = 0; i < per; ++i) {
        int idx = base + i;
        if (idx < n) { rowptr[idx] = run; run += deg[idx]; }
    }
    if (tid == 255) rowptr[n] = run;
}

__global__ void fill_csr_kernel(const int* __restrict__ ei, int* __restrict__ cursor,
                                int* __restrict__ eidx, int E, int Etot)
{
    int e = blockIdx.x * 256 + threadIdx.x;
    if (e >= Etot) return;
    int d = (e < E) ? ei[E + e] : e - E;
    int pos = atomicAdd(&cursor[d], 1);
    eidx[pos] = e;
}

// Gather aggregation, bf16 in / bf16 out (next-GEMM layout, pad zeroed).
template<int ACT>
__global__ __launch_bounds__(64) void gat_gather8_kernel(
    const int* __restrict__ rowptr, const int* __restrict__ eidx,
    const int* __restrict__ ei, const float* __restrict__ alpha,
    const __hip_bfloat16* __restrict__ lin, int Ftp,
    const float* __restrict__ bias,
    __hip_bfloat16* __restrict__ outh, int Kout,
    int E, int H, int F, int Ft)
{
    int d = blockIdx.x;
    int g = blockIdx.y * 64 + threadIdx.x;      // col group
    int c0 = g * 8;
    if (c0 >= Kout) return;
    bf16x8 res;
    if (c0 >= Ft) {   // pure pad group: write zeros
#pragma unroll
        for (int j = 0; j < 8; ++j) res[j] = 0;
        *(bf16x8*)(outh + (size_t)d * Kout + c0) = res;
        return;
    }
    int hj[8];
#pragma unroll
    for (int j = 0; j < 8; ++j) hj[j] = min((c0 + j) / F, H - 1);
    float acc[8] = {};
    int p0 = rowptr[d], p1 = rowptr[d + 1];
    for (int p = p0; p < p1; ++p) {
        int e = eidx[p];
        int s = (e < E) ? ei[e] : e - E;
        bf16x8 v = *(const bf16x8*)(lin + (size_t)s * Ftp + c0);
        const float* aE = alpha + (size_t)e * H;
        if (H == 1) {
            float a = aE[0];
#pragma unroll
            for (int j = 0; j < 8; ++j)
                acc[j] += a * bf16bits2float(v[j]);
        } else {
#pragma unroll
            for (int j = 0; j < 8; ++j)
                acc[j] += aE[hj[j]] * bf16bits2float(v[j]);
        }
    }
#pragma unroll
    for (int j = 0; j < 8; ++j) {
        int c = c0 + j;
        float val = 0.f;
        if (c < Ft) {
            val = acc[j] + bias[c];
            if (ACT == 1) val = fmaxf(val, 0.f);
            else if (ACT == 2) val = val > 0.f ? val : expm1f(val);
        }
        __hip_bfloat16 bv = __float2bfloat16(val);
        res[j] = *(const short*)&bv;
    }
    *(bf16x8*)(outh + (size_t)d * Kout + c0) = res;
}

// global max pool over bf16 h3 [N][3120] -> gbuf f32 [NB][3120]
__global__ void pool_max_bf16_kernel(const __hip_bfloat16* __restrict__ h,
                                     float* __restrict__ g, int B, int per, int C)
{
    int t = blockIdx.x * blockDim.x + threadIdx.x;
    if (t >= B * C) return;
    int b = t / C, f = t - b * C;
    const __hip_bfloat16* p = h + (size_t)b * per * C + f;
    float m = -INFINITY;
    for (int j = 0; j < per; ++j) m = fmaxf(m, __bfloat162float(p[(size_t)j * C]));
    g[t] = m;
}

// ---------------------------------------------------------------------------
// CNN branch
// ---------------------------------------------------------------------------
__global__ __launch_bounds__(256) void conv1_fact_kernel(
    const int* __restrict__ target, const float* __restrict__ emb,
    const float* __restrict__ w, const float* __restrict__ b,
    __hip_bfloat16* __restrict__ y)
{
    __shared__ float s_emb[VOCAB * EMB];
    __shared__ float s_S[VOCAB * 256];
    __shared__ int   s_trow[1000];
    int tid = threadIdx.x;
    int n = blockIdx.x;
    for (int i = tid; i < VOCAB * EMB; i += 256) s_emb[i] = emb[i];
    for (int i = tid; i < VOCAB * 256; i += 256) s_S[i] = 0.f;
    for (int i = tid; i < 1000; i += 256) s_trow[i] = target[n * 1000 + i];
    __syncthreads();
    {
        const float* wcol = w + (size_t)(tid >> 3) * 8000 + (tid & 7);
        for (int i = 0; i < 1000; i += 4) {
            int v0 = s_trow[i + 0], v1 = s_trow[i + 1];
            int v2 = s_trow[i + 2], v3 = s_trow[i + 3];
            float w0 = wcol[(i + 0) * 8];
            float w1 = wcol[(i + 1) * 8];
            float w2 = wcol[(i + 2) * 8];
            float w3 = wcol[(i + 3) * 8];
            s_S[v0 * 256 + tid] += w0;
            s_S[v1 * 256 + tid] += w1;
            s_S[v2 * 256 + tid] += w2;
            s_S[v3 * 256 + tid] += w3;
        }
    }
    __syncthreads();
    for (int idx = tid; idx < 121 * 32; idx += 256) {
        int t = idx >> 5, o = idx & 31;
        float acc = b[o];
#pragma unroll
        for (int v = 0; v < VOCAB; ++v) {
            const float* Sv = s_S + v * 256 + o * 8;
            const float* ev = s_emb + v * EMB + t;
#pragma unroll
            for (int k = 0; k < 8; ++k) acc += Sv[k] * ev[k];
        }
        y[((size_t)n * LP + t) * 32 + o] = __float2bfloat16(fmaxf(acc, 0.f));
    }
}

// maxpool(3) + NHC->flatten transpose
__global__ void pool3_kernel(const __hip_bfloat16* __restrict__ x, float* __restrict__ y)
{
    int idx = blockIdx.x * blockDim.x + threadIdx.x;
    if (idx >= NB * 128 * 33) return;
    int tp = idx % 33;
    int rest = idx / 33;
    int c = rest % 128;
    int n = rest / 128;
    const __hip_bfloat16* p = x + ((size_t)n * LP + tp * 3) * 128 + c;
    float m = __bfloat162float(p[0]);
    m = fmaxf(m, __bfloat162float(p[128]));
    m = fmaxf(m, __bfloat162float(p[256]));
    y[(size_t)n * 4224 + c * 33 + tp] = m;
}

// ---------------------------------------------------------------------------
// Host-side launch
// ---------------------------------------------------------------------------
extern "C" void kernel_launch(void* const* d_in, const int* in_sizes, int n_in,
                              void* d_out, int out_size, void* d_ws, size_t ws_size,
                              hipStream_t stream)
{
    const float* x      = (const float*)d_in[0];
    const int*   ei     = (const int*)d_in[1];
    const int*   target = (const int*)d_in[3];
    const float* W1  = (const float*)d_in[4];
    const float* as1 = (const float*)d_in[5];
    const float* ad1 = (const float*)d_in[6];
    const float* b1  = (const float*)d_in[7];
    const float* W2  = (const float*)d_in[8];
    const float* as2 = (const float*)d_in[9];
    const float* ad2 = (const float*)d_in[10];
    const float* b2  = (const float*)d_in[11];
    const float* W3  = (const float*)d_in[12];
    const float* as3 = (const float*)d_in[13];
    const float* ad3 = (const float*)d_in[14];
    const float* b3  = (const float*)d_in[15];
    const float* fc_g1_w = (const float*)d_in[16];
    const float* fc_g1_b = (const float*)d_in[17];
    const float* fc_g2_w = (const float*)d_in[18];
    const float* fc_g2_b = (const float*)d_in[19];
    const float* emb_xt  = (const float*)d_in[20];
    const float* cw1 = (const float*)d_in[21];
    const float* cb1 = (const float*)d_in[22];
    const float* cw2 = (const float*)d_in[23];
    const float* cb2 = (const float*)d_in[24];
    const float* cw3 = (const float*)d_in[25];
    const float* cb3 = (const float*)d_in[26];
    const float* cw4 = (const float*)d_in[27];
    const float* cb4 = (const float*)d_in[28];
    const float* fc1_xt_w = (const float*)d_in[29];
    const float* fc1_xt_b = (const float*)d_in[30];
    const float* fc2_xt_w = (const float*)d_in[31];
    const float* fc2_xt_b = (const float*)d_in[32];
    const float* fc1_w = (const float*)d_in[33];
    const float* fc1_b = (const float*)d_in[34];
    const float* fc2_w = (const float*)d_in[35];
    const float* fc2_b = (const float*)d_in[36];
    const float* out_w = (const float*)d_in[37];
    const float* out_b = (const float*)d_in[38];
    float* out = (float*)d_out;

    const int N = NNODES, E = NEDGES, Etot = E + N;
    const size_t MB = 1024 * 1024;

    // ---- workspace carve ----
    char* ws = (char*)d_ws;
    size_t off = 0;
    auto alloc = [&](size_t bytes) -> char* {
        char* p = ws + off;
        off = (off + bytes + 255) & ~(size_t)255;
        return p;
    };
    const size_t BIG = (size_t)N * 3120 * sizeof(float);   // 127.8 MB
    char*  bufA  = alloc(BIG);
    char*  bufB  = alloc(BIG);
    float*    a_s   = (float*)alloc((size_t)N * 10 * 4);
    float*    a_d   = (float*)alloc((size_t)N * 10 * 4);
    unsigned* mmax  = (unsigned*)alloc((size_t)N * 10 * 4);
    float*    denom = (float*)alloc((size_t)N * 10 * 4);
    float*    eval  = (float*)alloc((size_t)Etot * 10 * 4);
    float*    gbuf  = (float*)alloc((size_t)NB * 3120 * 4);
    float*    g1    = (float*)alloc((size_t)NB * 1024 * 4);
    float*    xt1   = (float*)alloc((size_t)NB * 1024 * 4);
    float*    xc    = (float*)alloc((size_t)NB * 256 * 4);
    float*    f1    = (float*)alloc((size_t)NB * 1024 * 4);
    float*    f2    = (float*)alloc((size_t)NB * 256 * 4);
    int*      deg     = (int*)alloc((size_t)N * 4);
    int*      rowptr  = (int*)alloc((size_t)(N + 1) * 4);
    int*      cursor  = (int*)alloc((size_t)N * 4);
    int*      eidx    = (int*)alloc((size_t)Etot * 4);

    // bf16 staging layout:
    //  bufA: linb [0,64MB) | Wt at +64MB (<=10.3MB)  (GAT phase); CNN scratch after
    //  bufB: hbf1 [0,17MB) ; hbf2 at +20MB ; hbf3 [0,64MB) ; Ptmp at +100MB
    __hip_bfloat16* linb = (__hip_bfloat16*)bufA;
    __hip_bfloat16* Wt   = (__hip_bfloat16*)(bufA + 64 * MB);
    __hip_bfloat16* hbf1 = (__hip_bfloat16*)bufB;
    __hip_bfloat16* hbf2 = (__hip_bfloat16*)(bufB + 20 * MB);
    __hip_bfloat16* hbf3 = (__hip_bfloat16*)bufB;
    float*          Ptmp = (float*)(bufB + 100 * MB);

    // CNN scratch in bufA (dead after GAT layer 3)
    char* cnn = bufA;
    auto calloc2 = [&](size_t bytes) -> char* {
        char* p = cnn;
        cnn += (bytes + 255) & ~(size_t)255;
        return p;
    };
    __hip_bfloat16* act1 = (__hip_bfloat16*)calloc2((size_t)NB * LP * 32 * 2 + 4096);
    __hip_bfloat16* act2 = (__hip_bfloat16*)calloc2((size_t)NB * LP * 64 * 2 + 4096);
    __hip_bfloat16* act3 = (__hip_bfloat16*)calloc2((size_t)NB * LP * 96 * 2 + 4096);
    __hip_bfloat16* act4 = (__hip_bfloat16*)calloc2((size_t)NB * LP * 128 * 2 + 4096);
    __hip_bfloat16* wt2  = (__hip_bfloat16*)calloc2((size_t)128 * 256 * 2);
    __hip_bfloat16* wt3  = (__hip_bfloat16*)calloc2((size_t)128 * 512 * 2);
    __hip_bfloat16* wt4  = (__hip_bfloat16*)calloc2((size_t)128 * 768 * 2);
    float* xt = (float*)calloc2((size_t)NB * 4224 * 4);

    // ---- build dst-CSR once ----
    {
        (void)hipMemsetAsync(deg, 0, (size_t)N * 4, stream);
        deg_kernel<<<(Etot + 255) / 256, 256, 0, stream>>>(ei, deg, E, Etot);
        scan_kernel<<<1, 256, 0, stream>>>(deg, rowptr, N);
        (void)hipMemcpyAsync(cursor, rowptr, (size_t)N * 4, hipMemcpyDeviceToDevice, stream);
        fill_csr_kernel<<<(Etot + 255) / 256, 256, 0, stream>>>(ei, cursor, eidx, E, Etot);
    }

    // ---- split-K head GEMM ----
    auto head_gemm = [&](const float* A, const float* B, const float* bias, float* C,
                         int M, int Nc, int K, int ldC, int act, int S) {
        (void)hipMemsetAsync(Ptmp, 0, (size_t)M * Nc * 4, stream);
        int kchunk = (K + S - 1) / S;
        dim3 g((Nc + 63) / 64, (M + 63) / 64, S);
        gemm_f32_splitk<<<g, 256, 0, stream>>>(A, B, Ptmp, M, Nc, K, kchunk);
        int tot = M * Nc;
        if (act == 1)
            bias_act_ld_kernel<1><<<(tot + 255) / 256, 256, 0, stream>>>(Ptmp, bias, C, M, Nc, ldC);
        else
            bias_act_ld_kernel<0><<<(tot + 255) / 256, 256, 0, stream>>>(Ptmp, bias, C, M, Nc, ldC);
    };

    // ---- GAT softmax + CSR-gather chain (bf16 lin in, bf16 h out) ----
    auto gat_tail = [&](const float* atts, const float* attd, const float* bias,
                        int H, int F, int Ftp, int act,
                        const __hip_bfloat16* lin, __hip_bfloat16* outh, int Kout) {
        attn_ab_kernel<<<N * H, 64, 0, stream>>>(lin, Ftp, atts, attd, a_s, a_d, H, F);
        (void)hipMemsetAsync(mmax, 0, (size_t)N * H * 4, stream);
        (void)hipMemsetAsync(denom, 0, (size_t)N * H * 4, stream);
        int tot = Etot * H;
        edge_max_kernel<<<(tot + 255) / 256, 256, 0, stream>>>(ei, a_s, a_d, eval, mmax, E, Etot, H);
        edge_exp_kernel<<<(tot + 255) / 256, 256, 0, stream>>>(ei, mmax, eval, denom, E, Etot, H);
        alpha_norm_kernel<<<(tot + 255) / 256, 256, 0, stream>>>(ei, denom, eval, E, Etot, H);
        int Ft = H * F;
        int groups = Kout / 8;
        dim3 gg(N, (groups + 63) / 64);
        if (act == 1)
            gat_gather8_kernel<1><<<gg, 64, 0, stream>>>(rowptr, eidx, ei, eval, lin, Ftp, bias, outh, Kout, E, H, F, Ft);
        else
            gat_gather8_kernel<2><<<gg, 64, 0, stream>>>(rowptr, eidx, ei, eval, lin, Ftp, bias, outh, Kout, E, H, F, Ft);
    };

    // ---- layer 1: f32 GEMM -> bf16 lin [N][784] (pad zeroed via memset) ----
    {
        (void)hipMemsetAsync(linb, 0, (size_t)N * 784 * 2, stream);
        dim3 gg((780 + 127) / 128, (N + 127) / 128);
        gemm_f32_big_bf16out<<<gg, 256, 0, stream>>>(x, W1, linb, N, 780, 78, 784);
        gat_tail(as1, ad1, b1, 10, 78, 784, 2, linb, hbf1, 832);
    }
    // ---- layer 2: MFMA GEMM (A=hbf1 [N][832]) -> lin [N][1560] ----
    {
        const int Kp = 832, Nout = 1560, Npad = 1664;
        transpose_cast_kernel<<<dim3(Kp / 32, Npad / 32), 256, 0, stream>>>(W2, Wt, 780, Nout, Kp, Npad);
        gemm_mfma_bf16<<<dim3(Npad / 128, N / 128), 256, 0, stream>>>(hbf1, Wt, linb, N, Nout, Kp, Nout);
        gat_tail(as2, ad2, b2, 2, 780, 1560, 1, linb, hbf2, 1600);
    }
    // ---- layer 3: MFMA GEMM (A=hbf2 [N][1600]) -> lin [N][3120] ----
    {
        const int Kp = 1600, Nout = 3120, Npad = 3200;
        transpose_cast_kernel<<<dim3(Kp / 32, Npad / 32), 256, 0, stream>>>(W3, Wt, 1560, Nout, Kp, Npad);
        gemm_mfma_bf16<<<dim3(Npad / 128, N / 128), 256, 0, stream>>>(hbf2, Wt, linb, N, Nout, Kp, Nout);
        gat_tail(as3, ad3, b3, 1, 3120, 3120, 1, linb, hbf3, 3120);
    }

    // global max pool (bf16 in) + graph FCs
    {
        int tot = NB * 3120;
        pool_max_bf16_kernel<<<(tot + 255) / 256, 256, 0, stream>>>(hbf3, gbuf, NB, N / NB, 3120);
        head_gemm(gbuf, fc_g1_w, fc_g1_b, g1, NB, 1024, 3120, 1024, 1, 16);
        head_gemm(g1, fc_g2_w, fc_g2_b, xc, NB, 128, 1024, 256, 0, 32);
    }

    // ---- CNN branch (bufA free now) ----
    {
        conv1_fact_kernel<<<NB, 256, 0, stream>>>(target, emb_xt, cw1, cb1, act1);
        conv_wt_kernel<<<(64 * 32 * 8 + 255) / 256, 256, 0, stream>>>(cw2, wt2, 64, 32);
        conv_wt_kernel<<<(96 * 64 * 8 + 255) / 256, 256, 0, stream>>>(cw3, wt3, 96, 64);
        conv_wt_kernel<<<(128 * 96 * 8 + 255) / 256, 256, 0, stream>>>(cw4, wt4, 128, 96);
        gemm_conv_bf16<32, 64, 114><<<dim3(1, NB), 256, 0, stream>>>(act1, wt2, cb2, act2);
        gemm_conv_bf16<64, 96, 107><<<dim3(1, NB), 256, 0, stream>>>(act2, wt3, cb3, act3);
        gemm_conv_bf16<96, 128, 100><<<dim3(1, NB), 256, 0, stream>>>(act3, wt4, cb4, act4);
        int tp = NB * 128 * 33;
        pool3_kernel<<<(tp + 255) / 256, 256, 0, stream>>>(act4, xt);
        head_gemm(xt, fc1_xt_w, fc1_xt_b, xt1, NB, 1024, 4224, 1024, 1, 16);
        head_gemm(xt1, fc2_xt_w, fc2_xt_b, xc + 128, NB, 128, 1024, 256, 0, 32);
    }

    // ---- fusion head ----
    {
        head_gemm(xc, fc1_w, fc1_b, f1, NB, 1024, 256, 1024, 1, 8);
        head_gemm(f1, fc2_w, fc2_b, f2, NB, 256, 1024, 256, 1, 16);
        out_head_kernel<<<1, 256, 0, stream>>>(f2, out_w, out_b, out);
    }
}

// Round 11
// 930.730 us; speedup vs baseline: 11.3770x; 1.1854x over previous
//
#include <hip/hip_runtime.h>
#include <hip/hip_bf16.h>
#include <math.h>

// ---------------------------------------------------------------------------
// Constants (problem-fixed)
// ---------------------------------------------------------------------------
static const int NNODES = 10240;
static const int NEDGES = 40960;
static const int NB     = 256;     // graphs / batch
static const int VOCAB  = 26;
static const int EMB    = 128;
static const int LP     = 128;     // padded t-length for NHC conv activations

typedef short bf16x8 __attribute__((ext_vector_type(8)));   // 8 bf16 (4 VGPRs)
typedef float f32x4  __attribute__((ext_vector_type(4)));   // 4 fp32

__device__ __forceinline__ float bf16bits2float(short s) {
    return __uint_as_float(((unsigned)(unsigned short)s) << 16);
}

// ---------------------------------------------------------------------------
// Split-K f32 GEMM for small head GEMMs (kept for fc_g2/fc2_xt/fusion head).
// ---------------------------------------------------------------------------
__global__ __launch_bounds__(256) void gemm_f32_splitk(
    const float* __restrict__ A, const float* __restrict__ B,
    float* __restrict__ P, int M, int N, int K, int kchunk)
{
    __shared__ float As[16][65];
    __shared__ float Bs[16][65];
    int tid = threadIdx.x;
    int bm = blockIdx.y * 64;
    int bn = blockIdx.x * 64;
    int k0 = blockIdx.z * kchunk;
    int k1 = min(k0 + kchunk, K);
    int tx = tid & 15, ty = tid >> 4;
    float acc[4][4] = {};
    for (int kb = k0; kb < k1; kb += 16) {
#pragma unroll
        for (int l = 0; l < 4; ++l) {
            int idx = tid + l * 256;
            int r = idx >> 4, c = idx & 15;
            int gr = bm + r, gc = kb + c;
            As[c][r] = (gr < M && gc < k1) ? A[(size_t)gr * K + gc] : 0.f;
        }
#pragma unroll
        for (int l = 0; l < 4; ++l) {
            int idx = tid + l * 256;
            int r = idx >> 6, c = idx & 63;
            int gr = kb + r, gc = bn + c;
            Bs[r][c] = (gr < k1 && gc < N) ? B[(size_t)gr * N + gc] : 0.f;
        }
        __syncthreads();
#pragma unroll
        for (int kk = 0; kk < 16; ++kk) {
            float a[4], b[4];
#pragma unroll
            for (int i = 0; i < 4; ++i) a[i] = As[kk][ty * 4 + i];
#pragma unroll
            for (int j = 0; j < 4; ++j) b[j] = Bs[kk][tx * 4 + j];
#pragma unroll
            for (int i = 0; i < 4; ++i)
#pragma unroll
                for (int j = 0; j < 4; ++j)
                    acc[i][j] += a[i] * b[j];
        }
        __syncthreads();
    }
#pragma unroll
    for (int i = 0; i < 4; ++i) {
        int gr = bm + ty * 4 + i;
        if (gr >= M) continue;
#pragma unroll
        for (int j = 0; j < 4; ++j) {
            int gc = bn + tx * 4 + j;
            if (gc >= N) continue;
            atomicAdd(&P[(size_t)gr * N + gc], acc[i][j]);
        }
    }
}

template<int ACT>
__global__ void bias_act_ld_kernel(const float* __restrict__ P,
                                   const float* __restrict__ bias,
                                   float* __restrict__ C, int M, int N, int ldC)
{
    int t = blockIdx.x * 256 + threadIdx.x;
    if (t >= M * N) return;
    int r = t / N, c = t - r * N;
    float v = P[t] + bias[c];
    if (ACT == 1) v = fmaxf(v, 0.f);
    C[(size_t)r * ldC + c] = v;
}

// reduce S partial slices + bias + relu -> C (ldC)
__global__ void reduce_bias_relu_kernel(const float* __restrict__ P,
                                        const float* __restrict__ bias,
                                        float* __restrict__ C,
                                        int M, int N, int S, int ldC)
{
    int t = blockIdx.x * 256 + threadIdx.x;
    if (t >= M * N) return;
    int r = t / N, c = t - r * N;
    float v = bias[c];
    for (int s = 0; s < S; ++s) v += P[(size_t)s * M * N + t];
    C[(size_t)r * ldC + c] = fmaxf(v, 0.f);
}

__global__ void out_head_kernel(const float* __restrict__ f2,
                                const float* __restrict__ w,
                                const float* __restrict__ b,
                                float* __restrict__ out)
{
    __shared__ float sw[256];
    int t = threadIdx.x;
    sw[t] = w[t];
    __syncthreads();
    float acc = 0.f;
    const float* row = f2 + (size_t)t * 256;
    for (int k = 0; k < 256; ++k) acc += row[k] * sw[k];
    out[t] = acc + b[0];
}

// ---------------------------------------------------------------------------
// Big tiled f32 GEMM with bf16 output: lin1 = x @ W1 (K=78).
// ---------------------------------------------------------------------------
__global__ __launch_bounds__(256) void gemm_f32_big_bf16out(
    const float* __restrict__ A, const float* __restrict__ B,
    __hip_bfloat16* __restrict__ C, int M, int N, int K, int ldC)
{
    __shared__ float As[16][132];
    __shared__ float Bs[16][132];
    int tid = threadIdx.x;
    int bm = blockIdx.y * 128;
    int bn = blockIdx.x * 128;
    int tx = tid & 15, ty = tid >> 4;

    int ar = tid >> 1;
    int ac = (tid & 1) * 8;
    int br = tid >> 4;
    int bc = (tid & 15) * 8;

    float acc[8][8] = {};
    int gar = bm + ar;
    const float* Arow = A + (size_t)gar * K;

    for (int k0 = 0; k0 < K; k0 += 16) {
#pragma unroll
        for (int c = 0; c < 8; ++c) {
            int gc = k0 + ac + c;
            As[ac + c][ar] = (gar < M && gc < K) ? Arow[gc] : 0.f;
        }
#pragma unroll
        for (int c = 0; c < 8; ++c) {
            int gr = k0 + br;
            int gc = bn + bc + c;
            Bs[br][bc + c] = (gr < K && gc < N) ? B[(size_t)gr * N + gc] : 0.f;
        }
        __syncthreads();
#pragma unroll
        for (int kk = 0; kk < 16; ++kk) {
            float a[8], b[8];
#pragma unroll
            for (int i = 0; i < 8; ++i) a[i] = As[kk][ty * 8 + i];
#pragma unroll
            for (int j = 0; j < 8; ++j) b[j] = Bs[kk][tx * 8 + j];
#pragma unroll
            for (int i = 0; i < 8; ++i)
#pragma unroll
                for (int j = 0; j < 8; ++j)
                    acc[i][j] += a[i] * b[j];
        }
        __syncthreads();
    }
#pragma unroll
    for (int i = 0; i < 8; ++i) {
        int gr = bm + ty * 8 + i;
        if (gr >= M) continue;
#pragma unroll
        for (int j = 0; j < 8; ++j) {
            int gc = bn + tx * 8 + j;
            if (gc >= N) continue;
            C[(size_t)gr * ldC + gc] = __float2bfloat16(acc[i][j]);
        }
    }
}

// ---------------------------------------------------------------------------
// casts
// ---------------------------------------------------------------------------
// out[r][k] ([M][Kp] bf16) = in[r][k] for k<K else 0
__global__ void cast_a_kernel(const float* __restrict__ in, __hip_bfloat16* __restrict__ out,
                              int M, int K, int Kp)
{
    int idx = blockIdx.x * 256 + threadIdx.x;
    if (idx >= M * Kp) return;
    int r = idx / Kp, k = idx - r * Kp;
    out[idx] = __float2bfloat16(k < K ? in[(size_t)r * K + k] : 0.f);
}

// out[n][k] ([Npad][Kp] bf16) = in[k][n], zero-padded
__global__ __launch_bounds__(256) void transpose_cast_kernel(
    const float* __restrict__ in, __hip_bfloat16* __restrict__ out,
    int K, int N, int Kp, int Npad)
{
    __shared__ float tile[32][33];
    int k0 = blockIdx.x * 32;
    int n0 = blockIdx.y * 32;
    int tx = threadIdx.x & 31;
    int ty = threadIdx.x >> 5;
#pragma unroll
    for (int j = 0; j < 4; ++j) {
        int k = k0 + ty + j * 8, n = n0 + tx;
        tile[ty + j * 8][tx] = (k < K && n < N) ? in[(size_t)k * N + n] : 0.f;
    }
    __syncthreads();
#pragma unroll
    for (int j = 0; j < 4; ++j) {
        int n = n0 + ty + j * 8, k = k0 + tx;
        if (n < Npad && k < Kp)
            out[(size_t)n * Kp + k] = __float2bfloat16(tile[tx][ty + j * 8]);
    }
}

// wt[o][k*Ci+i] = bf16(w[o][i][k])
__global__ void conv_wt_kernel(const float* __restrict__ w, __hip_bfloat16* __restrict__ wt,
                               int Co, int Ci)
{
    int idx = blockIdx.x * 256 + threadIdx.x;
    if (idx >= Co * Ci * 8) return;
    int o = idx / (Ci * 8);
    int rem = idx - o * Ci * 8;
    int i = rem >> 3, k = rem & 7;
    wt[(size_t)o * Ci * 8 + k * Ci + i] = __float2bfloat16(w[idx]);
}

// ---------------------------------------------------------------------------
// Shared MFMA staging
// ---------------------------------------------------------------------------
__device__ __forceinline__ void stage_tile(
    const __hip_bfloat16* __restrict__ gA, int ldA,
    const __hip_bfloat16* __restrict__ gB, int ldB,
    short* ldsbuf, int w, int l)
{
#pragma unroll
    for (int j = 0; j < 4; ++j) {
        int u = (w * 4 + j) * 64 + l;
        int r = u >> 3, s = u & 7;
        const __hip_bfloat16* src = gA + (size_t)r * ldA + ((s ^ (r & 7)) << 3);
        __builtin_amdgcn_global_load_lds(
            (const __attribute__((address_space(1))) void*)src,
            (__attribute__((address_space(3))) void*)(ldsbuf + (w * 4 + j) * 512),
            16, 0, 0);
    }
#pragma unroll
    for (int j = 0; j < 4; ++j) {
        int u = (w * 4 + j) * 64 + l;
        int r = u >> 3, s = u & 7;
        const __hip_bfloat16* src = gB + (size_t)r * ldB + ((s ^ (r & 7)) << 3);
        __builtin_amdgcn_global_load_lds(
            (const __attribute__((address_space(1))) void*)src,
            (__attribute__((address_space(3))) void*)(ldsbuf + 8192 + (w * 4 + j) * 512),
            16, 0, 0);
    }
}

// ---------------------------------------------------------------------------
// MFMA bf16 GEMM (FC form), bf16 output, XCD-bijective block swizzle (m204).
// ---------------------------------------------------------------------------
__global__ __launch_bounds__(256, 2) void gemm_mfma_bf16(
    const __hip_bfloat16* __restrict__ A,
    const __hip_bfloat16* __restrict__ Bt,
    __hip_bfloat16* __restrict__ C, int M, int N, int Kp, int ldC)
{
    __shared__ __align__(16) short lds[2][16384];
    const int tid = threadIdx.x;
    const int w = tid >> 6, l = tid & 63;

    // bijective XCD swizzle of the linear workgroup id
    int nwg = gridDim.x * gridDim.y;
    int wg = blockIdx.y * gridDim.x + blockIdx.x;
    int q = nwg >> 3, r8 = nwg & 7;
    int xcd = wg & 7, lo = wg >> 3;
    int swz = (xcd < r8) ? (xcd * (q + 1) + lo) : (r8 * (q + 1) + (xcd - r8) * q + lo);
    const int bm = (swz / gridDim.x) * 128, bn = (swz % gridDim.x) * 128;

    const int wr = w >> 1, wc = w & 1;
    const int lane15 = l & 15, lhi = l >> 4;

    const __hip_bfloat16* gA = A + (size_t)bm * Kp;
    const __hip_bfloat16* gB = Bt + (size_t)bn * Kp;

    f32x4 acc[4][4] = {};

    const int nk = Kp >> 6;
    stage_tile(gA, Kp, gB, Kp, &lds[0][0], w, l);
    __syncthreads();
    int cur = 0;
    for (int t = 0; t < nk; ++t) {
        if (t + 1 < nk)
            stage_tile(gA + (t + 1) * 64, Kp, gB + (t + 1) * 64, Kp, &lds[cur ^ 1][0], w, l);
        const short* bA = &lds[cur][0];
        const short* bB = &lds[cur][8192];
#pragma unroll
        for (int ks = 0; ks < 2; ++ks) {
            bf16x8 af[4], bfr[4];
#pragma unroll
            for (int m = 0; m < 4; ++m) {
                int r = wr * 64 + m * 16 + lane15;
                int slot = (ks * 4 + lhi) ^ (r & 7);
                af[m] = *(const bf16x8*)(bA + r * 64 + slot * 8);
            }
#pragma unroll
            for (int n = 0; n < 4; ++n) {
                int r = wc * 64 + n * 16 + lane15;
                int slot = (ks * 4 + lhi) ^ (r & 7);
                bfr[n] = *(const bf16x8*)(bB + r * 64 + slot * 8);
            }
#pragma unroll
            for (int m = 0; m < 4; ++m)
#pragma unroll
                for (int n = 0; n < 4; ++n)
                    acc[m][n] = __builtin_amdgcn_mfma_f32_16x16x32_bf16(
                        af[m], bfr[n], acc[m][n], 0, 0, 0);
        }
        __syncthreads();
        cur ^= 1;
    }
#pragma unroll
    for (int m = 0; m < 4; ++m) {
#pragma unroll
        for (int n = 0; n < 4; ++n) {
            int col = bn + wc * 64 + n * 16 + lane15;
            if (col >= N) continue;
            int row0 = bm + wr * 64 + m * 16 + lhi * 4;
#pragma unroll
            for (int q2 = 0; q2 < 4; ++q2)
                C[(size_t)(row0 + q2) * ldC + col] = __float2bfloat16(acc[m][n][q2]);
        }
    }
}

// ---------------------------------------------------------------------------
// MFMA bf16 split-K GEMM: P[z][M][N] f32 = A[M, kslice] @ Bt[N, kslice]^T
// grid (N/128, M/128, S); slice z covers 64-wide k-tiles [z*tps, z*tps+tps).
// Atomic-free: partials to distinct slices, reduced by reduce_bias_relu.
// ---------------------------------------------------------------------------
__global__ __launch_bounds__(256, 2) void gemm_mfma_splitk(
    const __hip_bfloat16* __restrict__ A,
    const __hip_bfloat16* __restrict__ Bt,
    float* __restrict__ P, int M, int N, int Kp, int tps)
{
    __shared__ __align__(16) short lds[2][16384];
    const int tid = threadIdx.x;
    const int w = tid >> 6, l = tid & 63;
    const int bm = blockIdx.y * 128, bn = blockIdx.x * 128;
    const int z = blockIdx.z;
    const int wr = w >> 1, wc = w & 1;
    const int lane15 = l & 15, lhi = l >> 4;

    const __hip_bfloat16* gA = A + (size_t)bm * Kp + z * tps * 64;
    const __hip_bfloat16* gB = Bt + (size_t)bn * Kp + z * tps * 64;

    f32x4 acc[4][4] = {};

    const int nk = tps;
    stage_tile(gA, Kp, gB, Kp, &lds[0][0], w, l);
    __syncthreads();
    int cur = 0;
    for (int t = 0; t < nk; ++t) {
        if (t + 1 < nk)
            stage_tile(gA + (t + 1) * 64, Kp, gB + (t + 1) * 64, Kp, &lds[cur ^ 1][0], w, l);
        const short* bA = &lds[cur][0];
        const short* bB = &lds[cur][8192];
#pragma unroll
        for (int ks = 0; ks < 2; ++ks) {
            bf16x8 af[4], bfr[4];
#pragma unroll
            for (int m = 0; m < 4; ++m) {
                int r = wr * 64 + m * 16 + lane15;
                int slot = (ks * 4 + lhi) ^ (r & 7);
                af[m] = *(const bf16x8*)(bA + r * 64 + slot * 8);
            }
#pragma unroll
            for (int n = 0; n < 4; ++n) {
                int r = wc * 64 + n * 16 + lane15;
                int slot = (ks * 4 + lhi) ^ (r & 7);
                bfr[n] = *(const bf16x8*)(bB + r * 64 + slot * 8);
            }
#pragma unroll
            for (int m = 0; m < 4; ++m)
#pragma unroll
                for (int n = 0; n < 4; ++n)
                    acc[m][n] = __builtin_amdgcn_mfma_f32_16x16x32_bf16(
                        af[m], bfr[n], acc[m][n], 0, 0, 0);
        }
        __syncthreads();
        cur ^= 1;
    }
    float* Pz = P + (size_t)z * M * N;
#pragma unroll
    for (int m = 0; m < 4; ++m) {
#pragma unroll
        for (int n = 0; n < 4; ++n) {
            int col = bn + wc * 64 + n * 16 + lane15;
            if (col >= N) continue;
            int row0 = bm + wr * 64 + m * 16 + lhi * 4;
#pragma unroll
            for (int q2 = 0; q2 < 4; ++q2) {
                int row = row0 + q2;
                if (row < M) Pz[(size_t)row * N + col] = acc[m][n][q2];
            }
        }
    }
}

// ---------------------------------------------------------------------------
// MFMA conv GEMM (zero-im2col, NHC bf16)
// ---------------------------------------------------------------------------
template<int Ci, int Co, int Lout>
__global__ __launch_bounds__(256, 2) void gemm_conv_bf16(
    const __hip_bfloat16* __restrict__ A,
    const __hip_bfloat16* __restrict__ Bt,
    const float* __restrict__ bias,
    __hip_bfloat16* __restrict__ C)
{
    const int Kp = 8 * Ci;
    __shared__ __align__(16) short lds[2][16384];
    const int tid = threadIdx.x;
    const int w = tid >> 6, l = tid & 63;
    const int bm = blockIdx.y * 128;          // = n*128
    const int wr = w >> 1, wc = w & 1;
    const int lane15 = l & 15, lhi = l >> 4;

    const __hip_bfloat16* gA = A + (size_t)bm * Ci;
    const __hip_bfloat16* gB = Bt;

    f32x4 acc[4][4] = {};

    const int nk = Kp >> 6;
    stage_tile(gA, Ci, gB, Kp, &lds[0][0], w, l);
    __syncthreads();
    int cur = 0;
    for (int t = 0; t < nk; ++t) {
        if (t + 1 < nk)
            stage_tile(gA + (t + 1) * 64, Ci, gB + (t + 1) * 64, Kp, &lds[cur ^ 1][0], w, l);
        const short* bA = &lds[cur][0];
        const short* bB = &lds[cur][8192];
#pragma unroll
        for (int ks = 0; ks < 2; ++ks) {
            bf16x8 af[4], bfr[4];
#pragma unroll
            for (int m = 0; m < 4; ++m) {
                int r = wr * 64 + m * 16 + lane15;
                int slot = (ks * 4 + lhi) ^ (r & 7);
                af[m] = *(const bf16x8*)(bA + r * 64 + slot * 8);
            }
#pragma unroll
            for (int n = 0; n < 4; ++n) {
                int r = wc * 64 + n * 16 + lane15;
                int slot = (ks * 4 + lhi) ^ (r & 7);
                bfr[n] = *(const bf16x8*)(bB + r * 64 + slot * 8);
            }
#pragma unroll
            for (int m = 0; m < 4; ++m)
#pragma unroll
                for (int n = 0; n < 4; ++n)
                    acc[m][n] = __builtin_amdgcn_mfma_f32_16x16x32_bf16(
                        af[m], bfr[n], acc[m][n], 0, 0, 0);
        }
        __syncthreads();
        cur ^= 1;
    }
#pragma unroll
    for (int m = 0; m < 4; ++m) {
#pragma unroll
        for (int n = 0; n < 4; ++n) {
            int col = wc * 64 + n * 16 + lane15;
            if (col >= Co) continue;
            float bb = bias[col];
            int lr0 = wr * 64 + m * 16 + lhi * 4;
#pragma unroll
            for (int q2 = 0; q2 < 4; ++q2) {
                int lr = lr0 + q2;
                if (lr < Lout)
                    C[((size_t)bm + lr) * Co + col] =
                        __float2bfloat16(fmaxf(acc[m][n][q2] + bb, 0.f));
            }
        }
    }
}

// ---------------------------------------------------------------------------
// GAT helpers
// ---------------------------------------------------------------------------
__device__ __forceinline__ unsigned fmap(float f) {
    unsigned u = __float_as_uint(f);
    return (u & 0x80000000u) ? ~u : (u | 0x80000000u);
}
__device__ __forceinline__ float funmap(unsigned u) {
    return (u & 0x80000000u) ? __uint_as_float(u ^ 0x80000000u)
                             : __uint_as_float(~u);
}

__global__ void attn_ab_kernel(const __hip_bfloat16* __restrict__ lin, int Ftp,
                               const float* __restrict__ att_s,
                               const float* __restrict__ att_d,
                               float* __restrict__ a_s, float* __restrict__ a_d,
                               int H, int F)
{
    int bid = blockIdx.x;           // n*H + h
    int n = bid / H, h = bid - n * H;
    int lane = threadIdx.x;
    const __hip_bfloat16* row = lin + (size_t)n * Ftp + h * F;
    const float* wsrc = att_s + h * F;
    const float* wdst = att_d + h * F;
    float ss = 0.f, sd = 0.f;
    for (int f = lane; f < F; f += 64) {
        float v = __bfloat162float(row[f]);
        ss += v * wsrc[f];
        sd += v * wdst[f];
    }
    for (int o = 32; o; o >>= 1) {
        ss += __shfl_down(ss, o);
        sd += __shfl_down(sd, o);
    }
    if (lane == 0) { a_s[bid] = ss; a_d[bid] = sd; }
}

__global__ void edge_max_kernel(const int* __restrict__ ei,
                                const float* __restrict__ a_s,
                                const float* __restrict__ a_d,
                                float* __restrict__ eval,
                                unsigned* __restrict__ mmax,
                                int E, int Etot, int H)
{
    int t = blockIdx.x * blockDim.x + threadIdx.x;
    if (t >= Etot * H) return;
    int e = t / H, h = t - e * H;
    int s, d;
    if (e < E) { s = ei[e]; d = ei[E + e]; } else { s = d = e - E; }
    float v = a_s[s * H + h] + a_d[d * H + h];
    v = v > 0.f ? v : 0.2f * v;
    eval[t] = v;
    atomicMax(&mmax[d * H + h], fmap(v));
}

__global__ void edge_exp_kernel(const int* __restrict__ ei,
                                const unsigned* __restrict__ mmax,
                                float* __restrict__ eval,
                                float* __restrict__ denom,
                                int E, int Etot, int H)
{
    int t = blockIdx.x * blockDim.x + threadIdx.x;
    if (t >= Etot * H) return;
    int e = t / H, h = t - e * H;
    int d = (e < E) ? ei[E + e] : e - E;
    float m = funmap(mmax[d * H + h]);
    float ex = expf(eval[t] - m);
    eval[t] = ex;
    atomicAdd(&denom[d * H + h], ex);
}

__global__ void alpha_norm_kernel(const int* __restrict__ ei,
                                  const float* __restrict__ denom,
                                  float* __restrict__ eval,
                                  int E, int Etot, int H)
{
    int t = blockIdx.x * blockDim.x + threadIdx.x;
    if (t >= Etot * H) return;
    int e = t / H, h = t - e * H;
    int d = (e < E) ? ei[E + e] : e - E;
    eval[t] = eval[t] / (denom[d * H + h] + 1e-16f);
}

// ---- dst-CSR build ----
__global__ void deg_kernel(const int* __restrict__ ei, int* __restrict__ deg,
                           int E, int Etot)
{
    int e = blockIdx.x * 256 + threadIdx.x;
    if (e >= Etot) return;
    int d = (e < E) ? ei[E + e] : e - E;
    atomicAdd(&deg[d], 1);
}

__global__ __launch_bounds__(256) void scan_kernel(const int* __restrict__ deg,
                                                   int* __restrict__ rowptr, int n)
{
    __shared__ int partial[256];
    int tid = threadIdx.x;
    const int per = (n + 255) / 256;
    int base = tid * per;
    int sum = 0;
    for (int i = 0; i < per; ++i) {
        int idx = base + i;
        if (idx < n) sum += deg[idx];
    }
    partial[tid] = sum;
    __syncthreads();
    for (int offs = 1; offs < 256; offs <<= 1) {
        int v = (tid >= offs) ? partial[tid - offs] : 0;
        __syncthreads();
        partial[tid] += v;
        __syncthreads();
    }
    int run = (tid == 0) ? 0 : partial[tid - 1];
    for (int i = 0; i < per; ++i) {
        int idx = base + i;
        if (idx < n) { rowptr[idx] = run; run += deg[idx]; }
    }
    if (tid == 255) rowptr[n] = run;
}

__global__ void fill_csr_kernel(const int* __restrict__ ei, int* __restrict__ cursor,
                                int* __restrict__ eidx, int E, int Etot)
{
    int e = blockIdx.x * 256 + threadIdx.x;
    if (e >= Etot) return;
    int d = (e < E) ? ei[E + e] : e - E;
    int pos = atomicAdd(&cursor[d], 1);
    eidx[pos] = e;
}

// Gather aggregation, bf16 in / bf16 out (next-GEMM layout, pad zeroed).
template<int ACT>
__global__ __launch_bounds__(64) void gat_gather8_kernel(
    const int* __restrict__ rowptr, const int* __restrict__ eidx,
    const int* __restrict__ ei, const float* __restrict__ alpha,
    const __hip_bfloat16* __restrict__ lin, int Ftp,
    const float* __restrict__ bias,
    __hip_bfloat16* __restrict__ outh, int Kout,
    int E, int H, int F, int Ft)
{
    int d = blockIdx.x;
    int g = blockIdx.y * 64 + threadIdx.x;      // col group
    int c0 = g * 8;
    if (c0 >= Kout) return;
    bf16x8 res;
    if (c0 >= Ft) {   // pure pad group: write zeros
#pragma unroll
        for (int j = 0; j < 8; ++j) res[j] = 0;
        *(bf16x8*)(outh + (size_t)d * Kout + c0) = res;
        return;
    }
    int hj[8];
#pragma unroll
    for (int j = 0; j < 8; ++j) hj[j] = min((c0 + j) / F, H - 1);
    float acc[8] = {};
    int p0 = rowptr[d], p1 = rowptr[d + 1];
    for (int p = p0; p < p1; ++p) {
        int e = eidx[p];
        int s = (e < E) ? ei[e] : e - E;
        bf16x8 v = *(const bf16x8*)(lin + (size_t)s * Ftp + c0);
        const float* aE = alpha + (size_t)e * H;
        if (H == 1) {
            float a = aE[0];
#pragma unroll
            for (int j = 0; j < 8; ++j)
                acc[j] += a * bf16bits2float(v[j]);
        } else {
#pragma unroll
            for (int j = 0; j < 8; ++j)
                acc[j] += aE[hj[j]] * bf16bits2float(v[j]);
        }
    }
#pragma unroll
    for (int j = 0; j < 8; ++j) {
        int c = c0 + j;
        float val = 0.f;
        if (c < Ft) {
            val = acc[j] + bias[c];
            if (ACT == 1) val = fmaxf(val, 0.f);
            else if (ACT == 2) val = val > 0.f ? val : expm1f(val);
        }
        __hip_bfloat16 bv = __float2bfloat16(val);
        res[j] = *(const short*)&bv;
    }
    *(bf16x8*)(outh + (size_t)d * Kout + c0) = res;
}

// global max pool over bf16 h3 [N][3120] -> gbuf f32 [NB][3120]
__global__ void pool_max_bf16_kernel(const __hip_bfloat16* __restrict__ h,
                                     float* __restrict__ g, int B, int per, int C)
{
    int t = blockIdx.x * blockDim.x + threadIdx.x;
    if (t >= B * C) return;
    int b = t / C, f = t - b * C;
    const __hip_bfloat16* p = h + (size_t)b * per * C + f;
    float m = -INFINITY;
    for (int j = 0; j < per; ++j) m = fmaxf(m, __bfloat162float(p[(size_t)j * C]));
    g[t] = m;
}

// ---------------------------------------------------------------------------
// CNN branch
// ---------------------------------------------------------------------------
__global__ __launch_bounds__(256) void conv1_fact_kernel(
    const int* __restrict__ target, const float* __restrict__ emb,
    const float* __restrict__ w, const float* __restrict__ b,
    __hip_bfloat16* __restrict__ y)
{
    __shared__ float s_emb[VOCAB * EMB];
    __shared__ float s_S[VOCAB * 256];
    __shared__ int   s_trow[1000];
    int tid = threadIdx.x;
    int n = blockIdx.x;
    for (int i = tid; i < VOCAB * EMB; i += 256) s_emb[i] = emb[i];
    for (int i = tid; i < VOCAB * 256; i += 256) s_S[i] = 0.f;
    for (int i = tid; i < 1000; i += 256) s_trow[i] = target[n * 1000 + i];
    __syncthreads();
    {
        const float* wcol = w + (size_t)(tid >> 3) * 8000 + (tid & 7);
        for (int i = 0; i < 1000; i += 4) {
            int v0 = s_trow[i + 0], v1 = s_trow[i + 1];
            int v2 = s_trow[i + 2], v3 = s_trow[i + 3];
            float w0 = wcol[(i + 0) * 8];
            float w1 = wcol[(i + 1) * 8];
            float w2 = wcol[(i + 2) * 8];
            float w3 = wcol[(i + 3) * 8];
            s_S[v0 * 256 + tid] += w0;
            s_S[v1 * 256 + tid] += w1;
            s_S[v2 * 256 + tid] += w2;
            s_S[v3 * 256 + tid] += w3;
        }
    }
    __syncthreads();
    for (int idx = tid; idx < 121 * 32; idx += 256) {
        int t = idx >> 5, o = idx & 31;
        float acc = b[o];
#pragma unroll
        for (int v = 0; v < VOCAB; ++v) {
            const float* Sv = s_S + v * 256 + o * 8;
            const float* ev = s_emb + v * EMB + t;
#pragma unroll
            for (int k = 0; k < 8; ++k) acc += Sv[k] * ev[k];
        }
        y[((size_t)n * LP + t) * 32 + o] = __float2bfloat16(fmaxf(acc, 0.f));
    }
}

// maxpool(3) + NHC->flatten transpose
__global__ void pool3_kernel(const __hip_bfloat16* __restrict__ x, float* __restrict__ y)
{
    int idx = blockIdx.x * blockDim.x + threadIdx.x;
    if (idx >= NB * 128 * 33) return;
    int tp = idx % 33;
    int rest = idx / 33;
    int c = rest % 128;
    int n = rest / 128;
    const __hip_bfloat16* p = x + ((size_t)n * LP + tp * 3) * 128 + c;
    float m = __bfloat162float(p[0]);
    m = fmaxf(m, __bfloat162float(p[128]));
    m = fmaxf(m, __bfloat162float(p[256]));
    y[(size_t)n * 4224 + c * 33 + tp] = m;
}

// ---------------------------------------------------------------------------
// Host-side launch
// ---------------------------------------------------------------------------
extern "C" void kernel_launch(void* const* d_in, const int* in_sizes, int n_in,
                              void* d_out, int out_size, void* d_ws, size_t ws_size,
                              hipStream_t stream)
{
    const float* x      = (const float*)d_in[0];
    const int*   ei     = (const int*)d_in[1];
    const int*   target = (const int*)d_in[3];
    const float* W1  = (const float*)d_in[4];
    const float* as1 = (const float*)d_in[5];
    const float* ad1 = (const float*)d_in[6];
    const float* b1  = (const float*)d_in[7];
    const float* W2  = (const float*)d_in[8];
    const float* as2 = (const float*)d_in[9];
    const float* ad2 = (const float*)d_in[10];
    const float* b2  = (const float*)d_in[11];
    const float* W3  = (const float*)d_in[12];
    const float* as3 = (const float*)d_in[13];
    const float* ad3 = (const float*)d_in[14];
    const float* b3  = (const float*)d_in[15];
    const float* fc_g1_w = (const float*)d_in[16];
    const float* fc_g1_b = (const float*)d_in[17];
    const float* fc_g2_w = (const float*)d_in[18];
    const float* fc_g2_b = (const float*)d_in[19];
    const float* emb_xt  = (const float*)d_in[20];
    const float* cw1 = (const float*)d_in[21];
    const float* cb1 = (const float*)d_in[22];
    const float* cw2 = (const float*)d_in[23];
    const float* cb2 = (const float*)d_in[24];
    const float* cw3 = (const float*)d_in[25];
    const float* cb3 = (const float*)d_in[26];
    const float* cw4 = (const float*)d_in[27];
    const float* cb4 = (const float*)d_in[28];
    const float* fc1_xt_w = (const float*)d_in[29];
    const float* fc1_xt_b = (const float*)d_in[30];
    const float* fc2_xt_w = (const float*)d_in[31];
    const float* fc2_xt_b = (const float*)d_in[32];
    const float* fc1_w = (const float*)d_in[33];
    const float* fc1_b = (const float*)d_in[34];
    const float* fc2_w = (const float*)d_in[35];
    const float* fc2_b = (const float*)d_in[36];
    const float* out_w = (const float*)d_in[37];
    const float* out_b = (const float*)d_in[38];
    float* out = (float*)d_out;

    const int N = NNODES, E = NEDGES, Etot = E + N;
    const size_t MB = 1024 * 1024;

    // ---- workspace carve ----
    char* ws = (char*)d_ws;
    size_t off = 0;
    auto alloc = [&](size_t bytes) -> char* {
        char* p = ws + off;
        off = (off + bytes + 255) & ~(size_t)255;
        return p;
    };
    const size_t BIG = (size_t)N * 3120 * sizeof(float);   // 127.8 MB
    char*  bufA  = alloc(BIG);
    char*  bufB  = alloc(BIG);
    float*    a_s   = (float*)alloc((size_t)N * 10 * 4);
    float*    a_d   = (float*)alloc((size_t)N * 10 * 4);
    unsigned* mmax  = (unsigned*)alloc((size_t)N * 10 * 4);
    float*    denom = (float*)alloc((size_t)N * 10 * 4);
    float*    eval  = (float*)alloc((size_t)Etot * 10 * 4);
    float*    gbuf  = (float*)alloc((size_t)NB * 3120 * 4);
    float*    g1    = (float*)alloc((size_t)NB * 1024 * 4);
    float*    xt1   = (float*)alloc((size_t)NB * 1024 * 4);
    float*    xc    = (float*)alloc((size_t)NB * 256 * 4);
    float*    f1    = (float*)alloc((size_t)NB * 1024 * 4);
    float*    f2    = (float*)alloc((size_t)NB * 256 * 4);
    int*      deg     = (int*)alloc((size_t)N * 4);
    int*      rowptr  = (int*)alloc((size_t)(N + 1) * 4);
    int*      cursor  = (int*)alloc((size_t)N * 4);
    int*      eidx    = (int*)alloc((size_t)Etot * 4);

    // bf16 staging layout:
    //  bufA: linb [0,64MB) | Wt at +64MB (GAT phase); CNN scratch after GAT
    //  bufB: hbf1 [0,17MB); hbf2 +20MB; hbf3 [0,64MB); head-phase: Ptmp +100MB,
    //        Ab2 +102MB (<=2.2MB), Wt2 +105MB (<=8.5MB), P4 +115MB (<=5MB)
    __hip_bfloat16* linb = (__hip_bfloat16*)bufA;
    __hip_bfloat16* Wt   = (__hip_bfloat16*)(bufA + 64 * MB);
    __hip_bfloat16* hbf1 = (__hip_bfloat16*)bufB;
    __hip_bfloat16* hbf2 = (__hip_bfloat16*)(bufB + 20 * MB);
    __hip_bfloat16* hbf3 = (__hip_bfloat16*)bufB;
    float*          Ptmp = (float*)(bufB + 100 * MB);
    __hip_bfloat16* Ab2  = (__hip_bfloat16*)(bufB + 102 * MB);
    __hip_bfloat16* Wt2  = (__hip_bfloat16*)(bufB + 105 * MB);
    float*          P4   = (float*)(bufB + 115 * MB);

    // CNN scratch in bufA (dead after GAT layer 3)
    char* cnn = bufA;
    auto calloc2 = [&](size_t bytes) -> char* {
        char* p = cnn;
        cnn += (bytes + 255) & ~(size_t)255;
        return p;
    };
    __hip_bfloat16* act1 = (__hip_bfloat16*)calloc2((size_t)NB * LP * 32 * 2 + 4096);
    __hip_bfloat16* act2 = (__hip_bfloat16*)calloc2((size_t)NB * LP * 64 * 2 + 4096);
    __hip_bfloat16* act3 = (__hip_bfloat16*)calloc2((size_t)NB * LP * 96 * 2 + 4096);
    __hip_bfloat16* act4 = (__hip_bfloat16*)calloc2((size_t)NB * LP * 128 * 2 + 4096);
    __hip_bfloat16* wt2  = (__hip_bfloat16*)calloc2((size_t)128 * 256 * 2);
    __hip_bfloat16* wt3  = (__hip_bfloat16*)calloc2((size_t)128 * 512 * 2);
    __hip_bfloat16* wt4  = (__hip_bfloat16*)calloc2((size_t)128 * 768 * 2);
    float* xt = (float*)calloc2((size_t)NB * 4224 * 4);

    // ---- build dst-CSR once ----
    {
        (void)hipMemsetAsync(deg, 0, (size_t)N * 4, stream);
        deg_kernel<<<(Etot + 255) / 256, 256, 0, stream>>>(ei, deg, E, Etot);
        scan_kernel<<<1, 256, 0, stream>>>(deg, rowptr, N);
        (void)hipMemcpyAsync(cursor, rowptr, (size_t)N * 4, hipMemcpyDeviceToDevice, stream);
        fill_csr_kernel<<<(Etot + 255) / 256, 256, 0, stream>>>(ei, cursor, eidx, E, Etot);
    }

    // ---- f32 split-K head GEMM (small heads) ----
    auto head_gemm = [&](const float* A, const float* B, const float* bias, float* C,
                         int M, int Nc, int K, int ldC, int act, int S) {
        (void)hipMemsetAsync(Ptmp, 0, (size_t)M * Nc * 4, stream);
        int kchunk = (K + S - 1) / S;
        dim3 g((Nc + 63) / 64, (M + 63) / 64, S);
        gemm_f32_splitk<<<g, 256, 0, stream>>>(A, B, Ptmp, M, Nc, K, kchunk);
        int tot = M * Nc;
        if (act == 1)
            bias_act_ld_kernel<1><<<(tot + 255) / 256, 256, 0, stream>>>(Ptmp, bias, C, M, Nc, ldC);
        else
            bias_act_ld_kernel<0><<<(tot + 255) / 256, 256, 0, stream>>>(Ptmp, bias, C, M, Nc, ldC);
    };

    // ---- bf16 MFMA split-K head GEMM (big-K heads, relu): C f32 [M][Nc] ----
    //  A f32 [M][K] -> Ab2 bf16 [M][Kp]; W f32 [K][Nc] -> Wt2 [Nc][Kp]; S slices.
    auto head_gemm_mfma = [&](const float* A, const float* W, const float* bias,
                              float* C, int M, int Nc, int K, int Kp, int S) {
        int tps = (Kp / 64) / S;   // host guarantees exact division
        cast_a_kernel<<<(M * Kp + 255) / 256, 256, 0, stream>>>(A, Ab2, M, K, Kp);
        transpose_cast_kernel<<<dim3(Kp / 32, Nc / 32), 256, 0, stream>>>(W, Wt2, K, Nc, Kp, Nc);
        dim3 g(Nc / 128, M / 128, S);
        gemm_mfma_splitk<<<g, 256, 0, stream>>>(Ab2, Wt2, P4, M, Nc, Kp, tps);
        int tot = M * Nc;
        reduce_bias_relu_kernel<<<(tot + 255) / 256, 256, 0, stream>>>(P4, bias, C, M, Nc, S, Nc);
    };

    // ---- GAT softmax + CSR-gather chain (bf16 lin in, bf16 h out) ----
    auto gat_tail = [&](const float* atts, const float* attd, const float* bias,
                        int H, int F, int Ftp, int act,
                        const __hip_bfloat16* lin, __hip_bfloat16* outh, int Kout) {
        attn_ab_kernel<<<N * H, 64, 0, stream>>>(lin, Ftp, atts, attd, a_s, a_d, H, F);
        (void)hipMemsetAsync(mmax, 0, (size_t)N * H * 4, stream);
        (void)hipMemsetAsync(denom, 0, (size_t)N * H * 4, stream);
        int tot = Etot * H;
        edge_max_kernel<<<(tot + 255) / 256, 256, 0, stream>>>(ei, a_s, a_d, eval, mmax, E, Etot, H);
        edge_exp_kernel<<<(tot + 255) / 256, 256, 0, stream>>>(ei, mmax, eval, denom, E, Etot, H);
        alpha_norm_kernel<<<(tot + 255) / 256, 256, 0, stream>>>(ei, denom, eval, E, Etot, H);
        int Ft = H * F;
        int groups = Kout / 8;
        dim3 gg(N, (groups + 63) / 64);
        if (act == 1)
            gat_gather8_kernel<1><<<gg, 64, 0, stream>>>(rowptr, eidx, ei, eval, lin, Ftp, bias, outh, Kout, E, H, F, Ft);
        else
            gat_gather8_kernel<2><<<gg, 64, 0, stream>>>(rowptr, eidx, ei, eval, lin, Ftp, bias, outh, Kout, E, H, F, Ft);
    };

    // ---- layer 1: f32 GEMM -> bf16 lin [N][784] ----
    {
        (void)hipMemsetAsync(linb, 0, (size_t)N * 784 * 2, stream);
        dim3 gg((780 + 127) / 128, (N + 127) / 128);
        gemm_f32_big_bf16out<<<gg, 256, 0, stream>>>(x, W1, linb, N, 780, 78, 784);
        gat_tail(as1, ad1, b1, 10, 78, 784, 2, linb, hbf1, 832);
    }
    // ---- layer 2: MFMA GEMM (A=hbf1 [N][832]) -> lin [N][1560] ----
    {
        const int Kp = 832, Nout = 1560, Npad = 1664;
        transpose_cast_kernel<<<dim3(Kp / 32, Npad / 32), 256, 0, stream>>>(W2, Wt, 780, Nout, Kp, Npad);
        gemm_mfma_bf16<<<dim3(Npad / 128, N / 128), 256, 0, stream>>>(hbf1, Wt, linb, N, Nout, Kp, Nout);
        gat_tail(as2, ad2, b2, 2, 780, 1560, 1, linb, hbf2, 1600);
    }
    // ---- layer 3: MFMA GEMM (A=hbf2 [N][1600]) -> lin [N][3120] ----
    {
        const int Kp = 1600, Nout = 3120, Npad = 3200;
        transpose_cast_kernel<<<dim3(Kp / 32, Npad / 32), 256, 0, stream>>>(W3, Wt, 1560, Nout, Kp, Npad);
        gemm_mfma_bf16<<<dim3(Npad / 128, N / 128), 256, 0, stream>>>(hbf2, Wt, linb, N, Nout, Kp, Nout);
        gat_tail(as3, ad3, b3, 1, 3120, 3120, 1, linb, hbf3, 3120);
    }

    // global max pool (bf16 in) + graph FCs
    {
        int tot = NB * 3120;
        pool_max_bf16_kernel<<<(tot + 255) / 256, 256, 0, stream>>>(hbf3, gbuf, NB, N / NB, 3120);
        // fc_g1: 256x1024, K=3120 -> Kp=3200 (50 tiles), S=5
        head_gemm_mfma(gbuf, fc_g1_w, fc_g1_b, g1, NB, 1024, 3120, 3200, 5);
        head_gemm(g1, fc_g2_w, fc_g2_b, xc, NB, 128, 1024, 256, 0, 32);
    }

    // ---- CNN branch (bufA free now) ----
    {
        conv1_fact_kernel<<<NB, 256, 0, stream>>>(target, emb_xt, cw1, cb1, act1);
        conv_wt_kernel<<<(64 * 32 * 8 + 255) / 256, 256, 0, stream>>>(cw2, wt2, 64, 32);
        conv_wt_kernel<<<(96 * 64 * 8 + 255) / 256, 256, 0, stream>>>(cw3, wt3, 96, 64);
        conv_wt_kernel<<<(128 * 96 * 8 + 255) / 256, 256, 0, stream>>>(cw4, wt4, 128, 96);
        gemm_conv_bf16<32, 64, 114><<<dim3(1, NB), 256, 0, stream>>>(act1, wt2, cb2, act2);
        gemm_conv_bf16<64, 96, 107><<<dim3(1, NB), 256, 0, stream>>>(act2, wt3, cb3, act3);
        gemm_conv_bf16<96, 128, 100><<<dim3(1, NB), 256, 0, stream>>>(act3, wt4, cb4, act4);
        int tp = NB * 128 * 33;
        pool3_kernel<<<(tp + 255) / 256, 256, 0, stream>>>(act4, xt);
        // fc1_xt: 256x1024, K=4224 -> Kp=4352 (68 tiles), S=4
        head_gemm_mfma(xt, fc1_xt_w, fc1_xt_b, xt1, NB, 1024, 4224, 4352, 4);
        head_gemm(xt1, fc2_xt_w, fc2_xt_b, xc + 128, NB, 128, 1024, 256, 0, 32);
    }

    // ---- fusion head ----
    {
        head_gemm(xc, fc1_w, fc1_b, f1, NB, 1024, 256, 1024, 1, 8);
        head_gemm(f1, fc2_w, fc2_b, f2, NB, 256, 1024, 256, 1, 16);
        out_head_kernel<<<1, 256, 0, stream>>>(f2, out_w, out_b, out);
    }
}

// Round 12
// 907.561 us; speedup vs baseline: 11.6674x; 1.0255x over previous
//
#include <hip/hip_runtime.h>
#include <hip/hip_bf16.h>
#include <math.h>

// ---------------------------------------------------------------------------
// Constants (problem-fixed)
// ---------------------------------------------------------------------------
static const int NNODES = 10240;
static const int NEDGES = 40960;
static const int NB     = 256;     // graphs / batch
static const int VOCAB  = 26;
static const int EMB    = 128;
static const int LP     = 128;     // padded t-length for NHC conv activations
static const int C1SPLIT = 8;      // conv1 phase-1 i-split (1000/8 = 125)

typedef short bf16x8 __attribute__((ext_vector_type(8)));   // 8 bf16 (4 VGPRs)
typedef float f32x4  __attribute__((ext_vector_type(4)));   // 4 fp32

__device__ __forceinline__ float bf16bits2float(short s) {
    return __uint_as_float(((unsigned)(unsigned short)s) << 16);
}

// ---------------------------------------------------------------------------
// Split-K f32 GEMM for small head GEMMs (fc_g2/fc2_xt/fusion head).
// ---------------------------------------------------------------------------
__global__ __launch_bounds__(256) void gemm_f32_splitk(
    const float* __restrict__ A, const float* __restrict__ B,
    float* __restrict__ P, int M, int N, int K, int kchunk)
{
    __shared__ float As[16][65];
    __shared__ float Bs[16][65];
    int tid = threadIdx.x;
    int bm = blockIdx.y * 64;
    int bn = blockIdx.x * 64;
    int k0 = blockIdx.z * kchunk;
    int k1 = min(k0 + kchunk, K);
    int tx = tid & 15, ty = tid >> 4;
    float acc[4][4] = {};
    for (int kb = k0; kb < k1; kb += 16) {
#pragma unroll
        for (int l = 0; l < 4; ++l) {
            int idx = tid + l * 256;
            int r = idx >> 4, c = idx & 15;
            int gr = bm + r, gc = kb + c;
            As[c][r] = (gr < M && gc < k1) ? A[(size_t)gr * K + gc] : 0.f;
        }
#pragma unroll
        for (int l = 0; l < 4; ++l) {
            int idx = tid + l * 256;
            int r = idx >> 6, c = idx & 63;
            int gr = kb + r, gc = bn + c;
            Bs[r][c] = (gr < k1 && gc < N) ? B[(size_t)gr * N + gc] : 0.f;
        }
        __syncthreads();
#pragma unroll
        for (int kk = 0; kk < 16; ++kk) {
            float a[4], b[4];
#pragma unroll
            for (int i = 0; i < 4; ++i) a[i] = As[kk][ty * 4 + i];
#pragma unroll
            for (int j = 0; j < 4; ++j) b[j] = Bs[kk][tx * 4 + j];
#pragma unroll
            for (int i = 0; i < 4; ++i)
#pragma unroll
                for (int j = 0; j < 4; ++j)
                    acc[i][j] += a[i] * b[j];
        }
        __syncthreads();
    }
#pragma unroll
    for (int i = 0; i < 4; ++i) {
        int gr = bm + ty * 4 + i;
        if (gr >= M) continue;
#pragma unroll
        for (int j = 0; j < 4; ++j) {
            int gc = bn + tx * 4 + j;
            if (gc >= N) continue;
            atomicAdd(&P[(size_t)gr * N + gc], acc[i][j]);
        }
    }
}

template<int ACT>
__global__ void bias_act_ld_kernel(const float* __restrict__ P,
                                   const float* __restrict__ bias,
                                   float* __restrict__ C, int M, int N, int ldC)
{
    int t = blockIdx.x * 256 + threadIdx.x;
    if (t >= M * N) return;
    int r = t / N, c = t - r * N;
    float v = P[t] + bias[c];
    if (ACT == 1) v = fmaxf(v, 0.f);
    C[(size_t)r * ldC + c] = v;
}

// reduce S partial slices + bias + relu -> C (ldC)
__global__ void reduce_bias_relu_kernel(const float* __restrict__ P,
                                        const float* __restrict__ bias,
                                        float* __restrict__ C,
                                        int M, int N, int S, int ldC)
{
    int t = blockIdx.x * 256 + threadIdx.x;
    if (t >= M * N) return;
    int r = t / N, c = t - r * N;
    float v = bias[c];
    for (int s = 0; s < S; ++s) v += P[(size_t)s * M * N + t];
    C[(size_t)r * ldC + c] = fmaxf(v, 0.f);
}

__global__ void out_head_kernel(const float* __restrict__ f2,
                                const float* __restrict__ w,
                                const float* __restrict__ b,
                                float* __restrict__ out)
{
    __shared__ float sw[256];
    int t = threadIdx.x;
    sw[t] = w[t];
    __syncthreads();
    float acc = 0.f;
    const float* row = f2 + (size_t)t * 256;
    for (int k = 0; k < 256; ++k) acc += row[k] * sw[k];
    out[t] = acc + b[0];
}

// ---------------------------------------------------------------------------
// Big tiled f32 GEMM with bf16 output: lin1 = x @ W1 (K=78).
// ---------------------------------------------------------------------------
__global__ __launch_bounds__(256) void gemm_f32_big_bf16out(
    const float* __restrict__ A, const float* __restrict__ B,
    __hip_bfloat16* __restrict__ C, int M, int N, int K, int ldC)
{
    __shared__ float As[16][132];
    __shared__ float Bs[16][132];
    int tid = threadIdx.x;
    int bm = blockIdx.y * 128;
    int bn = blockIdx.x * 128;
    int tx = tid & 15, ty = tid >> 4;

    int ar = tid >> 1;
    int ac = (tid & 1) * 8;
    int br = tid >> 4;
    int bc = (tid & 15) * 8;

    float acc[8][8] = {};
    int gar = bm + ar;
    const float* Arow = A + (size_t)gar * K;

    for (int k0 = 0; k0 < K; k0 += 16) {
#pragma unroll
        for (int c = 0; c < 8; ++c) {
            int gc = k0 + ac + c;
            As[ac + c][ar] = (gar < M && gc < K) ? Arow[gc] : 0.f;
        }
#pragma unroll
        for (int c = 0; c < 8; ++c) {
            int gr = k0 + br;
            int gc = bn + bc + c;
            Bs[br][bc + c] = (gr < K && gc < N) ? B[(size_t)gr * N + gc] : 0.f;
        }
        __syncthreads();
#pragma unroll
        for (int kk = 0; kk < 16; ++kk) {
            float a[8], b[8];
#pragma unroll
            for (int i = 0; i < 8; ++i) a[i] = As[kk][ty * 8 + i];
#pragma unroll
            for (int j = 0; j < 8; ++j) b[j] = Bs[kk][tx * 8 + j];
#pragma unroll
            for (int i = 0; i < 8; ++i)
#pragma unroll
                for (int j = 0; j < 8; ++j)
                    acc[i][j] += a[i] * b[j];
        }
        __syncthreads();
    }
#pragma unroll
    for (int i = 0; i < 8; ++i) {
        int gr = bm + ty * 8 + i;
        if (gr >= M) continue;
#pragma unroll
        for (int j = 0; j < 8; ++j) {
            int gc = bn + tx * 8 + j;
            if (gc >= N) continue;
            C[(size_t)gr * ldC + gc] = __float2bfloat16(acc[i][j]);
        }
    }
}

// ---------------------------------------------------------------------------
// casts
// ---------------------------------------------------------------------------
__global__ void cast_a_kernel(const float* __restrict__ in, __hip_bfloat16* __restrict__ out,
                              int M, int K, int Kp)
{
    int idx = blockIdx.x * 256 + threadIdx.x;
    if (idx >= M * Kp) return;
    int r = idx / Kp, k = idx - r * Kp;
    out[idx] = __float2bfloat16(k < K ? in[(size_t)r * K + k] : 0.f);
}

__global__ __launch_bounds__(256) void transpose_cast_kernel(
    const float* __restrict__ in, __hip_bfloat16* __restrict__ out,
    int K, int N, int Kp, int Npad)
{
    __shared__ float tile[32][33];
    int k0 = blockIdx.x * 32;
    int n0 = blockIdx.y * 32;
    int tx = threadIdx.x & 31;
    int ty = threadIdx.x >> 5;
#pragma unroll
    for (int j = 0; j < 4; ++j) {
        int k = k0 + ty + j * 8, n = n0 + tx;
        tile[ty + j * 8][tx] = (k < K && n < N) ? in[(size_t)k * N + n] : 0.f;
    }
    __syncthreads();
#pragma unroll
    for (int j = 0; j < 4; ++j) {
        int n = n0 + ty + j * 8, k = k0 + tx;
        if (n < Npad && k < Kp)
            out[(size_t)n * Kp + k] = __float2bfloat16(tile[tx][ty + j * 8]);
    }
}

// wt[o][k*Ci+i] = bf16(w[o][i][k])  (conv2-4 weights)
__global__ void conv_wt_kernel(const float* __restrict__ w, __hip_bfloat16* __restrict__ wt,
                               int Co, int Ci)
{
    int idx = blockIdx.x * 256 + threadIdx.x;
    if (idx >= Co * Ci * 8) return;
    int o = idx / (Ci * 8);
    int rem = idx - o * Ci * 8;
    int i = rem >> 3, k = rem & 7;
    wt[(size_t)o * Ci * 8 + k * Ci + i] = __float2bfloat16(w[idx]);
}

// conv1 weight transpose (f32): wt[i][o*8+k] = w[o][i][k]
__global__ void conv1_wt_kernel(const float* __restrict__ w, float* __restrict__ wt)
{
    int idx = blockIdx.x * 256 + threadIdx.x;
    if (idx >= 32 * 8000) return;
    int o = idx / 8000;
    int rem = idx - o * 8000;
    int i = rem >> 3, k = rem & 7;
    wt[(size_t)i * 256 + o * 8 + k] = w[idx];
}

// ---------------------------------------------------------------------------
// Shared MFMA staging
// ---------------------------------------------------------------------------
__device__ __forceinline__ void stage_tile(
    const __hip_bfloat16* __restrict__ gA, int ldA,
    const __hip_bfloat16* __restrict__ gB, int ldB,
    short* ldsbuf, int w, int l)
{
#pragma unroll
    for (int j = 0; j < 4; ++j) {
        int u = (w * 4 + j) * 64 + l;
        int r = u >> 3, s = u & 7;
        const __hip_bfloat16* src = gA + (size_t)r * ldA + ((s ^ (r & 7)) << 3);
        __builtin_amdgcn_global_load_lds(
            (const __attribute__((address_space(1))) void*)src,
            (__attribute__((address_space(3))) void*)(ldsbuf + (w * 4 + j) * 512),
            16, 0, 0);
    }
#pragma unroll
    for (int j = 0; j < 4; ++j) {
        int u = (w * 4 + j) * 64 + l;
        int r = u >> 3, s = u & 7;
        const __hip_bfloat16* src = gB + (size_t)r * ldB + ((s ^ (r & 7)) << 3);
        __builtin_amdgcn_global_load_lds(
            (const __attribute__((address_space(1))) void*)src,
            (__attribute__((address_space(3))) void*)(ldsbuf + 8192 + (w * 4 + j) * 512),
            16, 0, 0);
    }
}

// ---------------------------------------------------------------------------
// MFMA bf16 GEMM (FC form), bf16 output, XCD-bijective block swizzle (m204).
// ---------------------------------------------------------------------------
__global__ __launch_bounds__(256, 2) void gemm_mfma_bf16(
    const __hip_bfloat16* __restrict__ A,
    const __hip_bfloat16* __restrict__ Bt,
    __hip_bfloat16* __restrict__ C, int M, int N, int Kp, int ldC)
{
    __shared__ __align__(16) short lds[2][16384];
    const int tid = threadIdx.x;
    const int w = tid >> 6, l = tid & 63;

    int nwg = gridDim.x * gridDim.y;
    int wg = blockIdx.y * gridDim.x + blockIdx.x;
    int q = nwg >> 3, r8 = nwg & 7;
    int xcd = wg & 7, lo = wg >> 3;
    int swz = (xcd < r8) ? (xcd * (q + 1) + lo) : (r8 * (q + 1) + (xcd - r8) * q + lo);
    const int bm = (swz / gridDim.x) * 128, bn = (swz % gridDim.x) * 128;

    const int wr = w >> 1, wc = w & 1;
    const int lane15 = l & 15, lhi = l >> 4;

    const __hip_bfloat16* gA = A + (size_t)bm * Kp;
    const __hip_bfloat16* gB = Bt + (size_t)bn * Kp;

    f32x4 acc[4][4] = {};

    const int nk = Kp >> 6;
    stage_tile(gA, Kp, gB, Kp, &lds[0][0], w, l);
    __syncthreads();
    int cur = 0;
    for (int t = 0; t < nk; ++t) {
        if (t + 1 < nk)
            stage_tile(gA + (t + 1) * 64, Kp, gB + (t + 1) * 64, Kp, &lds[cur ^ 1][0], w, l);
        const short* bA = &lds[cur][0];
        const short* bB = &lds[cur][8192];
#pragma unroll
        for (int ks = 0; ks < 2; ++ks) {
            bf16x8 af[4], bfr[4];
#pragma unroll
            for (int m = 0; m < 4; ++m) {
                int r = wr * 64 + m * 16 + lane15;
                int slot = (ks * 4 + lhi) ^ (r & 7);
                af[m] = *(const bf16x8*)(bA + r * 64 + slot * 8);
            }
#pragma unroll
            for (int n = 0; n < 4; ++n) {
                int r = wc * 64 + n * 16 + lane15;
                int slot = (ks * 4 + lhi) ^ (r & 7);
                bfr[n] = *(const bf16x8*)(bB + r * 64 + slot * 8);
            }
#pragma unroll
            for (int m = 0; m < 4; ++m)
#pragma unroll
                for (int n = 0; n < 4; ++n)
                    acc[m][n] = __builtin_amdgcn_mfma_f32_16x16x32_bf16(
                        af[m], bfr[n], acc[m][n], 0, 0, 0);
        }
        __syncthreads();
        cur ^= 1;
    }
#pragma unroll
    for (int m = 0; m < 4; ++m) {
#pragma unroll
        for (int n = 0; n < 4; ++n) {
            int col = bn + wc * 64 + n * 16 + lane15;
            if (col >= N) continue;
            int row0 = bm + wr * 64 + m * 16 + lhi * 4;
#pragma unroll
            for (int q2 = 0; q2 < 4; ++q2)
                C[(size_t)(row0 + q2) * ldC + col] = __float2bfloat16(acc[m][n][q2]);
        }
    }
}

// ---------------------------------------------------------------------------
// MFMA bf16 split-K GEMM (atomic-free partial slices)
// ---------------------------------------------------------------------------
__global__ __launch_bounds__(256, 2) void gemm_mfma_splitk(
    const __hip_bfloat16* __restrict__ A,
    const __hip_bfloat16* __restrict__ Bt,
    float* __restrict__ P, int M, int N, int Kp, int tps)
{
    __shared__ __align__(16) short lds[2][16384];
    const int tid = threadIdx.x;
    const int w = tid >> 6, l = tid & 63;
    const int bm = blockIdx.y * 128, bn = blockIdx.x * 128;
    const int z = blockIdx.z;
    const int wr = w >> 1, wc = w & 1;
    const int lane15 = l & 15, lhi = l >> 4;

    const __hip_bfloat16* gA = A + (size_t)bm * Kp + z * tps * 64;
    const __hip_bfloat16* gB = Bt + (size_t)bn * Kp + z * tps * 64;

    f32x4 acc[4][4] = {};

    const int nk = tps;
    stage_tile(gA, Kp, gB, Kp, &lds[0][0], w, l);
    __syncthreads();
    int cur = 0;
    for (int t = 0; t < nk; ++t) {
        if (t + 1 < nk)
            stage_tile(gA + (t + 1) * 64, Kp, gB + (t + 1) * 64, Kp, &lds[cur ^ 1][0], w, l);
        const short* bA = &lds[cur][0];
        const short* bB = &lds[cur][8192];
#pragma unroll
        for (int ks = 0; ks < 2; ++ks) {
            bf16x8 af[4], bfr[4];
#pragma unroll
            for (int m = 0; m < 4; ++m) {
                int r = wr * 64 + m * 16 + lane15;
                int slot = (ks * 4 + lhi) ^ (r & 7);
                af[m] = *(const bf16x8*)(bA + r * 64 + slot * 8);
            }
#pragma unroll
            for (int n = 0; n < 4; ++n) {
                int r = wc * 64 + n * 16 + lane15;
                int slot = (ks * 4 + lhi) ^ (r & 7);
                bfr[n] = *(const bf16x8*)(bB + r * 64 + slot * 8);
            }
#pragma unroll
            for (int m = 0; m < 4; ++m)
#pragma unroll
                for (int n = 0; n < 4; ++n)
                    acc[m][n] = __builtin_amdgcn_mfma_f32_16x16x32_bf16(
                        af[m], bfr[n], acc[m][n], 0, 0, 0);
        }
        __syncthreads();
        cur ^= 1;
    }
    float* Pz = P + (size_t)z * M * N;
#pragma unroll
    for (int m = 0; m < 4; ++m) {
#pragma unroll
        for (int n = 0; n < 4; ++n) {
            int col = bn + wc * 64 + n * 16 + lane15;
            if (col >= N) continue;
            int row0 = bm + wr * 64 + m * 16 + lhi * 4;
#pragma unroll
            for (int q2 = 0; q2 < 4; ++q2) {
                int row = row0 + q2;
                if (row < M) Pz[(size_t)row * N + col] = acc[m][n][q2];
            }
        }
    }
}

// ---------------------------------------------------------------------------
// MFMA conv GEMM (zero-im2col, NHC bf16)
// ---------------------------------------------------------------------------
template<int Ci, int Co, int Lout>
__global__ __launch_bounds__(256, 2) void gemm_conv_bf16(
    const __hip_bfloat16* __restrict__ A,
    const __hip_bfloat16* __restrict__ Bt,
    const float* __restrict__ bias,
    __hip_bfloat16* __restrict__ C)
{
    const int Kp = 8 * Ci;
    __shared__ __align__(16) short lds[2][16384];
    const int tid = threadIdx.x;
    const int w = tid >> 6, l = tid & 63;
    const int bm = blockIdx.y * 128;          // = n*128
    const int wr = w >> 1, wc = w & 1;
    const int lane15 = l & 15, lhi = l >> 4;

    const __hip_bfloat16* gA = A + (size_t)bm * Ci;
    const __hip_bfloat16* gB = Bt;

    f32x4 acc[4][4] = {};

    const int nk = Kp >> 6;
    stage_tile(gA, Ci, gB, Kp, &lds[0][0], w, l);
    __syncthreads();
    int cur = 0;
    for (int t = 0; t < nk; ++t) {
        if (t + 1 < nk)
            stage_tile(gA + (t + 1) * 64, Ci, gB + (t + 1) * 64, Kp, &lds[cur ^ 1][0], w, l);
        const short* bA = &lds[cur][0];
        const short* bB = &lds[cur][8192];
#pragma unroll
        for (int ks = 0; ks < 2; ++ks) {
            bf16x8 af[4], bfr[4];
#pragma unroll
            for (int m = 0; m < 4; ++m) {
                int r = wr * 64 + m * 16 + lane15;
                int slot = (ks * 4 + lhi) ^ (r & 7);
                af[m] = *(const bf16x8*)(bA + r * 64 + slot * 8);
            }
#pragma unroll
            for (int n = 0; n < 4; ++n) {
                int r = wc * 64 + n * 16 + lane15;
                int slot = (ks * 4 + lhi) ^ (r & 7);
                bfr[n] = *(const bf16x8*)(bB + r * 64 + slot * 8);
            }
#pragma unroll
            for (int m = 0; m < 4; ++m)
#pragma unroll
                for (int n = 0; n < 4; ++n)
                    acc[m][n] = __builtin_amdgcn_mfma_f32_16x16x32_bf16(
                        af[m], bfr[n], acc[m][n], 0, 0, 0);
        }
        __syncthreads();
        cur ^= 1;
    }
#pragma unroll
    for (int m = 0; m < 4; ++m) {
#pragma unroll
        for (int n = 0; n < 4; ++n) {
            int col = wc * 64 + n * 16 + lane15;
            if (col >= Co) continue;
            float bb = bias[col];
            int lr0 = wr * 64 + m * 16 + lhi * 4;
#pragma unroll
            for (int q2 = 0; q2 < 4; ++q2) {
                int lr = lr0 + q2;
                if (lr < Lout)
                    C[((size_t)bm + lr) * Co + col] =
                        __float2bfloat16(fmaxf(acc[m][n][q2] + bb, 0.f));
            }
        }
    }
}

// ---------------------------------------------------------------------------
// GAT helpers
// ---------------------------------------------------------------------------
__device__ __forceinline__ unsigned fmap(float f) {
    unsigned u = __float_as_uint(f);
    return (u & 0x80000000u) ? ~u : (u | 0x80000000u);
}
__device__ __forceinline__ float funmap(unsigned u) {
    return (u & 0x80000000u) ? __uint_as_float(u ^ 0x80000000u)
                             : __uint_as_float(~u);
}

__global__ void attn_ab_kernel(const __hip_bfloat16* __restrict__ lin, int Ftp,
                               const float* __restrict__ att_s,
                               const float* __restrict__ att_d,
                               float* __restrict__ a_s, float* __restrict__ a_d,
                               int H, int F)
{
    int bid = blockIdx.x;           // n*H + h
    int n = bid / H, h = bid - n * H;
    int lane = threadIdx.x;
    const __hip_bfloat16* row = lin + (size_t)n * Ftp + h * F;
    const float* wsrc = att_s + h * F;
    const float* wdst = att_d + h * F;
    float ss = 0.f, sd = 0.f;
    for (int f = lane; f < F; f += 64) {
        float v = __bfloat162float(row[f]);
        ss += v * wsrc[f];
        sd += v * wdst[f];
    }
    for (int o = 32; o; o >>= 1) {
        ss += __shfl_down(ss, o);
        sd += __shfl_down(sd, o);
    }
    if (lane == 0) { a_s[bid] = ss; a_d[bid] = sd; }
}

__global__ void edge_max_kernel(const int* __restrict__ ei,
                                const float* __restrict__ a_s,
                                const float* __restrict__ a_d,
                                float* __restrict__ eval,
                                unsigned* __restrict__ mmax,
                                int E, int Etot, int H)
{
    int t = blockIdx.x * blockDim.x + threadIdx.x;
    if (t >= Etot * H) return;
    int e = t / H, h = t - e * H;
    int s, d;
    if (e < E) { s = ei[e]; d = ei[E + e]; } else { s = d = e - E; }
    float v = a_s[s * H + h] + a_d[d * H + h];
    v = v > 0.f ? v : 0.2f * v;
    eval[t] = v;
    atomicMax(&mmax[d * H + h], fmap(v));
}

__global__ void edge_exp_kernel(const int* __restrict__ ei,
                                const unsigned* __restrict__ mmax,
                                float* __restrict__ eval,
                                float* __restrict__ denom,
                                int E, int Etot, int H)
{
    int t = blockIdx.x * blockDim.x + threadIdx.x;
    if (t >= Etot * H) return;
    int e = t / H, h = t - e * H;
    int d = (e < E) ? ei[E + e] : e - E;
    float m = funmap(mmax[d * H + h]);
    float ex = expf(eval[t] - m);
    eval[t] = ex;
    atomicAdd(&denom[d * H + h], ex);
}

__global__ void alpha_norm_kernel(const int* __restrict__ ei,
                                  const float* __restrict__ denom,
                                  float* __restrict__ eval,
                                  int E, int Etot, int H)
{
    int t = blockIdx.x * blockDim.x + threadIdx.x;
    if (t >= Etot * H) return;
    int e = t / H, h = t - e * H;
    int d = (e < E) ? ei[E + e] : e - E;
    eval[t] = eval[t] / (denom[d * H + h] + 1e-16f);
}

// ---- dst-CSR build ----
__global__ void deg_kernel(const int* __restrict__ ei, int* __restrict__ deg,
                           int E, int Etot)
{
    int e = blockIdx.x * 256 + threadIdx.x;
    if (e >= Etot) return;
    int d = (e < E) ? ei[E + e] : e - E;
    atomicAdd(&deg[d], 1);
}

__global__ __launch_bounds__(256) void scan_kernel(const int* __restrict__ deg,
                                                   int* __restrict__ rowptr, int n)
{
    __shared__ int partial[256];
    int tid = threadIdx.x;
    const int per = (n + 255) / 256;
    int base = tid * per;
    int sum = 0;
    for (int i = 0; i < per; ++i) {
        int idx = base + i;
        if (idx < n) sum += deg[idx];
    }
    partial[tid] = sum;
    __syncthreads();
    for (int offs = 1; offs < 256; offs <<= 1) {
        int v = (tid >= offs) ? partial[tid - offs] : 0;
        __syncthreads();
        partial[tid] += v;
        __syncthreads();
    }
    int run = (tid == 0) ? 0 : partial[tid - 1];
    for (int i = 0; i < per; ++i) {
        int idx = base + i;
        if (idx < n) { rowptr[idx] = run; run += deg[idx]; }
    }
    if (tid == 255) rowptr[n] = run;
}

__global__ void fill_csr_kernel(const int* __restrict__ ei, int* __restrict__ cursor,
                                int* __restrict__ eidx, int E, int Etot)
{
    int e = blockIdx.x * 256 + threadIdx.x;
    if (e >= Etot) return;
    int d = (e < E) ? ei[E + e] : e - E;
    int pos = atomicAdd(&cursor[d], 1);
    eidx[pos] = e;
}

// Gather aggregation, bf16 in / bf16 out (next-GEMM layout, pad zeroed).
template<int ACT>
__global__ __launch_bounds__(64) void gat_gather8_kernel(
    const int* __restrict__ rowptr, const int* __restrict__ eidx,
    const int* __restrict__ ei, const float* __restrict__ alpha,
    const __hip_bfloat16* __restrict__ lin, int Ftp,
    const float* __restrict__ bias,
    __hip_bfloat16* __restrict__ outh, int Kout,
    int E, int H, int F, int Ft)
{
    int d = blockIdx.x;
    int g = blockIdx.y * 64 + threadIdx.x;      // col group
    int c0 = g * 8;
    if (c0 >= Kout) return;
    bf16x8 res;
    if (c0 >= Ft) {   // pure pad group: write zeros
#pragma unroll
        for (int j = 0; j < 8; ++j) res[j] = 0;
        *(bf16x8*)(outh + (size_t)d * Kout + c0) = res;
        return;
    }
    int hj[8];
#pragma unroll
    for (int j = 0; j < 8; ++j) hj[j] = min((c0 + j) / F, H - 1);
    float acc[8] = {};
    int p0 = rowptr[d], p1 = rowptr[d + 1];
    for (int p = p0; p < p1; ++p) {
        int e = eidx[p];
        int s = (e < E) ? ei[e] : e - E;
        bf16x8 v = *(const bf16x8*)(lin + (size_t)s * Ftp + c0);
        const float* aE = alpha + (size_t)e * H;
        if (H == 1) {
            float a = aE[0];
#pragma unroll
            for (int j = 0; j < 8; ++j)
                acc[j] += a * bf16bits2float(v[j]);
        } else {
#pragma unroll
            for (int j = 0; j < 8; ++j)
                acc[j] += aE[hj[j]] * bf16bits2float(v[j]);
        }
    }
#pragma unroll
    for (int j = 0; j < 8; ++j) {
        int c = c0 + j;
        float val = 0.f;
        if (c < Ft) {
            val = acc[j] + bias[c];
            if (ACT == 1) val = fmaxf(val, 0.f);
            else if (ACT == 2) val = val > 0.f ? val : expm1f(val);
        }
        __hip_bfloat16 bv = __float2bfloat16(val);
        res[j] = *(const short*)&bv;
    }
    *(bf16x8*)(outh + (size_t)d * Kout + c0) = res;
}

// global max pool over bf16 h3 [N][3120] -> gbuf f32 [NB][3120]
__global__ void pool_max_bf16_kernel(const __hip_bfloat16* __restrict__ h,
                                     float* __restrict__ g, int B, int per, int C)
{
    int t = blockIdx.x * blockDim.x + threadIdx.x;
    if (t >= B * C) return;
    int b = t / C, f = t - b * C;
    const __hip_bfloat16* p = h + (size_t)b * per * C + f;
    float m = -INFINITY;
    for (int j = 0; j < per; ++j) m = fmaxf(m, __bfloat162float(p[(size_t)j * C]));
    g[t] = m;
}

// ---------------------------------------------------------------------------
// CNN branch — conv1 vocab-factorized, split phase 1
// ---------------------------------------------------------------------------
// phase 1: block (n, z) accumulates S over i in [z*125,(z+1)*125)
// wt is k-major transposed f32 [1000][256] -> coalesced loads.
__global__ __launch_bounds__(256) void conv1_p1_kernel(
    const int* __restrict__ target, const float* __restrict__ wt,
    float* __restrict__ Spart)
{
    __shared__ float s_S[VOCAB * 256];
    __shared__ int   s_trow[125];
    int tid = threadIdx.x;
    int n = blockIdx.x, z = blockIdx.y;
    for (int i = tid; i < VOCAB * 256; i += 256) s_S[i] = 0.f;
    if (tid < 125) s_trow[tid] = target[n * 1000 + z * 125 + tid];
    __syncthreads();
    const float* wz = wt + (size_t)(z * 125) * 256 + tid;
    for (int i = 0; i < 125; ++i) {
        int v = s_trow[i];
        s_S[v * 256 + tid] += wz[(size_t)i * 256];
    }
    __syncthreads();
    float* outp = Spart + ((size_t)n * C1SPLIT + z) * (VOCAB * 256);
    for (int i = tid; i < VOCAB * 256; i += 256) outp[i] = s_S[i];
}

// phase 2: sum partials + emb product -> NHC bf16 act1
__global__ __launch_bounds__(256) void conv1_p2_kernel(
    const float* __restrict__ Spart, const float* __restrict__ emb,
    const float* __restrict__ b, __hip_bfloat16* __restrict__ y)
{
    __shared__ float s_emb[VOCAB * EMB];
    __shared__ float s_S[VOCAB * 256];
    int tid = threadIdx.x;
    int n = blockIdx.x;
    for (int i = tid; i < VOCAB * EMB; i += 256) s_emb[i] = emb[i];
    const float* base = Spart + (size_t)n * C1SPLIT * (VOCAB * 256);
    for (int i = tid; i < VOCAB * 256; i += 256) {
        float s = 0.f;
#pragma unroll
        for (int z = 0; z < C1SPLIT; ++z) s += base[(size_t)z * (VOCAB * 256) + i];
        s_S[i] = s;
    }
    __syncthreads();
    for (int idx = tid; idx < 121 * 32; idx += 256) {
        int t = idx >> 5, o = idx & 31;
        float acc = b[o];
#pragma unroll
        for (int v = 0; v < VOCAB; ++v) {
            const float* Sv = s_S + v * 256 + o * 8;
            const float* ev = s_emb + v * EMB + t;
#pragma unroll
            for (int k = 0; k < 8; ++k) acc += Sv[k] * ev[k];
        }
        y[((size_t)n * LP + t) * 32 + o] = __float2bfloat16(fmaxf(acc, 0.f));
    }
}

// maxpool(3) + NHC->flatten transpose
__global__ void pool3_kernel(const __hip_bfloat16* __restrict__ x, float* __restrict__ y)
{
    int idx = blockIdx.x * blockDim.x + threadIdx.x;
    if (idx >= NB * 128 * 33) return;
    int tp = idx % 33;
    int rest = idx / 33;
    int c = rest % 128;
    int n = rest / 128;
    const __hip_bfloat16* p = x + ((size_t)n * LP + tp * 3) * 128 + c;
    float m = __bfloat162float(p[0]);
    m = fmaxf(m, __bfloat162float(p[128]));
    m = fmaxf(m, __bfloat162float(p[256]));
    y[(size_t)n * 4224 + c * 33 + tp] = m;
}

// ---------------------------------------------------------------------------
// Host-side launch
// ---------------------------------------------------------------------------
extern "C" void kernel_launch(void* const* d_in, const int* in_sizes, int n_in,
                              void* d_out, int out_size, void* d_ws, size_t ws_size,
                              hipStream_t stream)
{
    const float* x      = (const float*)d_in[0];
    const int*   ei     = (const int*)d_in[1];
    const int*   target = (const int*)d_in[3];
    const float* W1  = (const float*)d_in[4];
    const float* as1 = (const float*)d_in[5];
    const float* ad1 = (const float*)d_in[6];
    const float* b1  = (const float*)d_in[7];
    const float* W2  = (const float*)d_in[8];
    const float* as2 = (const float*)d_in[9];
    const float* ad2 = (const float*)d_in[10];
    const float* b2  = (const float*)d_in[11];
    const float* W3  = (const float*)d_in[12];
    const float* as3 = (const float*)d_in[13];
    const float* ad3 = (const float*)d_in[14];
    const float* b3  = (const float*)d_in[15];
    const float* fc_g1_w = (const float*)d_in[16];
    const float* fc_g1_b = (const float*)d_in[17];
    const float* fc_g2_w = (const float*)d_in[18];
    const float* fc_g2_b = (const float*)d_in[19];
    const float* emb_xt  = (const float*)d_in[20];
    const float* cw1 = (const float*)d_in[21];
    const float* cb1 = (const float*)d_in[22];
    const float* cw2 = (const float*)d_in[23];
    const float* cb2 = (const float*)d_in[24];
    const float* cw3 = (const float*)d_in[25];
    const float* cb3 = (const float*)d_in[26];
    const float* cw4 = (const float*)d_in[27];
    const float* cb4 = (const float*)d_in[28];
    const float* fc1_xt_w = (const float*)d_in[29];
    const float* fc1_xt_b = (const float*)d_in[30];
    const float* fc2_xt_w = (const float*)d_in[31];
    const float* fc2_xt_b = (const float*)d_in[32];
    const float* fc1_w = (const float*)d_in[33];
    const float* fc1_b = (const float*)d_in[34];
    const float* fc2_w = (const float*)d_in[35];
    const float* fc2_b = (const float*)d_in[36];
    const float* out_w = (const float*)d_in[37];
    const float* out_b = (const float*)d_in[38];
    float* out = (float*)d_out;

    const int N = NNODES, E = NEDGES, Etot = E + N;
    const size_t MB = 1024 * 1024;

    // ---- workspace carve ----
    char* ws = (char*)d_ws;
    size_t off = 0;
    auto alloc = [&](size_t bytes) -> char* {
        char* p = ws + off;
        off = (off + bytes + 255) & ~(size_t)255;
        return p;
    };
    const size_t BIG = (size_t)N * 3120 * sizeof(float);   // 127.8 MB
    char*  bufA  = alloc(BIG);
    char*  bufB  = alloc(BIG);
    float*    a_s   = (float*)alloc((size_t)N * 10 * 4);
    float*    a_d   = (float*)alloc((size_t)N * 10 * 4);
    unsigned* mmax  = (unsigned*)alloc((size_t)N * 10 * 4);
    float*    denom = (float*)alloc((size_t)N * 10 * 4);
    float*    eval  = (float*)alloc((size_t)Etot * 10 * 4);
    float*    gbuf  = (float*)alloc((size_t)NB * 3120 * 4);
    float*    g1    = (float*)alloc((size_t)NB * 1024 * 4);
    float*    xt1   = (float*)alloc((size_t)NB * 1024 * 4);
    float*    xc    = (float*)alloc((size_t)NB * 256 * 4);
    float*    f1    = (float*)alloc((size_t)NB * 1024 * 4);
    float*    f2    = (float*)alloc((size_t)NB * 256 * 4);
    int*      deg     = (int*)alloc((size_t)N * 4);
    int*      rowptr  = (int*)alloc((size_t)(N + 1) * 4);
    int*      cursor  = (int*)alloc((size_t)N * 4);
    int*      eidx    = (int*)alloc((size_t)Etot * 4);

    __hip_bfloat16* linb = (__hip_bfloat16*)bufA;
    __hip_bfloat16* Wt   = (__hip_bfloat16*)(bufA + 64 * MB);
    __hip_bfloat16* hbf1 = (__hip_bfloat16*)bufB;
    __hip_bfloat16* hbf2 = (__hip_bfloat16*)(bufB + 20 * MB);
    __hip_bfloat16* hbf3 = (__hip_bfloat16*)bufB;
    float*          Ptmp = (float*)(bufB + 100 * MB);
    __hip_bfloat16* Ab2  = (__hip_bfloat16*)(bufB + 102 * MB);
    __hip_bfloat16* Wt2  = (__hip_bfloat16*)(bufB + 105 * MB);
    float*          P4   = (float*)(bufB + 115 * MB);

    // CNN scratch in bufA (dead after GAT layer 3)
    char* cnn = bufA;
    auto calloc2 = [&](size_t bytes) -> char* {
        char* p = cnn;
        cnn += (bytes + 255) & ~(size_t)255;
        return p;
    };
    __hip_bfloat16* act1 = (__hip_bfloat16*)calloc2((size_t)NB * LP * 32 * 2 + 4096);
    __hip_bfloat16* act2 = (__hip_bfloat16*)calloc2((size_t)NB * LP * 64 * 2 + 4096);
    __hip_bfloat16* act3 = (__hip_bfloat16*)calloc2((size_t)NB * LP * 96 * 2 + 4096);
    __hip_bfloat16* act4 = (__hip_bfloat16*)calloc2((size_t)NB * LP * 128 * 2 + 4096);
    __hip_bfloat16* wt2  = (__hip_bfloat16*)calloc2((size_t)128 * 256 * 2);
    __hip_bfloat16* wt3  = (__hip_bfloat16*)calloc2((size_t)128 * 512 * 2);
    __hip_bfloat16* wt4  = (__hip_bfloat16*)calloc2((size_t)128 * 768 * 2);
    float* xt = (float*)calloc2((size_t)NB * 4224 * 4);
    float* wt1f  = (float*)calloc2((size_t)1000 * 256 * 4);                 // 1.02 MB
    float* Spart = (float*)calloc2((size_t)NB * C1SPLIT * VOCAB * 256 * 4); // 54.5 MB

    // ---- build dst-CSR once ----
    {
        (void)hipMemsetAsync(deg, 0, (size_t)N * 4, stream);
        deg_kernel<<<(Etot + 255) / 256, 256, 0, stream>>>(ei, deg, E, Etot);
        scan_kernel<<<1, 256, 0, stream>>>(deg, rowptr, N);
        (void)hipMemcpyAsync(cursor, rowptr, (size_t)N * 4, hipMemcpyDeviceToDevice, stream);
        fill_csr_kernel<<<(Etot + 255) / 256, 256, 0, stream>>>(ei, cursor, eidx, E, Etot);
    }

    // ---- f32 split-K head GEMM (small heads) ----
    auto head_gemm = [&](const float* A, const float* B, const float* bias, float* C,
                         int M, int Nc, int K, int ldC, int act, int S) {
        (void)hipMemsetAsync(Ptmp, 0, (size_t)M * Nc * 4, stream);
        int kchunk = (K + S - 1) / S;
        dim3 g((Nc + 63) / 64, (M + 63) / 64, S);
        gemm_f32_splitk<<<g, 256, 0, stream>>>(A, B, Ptmp, M, Nc, K, kchunk);
        int tot = M * Nc;
        if (act == 1)
            bias_act_ld_kernel<1><<<(tot + 255) / 256, 256, 0, stream>>>(Ptmp, bias, C, M, Nc, ldC);
        else
            bias_act_ld_kernel<0><<<(tot + 255) / 256, 256, 0, stream>>>(Ptmp, bias, C, M, Nc, ldC);
    };

    // ---- bf16 MFMA split-K head GEMM (big-K heads, relu) ----
    auto head_gemm_mfma = [&](const float* A, const float* W, const float* bias,
                              float* C, int M, int Nc, int K, int Kp, int S) {
        int tps = (Kp / 64) / S;
        cast_a_kernel<<<(M * Kp + 255) / 256, 256, 0, stream>>>(A, Ab2, M, K, Kp);
        transpose_cast_kernel<<<dim3(Kp / 32, Nc / 32), 256, 0, stream>>>(W, Wt2, K, Nc, Kp, Nc);
        dim3 g(Nc / 128, M / 128, S);
        gemm_mfma_splitk<<<g, 256, 0, stream>>>(Ab2, Wt2, P4, M, Nc, Kp, tps);
        int tot = M * Nc;
        reduce_bias_relu_kernel<<<(tot + 255) / 256, 256, 0, stream>>>(P4, bias, C, M, Nc, S, Nc);
    };

    // ---- GAT softmax + CSR-gather chain ----
    auto gat_tail = [&](const float* atts, const float* attd, const float* bias,
                        int H, int F, int Ftp, int act,
                        const __hip_bfloat16* lin, __hip_bfloat16* outh, int Kout) {
        attn_ab_kernel<<<N * H, 64, 0, stream>>>(lin, Ftp, atts, attd, a_s, a_d, H, F);
        (void)hipMemsetAsync(mmax, 0, (size_t)N * H * 4, stream);
        (void)hipMemsetAsync(denom, 0, (size_t)N * H * 4, stream);
        int tot = Etot * H;
        edge_max_kernel<<<(tot + 255) / 256, 256, 0, stream>>>(ei, a_s, a_d, eval, mmax, E, Etot, H);
        edge_exp_kernel<<<(tot + 255) / 256, 256, 0, stream>>>(ei, mmax, eval, denom, E, Etot, H);
        alpha_norm_kernel<<<(tot + 255) / 256, 256, 0, stream>>>(ei, denom, eval, E, Etot, H);
        int Ft = H * F;
        int groups = Kout / 8;
        dim3 gg(N, (groups + 63) / 64);
        if (act == 1)
            gat_gather8_kernel<1><<<gg, 64, 0, stream>>>(rowptr, eidx, ei, eval, lin, Ftp, bias, outh, Kout, E, H, F, Ft);
        else
            gat_gather8_kernel<2><<<gg, 64, 0, stream>>>(rowptr, eidx, ei, eval, lin, Ftp, bias, outh, Kout, E, H, F, Ft);
    };

    // ---- layer 1: f32 GEMM -> bf16 lin [N][784] ----
    {
        (void)hipMemsetAsync(linb, 0, (size_t)N * 784 * 2, stream);
        dim3 gg((780 + 127) / 128, (N + 127) / 128);
        gemm_f32_big_bf16out<<<gg, 256, 0, stream>>>(x, W1, linb, N, 780, 78, 784);
        gat_tail(as1, ad1, b1, 10, 78, 784, 2, linb, hbf1, 832);
    }
    // ---- layer 2: MFMA GEMM -> lin [N][1560] ----
    {
        const int Kp = 832, Nout = 1560, Npad = 1664;
        transpose_cast_kernel<<<dim3(Kp / 32, Npad / 32), 256, 0, stream>>>(W2, Wt, 780, Nout, Kp, Npad);
        gemm_mfma_bf16<<<dim3(Npad / 128, N / 128), 256, 0, stream>>>(hbf1, Wt, linb, N, Nout, Kp, Nout);
        gat_tail(as2, ad2, b2, 2, 780, 1560, 1, linb, hbf2, 1600);
    }
    // ---- layer 3: MFMA GEMM -> lin [N][3120] ----
    {
        const int Kp = 1600, Nout = 3120, Npad = 3200;
        transpose_cast_kernel<<<dim3(Kp / 32, Npad / 32), 256, 0, stream>>>(W3, Wt, 1560, Nout, Kp, Npad);
        gemm_mfma_bf16<<<dim3(Npad / 128, N / 128), 256, 0, stream>>>(hbf2, Wt, linb, N, Nout, Kp, Nout);
        gat_tail(as3, ad3, b3, 1, 3120, 3120, 1, linb, hbf3, 3120);
    }

    // global max pool (bf16 in) + graph FCs
    {
        int tot = NB * 3120;
        pool_max_bf16_kernel<<<(tot + 255) / 256, 256, 0, stream>>>(hbf3, gbuf, NB, N / NB, 3120);
        head_gemm_mfma(gbuf, fc_g1_w, fc_g1_b, g1, NB, 1024, 3120, 3200, 5);
        head_gemm(g1, fc_g2_w, fc_g2_b, xc, NB, 128, 1024, 256, 0, 32);
    }

    // ---- CNN branch (bufA free now) ----
    {
        conv1_wt_kernel<<<(32 * 8000 + 255) / 256, 256, 0, stream>>>(cw1, wt1f);
        conv1_p1_kernel<<<dim3(NB, C1SPLIT), 256, 0, stream>>>(target, wt1f, Spart);
        conv1_p2_kernel<<<NB, 256, 0, stream>>>(Spart, emb_xt, cb1, act1);
        conv_wt_kernel<<<(64 * 32 * 8 + 255) / 256, 256, 0, stream>>>(cw2, wt2, 64, 32);
        conv_wt_kernel<<<(96 * 64 * 8 + 255) / 256, 256, 0, stream>>>(cw3, wt3, 96, 64);
        conv_wt_kernel<<<(128 * 96 * 8 + 255) / 256, 256, 0, stream>>>(cw4, wt4, 128, 96);
        gemm_conv_bf16<32, 64, 114><<<dim3(1, NB), 256, 0, stream>>>(act1, wt2, cb2, act2);
        gemm_conv_bf16<64, 96, 107><<<dim3(1, NB), 256, 0, stream>>>(act2, wt3, cb3, act3);
        gemm_conv_bf16<96, 128, 100><<<dim3(1, NB), 256, 0, stream>>>(act3, wt4, cb4, act4);
        int tp = NB * 128 * 33;
        pool3_kernel<<<(tp + 255) / 256, 256, 0, stream>>>(act4, xt);
        head_gemm_mfma(xt, fc1_xt_w, fc1_xt_b, xt1, NB, 1024, 4224, 4352, 4);
        head_gemm(xt1, fc2_xt_w, fc2_xt_b, xc + 128, NB, 128, 1024, 256, 0, 32);
    }

    // ---- fusion head ----
    {
        head_gemm(xc, fc1_w, fc1_b, f1, NB, 1024, 256, 1024, 1, 8);
        head_gemm(f1, fc2_w, fc2_b, f2, NB, 256, 1024, 256, 1, 16);
        out_head_kernel<<<1, 256, 0, stream>>>(f2, out_w, out_b, out);
    }
}

// Round 13
// 878.152 us; speedup vs baseline: 12.0582x; 1.0335x over previous
//
#include <hip/hip_runtime.h>
#include <hip/hip_bf16.h>
#include <math.h>

// ---------------------------------------------------------------------------
// Constants (problem-fixed)
// ---------------------------------------------------------------------------
static const int NNODES = 10240;
static const int NEDGES = 40960;
static const int NB     = 256;     // graphs / batch
static const int VOCAB  = 26;
static const int EMB    = 128;
static const int LP     = 128;     // padded t-length for NHC conv activations
static const int C1SPLIT = 8;      // conv1 phase-1 i-split (1000/8 = 125)

typedef short bf16x8 __attribute__((ext_vector_type(8)));   // 8 bf16 (4 VGPRs)
typedef float f32x4  __attribute__((ext_vector_type(4)));   // 4 fp32

__device__ __forceinline__ float bf16bits2float(short s) {
    return __uint_as_float(((unsigned)(unsigned short)s) << 16);
}

// ---------------------------------------------------------------------------
// Split-K f32 GEMM for small head GEMMs (fc_g2/fc2_xt/fusion head).
// ---------------------------------------------------------------------------
__global__ __launch_bounds__(256) void gemm_f32_splitk(
    const float* __restrict__ A, const float* __restrict__ B,
    float* __restrict__ P, int M, int N, int K, int kchunk)
{
    __shared__ float As[16][65];
    __shared__ float Bs[16][65];
    int tid = threadIdx.x;
    int bm = blockIdx.y * 64;
    int bn = blockIdx.x * 64;
    int k0 = blockIdx.z * kchunk;
    int k1 = min(k0 + kchunk, K);
    int tx = tid & 15, ty = tid >> 4;
    float acc[4][4] = {};
    for (int kb = k0; kb < k1; kb += 16) {
#pragma unroll
        for (int l = 0; l < 4; ++l) {
            int idx = tid + l * 256;
            int r = idx >> 4, c = idx & 15;
            int gr = bm + r, gc = kb + c;
            As[c][r] = (gr < M && gc < k1) ? A[(size_t)gr * K + gc] : 0.f;
        }
#pragma unroll
        for (int l = 0; l < 4; ++l) {
            int idx = tid + l * 256;
            int r = idx >> 6, c = idx & 63;
            int gr = kb + r, gc = bn + c;
            Bs[r][c] = (gr < k1 && gc < N) ? B[(size_t)gr * N + gc] : 0.f;
        }
        __syncthreads();
#pragma unroll
        for (int kk = 0; kk < 16; ++kk) {
            float a[4], b[4];
#pragma unroll
            for (int i = 0; i < 4; ++i) a[i] = As[kk][ty * 4 + i];
#pragma unroll
            for (int j = 0; j < 4; ++j) b[j] = Bs[kk][tx * 4 + j];
#pragma unroll
            for (int i = 0; i < 4; ++i)
#pragma unroll
                for (int j = 0; j < 4; ++j)
                    acc[i][j] += a[i] * b[j];
        }
        __syncthreads();
    }
#pragma unroll
    for (int i = 0; i < 4; ++i) {
        int gr = bm + ty * 4 + i;
        if (gr >= M) continue;
#pragma unroll
        for (int j = 0; j < 4; ++j) {
            int gc = bn + tx * 4 + j;
            if (gc >= N) continue;
            atomicAdd(&P[(size_t)gr * N + gc], acc[i][j]);
        }
    }
}

template<int ACT>
__global__ void bias_act_ld_kernel(const float* __restrict__ P,
                                   const float* __restrict__ bias,
                                   float* __restrict__ C, int M, int N, int ldC)
{
    int t = blockIdx.x * 256 + threadIdx.x;
    if (t >= M * N) return;
    int r = t / N, c = t - r * N;
    float v = P[t] + bias[c];
    if (ACT == 1) v = fmaxf(v, 0.f);
    C[(size_t)r * ldC + c] = v;
}

// reduce S partial slices + bias + relu -> C (ldC)
__global__ void reduce_bias_relu_kernel(const float* __restrict__ P,
                                        const float* __restrict__ bias,
                                        float* __restrict__ C,
                                        int M, int N, int S, int ldC)
{
    int t = blockIdx.x * 256 + threadIdx.x;
    if (t >= M * N) return;
    int r = t / N, c = t - r * N;
    float v = bias[c];
    for (int s = 0; s < S; ++s) v += P[(size_t)s * M * N + t];
    C[(size_t)r * ldC + c] = fmaxf(v, 0.f);
}

__global__ void out_head_kernel(const float* __restrict__ f2,
                                const float* __restrict__ w,
                                const float* __restrict__ b,
                                float* __restrict__ out)
{
    __shared__ float sw[256];
    int t = threadIdx.x;
    sw[t] = w[t];
    __syncthreads();
    float acc = 0.f;
    const float* row = f2 + (size_t)t * 256;
    for (int k = 0; k < 256; ++k) acc += row[k] * sw[k];
    out[t] = acc + b[0];
}

// ---------------------------------------------------------------------------
// casts
// ---------------------------------------------------------------------------
__global__ void cast_a_kernel(const float* __restrict__ in, __hip_bfloat16* __restrict__ out,
                              int M, int K, int Kp)
{
    int idx = blockIdx.x * 256 + threadIdx.x;
    if (idx >= M * Kp) return;
    int r = idx / Kp, k = idx - r * Kp;
    out[idx] = __float2bfloat16(k < K ? in[(size_t)r * K + k] : 0.f);
}

__global__ __launch_bounds__(256) void transpose_cast_kernel(
    const float* __restrict__ in, __hip_bfloat16* __restrict__ out,
    int K, int N, int Kp, int Npad)
{
    __shared__ float tile[32][33];
    int k0 = blockIdx.x * 32;
    int n0 = blockIdx.y * 32;
    int tx = threadIdx.x & 31;
    int ty = threadIdx.x >> 5;
#pragma unroll
    for (int j = 0; j < 4; ++j) {
        int k = k0 + ty + j * 8, n = n0 + tx;
        tile[ty + j * 8][tx] = (k < K && n < N) ? in[(size_t)k * N + n] : 0.f;
    }
    __syncthreads();
#pragma unroll
    for (int j = 0; j < 4; ++j) {
        int n = n0 + ty + j * 8, k = k0 + tx;
        if (n < Npad && k < Kp)
            out[(size_t)n * Kp + k] = __float2bfloat16(tile[tx][ty + j * 8]);
    }
}

// wt[o][k*Ci+i] = bf16(w[o][i][k])  (conv2-4 weights)
__global__ void conv_wt_kernel(const float* __restrict__ w, __hip_bfloat16* __restrict__ wt,
                               int Co, int Ci)
{
    int idx = blockIdx.x * 256 + threadIdx.x;
    if (idx >= Co * Ci * 8) return;
    int o = idx / (Ci * 8);
    int rem = idx - o * Ci * 8;
    int i = rem >> 3, k = rem & 7;
    wt[(size_t)o * Ci * 8 + k * Ci + i] = __float2bfloat16(w[idx]);
}

// conv1 weight transpose (f32): wt[i][o*8+k] = w[o][i][k]
__global__ void conv1_wt_kernel(const float* __restrict__ w, float* __restrict__ wt)
{
    int idx = blockIdx.x * 256 + threadIdx.x;
    if (idx >= 32 * 8000) return;
    int o = idx / 8000;
    int rem = idx - o * 8000;
    int i = rem >> 3, k = rem & 7;
    wt[(size_t)i * 256 + o * 8 + k] = w[idx];
}

// ---------------------------------------------------------------------------
// Shared MFMA staging
// ---------------------------------------------------------------------------
__device__ __forceinline__ void stage_tile(
    const __hip_bfloat16* __restrict__ gA, int ldA,
    const __hip_bfloat16* __restrict__ gB, int ldB,
    short* ldsbuf, int w, int l)
{
#pragma unroll
    for (int j = 0; j < 4; ++j) {
        int u = (w * 4 + j) * 64 + l;
        int r = u >> 3, s = u & 7;
        const __hip_bfloat16* src = gA + (size_t)r * ldA + ((s ^ (r & 7)) << 3);
        __builtin_amdgcn_global_load_lds(
            (const __attribute__((address_space(1))) void*)src,
            (__attribute__((address_space(3))) void*)(ldsbuf + (w * 4 + j) * 512),
            16, 0, 0);
    }
#pragma unroll
    for (int j = 0; j < 4; ++j) {
        int u = (w * 4 + j) * 64 + l;
        int r = u >> 3, s = u & 7;
        const __hip_bfloat16* src = gB + (size_t)r * ldB + ((s ^ (r & 7)) << 3);
        __builtin_amdgcn_global_load_lds(
            (const __attribute__((address_space(1))) void*)src,
            (__attribute__((address_space(3))) void*)(ldsbuf + 8192 + (w * 4 + j) * 512),
            16, 0, 0);
    }
}

// ---------------------------------------------------------------------------
// MFMA bf16 GEMM (FC form), bf16 output, XCD-bijective block swizzle (m204).
// ---------------------------------------------------------------------------
__global__ __launch_bounds__(256, 2) void gemm_mfma_bf16(
    const __hip_bfloat16* __restrict__ A,
    const __hip_bfloat16* __restrict__ Bt,
    __hip_bfloat16* __restrict__ C, int M, int N, int Kp, int ldC)
{
    __shared__ __align__(16) short lds[2][16384];
    const int tid = threadIdx.x;
    const int w = tid >> 6, l = tid & 63;

    int nwg = gridDim.x * gridDim.y;
    int wg = blockIdx.y * gridDim.x + blockIdx.x;
    int q = nwg >> 3, r8 = nwg & 7;
    int xcd = wg & 7, lo = wg >> 3;
    int swz = (xcd < r8) ? (xcd * (q + 1) + lo) : (r8 * (q + 1) + (xcd - r8) * q + lo);
    const int bm = (swz / gridDim.x) * 128, bn = (swz % gridDim.x) * 128;

    const int wr = w >> 1, wc = w & 1;
    const int lane15 = l & 15, lhi = l >> 4;

    const __hip_bfloat16* gA = A + (size_t)bm * Kp;
    const __hip_bfloat16* gB = Bt + (size_t)bn * Kp;

    f32x4 acc[4][4] = {};

    const int nk = Kp >> 6;
    stage_tile(gA, Kp, gB, Kp, &lds[0][0], w, l);
    __syncthreads();
    int cur = 0;
    for (int t = 0; t < nk; ++t) {
        if (t + 1 < nk)
            stage_tile(gA + (t + 1) * 64, Kp, gB + (t + 1) * 64, Kp, &lds[cur ^ 1][0], w, l);
        const short* bA = &lds[cur][0];
        const short* bB = &lds[cur][8192];
#pragma unroll
        for (int ks = 0; ks < 2; ++ks) {
            bf16x8 af[4], bfr[4];
#pragma unroll
            for (int m = 0; m < 4; ++m) {
                int r = wr * 64 + m * 16 + lane15;
                int slot = (ks * 4 + lhi) ^ (r & 7);
                af[m] = *(const bf16x8*)(bA + r * 64 + slot * 8);
            }
#pragma unroll
            for (int n = 0; n < 4; ++n) {
                int r = wc * 64 + n * 16 + lane15;
                int slot = (ks * 4 + lhi) ^ (r & 7);
                bfr[n] = *(const bf16x8*)(bB + r * 64 + slot * 8);
            }
#pragma unroll
            for (int m = 0; m < 4; ++m)
#pragma unroll
                for (int n = 0; n < 4; ++n)
                    acc[m][n] = __builtin_amdgcn_mfma_f32_16x16x32_bf16(
                        af[m], bfr[n], acc[m][n], 0, 0, 0);
        }
        __syncthreads();
        cur ^= 1;
    }
#pragma unroll
    for (int m = 0; m < 4; ++m) {
#pragma unroll
        for (int n = 0; n < 4; ++n) {
            int col = bn + wc * 64 + n * 16 + lane15;
            if (col >= N) continue;
            int row0 = bm + wr * 64 + m * 16 + lhi * 4;
#pragma unroll
            for (int q2 = 0; q2 < 4; ++q2)
                C[(size_t)(row0 + q2) * ldC + col] = __float2bfloat16(acc[m][n][q2]);
        }
    }
}

// ---------------------------------------------------------------------------
// MFMA bf16 split-K GEMM (atomic-free partial slices)
// ---------------------------------------------------------------------------
__global__ __launch_bounds__(256, 2) void gemm_mfma_splitk(
    const __hip_bfloat16* __restrict__ A,
    const __hip_bfloat16* __restrict__ Bt,
    float* __restrict__ P, int M, int N, int Kp, int tps)
{
    __shared__ __align__(16) short lds[2][16384];
    const int tid = threadIdx.x;
    const int w = tid >> 6, l = tid & 63;
    const int bm = blockIdx.y * 128, bn = blockIdx.x * 128;
    const int z = blockIdx.z;
    const int wr = w >> 1, wc = w & 1;
    const int lane15 = l & 15, lhi = l >> 4;

    const __hip_bfloat16* gA = A + (size_t)bm * Kp + z * tps * 64;
    const __hip_bfloat16* gB = Bt + (size_t)bn * Kp + z * tps * 64;

    f32x4 acc[4][4] = {};

    const int nk = tps;
    stage_tile(gA, Kp, gB, Kp, &lds[0][0], w, l);
    __syncthreads();
    int cur = 0;
    for (int t = 0; t < nk; ++t) {
        if (t + 1 < nk)
            stage_tile(gA + (t + 1) * 64, Kp, gB + (t + 1) * 64, Kp, &lds[cur ^ 1][0], w, l);
        const short* bA = &lds[cur][0];
        const short* bB = &lds[cur][8192];
#pragma unroll
        for (int ks = 0; ks < 2; ++ks) {
            bf16x8 af[4], bfr[4];
#pragma unroll
            for (int m = 0; m < 4; ++m) {
                int r = wr * 64 + m * 16 + lane15;
                int slot = (ks * 4 + lhi) ^ (r & 7);
                af[m] = *(const bf16x8*)(bA + r * 64 + slot * 8);
            }
#pragma unroll
            for (int n = 0; n < 4; ++n) {
                int r = wc * 64 + n * 16 + lane15;
                int slot = (ks * 4 + lhi) ^ (r & 7);
                bfr[n] = *(const bf16x8*)(bB + r * 64 + slot * 8);
            }
#pragma unroll
            for (int m = 0; m < 4; ++m)
#pragma unroll
                for (int n = 0; n < 4; ++n)
                    acc[m][n] = __builtin_amdgcn_mfma_f32_16x16x32_bf16(
                        af[m], bfr[n], acc[m][n], 0, 0, 0);
        }
        __syncthreads();
        cur ^= 1;
    }
    float* Pz = P + (size_t)z * M * N;
#pragma unroll
    for (int m = 0; m < 4; ++m) {
#pragma unroll
        for (int n = 0; n < 4; ++n) {
            int col = bn + wc * 64 + n * 16 + lane15;
            if (col >= N) continue;
            int row0 = bm + wr * 64 + m * 16 + lhi * 4;
#pragma unroll
            for (int q2 = 0; q2 < 4; ++q2) {
                int row = row0 + q2;
                if (row < M) Pz[(size_t)row * N + col] = acc[m][n][q2];
            }
        }
    }
}

// ---------------------------------------------------------------------------
// MFMA conv GEMM (zero-im2col, NHC bf16)
// ---------------------------------------------------------------------------
template<int Ci, int Co, int Lout>
__global__ __launch_bounds__(256, 2) void gemm_conv_bf16(
    const __hip_bfloat16* __restrict__ A,
    const __hip_bfloat16* __restrict__ Bt,
    const float* __restrict__ bias,
    __hip_bfloat16* __restrict__ C)
{
    const int Kp = 8 * Ci;
    __shared__ __align__(16) short lds[2][16384];
    const int tid = threadIdx.x;
    const int w = tid >> 6, l = tid & 63;
    const int bm = blockIdx.y * 128;          // = n*128
    const int wr = w >> 1, wc = w & 1;
    const int lane15 = l & 15, lhi = l >> 4;

    const __hip_bfloat16* gA = A + (size_t)bm * Ci;
    const __hip_bfloat16* gB = Bt;

    f32x4 acc[4][4] = {};

    const int nk = Kp >> 6;
    stage_tile(gA, Ci, gB, Kp, &lds[0][0], w, l);
    __syncthreads();
    int cur = 0;
    for (int t = 0; t < nk; ++t) {
        if (t + 1 < nk)
            stage_tile(gA + (t + 1) * 64, Ci, gB + (t + 1) * 64, Kp, &lds[cur ^ 1][0], w, l);
        const short* bA = &lds[cur][0];
        const short* bB = &lds[cur][8192];
#pragma unroll
        for (int ks = 0; ks < 2; ++ks) {
            bf16x8 af[4], bfr[4];
#pragma unroll
            for (int m = 0; m < 4; ++m) {
                int r = wr * 64 + m * 16 + lane15;
                int slot = (ks * 4 + lhi) ^ (r & 7);
                af[m] = *(const bf16x8*)(bA + r * 64 + slot * 8);
            }
#pragma unroll
            for (int n = 0; n < 4; ++n) {
                int r = wc * 64 + n * 16 + lane15;
                int slot = (ks * 4 + lhi) ^ (r & 7);
                bfr[n] = *(const bf16x8*)(bB + r * 64 + slot * 8);
            }
#pragma unroll
            for (int m = 0; m < 4; ++m)
#pragma unroll
                for (int n = 0; n < 4; ++n)
                    acc[m][n] = __builtin_amdgcn_mfma_f32_16x16x32_bf16(
                        af[m], bfr[n], acc[m][n], 0, 0, 0);
        }
        __syncthreads();
        cur ^= 1;
    }
#pragma unroll
    for (int m = 0; m < 4; ++m) {
#pragma unroll
        for (int n = 0; n < 4; ++n) {
            int col = wc * 64 + n * 16 + lane15;
            if (col >= Co) continue;
            float bb = bias[col];
            int lr0 = wr * 64 + m * 16 + lhi * 4;
#pragma unroll
            for (int q2 = 0; q2 < 4; ++q2) {
                int lr = lr0 + q2;
                if (lr < Lout)
                    C[((size_t)bm + lr) * Co + col] =
                        __float2bfloat16(fmaxf(acc[m][n][q2] + bb, 0.f));
            }
        }
    }
}

// ---------------------------------------------------------------------------
// GAT helpers
// ---------------------------------------------------------------------------
__device__ __forceinline__ unsigned fmap(float f) {
    unsigned u = __float_as_uint(f);
    return (u & 0x80000000u) ? ~u : (u | 0x80000000u);
}
__device__ __forceinline__ float funmap(unsigned u) {
    return (u & 0x80000000u) ? __uint_as_float(u ^ 0x80000000u)
                             : __uint_as_float(~u);
}

__global__ void attn_ab_kernel(const __hip_bfloat16* __restrict__ lin, int Ftp,
                               const float* __restrict__ att_s,
                               const float* __restrict__ att_d,
                               float* __restrict__ a_s, float* __restrict__ a_d,
                               int H, int F)
{
    int bid = blockIdx.x;           // n*H + h
    int n = bid / H, h = bid - n * H;
    int lane = threadIdx.x;
    const __hip_bfloat16* row = lin + (size_t)n * Ftp + h * F;
    const float* wsrc = att_s + h * F;
    const float* wdst = att_d + h * F;
    float ss = 0.f, sd = 0.f;
    for (int f = lane; f < F; f += 64) {
        float v = __bfloat162float(row[f]);
        ss += v * wsrc[f];
        sd += v * wdst[f];
    }
    for (int o = 32; o; o >>= 1) {
        ss += __shfl_down(ss, o);
        sd += __shfl_down(sd, o);
    }
    if (lane == 0) { a_s[bid] = ss; a_d[bid] = sd; }
}

__global__ void edge_max_kernel(const int* __restrict__ ei,
                                const float* __restrict__ a_s,
                                const float* __restrict__ a_d,
                                float* __restrict__ eval,
                                unsigned* __restrict__ mmax,
                                int E, int Etot, int H)
{
    int t = blockIdx.x * blockDim.x + threadIdx.x;
    if (t >= Etot * H) return;
    int e = t / H, h = t - e * H;
    int s, d;
    if (e < E) { s = ei[e]; d = ei[E + e]; } else { s = d = e - E; }
    float v = a_s[s * H + h] + a_d[d * H + h];
    v = v > 0.f ? v : 0.2f * v;
    eval[t] = v;
    atomicMax(&mmax[d * H + h], fmap(v));
}

__global__ void edge_exp_kernel(const int* __restrict__ ei,
                                const unsigned* __restrict__ mmax,
                                float* __restrict__ eval,
                                float* __restrict__ denom,
                                int E, int Etot, int H)
{
    int t = blockIdx.x * blockDim.x + threadIdx.x;
    if (t >= Etot * H) return;
    int e = t / H, h = t - e * H;
    int d = (e < E) ? ei[E + e] : e - E;
    float m = funmap(mmax[d * H + h]);
    float ex = expf(eval[t] - m);
    eval[t] = ex;
    atomicAdd(&denom[d * H + h], ex);
}

// ---- dst-CSR build ----
__global__ void deg_kernel(const int* __restrict__ ei, int* __restrict__ deg,
                           int E, int Etot)
{
    int e = blockIdx.x * 256 + threadIdx.x;
    if (e >= Etot) return;
    int d = (e < E) ? ei[E + e] : e - E;
    atomicAdd(&deg[d], 1);
}

__global__ __launch_bounds__(256) void scan_kernel(const int* __restrict__ deg,
                                                   int* __restrict__ rowptr, int n)
{
    __shared__ int partial[256];
    int tid = threadIdx.x;
    const int per = (n + 255) / 256;
    int base = tid * per;
    int sum = 0;
    for (int i = 0; i < per; ++i) {
        int idx = base + i;
        if (idx < n) sum += deg[idx];
    }
    partial[tid] = sum;
    __syncthreads();
    for (int offs = 1; offs < 256; offs <<= 1) {
        int v = (tid >= offs) ? partial[tid - offs] : 0;
        __syncthreads();
        partial[tid] += v;
        __syncthreads();
    }
    int run = (tid == 0) ? 0 : partial[tid - 1];
    for (int i = 0; i < per; ++i) {
        int idx = base + i;
        if (idx < n) { rowptr[idx] = run; run += deg[idx]; }
    }
    if (tid == 255) rowptr[n] = run;
}

__global__ void fill_csr_kernel(const int* __restrict__ ei, int* __restrict__ cursor,
                                int* __restrict__ eidx, int E, int Etot)
{
    int e = blockIdx.x * 256 + threadIdx.x;
    if (e >= Etot) return;
    int d = (e < E) ? ei[E + e] : e - E;
    int pos = atomicAdd(&cursor[d], 1);
    eidx[pos] = e;
}

// Gather aggregation with fused alpha normalization.
// alpha[e,h] = eval[e,h] / (denom[d,h]+1e-16); d is block-uniform.
template<int ACT>
__global__ __launch_bounds__(64) void gat_gather8_kernel(
    const int* __restrict__ rowptr, const int* __restrict__ eidx,
    const int* __restrict__ ei, const float* __restrict__ eval,
    const float* __restrict__ denom,
    const __hip_bfloat16* __restrict__ lin, int Ftp,
    const float* __restrict__ bias,
    __hip_bfloat16* __restrict__ outh, int Kout,
    int E, int H, int F, int Ft)
{
    int d = blockIdx.x;
    int g = blockIdx.y * 64 + threadIdx.x;      // col group
    int c0 = g * 8;
    if (c0 >= Kout) return;
    bf16x8 res;
    if (c0 >= Ft) {   // pure pad group: write zeros
#pragma unroll
        for (int j = 0; j < 8; ++j) res[j] = 0;
        *(bf16x8*)(outh + (size_t)d * Kout + c0) = res;
        return;
    }
    int hj[8];
    float rdh[8];
#pragma unroll
    for (int j = 0; j < 8; ++j) {
        hj[j] = min((c0 + j) / F, H - 1);
        rdh[j] = 1.f / (denom[d * H + hj[j]] + 1e-16f);
    }
    float acc[8] = {};
    int p0 = rowptr[d], p1 = rowptr[d + 1];
    for (int p = p0; p < p1; ++p) {
        int e = eidx[p];
        int s = (e < E) ? ei[e] : e - E;
        bf16x8 v = *(const bf16x8*)(lin + (size_t)s * Ftp + c0);
        const float* aE = eval + (size_t)e * H;
        if (H == 1) {
            float a = aE[0] * rdh[0];
#pragma unroll
            for (int j = 0; j < 8; ++j)
                acc[j] += a * bf16bits2float(v[j]);
        } else {
#pragma unroll
            for (int j = 0; j < 8; ++j)
                acc[j] += aE[hj[j]] * rdh[j] * bf16bits2float(v[j]);
        }
    }
#pragma unroll
    for (int j = 0; j < 8; ++j) {
        int c = c0 + j;
        float val = 0.f;
        if (c < Ft) {
            val = acc[j] + bias[c];
            if (ACT == 1) val = fmaxf(val, 0.f);
            else if (ACT == 2) val = val > 0.f ? val : expm1f(val);
        }
        __hip_bfloat16 bv = __float2bfloat16(val);
        res[j] = *(const short*)&bv;
    }
    *(bf16x8*)(outh + (size_t)d * Kout + c0) = res;
}

// global max pool over bf16 h3 [N][3120] -> bf16 [NB][Kout] padded (pads zero)
__global__ void pool_max_bf16_kernel(const __hip_bfloat16* __restrict__ h,
                                     __hip_bfloat16* __restrict__ g,
                                     int B, int per, int C, int Kout)
{
    int t = blockIdx.x * blockDim.x + threadIdx.x;
    if (t >= B * Kout) return;
    int b = t / Kout, f = t - b * Kout;
    if (f >= C) { g[t] = __float2bfloat16(0.f); return; }
    const __hip_bfloat16* p = h + (size_t)b * per * C + f;
    float m = -INFINITY;
    for (int j = 0; j < per; ++j) m = fmaxf(m, __bfloat162float(p[(size_t)j * C]));
    g[t] = __float2bfloat16(m);
}

// ---------------------------------------------------------------------------
// CNN branch — conv1 vocab-factorized, split phase 1
// ---------------------------------------------------------------------------
__global__ __launch_bounds__(256) void conv1_p1_kernel(
    const int* __restrict__ target, const float* __restrict__ wt,
    float* __restrict__ Spart)
{
    __shared__ float s_S[VOCAB * 256];
    __shared__ int   s_trow[125];
    int tid = threadIdx.x;
    int n = blockIdx.x, z = blockIdx.y;
    for (int i = tid; i < VOCAB * 256; i += 256) s_S[i] = 0.f;
    if (tid < 125) s_trow[tid] = target[n * 1000 + z * 125 + tid];
    __syncthreads();
    const float* wz = wt + (size_t)(z * 125) * 256 + tid;
    for (int i = 0; i < 125; ++i) {
        int v = s_trow[i];
        s_S[v * 256 + tid] += wz[(size_t)i * 256];
    }
    __syncthreads();
    float* outp = Spart + ((size_t)n * C1SPLIT + z) * (VOCAB * 256);
    for (int i = tid; i < VOCAB * 256; i += 256) outp[i] = s_S[i];
}

__global__ __launch_bounds__(256) void conv1_p2_kernel(
    const float* __restrict__ Spart, const float* __restrict__ emb,
    const float* __restrict__ b, __hip_bfloat16* __restrict__ y)
{
    __shared__ float s_emb[VOCAB * EMB];
    __shared__ float s_S[VOCAB * 256];
    int tid = threadIdx.x;
    int n = blockIdx.x;
    for (int i = tid; i < VOCAB * EMB; i += 256) s_emb[i] = emb[i];
    const float* base = Spart + (size_t)n * C1SPLIT * (VOCAB * 256);
    for (int i = tid; i < VOCAB * 256; i += 256) {
        float s = 0.f;
#pragma unroll
        for (int z = 0; z < C1SPLIT; ++z) s += base[(size_t)z * (VOCAB * 256) + i];
        s_S[i] = s;
    }
    __syncthreads();
    for (int idx = tid; idx < 121 * 32; idx += 256) {
        int t = idx >> 5, o = idx & 31;
        float acc = b[o];
#pragma unroll
        for (int v = 0; v < VOCAB; ++v) {
            const float* Sv = s_S + v * 256 + o * 8;
            const float* ev = s_emb + v * EMB + t;
#pragma unroll
            for (int k = 0; k < 8; ++k) acc += Sv[k] * ev[k];
        }
        y[((size_t)n * LP + t) * 32 + o] = __float2bfloat16(fmaxf(acc, 0.f));
    }
}

// maxpool(3) + NHC->flatten transpose -> bf16 [NB][4352] padded (pads zero)
__global__ void pool3_kernel(const __hip_bfloat16* __restrict__ x,
                             __hip_bfloat16* __restrict__ y)
{
    int idx = blockIdx.x * blockDim.x + threadIdx.x;
    if (idx >= NB * 4352) return;
    int col = idx % 4352;
    int n = idx / 4352;
    if (col >= 4224) { y[idx] = __float2bfloat16(0.f); return; }
    int c = col / 33, tp = col - c * 33;
    const __hip_bfloat16* p = x + ((size_t)n * LP + tp * 3) * 128 + c;
    float m = __bfloat162float(p[0]);
    m = fmaxf(m, __bfloat162float(p[128]));
    m = fmaxf(m, __bfloat162float(p[256]));
    y[idx] = __float2bfloat16(m);
}

// ---------------------------------------------------------------------------
// Host-side launch
// ---------------------------------------------------------------------------
extern "C" void kernel_launch(void* const* d_in, const int* in_sizes, int n_in,
                              void* d_out, int out_size, void* d_ws, size_t ws_size,
                              hipStream_t stream)
{
    const float* x      = (const float*)d_in[0];
    const int*   ei     = (const int*)d_in[1];
    const int*   target = (const int*)d_in[3];
    const float* W1  = (const float*)d_in[4];
    const float* as1 = (const float*)d_in[5];
    const float* ad1 = (const float*)d_in[6];
    const float* b1  = (const float*)d_in[7];
    const float* W2  = (const float*)d_in[8];
    const float* as2 = (const float*)d_in[9];
    const float* ad2 = (const float*)d_in[10];
    const float* b2  = (const float*)d_in[11];
    const float* W3  = (const float*)d_in[12];
    const float* as3 = (const float*)d_in[13];
    const float* ad3 = (const float*)d_in[14];
    const float* b3  = (const float*)d_in[15];
    const float* fc_g1_w = (const float*)d_in[16];
    const float* fc_g1_b = (const float*)d_in[17];
    const float* fc_g2_w = (const float*)d_in[18];
    const float* fc_g2_b = (const float*)d_in[19];
    const float* emb_xt  = (const float*)d_in[20];
    const float* cw1 = (const float*)d_in[21];
    const float* cb1 = (const float*)d_in[22];
    const float* cw2 = (const float*)d_in[23];
    const float* cb2 = (const float*)d_in[24];
    const float* cw3 = (const float*)d_in[25];
    const float* cb3 = (const float*)d_in[26];
    const float* cw4 = (const float*)d_in[27];
    const float* cb4 = (const float*)d_in[28];
    const float* fc1_xt_w = (const float*)d_in[29];
    const float* fc1_xt_b = (const float*)d_in[30];
    const float* fc2_xt_w = (const float*)d_in[31];
    const float* fc2_xt_b = (const float*)d_in[32];
    const float* fc1_w = (const float*)d_in[33];
    const float* fc1_b = (const float*)d_in[34];
    const float* fc2_w = (const float*)d_in[35];
    const float* fc2_b = (const float*)d_in[36];
    const float* out_w = (const float*)d_in[37];
    const float* out_b = (const float*)d_in[38];
    float* out = (float*)d_out;

    const int N = NNODES, E = NEDGES, Etot = E + N;
    const size_t MB = 1024 * 1024;

    // ---- workspace carve ----
    char* ws = (char*)d_ws;
    size_t off = 0;
    auto alloc = [&](size_t bytes) -> char* {
        char* p = ws + off;
        off = (off + bytes + 255) & ~(size_t)255;
        return p;
    };
    const size_t BIG = (size_t)N * 3120 * sizeof(float);   // 127.8 MB
    char*  bufA  = alloc(BIG);
    char*  bufB  = alloc(BIG);
    float*    a_s   = (float*)alloc((size_t)N * 10 * 4);
    float*    a_d   = (float*)alloc((size_t)N * 10 * 4);
    char*     mmdn  = alloc((size_t)2 * N * 10 * 4);   // mmax | denom (combined)
    float*    eval  = (float*)alloc((size_t)Etot * 10 * 4);
    float*    g1    = (float*)alloc((size_t)NB * 1024 * 4);
    float*    xt1   = (float*)alloc((size_t)NB * 1024 * 4);
    float*    xc    = (float*)alloc((size_t)NB * 256 * 4);
    float*    f1    = (float*)alloc((size_t)NB * 1024 * 4);
    float*    f2    = (float*)alloc((size_t)NB * 256 * 4);
    __hip_bfloat16* gbufb = (__hip_bfloat16*)alloc((size_t)NB * 3200 * 2);
    __hip_bfloat16* xtb   = (__hip_bfloat16*)alloc((size_t)NB * 4352 * 2);
    int*      deg     = (int*)alloc((size_t)N * 4);
    int*      rowptr  = (int*)alloc((size_t)(N + 1) * 4);
    int*      cursor  = (int*)alloc((size_t)N * 4);
    int*      eidx    = (int*)alloc((size_t)Etot * 4);

    __hip_bfloat16* linb = (__hip_bfloat16*)bufA;
    __hip_bfloat16* Wt   = (__hip_bfloat16*)(bufA + 64 * MB);
    __hip_bfloat16* xb   = (__hip_bfloat16*)(bufA + 80 * MB);   // lin1 A, 2.6 MB
    __hip_bfloat16* hbf1 = (__hip_bfloat16*)bufB;
    __hip_bfloat16* hbf2 = (__hip_bfloat16*)(bufB + 20 * MB);
    __hip_bfloat16* hbf3 = (__hip_bfloat16*)bufB;
    float*          Ptmp = (float*)(bufB + 100 * MB);
    __hip_bfloat16* Wt2  = (__hip_bfloat16*)(bufB + 105 * MB);
    float*          P4   = (float*)(bufB + 115 * MB);

    // CNN scratch in bufA (dead after GAT layer 3)
    char* cnn = bufA;
    auto calloc2 = [&](size_t bytes) -> char* {
        char* p = cnn;
        cnn += (bytes + 255) & ~(size_t)255;
        return p;
    };
    __hip_bfloat16* act1 = (__hip_bfloat16*)calloc2((size_t)NB * LP * 32 * 2 + 4096);
    __hip_bfloat16* act2 = (__hip_bfloat16*)calloc2((size_t)NB * LP * 64 * 2 + 4096);
    __hip_bfloat16* act3 = (__hip_bfloat16*)calloc2((size_t)NB * LP * 96 * 2 + 4096);
    __hip_bfloat16* act4 = (__hip_bfloat16*)calloc2((size_t)NB * LP * 128 * 2 + 4096);
    __hip_bfloat16* wt2  = (__hip_bfloat16*)calloc2((size_t)128 * 256 * 2);
    __hip_bfloat16* wt3  = (__hip_bfloat16*)calloc2((size_t)128 * 512 * 2);
    __hip_bfloat16* wt4  = (__hip_bfloat16*)calloc2((size_t)128 * 768 * 2);
    float* wt1f  = (float*)calloc2((size_t)1000 * 256 * 4);                 // 1.02 MB
    float* Spart = (float*)calloc2((size_t)NB * C1SPLIT * VOCAB * 256 * 4); // 54.5 MB

    // ---- build dst-CSR once ----
    {
        (void)hipMemsetAsync(deg, 0, (size_t)N * 4, stream);
        deg_kernel<<<(Etot + 255) / 256, 256, 0, stream>>>(ei, deg, E, Etot);
        scan_kernel<<<1, 256, 0, stream>>>(deg, rowptr, N);
        (void)hipMemcpyAsync(cursor, rowptr, (size_t)N * 4, hipMemcpyDeviceToDevice, stream);
        fill_csr_kernel<<<(Etot + 255) / 256, 256, 0, stream>>>(ei, cursor, eidx, E, Etot);
    }

    // ---- f32 split-K head GEMM (small heads) ----
    auto head_gemm = [&](const float* A, const float* B, const float* bias, float* C,
                         int M, int Nc, int K, int ldC, int act, int S) {
        (void)hipMemsetAsync(Ptmp, 0, (size_t)M * Nc * 4, stream);
        int kchunk = (K + S - 1) / S;
        dim3 g((Nc + 63) / 64, (M + 63) / 64, S);
        gemm_f32_splitk<<<g, 256, 0, stream>>>(A, B, Ptmp, M, Nc, K, kchunk);
        int tot = M * Nc;
        if (act == 1)
            bias_act_ld_kernel<1><<<(tot + 255) / 256, 256, 0, stream>>>(Ptmp, bias, C, M, Nc, ldC);
        else
            bias_act_ld_kernel<0><<<(tot + 255) / 256, 256, 0, stream>>>(Ptmp, bias, C, M, Nc, ldC);
    };

    // ---- bf16 MFMA split-K head GEMM (A pre-cast bf16 [M][Kp], relu) ----
    auto head_gemm_mfma = [&](const __hip_bfloat16* Ab_, const float* W, const float* bias,
                              float* C, int M, int Nc, int K, int Kp, int S) {
        int tps = (Kp / 64) / S;
        transpose_cast_kernel<<<dim3(Kp / 32, Nc / 32), 256, 0, stream>>>(W, Wt2, K, Nc, Kp, Nc);
        dim3 g(Nc / 128, M / 128, S);
        gemm_mfma_splitk<<<g, 256, 0, stream>>>(Ab_, Wt2, P4, M, Nc, Kp, tps);
        int tot = M * Nc;
        reduce_bias_relu_kernel<<<(tot + 255) / 256, 256, 0, stream>>>(P4, bias, C, M, Nc, S, Nc);
    };

    // ---- GAT softmax + CSR-gather chain ----
    auto gat_tail = [&](const float* atts, const float* attd, const float* bias,
                        int H, int F, int Ftp, int act,
                        const __hip_bfloat16* lin, __hip_bfloat16* outh, int Kout) {
        unsigned* mmax = (unsigned*)mmdn;
        float* denom = (float*)(mmdn + (size_t)N * H * 4);
        attn_ab_kernel<<<N * H, 64, 0, stream>>>(lin, Ftp, atts, attd, a_s, a_d, H, F);
        (void)hipMemsetAsync(mmdn, 0, (size_t)2 * N * H * 4, stream);
        int tot = Etot * H;
        edge_max_kernel<<<(tot + 255) / 256, 256, 0, stream>>>(ei, a_s, a_d, eval, mmax, E, Etot, H);
        edge_exp_kernel<<<(tot + 255) / 256, 256, 0, stream>>>(ei, mmax, eval, denom, E, Etot, H);
        int Ft = H * F;
        int groups = Kout / 8;
        dim3 gg(N, (groups + 63) / 64);
        if (act == 1)
            gat_gather8_kernel<1><<<gg, 64, 0, stream>>>(rowptr, eidx, ei, eval, denom, lin, Ftp, bias, outh, Kout, E, H, F, Ft);
        else
            gat_gather8_kernel<2><<<gg, 64, 0, stream>>>(rowptr, eidx, ei, eval, denom, lin, Ftp, bias, outh, Kout, E, H, F, Ft);
    };

    // ---- layer 1: MFMA GEMM (x cast to bf16, Kp=128) -> bf16 lin [N][784] ----
    {
        (void)hipMemsetAsync(linb, 0, (size_t)N * 784 * 2, stream);
        cast_a_kernel<<<(N * 128 + 255) / 256, 256, 0, stream>>>(x, xb, N, 78, 128);
        transpose_cast_kernel<<<dim3(4, 28), 256, 0, stream>>>(W1, Wt, 78, 780, 128, 896);
        gemm_mfma_bf16<<<dim3(7, N / 128), 256, 0, stream>>>(xb, Wt, linb, N, 780, 128, 784);
        gat_tail(as1, ad1, b1, 10, 78, 784, 2, linb, hbf1, 832);
    }
    // ---- layer 2: MFMA GEMM -> lin [N][1560] ----
    {
        const int Kp = 832, Nout = 1560, Npad = 1664;
        transpose_cast_kernel<<<dim3(Kp / 32, Npad / 32), 256, 0, stream>>>(W2, Wt, 780, Nout, Kp, Npad);
        gemm_mfma_bf16<<<dim3(Npad / 128, N / 128), 256, 0, stream>>>(hbf1, Wt, linb, N, Nout, Kp, Nout);
        gat_tail(as2, ad2, b2, 2, 780, 1560, 1, linb, hbf2, 1600);
    }
    // ---- layer 3: MFMA GEMM -> lin [N][3120] ----
    {
        const int Kp = 1600, Nout = 3120, Npad = 3200;
        transpose_cast_kernel<<<dim3(Kp / 32, Npad / 32), 256, 0, stream>>>(W3, Wt, 1560, Nout, Kp, Npad);
        gemm_mfma_bf16<<<dim3(Npad / 128, N / 128), 256, 0, stream>>>(hbf2, Wt, linb, N, Nout, Kp, Nout);
        gat_tail(as3, ad3, b3, 1, 3120, 3120, 1, linb, hbf3, 3120);
    }

    // global max pool (bf16 in, bf16 padded out) + graph FCs
    {
        int tot = NB * 3200;
        pool_max_bf16_kernel<<<(tot + 255) / 256, 256, 0, stream>>>(hbf3, gbufb, NB, N / NB, 3120, 3200);
        head_gemm_mfma(gbufb, fc_g1_w, fc_g1_b, g1, NB, 1024, 3120, 3200, 5);
        head_gemm(g1, fc_g2_w, fc_g2_b, xc, NB, 128, 1024, 256, 0, 32);
    }

    // ---- CNN branch (bufA free now) ----
    {
        conv1_wt_kernel<<<(32 * 8000 + 255) / 256, 256, 0, stream>>>(cw1, wt1f);
        conv1_p1_kernel<<<dim3(NB, C1SPLIT), 256, 0, stream>>>(target, wt1f, Spart);
        conv1_p2_kernel<<<NB, 256, 0, stream>>>(Spart, emb_xt, cb1, act1);
        conv_wt_kernel<<<(64 * 32 * 8 + 255) / 256, 256, 0, stream>>>(cw2, wt2, 64, 32);
        conv_wt_kernel<<<(96 * 64 * 8 + 255) / 256, 256, 0, stream>>>(cw3, wt3, 96, 64);
        conv_wt_kernel<<<(128 * 96 * 8 + 255) / 256, 256, 0, stream>>>(cw4, wt4, 128, 96);
        gemm_conv_bf16<32, 64, 114><<<dim3(1, NB), 256, 0, stream>>>(act1, wt2, cb2, act2);
        gemm_conv_bf16<64, 96, 107><<<dim3(1, NB), 256, 0, stream>>>(act2, wt3, cb3, act3);
        gemm_conv_bf16<96, 128, 100><<<dim3(1, NB), 256, 0, stream>>>(act3, wt4, cb4, act4);
        int tp = NB * 4352;
        pool3_kernel<<<(tp + 255) / 256, 256, 0, stream>>>(act4, xtb);
        head_gemm_mfma(xtb, fc1_xt_w, fc1_xt_b, xt1, NB, 1024, 4224, 4352, 4);
        head_gemm(xt1, fc2_xt_w, fc2_xt_b, xc + 128, NB, 128, 1024, 256, 0, 32);
    }

    // ---- fusion head ----
    {
        head_gemm(xc, fc1_w, fc1_b, f1, NB, 1024, 256, 1024, 1, 8);
        head_gemm(f1, fc2_w, fc2_b, f2, NB, 256, 1024, 256, 1, 16);
        out_head_kernel<<<1, 256, 0, stream>>>(f2, out_w, out_b, out);
    }
}

// Round 14
// 793.478 us; speedup vs baseline: 13.3449x; 1.1067x over previous
//
#include <hip/hip_runtime.h>
#include <hip/hip_bf16.h>
#include <math.h>

// ---------------------------------------------------------------------------
// Constants (problem-fixed)
// ---------------------------------------------------------------------------
static const int NNODES = 10240;
static const int NEDGES = 40960;
static const int NB     = 256;     // graphs / batch
static const int VOCAB  = 26;
static const int EMB    = 128;
static const int LP     = 128;     // padded t-length for NHC conv activations
static const int C1SPLIT = 8;      // conv1 phase-1 i-split (1000/8 = 125)

typedef short bf16x8 __attribute__((ext_vector_type(8)));   // 8 bf16 (4 VGPRs)
typedef float f32x4  __attribute__((ext_vector_type(4)));   // 4 fp32

__device__ __forceinline__ float bf16bits2float(short s) {
    return __uint_as_float(((unsigned)(unsigned short)s) << 16);
}

// ---------------------------------------------------------------------------
// Slice split-K f32 GEMM (atomic-free): P[z][M][N] = A@B over k-slice z.
// ---------------------------------------------------------------------------
__global__ __launch_bounds__(256) void gemm_f32_splitk_sl(
    const float* __restrict__ A, const float* __restrict__ B,
    float* __restrict__ P, int M, int N, int K, int kchunk)
{
    __shared__ float As[16][65];
    __shared__ float Bs[16][65];
    int tid = threadIdx.x;
    int bm = blockIdx.y * 64;
    int bn = blockIdx.x * 64;
    int z = blockIdx.z;
    int k0 = z * kchunk;
    int k1 = min(k0 + kchunk, K);
    int tx = tid & 15, ty = tid >> 4;
    float acc[4][4] = {};
    for (int kb = k0; kb < k1; kb += 16) {
#pragma unroll
        for (int l = 0; l < 4; ++l) {
            int idx = tid + l * 256;
            int r = idx >> 4, c = idx & 15;
            int gr = bm + r, gc = kb + c;
            As[c][r] = (gr < M && gc < k1) ? A[(size_t)gr * K + gc] : 0.f;
        }
#pragma unroll
        for (int l = 0; l < 4; ++l) {
            int idx = tid + l * 256;
            int r = idx >> 6, c = idx & 63;
            int gr = kb + r, gc = bn + c;
            Bs[r][c] = (gr < k1 && gc < N) ? B[(size_t)gr * N + gc] : 0.f;
        }
        __syncthreads();
#pragma unroll
        for (int kk = 0; kk < 16; ++kk) {
            float a[4], b[4];
#pragma unroll
            for (int i = 0; i < 4; ++i) a[i] = As[kk][ty * 4 + i];
#pragma unroll
            for (int j = 0; j < 4; ++j) b[j] = Bs[kk][tx * 4 + j];
#pragma unroll
            for (int i = 0; i < 4; ++i)
#pragma unroll
                for (int j = 0; j < 4; ++j)
                    acc[i][j] += a[i] * b[j];
        }
        __syncthreads();
    }
    float* Pz = P + (size_t)z * M * N;
#pragma unroll
    for (int i = 0; i < 4; ++i) {
        int gr = bm + ty * 4 + i;
        if (gr >= M) continue;
#pragma unroll
        for (int j = 0; j < 4; ++j) {
            int gc = bn + tx * 4 + j;
            if (gc >= N) continue;
            Pz[(size_t)gr * N + gc] = acc[i][j];
        }
    }
}

// reduce S slices + bias + act -> C (ldC)
template<int ACT>
__global__ void reduce_bias_act_ld_kernel(const float* __restrict__ P,
                                          const float* __restrict__ bias,
                                          float* __restrict__ C,
                                          int M, int N, int S, int ldC)
{
    int t = blockIdx.x * 256 + threadIdx.x;
    if (t >= M * N) return;
    int r = t / N, c = t - r * N;
    float v = bias[c];
    for (int s = 0; s < S; ++s) v += P[(size_t)s * M * N + t];
    if (ACT == 1) v = fmaxf(v, 0.f);
    C[(size_t)r * ldC + c] = v;
}

__global__ void out_head_kernel(const float* __restrict__ f2,
                                const float* __restrict__ w,
                                const float* __restrict__ b,
                                float* __restrict__ out)
{
    __shared__ float sw[256];
    int t = threadIdx.x;
    sw[t] = w[t];
    __syncthreads();
    float acc = 0.f;
    const float* row = f2 + (size_t)t * 256;
    for (int k = 0; k < 256; ++k) acc += row[k] * sw[k];
    out[t] = acc + b[0];
}

// ---------------------------------------------------------------------------
// casts
// ---------------------------------------------------------------------------
__global__ void cast_a_kernel(const float* __restrict__ in, __hip_bfloat16* __restrict__ out,
                              int M, int K, int Kp)
{
    int idx = blockIdx.x * 256 + threadIdx.x;
    if (idx >= M * Kp) return;
    int r = idx / Kp, k = idx - r * Kp;
    out[idx] = __float2bfloat16(k < K ? in[(size_t)r * K + k] : 0.f);
}

__global__ __launch_bounds__(256) void transpose_cast_kernel(
    const float* __restrict__ in, __hip_bfloat16* __restrict__ out,
    int K, int N, int Kp, int Npad)
{
    __shared__ float tile[32][33];
    int k0 = blockIdx.x * 32;
    int n0 = blockIdx.y * 32;
    int tx = threadIdx.x & 31;
    int ty = threadIdx.x >> 5;
#pragma unroll
    for (int j = 0; j < 4; ++j) {
        int k = k0 + ty + j * 8, n = n0 + tx;
        tile[ty + j * 8][tx] = (k < K && n < N) ? in[(size_t)k * N + n] : 0.f;
    }
    __syncthreads();
#pragma unroll
    for (int j = 0; j < 4; ++j) {
        int n = n0 + ty + j * 8, k = k0 + tx;
        if (n < Npad && k < Kp)
            out[(size_t)n * Kp + k] = __float2bfloat16(tile[tx][ty + j * 8]);
    }
}

// merged conv weight prep: conv2/3/4 k-major bf16 + conv1 f32 transpose
__global__ void conv_wt_all_kernel(
    const float* __restrict__ cw2, const float* __restrict__ cw3,
    const float* __restrict__ cw4, const float* __restrict__ cw1,
    __hip_bfloat16* __restrict__ wt2, __hip_bfloat16* __restrict__ wt3,
    __hip_bfloat16* __restrict__ wt4, float* __restrict__ wt1f)
{
    int idx = blockIdx.x * 256 + threadIdx.x;
    const int n2 = 64 * 32 * 8, n3 = 96 * 64 * 8, n4 = 128 * 96 * 8;
    if (idx < n2) {
        int o = idx / (32 * 8), rem = idx - o * 32 * 8;
        int i = rem >> 3, k = rem & 7;
        wt2[(size_t)o * 256 + k * 32 + i] = __float2bfloat16(cw2[idx]);
    } else if (idx < n2 + n3) {
        int j = idx - n2;
        int o = j / (64 * 8), rem = j - o * 64 * 8;
        int i = rem >> 3, k = rem & 7;
        wt3[(size_t)o * 512 + k * 64 + i] = __float2bfloat16(cw3[j]);
    } else if (idx < n2 + n3 + n4) {
        int j = idx - n2 - n3;
        int o = j / (96 * 8), rem = j - o * 96 * 8;
        int i = rem >> 3, k = rem & 7;
        wt4[(size_t)o * 768 + k * 96 + i] = __float2bfloat16(cw4[j]);
    } else {
        int j = idx - n2 - n3 - n4;
        if (j >= 32 * 8000) return;
        int o = j / 8000, rem = j - o * 8000;
        int i = rem >> 3, k = rem & 7;
        wt1f[(size_t)i * 256 + o * 8 + k] = cw1[j];
    }
}

// ---------------------------------------------------------------------------
// Shared MFMA staging
// ---------------------------------------------------------------------------
__device__ __forceinline__ void stage_tile(
    const __hip_bfloat16* __restrict__ gA, int ldA,
    const __hip_bfloat16* __restrict__ gB, int ldB,
    short* ldsbuf, int w, int l)
{
#pragma unroll
    for (int j = 0; j < 4; ++j) {
        int u = (w * 4 + j) * 64 + l;
        int r = u >> 3, s = u & 7;
        const __hip_bfloat16* src = gA + (size_t)r * ldA + ((s ^ (r & 7)) << 3);
        __builtin_amdgcn_global_load_lds(
            (const __attribute__((address_space(1))) void*)src,
            (__attribute__((address_space(3))) void*)(ldsbuf + (w * 4 + j) * 512),
            16, 0, 0);
    }
#pragma unroll
    for (int j = 0; j < 4; ++j) {
        int u = (w * 4 + j) * 64 + l;
        int r = u >> 3, s = u & 7;
        const __hip_bfloat16* src = gB + (size_t)r * ldB + ((s ^ (r & 7)) << 3);
        __builtin_amdgcn_global_load_lds(
            (const __attribute__((address_space(1))) void*)src,
            (__attribute__((address_space(3))) void*)(ldsbuf + 8192 + (w * 4 + j) * 512),
            16, 0, 0);
    }
}

// ---------------------------------------------------------------------------
// MFMA bf16 GEMM (FC form), bf16 output, XCD-bijective block swizzle (m204).
// ---------------------------------------------------------------------------
__global__ __launch_bounds__(256, 2) void gemm_mfma_bf16(
    const __hip_bfloat16* __restrict__ A,
    const __hip_bfloat16* __restrict__ Bt,
    __hip_bfloat16* __restrict__ C, int M, int N, int Kp, int ldC)
{
    __shared__ __align__(16) short lds[2][16384];
    const int tid = threadIdx.x;
    const int w = tid >> 6, l = tid & 63;

    int nwg = gridDim.x * gridDim.y;
    int wg = blockIdx.y * gridDim.x + blockIdx.x;
    int q = nwg >> 3, r8 = nwg & 7;
    int xcd = wg & 7, lo = wg >> 3;
    int swz = (xcd < r8) ? (xcd * (q + 1) + lo) : (r8 * (q + 1) + (xcd - r8) * q + lo);
    const int bm = (swz / gridDim.x) * 128, bn = (swz % gridDim.x) * 128;

    const int wr = w >> 1, wc = w & 1;
    const int lane15 = l & 15, lhi = l >> 4;

    const __hip_bfloat16* gA = A + (size_t)bm * Kp;
    const __hip_bfloat16* gB = Bt + (size_t)bn * Kp;

    f32x4 acc[4][4] = {};

    const int nk = Kp >> 6;
    stage_tile(gA, Kp, gB, Kp, &lds[0][0], w, l);
    __syncthreads();
    int cur = 0;
    for (int t = 0; t < nk; ++t) {
        if (t + 1 < nk)
            stage_tile(gA + (t + 1) * 64, Kp, gB + (t + 1) * 64, Kp, &lds[cur ^ 1][0], w, l);
        const short* bA = &lds[cur][0];
        const short* bB = &lds[cur][8192];
#pragma unroll
        for (int ks = 0; ks < 2; ++ks) {
            bf16x8 af[4], bfr[4];
#pragma unroll
            for (int m = 0; m < 4; ++m) {
                int r = wr * 64 + m * 16 + lane15;
                int slot = (ks * 4 + lhi) ^ (r & 7);
                af[m] = *(const bf16x8*)(bA + r * 64 + slot * 8);
            }
#pragma unroll
            for (int n = 0; n < 4; ++n) {
                int r = wc * 64 + n * 16 + lane15;
                int slot = (ks * 4 + lhi) ^ (r & 7);
                bfr[n] = *(const bf16x8*)(bB + r * 64 + slot * 8);
            }
#pragma unroll
            for (int m = 0; m < 4; ++m)
#pragma unroll
                for (int n = 0; n < 4; ++n)
                    acc[m][n] = __builtin_amdgcn_mfma_f32_16x16x32_bf16(
                        af[m], bfr[n], acc[m][n], 0, 0, 0);
        }
        __syncthreads();
        cur ^= 1;
    }
#pragma unroll
    for (int m = 0; m < 4; ++m) {
#pragma unroll
        for (int n = 0; n < 4; ++n) {
            int col = bn + wc * 64 + n * 16 + lane15;
            if (col >= N) continue;
            int row0 = bm + wr * 64 + m * 16 + lhi * 4;
#pragma unroll
            for (int q2 = 0; q2 < 4; ++q2)
                C[(size_t)(row0 + q2) * ldC + col] = __float2bfloat16(acc[m][n][q2]);
        }
    }
}

// ---------------------------------------------------------------------------
// MFMA bf16 split-K GEMM (atomic-free partial slices)
// ---------------------------------------------------------------------------
__global__ __launch_bounds__(256, 2) void gemm_mfma_splitk(
    const __hip_bfloat16* __restrict__ A,
    const __hip_bfloat16* __restrict__ Bt,
    float* __restrict__ P, int M, int N, int Kp, int tps)
{
    __shared__ __align__(16) short lds[2][16384];
    const int tid = threadIdx.x;
    const int w = tid >> 6, l = tid & 63;
    const int bm = blockIdx.y * 128, bn = blockIdx.x * 128;
    const int z = blockIdx.z;
    const int wr = w >> 1, wc = w & 1;
    const int lane15 = l & 15, lhi = l >> 4;

    const __hip_bfloat16* gA = A + (size_t)bm * Kp + z * tps * 64;
    const __hip_bfloat16* gB = Bt + (size_t)bn * Kp + z * tps * 64;

    f32x4 acc[4][4] = {};

    const int nk = tps;
    stage_tile(gA, Kp, gB, Kp, &lds[0][0], w, l);
    __syncthreads();
    int cur = 0;
    for (int t = 0; t < nk; ++t) {
        if (t + 1 < nk)
            stage_tile(gA + (t + 1) * 64, Kp, gB + (t + 1) * 64, Kp, &lds[cur ^ 1][0], w, l);
        const short* bA = &lds[cur][0];
        const short* bB = &lds[cur][8192];
#pragma unroll
        for (int ks = 0; ks < 2; ++ks) {
            bf16x8 af[4], bfr[4];
#pragma unroll
            for (int m = 0; m < 4; ++m) {
                int r = wr * 64 + m * 16 + lane15;
                int slot = (ks * 4 + lhi) ^ (r & 7);
                af[m] = *(const bf16x8*)(bA + r * 64 + slot * 8);
            }
#pragma unroll
            for (int n = 0; n < 4; ++n) {
                int r = wc * 64 + n * 16 + lane15;
                int slot = (ks * 4 + lhi) ^ (r & 7);
                bfr[n] = *(const bf16x8*)(bB + r * 64 + slot * 8);
            }
#pragma unroll
            for (int m = 0; m < 4; ++m)
#pragma unroll
                for (int n = 0; n < 4; ++n)
                    acc[m][n] = __builtin_amdgcn_mfma_f32_16x16x32_bf16(
                        af[m], bfr[n], acc[m][n], 0, 0, 0);
        }
        __syncthreads();
        cur ^= 1;
    }
    float* Pz = P + (size_t)z * M * N;
#pragma unroll
    for (int m = 0; m < 4; ++m) {
#pragma unroll
        for (int n = 0; n < 4; ++n) {
            int col = bn + wc * 64 + n * 16 + lane15;
            if (col >= N) continue;
            int row0 = bm + wr * 64 + m * 16 + lhi * 4;
#pragma unroll
            for (int q2 = 0; q2 < 4; ++q2) {
                int row = row0 + q2;
                if (row < M) Pz[(size_t)row * N + col] = acc[m][n][q2];
            }
        }
    }
}

// ---------------------------------------------------------------------------
// MFMA conv GEMM (zero-im2col, NHC bf16)
// ---------------------------------------------------------------------------
template<int Ci, int Co, int Lout>
__global__ __launch_bounds__(256, 2) void gemm_conv_bf16(
    const __hip_bfloat16* __restrict__ A,
    const __hip_bfloat16* __restrict__ Bt,
    const float* __restrict__ bias,
    __hip_bfloat16* __restrict__ C)
{
    const int Kp = 8 * Ci;
    __shared__ __align__(16) short lds[2][16384];
    const int tid = threadIdx.x;
    const int w = tid >> 6, l = tid & 63;
    const int bm = blockIdx.y * 128;          // = n*128
    const int wr = w >> 1, wc = w & 1;
    const int lane15 = l & 15, lhi = l >> 4;

    const __hip_bfloat16* gA = A + (size_t)bm * Ci;
    const __hip_bfloat16* gB = Bt;

    f32x4 acc[4][4] = {};

    const int nk = Kp >> 6;
    stage_tile(gA, Ci, gB, Kp, &lds[0][0], w, l);
    __syncthreads();
    int cur = 0;
    for (int t = 0; t < nk; ++t) {
        if (t + 1 < nk)
            stage_tile(gA + (t + 1) * 64, Ci, gB + (t + 1) * 64, Kp, &lds[cur ^ 1][0], w, l);
        const short* bA = &lds[cur][0];
        const short* bB = &lds[cur][8192];
#pragma unroll
        for (int ks = 0; ks < 2; ++ks) {
            bf16x8 af[4], bfr[4];
#pragma unroll
            for (int m = 0; m < 4; ++m) {
                int r = wr * 64 + m * 16 + lane15;
                int slot = (ks * 4 + lhi) ^ (r & 7);
                af[m] = *(const bf16x8*)(bA + r * 64 + slot * 8);
            }
#pragma unroll
            for (int n = 0; n < 4; ++n) {
                int r = wc * 64 + n * 16 + lane15;
                int slot = (ks * 4 + lhi) ^ (r & 7);
                bfr[n] = *(const bf16x8*)(bB + r * 64 + slot * 8);
            }
#pragma unroll
            for (int m = 0; m < 4; ++m)
#pragma unroll
                for (int n = 0; n < 4; ++n)
                    acc[m][n] = __builtin_amdgcn_mfma_f32_16x16x32_bf16(
                        af[m], bfr[n], acc[m][n], 0, 0, 0);
        }
        __syncthreads();
        cur ^= 1;
    }
#pragma unroll
    for (int m = 0; m < 4; ++m) {
#pragma unroll
        for (int n = 0; n < 4; ++n) {
            int col = wc * 64 + n * 16 + lane15;
            if (col >= Co) continue;
            float bb = bias[col];
            int lr0 = wr * 64 + m * 16 + lhi * 4;
#pragma unroll
            for (int q2 = 0; q2 < 4; ++q2) {
                int lr = lr0 + q2;
                if (lr < Lout)
                    C[((size_t)bm + lr) * Co + col] =
                        __float2bfloat16(fmaxf(acc[m][n][q2] + bb, 0.f));
            }
        }
    }
}

// conv4 with fused maxpool(3)+flatten: block n computes 128x128 (t,c) tile,
// stashes acc+bias in LDS, then writes xtb[n][c*33+tp] = relu(max3) directly.
__global__ __launch_bounds__(256, 2) void gemm_conv4_pool_bf16(
    const __hip_bfloat16* __restrict__ A,     // act3 NHC [n*128+t][96]
    const __hip_bfloat16* __restrict__ Bt,    // wt4 [128][768]
    const float* __restrict__ bias,
    __hip_bfloat16* __restrict__ xtb)         // [NB][4352], pads zeroed
{
    const int Ci = 96, Kp = 768;
    __shared__ __align__(16) short lds[2][16384];
    const int tid = threadIdx.x;
    const int w = tid >> 6, l = tid & 63;
    const int bm = blockIdx.y * 128;          // = n*128
    const int wr = w >> 1, wc = w & 1;
    const int lane15 = l & 15, lhi = l >> 4;

    const __hip_bfloat16* gA = A + (size_t)bm * Ci;
    const __hip_bfloat16* gB = Bt;

    f32x4 acc[4][4] = {};

    const int nk = Kp >> 6;
    stage_tile(gA, Ci, gB, Kp, &lds[0][0], w, l);
    __syncthreads();
    int cur = 0;
    for (int t = 0; t < nk; ++t) {
        if (t + 1 < nk)
            stage_tile(gA + (t + 1) * 64, Ci, gB + (t + 1) * 64, Kp, &lds[cur ^ 1][0], w, l);
        const short* bA = &lds[cur][0];
        const short* bB = &lds[cur][8192];
#pragma unroll
        for (int ks = 0; ks < 2; ++ks) {
            bf16x8 af[4], bfr[4];
#pragma unroll
            for (int m = 0; m < 4; ++m) {
                int r = wr * 64 + m * 16 + lane15;
                int slot = (ks * 4 + lhi) ^ (r & 7);
                af[m] = *(const bf16x8*)(bA + r * 64 + slot * 8);
            }
#pragma unroll
            for (int n = 0; n < 4; ++n) {
                int r = wc * 64 + n * 16 + lane15;
                int slot = (ks * 4 + lhi) ^ (r & 7);
                bfr[n] = *(const bf16x8*)(bB + r * 64 + slot * 8);
            }
#pragma unroll
            for (int m = 0; m < 4; ++m)
#pragma unroll
                for (int n = 0; n < 4; ++n)
                    acc[m][n] = __builtin_amdgcn_mfma_f32_16x16x32_bf16(
                        af[m], bfr[n], acc[m][n], 0, 0, 0);
        }
        __syncthreads();
        cur ^= 1;
    }
    // stash acc+bias (pre-relu) into LDS as f32 [128][128] (64 KB, staging dead)
    float* pbuf = (float*)&lds[0][0];
#pragma unroll
    for (int m = 0; m < 4; ++m) {
#pragma unroll
        for (int n = 0; n < 4; ++n) {
            int col = wc * 64 + n * 16 + lane15;     // < 128 always (Co=128)
            float bb = bias[col];
            int lr0 = wr * 64 + m * 16 + lhi * 4;
#pragma unroll
            for (int q2 = 0; q2 < 4; ++q2)
                pbuf[(lr0 + q2) * 128 + col] = acc[m][n][q2] + bb;
        }
    }
    __syncthreads();
    // pool: xtb[n][c*33+tp] = relu(max(pbuf[3tp..3tp+2][c])); pads zero
    int nb = blockIdx.y;
    for (int idx = tid; idx < 4352; idx += 256) {
        __hip_bfloat16 v;
        if (idx >= 4224) {
            v = __float2bfloat16(0.f);
        } else {
            int c = idx / 33, tp = idx - c * 33;
            float m3 = fmaxf(fmaxf(pbuf[(tp * 3) * 128 + c], pbuf[(tp * 3 + 1) * 128 + c]),
                             pbuf[(tp * 3 + 2) * 128 + c]);
            v = __float2bfloat16(fmaxf(m3, 0.f));
        }
        xtb[(size_t)nb * 4352 + idx] = v;
    }
}

// ---------------------------------------------------------------------------
// GAT helpers
// ---------------------------------------------------------------------------
__device__ __forceinline__ unsigned fmap(float f) {
    unsigned u = __float_as_uint(f);
    return (u & 0x80000000u) ? ~u : (u | 0x80000000u);
}
__device__ __forceinline__ float funmap(unsigned u) {
    return (u & 0x80000000u) ? __uint_as_float(u ^ 0x80000000u)
                             : __uint_as_float(~u);
}

__global__ void attn_ab_kernel(const __hip_bfloat16* __restrict__ lin, int Ftp,
                               const float* __restrict__ att_s,
                               const float* __restrict__ att_d,
                               float* __restrict__ a_s, float* __restrict__ a_d,
                               int H, int F)
{
    int bid = blockIdx.x;           // n*H + h
    int n = bid / H, h = bid - n * H;
    int lane = threadIdx.x;
    const __hip_bfloat16* row = lin + (size_t)n * Ftp + h * F;
    const float* wsrc = att_s + h * F;
    const float* wdst = att_d + h * F;
    float ss = 0.f, sd = 0.f;
    for (int f = lane; f < F; f += 64) {
        float v = __bfloat162float(row[f]);
        ss += v * wsrc[f];
        sd += v * wdst[f];
    }
    for (int o = 32; o; o >>= 1) {
        ss += __shfl_down(ss, o);
        sd += __shfl_down(sd, o);
    }
    if (lane == 0) { a_s[bid] = ss; a_d[bid] = sd; }
}

__global__ void edge_max_kernel(const int* __restrict__ ei,
                                const float* __restrict__ a_s,
                                const float* __restrict__ a_d,
                                float* __restrict__ eval,
                                unsigned* __restrict__ mmax,
                                int E, int Etot, int H)
{
    int t = blockIdx.x * blockDim.x + threadIdx.x;
    if (t >= Etot * H) return;
    int e = t / H, h = t - e * H;
    int s, d;
    if (e < E) { s = ei[e]; d = ei[E + e]; } else { s = d = e - E; }
    float v = a_s[s * H + h] + a_d[d * H + h];
    v = v > 0.f ? v : 0.2f * v;
    eval[t] = v;
    atomicMax(&mmax[d * H + h], fmap(v));
}

__global__ void edge_exp_kernel(const int* __restrict__ ei,
                                const unsigned* __restrict__ mmax,
                                float* __restrict__ eval,
                                float* __restrict__ denom,
                                int E, int Etot, int H)
{
    int t = blockIdx.x * blockDim.x + threadIdx.x;
    if (t >= Etot * H) return;
    int e = t / H, h = t - e * H;
    int d = (e < E) ? ei[E + e] : e - E;
    float m = funmap(mmax[d * H + h]);
    float ex = expf(eval[t] - m);
    eval[t] = ex;
    atomicAdd(&denom[d * H + h], ex);
}

// ---- dst-CSR build ----
__global__ void deg_kernel(const int* __restrict__ ei, int* __restrict__ deg,
                           int E, int Etot)
{
    int e = blockIdx.x * 256 + threadIdx.x;
    if (e >= Etot) return;
    int d = (e < E) ? ei[E + e] : e - E;
    atomicAdd(&deg[d], 1);
}

__global__ __launch_bounds__(256) void scan_kernel(const int* __restrict__ deg,
                                                   int* __restrict__ rowptr,
                                                   int* __restrict__ cursor, int n)
{
    __shared__ int partial[256];
    int tid = threadIdx.x;
    const int per = (n + 255) / 256;
    int base = tid * per;
    int sum = 0;
    for (int i = 0; i < per; ++i) {
        int idx = base + i;
        if (idx < n) sum += deg[idx];
    }
    partial[tid] = sum;
    __syncthreads();
    for (int offs = 1; offs < 256; offs <<= 1) {
        int v = (tid >= offs) ? partial[tid - offs] : 0;
        __syncthreads();
        partial[tid] += v;
        __syncthreads();
    }
    int run = (tid == 0) ? 0 : partial[tid - 1];
    for (int i = 0; i < per; ++i) {
        int idx = base + i;
        if (idx < n) { rowptr[idx] = run; cursor[idx] = run; run += deg[idx]; }
    }
    if (tid == 255) rowptr[n] = run;
}

__global__ void fill_csr_kernel(const int* __restrict__ ei, int* __restrict__ cursor,
                                int* __restrict__ eidx, int E, int Etot)
{
    int e = blockIdx.x * 256 + threadIdx.x;
    if (e >= Etot) return;
    int d = (e < E) ? ei[E + e] : e - E;
    int pos = atomicAdd(&cursor[d], 1);
    eidx[pos] = e;
}

// Gather aggregation with fused alpha normalization.
template<int ACT>
__global__ __launch_bounds__(64) void gat_gather8_kernel(
    const int* __restrict__ rowptr, const int* __restrict__ eidx,
    const int* __restrict__ ei, const float* __restrict__ eval,
    const float* __restrict__ denom,
    const __hip_bfloat16* __restrict__ lin, int Ftp,
    const float* __restrict__ bias,
    __hip_bfloat16* __restrict__ outh, int Kout,
    int E, int H, int F, int Ft)
{
    int d = blockIdx.x;
    int g = blockIdx.y * 64 + threadIdx.x;      // col group
    int c0 = g * 8;
    if (c0 >= Kout) return;
    bf16x8 res;
    if (c0 >= Ft) {   // pure pad group: write zeros
#pragma unroll
        for (int j = 0; j < 8; ++j) res[j] = 0;
        *(bf16x8*)(outh + (size_t)d * Kout + c0) = res;
        return;
    }
    int hj[8];
    float rdh[8];
#pragma unroll
    for (int j = 0; j < 8; ++j) {
        hj[j] = min((c0 + j) / F, H - 1);
        rdh[j] = 1.f / (denom[d * H + hj[j]] + 1e-16f);
    }
    float acc[8] = {};
    int p0 = rowptr[d], p1 = rowptr[d + 1];
    for (int p = p0; p < p1; ++p) {
        int e = eidx[p];
        int s = (e < E) ? ei[e] : e - E;
        bf16x8 v = *(const bf16x8*)(lin + (size_t)s * Ftp + c0);
        const float* aE = eval + (size_t)e * H;
        if (H == 1) {
            float a = aE[0] * rdh[0];
#pragma unroll
            for (int j = 0; j < 8; ++j)
                acc[j] += a * bf16bits2float(v[j]);
        } else {
#pragma unroll
            for (int j = 0; j < 8; ++j)
                acc[j] += aE[hj[j]] * rdh[j] * bf16bits2float(v[j]);
        }
    }
#pragma unroll
    for (int j = 0; j < 8; ++j) {
        int c = c0 + j;
        float val = 0.f;
        if (c < Ft) {
            val = acc[j] + bias[c];
            if (ACT == 1) val = fmaxf(val, 0.f);
            else if (ACT == 2) val = val > 0.f ? val : expm1f(val);
        }
        __hip_bfloat16 bv = __float2bfloat16(val);
        res[j] = *(const short*)&bv;
    }
    *(bf16x8*)(outh + (size_t)d * Kout + c0) = res;
}

// global max pool over bf16 h3 [N][3120] -> bf16 [NB][Kout] padded (pads zero)
__global__ void pool_max_bf16_kernel(const __hip_bfloat16* __restrict__ h,
                                     __hip_bfloat16* __restrict__ g,
                                     int B, int per, int C, int Kout)
{
    int t = blockIdx.x * blockDim.x + threadIdx.x;
    if (t >= B * Kout) return;
    int b = t / Kout, f = t - b * Kout;
    if (f >= C) { g[t] = __float2bfloat16(0.f); return; }
    const __hip_bfloat16* p = h + (size_t)b * per * C + f;
    float m = -INFINITY;
    for (int j = 0; j < per; ++j) m = fmaxf(m, __bfloat162float(p[(size_t)j * C]));
    g[t] = __float2bfloat16(m);
}

// ---------------------------------------------------------------------------
// CNN branch — conv1 vocab-factorized, split phase 1
// ---------------------------------------------------------------------------
__global__ __launch_bounds__(256) void conv1_p1_kernel(
    const int* __restrict__ target, const float* __restrict__ wt,
    float* __restrict__ Spart)
{
    __shared__ float s_S[VOCAB * 256];
    __shared__ int   s_trow[125];
    int tid = threadIdx.x;
    int n = blockIdx.x, z = blockIdx.y;
    for (int i = tid; i < VOCAB * 256; i += 256) s_S[i] = 0.f;
    if (tid < 125) s_trow[tid] = target[n * 1000 + z * 125 + tid];
    __syncthreads();
    const float* wz = wt + (size_t)(z * 125) * 256 + tid;
    for (int i = 0; i < 125; ++i) {
        int v = s_trow[i];
        s_S[v * 256 + tid] += wz[(size_t)i * 256];
    }
    __syncthreads();
    float* outp = Spart + ((size_t)n * C1SPLIT + z) * (VOCAB * 256);
    for (int i = tid; i < VOCAB * 256; i += 256) outp[i] = s_S[i];
}

__global__ __launch_bounds__(256) void conv1_p2_kernel(
    const float* __restrict__ Spart, const float* __restrict__ emb,
    const float* __restrict__ b, __hip_bfloat16* __restrict__ y)
{
    __shared__ float s_emb[VOCAB * EMB];
    __shared__ float s_S[VOCAB * 256];
    int tid = threadIdx.x;
    int n = blockIdx.x;
    for (int i = tid; i < VOCAB * EMB; i += 256) s_emb[i] = emb[i];
    const float* base = Spart + (size_t)n * C1SPLIT * (VOCAB * 256);
    for (int i = tid; i < VOCAB * 256; i += 256) {
        float s = 0.f;
#pragma unroll
        for (int z = 0; z < C1SPLIT; ++z) s += base[(size_t)z * (VOCAB * 256) + i];
        s_S[i] = s;
    }
    __syncthreads();
    for (int idx = tid; idx < 121 * 32; idx += 256) {
        int t = idx >> 5, o = idx & 31;
        float acc = b[o];
#pragma unroll
        for (int v = 0; v < VOCAB; ++v) {
            const float* Sv = s_S + v * 256 + o * 8;
            const float* ev = s_emb + v * EMB + t;
#pragma unroll
            for (int k = 0; k < 8; ++k) acc += Sv[k] * ev[k];
        }
        y[((size_t)n * LP + t) * 32 + o] = __float2bfloat16(fmaxf(acc, 0.f));
    }
}

// ---------------------------------------------------------------------------
// Host-side launch
// ---------------------------------------------------------------------------
extern "C" void kernel_launch(void* const* d_in, const int* in_sizes, int n_in,
                              void* d_out, int out_size, void* d_ws, size_t ws_size,
                              hipStream_t stream)
{
    const float* x      = (const float*)d_in[0];
    const int*   ei     = (const int*)d_in[1];
    const int*   target = (const int*)d_in[3];
    const float* W1  = (const float*)d_in[4];
    const float* as1 = (const float*)d_in[5];
    const float* ad1 = (const float*)d_in[6];
    const float* b1  = (const float*)d_in[7];
    const float* W2  = (const float*)d_in[8];
    const float* as2 = (const float*)d_in[9];
    const float* ad2 = (const float*)d_in[10];
    const float* b2  = (const float*)d_in[11];
    const float* W3  = (const float*)d_in[12];
    const float* as3 = (const float*)d_in[13];
    const float* ad3 = (const float*)d_in[14];
    const float* b3  = (const float*)d_in[15];
    const float* fc_g1_w = (const float*)d_in[16];
    const float* fc_g1_b = (const float*)d_in[17];
    const float* fc_g2_w = (const float*)d_in[18];
    const float* fc_g2_b = (const float*)d_in[19];
    const float* emb_xt  = (const float*)d_in[20];
    const float* cw1 = (const float*)d_in[21];
    const float* cb1 = (const float*)d_in[22];
    const float* cw2 = (const float*)d_in[23];
    const float* cb2 = (const float*)d_in[24];
    const float* cw3 = (const float*)d_in[25];
    const float* cb3 = (const float*)d_in[26];
    const float* cw4 = (const float*)d_in[27];
    const float* cb4 = (const float*)d_in[28];
    const float* fc1_xt_w = (const float*)d_in[29];
    const float* fc1_xt_b = (const float*)d_in[30];
    const float* fc2_xt_w = (const float*)d_in[31];
    const float* fc2_xt_b = (const float*)d_in[32];
    const float* fc1_w = (const float*)d_in[33];
    const float* fc1_b = (const float*)d_in[34];
    const float* fc2_w = (const float*)d_in[35];
    const float* fc2_b = (const float*)d_in[36];
    const float* out_w = (const float*)d_in[37];
    const float* out_b = (const float*)d_in[38];
    float* out = (float*)d_out;

    const int N = NNODES, E = NEDGES, Etot = E + N;
    const size_t MB = 1024 * 1024;

    // ---- workspace carve ----
    char* ws = (char*)d_ws;
    size_t off = 0;
    auto alloc = [&](size_t bytes) -> char* {
        char* p = ws + off;
        off = (off + bytes + 255) & ~(size_t)255;
        return p;
    };
    const size_t BIG = (size_t)N * 3120 * sizeof(float);   // 127.8 MB
    char*  bufA  = alloc(BIG);
    char*  bufB  = alloc(BIG);
    float*    a_s   = (float*)alloc((size_t)N * 10 * 4);
    float*    a_d   = (float*)alloc((size_t)N * 10 * 4);
    char*     mmdn  = alloc((size_t)2 * N * 10 * 4);   // mmax | denom (combined)
    float*    eval  = (float*)alloc((size_t)Etot * 10 * 4);
    float*    g1    = (float*)alloc((size_t)NB * 1024 * 4);
    float*    xt1   = (float*)alloc((size_t)NB * 1024 * 4);
    float*    xc    = (float*)alloc((size_t)NB * 256 * 4);
    float*    f1    = (float*)alloc((size_t)NB * 1024 * 4);
    float*    f2    = (float*)alloc((size_t)NB * 256 * 4);
    __hip_bfloat16* gbufb = (__hip_bfloat16*)alloc((size_t)NB * 3200 * 2);
    __hip_bfloat16* xtb   = (__hip_bfloat16*)alloc((size_t)NB * 4352 * 2);
    int*      deg     = (int*)alloc((size_t)N * 4);
    int*      rowptr  = (int*)alloc((size_t)(N + 1) * 4);
    int*      cursor  = (int*)alloc((size_t)N * 4);
    int*      eidx    = (int*)alloc((size_t)Etot * 4);

    __hip_bfloat16* linb = (__hip_bfloat16*)bufA;
    __hip_bfloat16* Wt   = (__hip_bfloat16*)(bufA + 64 * MB);
    __hip_bfloat16* xb   = (__hip_bfloat16*)(bufA + 80 * MB);   // lin1 A, 2.6 MB
    __hip_bfloat16* hbf1 = (__hip_bfloat16*)bufB;
    __hip_bfloat16* hbf2 = (__hip_bfloat16*)(bufB + 20 * MB);
    __hip_bfloat16* hbf3 = (__hip_bfloat16*)bufB;
    __hip_bfloat16* Wt2  = (__hip_bfloat16*)(bufB + 105 * MB);
    float*          P4   = (float*)(bufB + 115 * MB);           // 12.8 MB slices

    // CNN scratch in bufA (dead after GAT layer 3)
    char* cnn = bufA;
    auto calloc2 = [&](size_t bytes) -> char* {
        char* p = cnn;
        cnn += (bytes + 255) & ~(size_t)255;
        return p;
    };
    __hip_bfloat16* act1 = (__hip_bfloat16*)calloc2((size_t)NB * LP * 32 * 2 + 4096);
    __hip_bfloat16* act2 = (__hip_bfloat16*)calloc2((size_t)NB * LP * 64 * 2 + 4096);
    __hip_bfloat16* act3 = (__hip_bfloat16*)calloc2((size_t)NB * LP * 96 * 2 + 4096);
    __hip_bfloat16* wt2  = (__hip_bfloat16*)calloc2((size_t)128 * 256 * 2);
    __hip_bfloat16* wt3  = (__hip_bfloat16*)calloc2((size_t)128 * 512 * 2);
    __hip_bfloat16* wt4  = (__hip_bfloat16*)calloc2((size_t)128 * 768 * 2);
    float* wt1f  = (float*)calloc2((size_t)1000 * 256 * 4);                 // 1.02 MB
    float* Spart = (float*)calloc2((size_t)NB * C1SPLIT * VOCAB * 256 * 4); // 54.5 MB

    // ---- build dst-CSR once ----
    {
        (void)hipMemsetAsync(deg, 0, (size_t)N * 4, stream);
        deg_kernel<<<(Etot + 255) / 256, 256, 0, stream>>>(ei, deg, E, Etot);
        scan_kernel<<<1, 256, 0, stream>>>(deg, rowptr, cursor, N);
        fill_csr_kernel<<<(Etot + 255) / 256, 256, 0, stream>>>(ei, cursor, eidx, E, Etot);
    }

    // ---- f32 slice split-K head GEMM (small heads, atomic-free) ----
    auto head_gemm = [&](const float* A, const float* B, const float* bias, float* C,
                         int M, int Nc, int K, int ldC, int act, int S) {
        int kchunk = (K + S - 1) / S;
        dim3 g((Nc + 63) / 64, (M + 63) / 64, S);
        gemm_f32_splitk_sl<<<g, 256, 0, stream>>>(A, B, P4, M, Nc, K, kchunk);
        int tot = M * Nc;
        if (act == 1)
            reduce_bias_act_ld_kernel<1><<<(tot + 255) / 256, 256, 0, stream>>>(P4, bias, C, M, Nc, S, ldC);
        else
            reduce_bias_act_ld_kernel<0><<<(tot + 255) / 256, 256, 0, stream>>>(P4, bias, C, M, Nc, S, ldC);
    };

    // ---- bf16 MFMA split-K head GEMM (A pre-cast bf16 [M][Kp], relu) ----
    auto head_gemm_mfma = [&](const __hip_bfloat16* Ab_, const float* W, const float* bias,
                              float* C, int M, int Nc, int K, int Kp, int S) {
        int tps = (Kp / 64) / S;
        transpose_cast_kernel<<<dim3(Kp / 32, Nc / 32), 256, 0, stream>>>(W, Wt2, K, Nc, Kp, Nc);
        dim3 g(Nc / 128, M / 128, S);
        gemm_mfma_splitk<<<g, 256, 0, stream>>>(Ab_, Wt2, P4, M, Nc, Kp, tps);
        int tot = M * Nc;
        reduce_bias_act_ld_kernel<1><<<(tot + 255) / 256, 256, 0, stream>>>(P4, bias, C, M, Nc, S, Nc);
    };

    // ---- GAT softmax + CSR-gather chain ----
    auto gat_tail = [&](const float* atts, const float* attd, const float* bias,
                        int H, int F, int Ftp, int act,
                        const __hip_bfloat16* lin, __hip_bfloat16* outh, int Kout) {
        unsigned* mmax = (unsigned*)mmdn;
        float* denom = (float*)(mmdn + (size_t)N * H * 4);
        attn_ab_kernel<<<N * H, 64, 0, stream>>>(lin, Ftp, atts, attd, a_s, a_d, H, F);
        (void)hipMemsetAsync(mmdn, 0, (size_t)2 * N * H * 4, stream);
        int tot = Etot * H;
        edge_max_kernel<<<(tot + 255) / 256, 256, 0, stream>>>(ei, a_s, a_d, eval, mmax, E, Etot, H);
        edge_exp_kernel<<<(tot + 255) / 256, 256, 0, stream>>>(ei, mmax, eval, denom, E, Etot, H);
        int Ft = H * F;
        int groups = Kout / 8;
        dim3 gg(N, (groups + 63) / 64);
        if (act == 1)
            gat_gather8_kernel<1><<<gg, 64, 0, stream>>>(rowptr, eidx, ei, eval, denom, lin, Ftp, bias, outh, Kout, E, H, F, Ft);
        else
            gat_gather8_kernel<2><<<gg, 64, 0, stream>>>(rowptr, eidx, ei, eval, denom, lin, Ftp, bias, outh, Kout, E, H, F, Ft);
    };

    // ---- layer 1: MFMA GEMM (x cast to bf16, Kp=128) -> bf16 lin [N][784] ----
    {
        (void)hipMemsetAsync(linb, 0, (size_t)N * 784 * 2, stream);
        cast_a_kernel<<<(N * 128 + 255) / 256, 256, 0, stream>>>(x, xb, N, 78, 128);
        transpose_cast_kernel<<<dim3(4, 28), 256, 0, stream>>>(W1, Wt, 78, 780, 128, 896);
        gemm_mfma_bf16<<<dim3(7, N / 128), 256, 0, stream>>>(xb, Wt, linb, N, 780, 128, 784);
        gat_tail(as1, ad1, b1, 10, 78, 784, 2, linb, hbf1, 832);
    }
    // ---- layer 2: MFMA GEMM -> lin [N][1560] ----
    {
        const int Kp = 832, Nout = 1560, Npad = 1664;
        transpose_cast_kernel<<<dim3(Kp / 32, Npad / 32), 256, 0, stream>>>(W2, Wt, 780, Nout, Kp, Npad);
        gemm_mfma_bf16<<<dim3(Npad / 128, N / 128), 256, 0, stream>>>(hbf1, Wt, linb, N, Nout, Kp, Nout);
        gat_tail(as2, ad2, b2, 2, 780, 1560, 1, linb, hbf2, 1600);
    }
    // ---- layer 3: MFMA GEMM -> lin [N][3120] ----
    {
        const int Kp = 1600, Nout = 3120, Npad = 3200;
        transpose_cast_kernel<<<dim3(Kp / 32, Npad / 32), 256, 0, stream>>>(W3, Wt, 1560, Nout, Kp, Npad);
        gemm_mfma_bf16<<<dim3(Npad / 128, N / 128), 256, 0, stream>>>(hbf2, Wt, linb, N, Nout, Kp, Nout);
        gat_tail(as3, ad3, b3, 1, 3120, 3120, 1, linb, hbf3, 3120);
    }

    // global max pool (bf16 in, bf16 padded out) + graph FCs
    {
        int tot = NB * 3200;
        pool_max_bf16_kernel<<<(tot + 255) / 256, 256, 0, stream>>>(hbf3, gbufb, NB, N / NB, 3120, 3200);
        head_gemm_mfma(gbufb, fc_g1_w, fc_g1_b, g1, NB, 1024, 3120, 3200, 5);
        head_gemm(g1, fc_g2_w, fc_g2_b, xc, NB, 128, 1024, 256, 0, 32);
    }

    // ---- CNN branch (bufA free now) ----
    {
        conv_wt_all_kernel<<<(64 * 32 * 8 + 96 * 64 * 8 + 128 * 96 * 8 + 32 * 8000 + 255) / 256,
                             256, 0, stream>>>(cw2, cw3, cw4, cw1, wt2, wt3, wt4, wt1f);
        conv1_p1_kernel<<<dim3(NB, C1SPLIT), 256, 0, stream>>>(target, wt1f, Spart);
        conv1_p2_kernel<<<NB, 256, 0, stream>>>(Spart, emb_xt, cb1, act1);
        gemm_conv_bf16<32, 64, 114><<<dim3(1, NB), 256, 0, stream>>>(act1, wt2, cb2, act2);
        gemm_conv_bf16<64, 96, 107><<<dim3(1, NB), 256, 0, stream>>>(act2, wt3, cb3, act3);
        gemm_conv4_pool_bf16<<<dim3(1, NB), 256, 0, stream>>>(act3, wt4, cb4, xtb);
        head_gemm_mfma(xtb, fc1_xt_w, fc1_xt_b, xt1, NB, 1024, 4224, 4352, 4);
        head_gemm(xt1, fc2_xt_w, fc2_xt_b, xc + 128, NB, 128, 1024, 256, 0, 32);
    }

    // ---- fusion head ----
    {
        head_gemm(xc, fc1_w, fc1_b, f1, NB, 1024, 256, 1024, 1, 8);
        head_gemm(f1, fc2_w, fc2_b, f2, NB, 256, 1024, 256, 1, 16);
        out_head_kernel<<<1, 256, 0, stream>>>(f2, out_w, out_b, out);
    }
}